// Round 1
// baseline (6525.363 us; speedup 1.0000x reference)
//
#include <hip/hip_runtime.h>
#include <hip/hip_bf16.h>

#define BD 8
#define SD 1024
#define DM 1024
#define NH 16
#define DH 64
#define RK 128
#define NC 64
#define NE 32
#define NK 16384
#define KNOW_K 8

// ---------------- LayerNorm: one block per token ----------------
__global__ void __launch_bounds__(256) ln_kernel(const float* __restrict__ x,
                                                 const float* __restrict__ sc,
                                                 const float* __restrict__ bi,
                                                 float* __restrict__ out) {
    const int tok = blockIdx.x;
    __shared__ float xs[DM];
    __shared__ float red[256];
    const float* xp = x + (size_t)tok * DM;
    float s = 0.f;
    for (int i = threadIdx.x; i < DM; i += 256) { float v = xp[i]; xs[i] = v; s += v; }
    red[threadIdx.x] = s; __syncthreads();
    for (int st = 128; st; st >>= 1) { if (threadIdx.x < st) red[threadIdx.x] += red[threadIdx.x + st]; __syncthreads(); }
    float mu = red[0] * (1.f / DM);
    __syncthreads();
    float vs = 0.f;
    for (int i = threadIdx.x; i < DM; i += 256) { float d = xs[i] - mu; vs += d * d; }
    red[threadIdx.x] = vs; __syncthreads();
    for (int st = 128; st; st >>= 1) { if (threadIdx.x < st) red[threadIdx.x] += red[threadIdx.x + st]; __syncthreads(); }
    float rs = rsqrtf(red[0] * (1.f / DM) + 1e-5f);
    for (int i = threadIdx.x; i < DM; i += 256)
        out[(size_t)tok * DM + i] = (xs[i] - mu) * rs * sc[i] + bi[i];
}

// ------------- Phase-1 routers: Wc(64) WQr(32) WKr(32) WVr(32), one block/token -------------
__global__ void __launch_bounds__(256) route4_kernel(const float* __restrict__ n1,
                                                     const float* __restrict__ imp,
                                                     const float* __restrict__ Wc,
                                                     const float* __restrict__ WQr,
                                                     const float* __restrict__ WKr,
                                                     const float* __restrict__ WVr,
                                                     float* __restrict__ wpref) {
    const int tok = blockIdx.x;
    __shared__ float xs[DM];
    __shared__ float lg[160];
    __shared__ float mseg[4], sseg[4];
    for (int i = threadIdx.x; i < DM; i += 256) xs[i] = n1[(size_t)tok * DM + i];
    __syncthreads();
    const int t = threadIdx.x;
    if (t < 160) {
        const float* w; int col, n;
        if (t < 64)       { w = Wc;  col = t;       n = 64; }
        else if (t < 96)  { w = WQr; col = t - 64;  n = 32; }
        else if (t < 128) { w = WKr; col = t - 96;  n = 32; }
        else              { w = WVr; col = t - 128; n = 32; }
        float acc = 0.f;
        for (int d = 0; d < DM; d++) acc += xs[d] * w[d * n + col];
        lg[t] = acc;
    }
    __syncthreads();
    if (t < 4) {
        int o = (t == 0) ? 0 : (64 + 32 * (t - 1));
        int n = (t == 0) ? 64 : 32;
        float m = -1e30f;
        for (int i = 0; i < n; i++) m = fmaxf(m, lg[o + i]);
        float ss = 0.f;
        for (int i = 0; i < n; i++) ss += expf(lg[o + i] - m);
        mseg[t] = m; sseg[t] = ss;
    }
    __syncthreads();
    if (t < 160) {
        int seg = (t < 64) ? 0 : ((t < 96) ? 1 : ((t < 128) ? 2 : 3));
        float p = expf(lg[t] - mseg[seg]) / sseg[seg];
        wpref[(size_t)tok * 160 + t] = imp[tok] * p;
    }
}

// ------------- Phase-2 router: Wm(64) -------------
__global__ void __launch_bounds__(256) routem_kernel(const float* __restrict__ n2,
                                                     const float* __restrict__ imp,
                                                     const float* __restrict__ Wm,
                                                     float* __restrict__ wpref) {
    const int tok = blockIdx.x;
    __shared__ float xs[DM];
    __shared__ float lg[64];
    __shared__ float mm_, ss_;
    for (int i = threadIdx.x; i < DM; i += 256) xs[i] = n2[(size_t)tok * DM + i];
    __syncthreads();
    const int t = threadIdx.x;
    if (t < 64) {
        float acc = 0.f;
        for (int d = 0; d < DM; d++) acc += xs[d] * Wm[d * 64 + t];
        lg[t] = acc;
    }
    __syncthreads();
    if (t == 0) {
        float m = -1e30f;
        for (int i = 0; i < 64; i++) m = fmaxf(m, lg[i]);
        float ss = 0.f;
        for (int i = 0; i < 64; i++) ss += expf(lg[i] - m);
        mm_ = m; ss_ = ss;
    }
    __syncthreads();
    if (t < 64) {
        float p = expf(lg[t] - mm_) / ss_;
        wpref[(size_t)tok * 64 + t] = imp[tok] * p;
    }
}

// ------------- deterministic reduce over S: dense[b, outoff+c] = sum_s wpref[(b,s),c] -------------
__global__ void __launch_bounds__(256) reduce_pref(const float* __restrict__ wpref,
                                                   float* __restrict__ dense,
                                                   int ncols, int outoff) {
    const int b = blockIdx.x / ncols, c = blockIdx.x % ncols;
    __shared__ float red[256];
    float s = 0.f;
    for (int si = threadIdx.x; si < SD; si += 256)
        s += wpref[((size_t)(b * SD + si)) * ncols + c];
    red[threadIdx.x] = s; __syncthreads();
    for (int st = 128; st; st >>= 1) { if (threadIdx.x < st) red[threadIdx.x] += red[threadIdx.x + st]; __syncthreads(); }
    if (threadIdx.x == 0) dense[b * 224 + outoff + c] = red[0];
}

// ------------- top-k sparsify + renormalize (serial per (b, router)) -------------
__global__ void topk_kernel(const float* __restrict__ dense,
                            int* __restrict__ ridx, float* __restrict__ rw,
                            int r0, int nr) {
    const int t = threadIdx.x;
    if (t >= BD * nr) return;
    const int b = t / nr, r = r0 + (t % nr);
    const int offs[5] = {0, 64, 96, 128, 160};
    const int ns[5]   = {64, 32, 32, 32, 64};
    const int ks[5]   = {8, 4, 4, 4, 8};
    const float* dv = dense + b * 224 + offs[r];
    const int n = ns[r], k = ks[r];
    unsigned long long mask = 0;
    float vals[8]; int idxs[8];
    float ssum = 0.f;
    for (int kk = 0; kk < k; kk++) {
        float best = -1e30f; int bi = 0;
        for (int i = 0; i < n; i++)
            if (!((mask >> i) & 1ull) && dv[i] > best) { best = dv[i]; bi = i; }
        mask |= 1ull << bi;
        vals[kk] = best; idxs[kk] = bi; ssum += best;
    }
    float inv = 1.f / (ssum + 1e-8f);
    for (int kk = 0; kk < 8; kk++) {
        ridx[(b * 5 + r) * 8 + kk] = (kk < k) ? idxs[kk] : 0;
        rw[(b * 5 + r) * 8 + kk]   = (kk < k) ? vals[kk] * inv : 0.f;
    }
}

// ------------- mixture: out[b][e] = sum_k w * pool[idx][e], e < 131072 -------------
__global__ void __launch_bounds__(256) combine_kernel(const float* __restrict__ pool,
                                                      const int* __restrict__ ridx,
                                                      const float* __restrict__ rw,
                                                      int router, int kc,
                                                      float* __restrict__ out) {
    const size_t gid = (size_t)blockIdx.x * 256 + threadIdx.x;
    const int b = (int)(gid >> 17);
    const size_t dr = gid & 131071;
    const int* ii = ridx + (b * 5 + router) * 8;
    const float* ww = rw + (b * 5 + router) * 8;
    float acc = 0.f;
    for (int kk = 0; kk < kc; kk++)
        acc += ww[kk] * pool[((size_t)ii[kk] << 17) + dr];
    out[gid] = acc;
}

// ------------- generic batched fp32 GEMM: C[b] = A[b] @ B[b] (+ X) ; 64x64 tile, 4x4 micro -------------
__global__ void __launch_bounds__(256) mm64_kernel(const float* __restrict__ A,
                                                   const float* __restrict__ Bm,
                                                   const float* __restrict__ X,
                                                   float* __restrict__ C,
                                                   int N, int Kd,
                                                   long long sA, long long sB, long long sC, long long sX,
                                                   int hasX) {
    const int bz = blockIdx.z;
    const float* Ab = A + (size_t)bz * sA;
    const float* Bb = Bm + (size_t)bz * sB;
    float* Cb = C + (size_t)bz * sC;
    __shared__ float As[16][65];
    __shared__ float Bs[16][64];
    const int t = threadIdx.x;
    const int tx = t % 16, ty = t / 16;
    const int row0 = blockIdx.y * 64, col0 = blockIdx.x * 64;
    const int lc = t % 16, lr = t / 16;   // A loader
    const int bn = t % 64, bk = t / 64;   // B loader
    float acc[4][4] = {};
    for (int k0 = 0; k0 < Kd; k0 += 16) {
        #pragma unroll
        for (int i = 0; i < 4; i++)
            As[lc][lr + 16 * i] = Ab[(size_t)(row0 + lr + 16 * i) * Kd + k0 + lc];
        #pragma unroll
        for (int i = 0; i < 4; i++)
            Bs[bk + 4 * i][bn] = Bb[(size_t)(k0 + bk + 4 * i) * N + col0 + bn];
        __syncthreads();
        #pragma unroll
        for (int k = 0; k < 16; k++) {
            float a[4];
            #pragma unroll
            for (int i = 0; i < 4; i++) a[i] = As[k][ty * 4 + i];
            float4 bv = *(const float4*)&Bs[k][tx * 4];
            float b4[4] = {bv.x, bv.y, bv.z, bv.w};
            #pragma unroll
            for (int i = 0; i < 4; i++)
                #pragma unroll
                for (int j = 0; j < 4; j++) acc[i][j] += a[i] * b4[j];
        }
        __syncthreads();
    }
    #pragma unroll
    for (int i = 0; i < 4; i++) {
        const size_t r = row0 + ty * 4 + i;
        float4 v;
        float* vv = (float*)&v;
        #pragma unroll
        for (int j = 0; j < 4; j++) vv[j] = acc[i][j];
        if (hasX) {
            float4 xv = *(const float4*)&X[(size_t)bz * sX + r * N + col0 + tx * 4];
            v.x += xv.x; v.y += xv.y; v.z += xv.z; v.w += xv.w;
        }
        *(float4*)&Cb[r * N + col0 + tx * 4] = v;
    }
}

// ------------- causal attention, one block per (b, h, q) -------------
__global__ void __launch_bounds__(256) attn_kernel(const float* __restrict__ Q,
                                                   const float* __restrict__ K,
                                                   const float* __restrict__ V,
                                                   float* __restrict__ O) {
    const int q = blockIdx.x, hh = blockIdx.y, b = blockIdx.z;
    __shared__ float sc[SD];
    __shared__ float qv[DH];
    __shared__ float red[256];
    const size_t base = (size_t)b * SD * DM + hh * DH;
    const int t = threadIdx.x;
    if (t < DH) qv[t] = Q[base + (size_t)q * DM + t];
    __syncthreads();
    const int L = q + 1;
    float lmax = -1e30f;
    for (int k = t; k < L; k += 256) {
        const float* kp = K + base + (size_t)k * DM;
        float a = 0.f;
        #pragma unroll
        for (int d = 0; d < DH; d++) a += qv[d] * kp[d];
        a *= 0.125f;
        sc[k] = a;
        lmax = fmaxf(lmax, a);
    }
    red[t] = lmax; __syncthreads();
    for (int st = 128; st; st >>= 1) { if (t < st) red[t] = fmaxf(red[t], red[t + st]); __syncthreads(); }
    const float m = red[0];
    __syncthreads();
    float ls = 0.f;
    for (int k = t; k < L; k += 256) { float e = __expf(sc[k] - m); sc[k] = e; ls += e; }
    red[t] = ls; __syncthreads();
    for (int st = 128; st; st >>= 1) { if (t < st) red[t] += red[t + st]; __syncthreads(); }
    const float inv = 1.f / red[0];
    __syncthreads();
    const int d = t & 63, c = t >> 6;
    float acc = 0.f;
    for (int k = c; k < L; k += 4) acc += sc[k] * V[base + (size_t)k * DM + d];
    red[t] = acc; __syncthreads();
    if (c == 0) {
        float v = (red[d] + red[64 + d] + red[128 + d] + red[192 + d]) * inv;
        O[(size_t)(b * SD + q) * DM + hh * DH + d] = v;
    }
}

// ------------- knowledge: 16 tokens/block, top-8 over 16384, softmax, gather-V, += into out -------------
__global__ void __launch_bounds__(256) know_kernel(const float* __restrict__ Qm,
                                                   const float* __restrict__ kK,
                                                   const float* __restrict__ kV,
                                                   float* __restrict__ out) {
    const int t = threadIdx.x;
    const int tok0 = blockIdx.x * 16;
    __shared__ float qs[16][129];
    __shared__ float ks[128][65];
    __shared__ float cv[2048];
    __shared__ int   ci[2048];
    __shared__ float tw[16][8];
    __shared__ int   tix[16][8];
    for (int i = t; i < 16 * 128; i += 256) qs[i >> 7][i & 127] = Qm[(size_t)tok0 * 128 + i];
    const int tokL = t >> 4, sub = t & 15;
    float tv[8]; int ti_[8];
    #pragma unroll
    for (int kk = 0; kk < 8; kk++) { tv[kk] = -1e30f; ti_[kk] = 0; }
    auto insert = [&](float v, int gi) {
        float mn = tv[0]; int ms = 0;
        #pragma unroll
        for (int kk = 1; kk < 8; kk++) if (tv[kk] < mn) { mn = tv[kk]; ms = kk; }
        if (v > mn) { tv[ms] = v; ti_[ms] = gi; }
    };
    for (int tile = 0; tile < NK / 64; tile++) {
        __syncthreads();
        for (int i = t; i < 64 * 128; i += 256) {
            int j = i >> 7, r = i & 127;
            ks[r][j] = kK[((size_t)(tile * 64 + j) << 7) + r];
        }
        __syncthreads();
        float a0 = 0, a1 = 0, a2 = 0, a3 = 0;
        for (int r = 0; r < 128; r++) {
            float qvv = qs[tokL][r];
            a0 += qvv * ks[r][sub];
            a1 += qvv * ks[r][sub + 16];
            a2 += qvv * ks[r][sub + 32];
            a3 += qvv * ks[r][sub + 48];
        }
        const float scl = 0.0883883476483184f; // 1/sqrt(128)
        insert(a0 * scl, tile * 64 + sub);
        insert(a1 * scl, tile * 64 + sub + 16);
        insert(a2 * scl, tile * 64 + sub + 32);
        insert(a3 * scl, tile * 64 + sub + 48);
    }
    #pragma unroll
    for (int kk = 0; kk < 8; kk++) { cv[t * 8 + kk] = tv[kk]; ci[t * 8 + kk] = ti_[kk]; }
    __syncthreads();
    if (sub == 0) {
        const int base = tokL * 128;
        float bv[8]; int bi[8];
        for (int kk = 0; kk < 8; kk++) {
            float best = -1e30f; int bs = 0;
            for (int s = 0; s < 128; s++) { float v = cv[base + s]; if (v > best) { best = v; bs = s; } }
            bv[kk] = best; bi[kk] = ci[base + bs]; cv[base + bs] = -1e31f;
        }
        float m = bv[0];
        for (int kk = 1; kk < 8; kk++) m = fmaxf(m, bv[kk]);
        float ssum = 0.f; float e[8];
        for (int kk = 0; kk < 8; kk++) { e[kk] = __expf(bv[kk] - m); ssum += e[kk]; }
        float inv = 1.f / ssum;
        for (int kk = 0; kk < 8; kk++) { tw[tokL][kk] = e[kk] * inv; tix[tokL][kk] = bi[kk]; }
    }
    __syncthreads();
    for (int i = 0; i < 16; i++) {
        const size_t ob = (size_t)(tok0 + i) * DM;
        for (int d = t; d < DM; d += 256) {
            float acc = 0.f;
            #pragma unroll
            for (int kk = 0; kk < 8; kk++)
                acc += tw[i][kk] * kV[((size_t)tix[i][kk] << 10) + d];
            out[ob + d] += acc;
        }
    }
}

extern "C" void kernel_launch(void* const* d_in, const int* in_sizes, int n_in,
                              void* d_out, int out_size, void* d_ws, size_t ws_size,
                              hipStream_t stream) {
    const float* x    = (const float*)d_in[0];
    const float* imp  = (const float*)d_in[1];
    const float* Wc   = (const float*)d_in[2];
    const float* WQr  = (const float*)d_in[3];
    const float* WKr  = (const float*)d_in[4];
    const float* WVr  = (const float*)d_in[5];
    const float* Wm   = (const float*)d_in[6];
    const float* cneu = (const float*)d_in[7];
    const float* epool= (const float*)d_in[8];
    const float* kK   = (const float*)d_in[9];
    const float* kV   = (const float*)d_in[10];
    const float* WO   = (const float*)d_in[11];
    const float* ln1s = (const float*)d_in[12];
    const float* ln1b = (const float*)d_in[13];
    const float* ln2s = (const float*)d_in[14];
    const float* ln2b = (const float*)d_in[15];
    float* out = (float*)d_out;

    float* ws = (float*)d_ws;
    size_t o = 0;
    float* n1    = ws + o; o += (size_t)BD * SD * DM;    // 8388608 (reused as n2)
    float* wpref = ws + o; o += (size_t)BD * SD * 160;   // 1310720 (reused for Wm phase)
    float* dense = ws + o; o += (size_t)BD * 224;
    int*   ridx  = (int*)(ws + o); o += (size_t)BD * 5 * 8;
    float* rw    = ws + o; o += (size_t)BD * 5 * 8;
    float* scomp = ws + o; o += (size_t)BD * DM * RK;    // 1048576 (reused as sc_m)
    float* EQ    = ws + o; o += (size_t)BD * RK * DM;
    float* EK    = ws + o; o += (size_t)BD * RK * DM;
    float* EV    = ws + o; o += (size_t)BD * RK * DM;
    float* hbuf  = ws + o; o += (size_t)BD * SD * RK;    // 1048576 (reused as Qm)
    float* Qb    = ws + o; o += (size_t)BD * SD * DM;
    float* Kb    = ws + o; o += (size_t)BD * SD * DM;
    float* Vb    = ws + o; o += (size_t)BD * SD * DM;
    float* attn  = ws + o; o += (size_t)BD * SD * DM;

    const int NTOK = BD * SD;

    // 1. n1 = LN(x)
    ln_kernel<<<NTOK, 256, 0, stream>>>(x, ln1s, ln1b, n1);
    // 2. phase-1 routing
    route4_kernel<<<NTOK, 256, 0, stream>>>(n1, imp, Wc, WQr, WKr, WVr, wpref);
    reduce_pref<<<BD * 160, 256, 0, stream>>>(wpref, dense, 160, 0);
    topk_kernel<<<1, 64, 0, stream>>>(dense, ridx, rw, 0, 4);
    // 3. mixtures
    combine_kernel<<<BD * (DM * RK) / 256, 256, 0, stream>>>(cneu, ridx, rw, 0, 8, scomp);
    combine_kernel<<<BD * (RK * DM) / 256, 256, 0, stream>>>(epool, ridx, rw, 1, 4, EQ);
    combine_kernel<<<BD * (RK * DM) / 256, 256, 0, stream>>>(epool, ridx, rw, 2, 4, EK);
    combine_kernel<<<BD * (RK * DM) / 256, 256, 0, stream>>>(epool, ridx, rw, 3, 4, EV);
    // 4. h = n1 @ scomp   [S,D]@[D,R] per batch
    mm64_kernel<<<dim3(RK / 64, SD / 64, BD), 256, 0, stream>>>(
        n1, scomp, nullptr, hbuf, RK, DM,
        (long long)SD * DM, (long long)DM * RK, (long long)SD * RK, 0, 0);
    // 5. Q/K/V = h @ E    [S,R]@[R,D] per batch
    mm64_kernel<<<dim3(DM / 64, SD / 64, BD), 256, 0, stream>>>(
        hbuf, EQ, nullptr, Qb, DM, RK,
        (long long)SD * RK, (long long)RK * DM, (long long)SD * DM, 0, 0);
    mm64_kernel<<<dim3(DM / 64, SD / 64, BD), 256, 0, stream>>>(
        hbuf, EK, nullptr, Kb, DM, RK,
        (long long)SD * RK, (long long)RK * DM, (long long)SD * DM, 0, 0);
    mm64_kernel<<<dim3(DM / 64, SD / 64, BD), 256, 0, stream>>>(
        hbuf, EV, nullptr, Vb, DM, RK,
        (long long)SD * RK, (long long)RK * DM, (long long)SD * DM, 0, 0);
    // 6. causal attention
    attn_kernel<<<dim3(SD, NH, BD), 256, 0, stream>>>(Qb, Kb, Vb, attn);
    // 7. d_out = x + attn @ W_O   [B*S, D] @ [D, D]
    mm64_kernel<<<dim3(DM / 64, (BD * SD) / 64, 1), 256, 0, stream>>>(
        attn, WO, x, out, DM, DM, 0, 0, 0, 0, 1);
    // 8. n2 = LN(d_out)
    ln_kernel<<<NTOK, 256, 0, stream>>>(out, ln2s, ln2b, n1);
    // 9. memory routing
    routem_kernel<<<NTOK, 256, 0, stream>>>(n1, imp, Wm, wpref);
    reduce_pref<<<BD * 64, 256, 0, stream>>>(wpref, dense, 64, 160);
    topk_kernel<<<1, 64, 0, stream>>>(dense, ridx, rw, 4, 1);
    // 10. sc_m mixture + Qm = n2 @ sc_m
    combine_kernel<<<BD * (DM * RK) / 256, 256, 0, stream>>>(cneu, ridx, rw, 4, 8, scomp);
    mm64_kernel<<<dim3(RK / 64, SD / 64, BD), 256, 0, stream>>>(
        n1, scomp, nullptr, hbuf, RK, DM,
        (long long)SD * DM, (long long)DM * RK, (long long)SD * RK, 0, 0);
    // 11. knowledge lookup, += into d_out
    know_kernel<<<NTOK / 16, 256, 0, stream>>>(hbuf, kK, kV, out);
}

// Round 2
// 2962.224 us; speedup vs baseline: 2.2029x; 2.2029x over previous
//
#include <hip/hip_runtime.h>
#include <hip/hip_bf16.h>

#define BD 8
#define SD 1024
#define DM 1024
#define NH 16
#define DH 64
#define RK 128
#define NC 64
#define NE 32
#define NK 16384
#define KNOW_K 8

typedef __attribute__((ext_vector_type(8))) short bf16x8;
typedef __attribute__((ext_vector_type(4))) float f32x4;

__device__ __forceinline__ unsigned short f2b(float f) {
    unsigned u = __float_as_uint(f);
    unsigned r = (u + 0x7FFFu + ((u >> 16) & 1u)) >> 16;
    return (unsigned short)r;
}

// ---------------- LayerNorm: one block per token ----------------
__global__ void __launch_bounds__(256) ln_kernel(const float* __restrict__ x,
                                                 const float* __restrict__ sc,
                                                 const float* __restrict__ bi,
                                                 float* __restrict__ out) {
    const int tok = blockIdx.x;
    __shared__ float xs[DM];
    __shared__ float red[256];
    const float* xp = x + (size_t)tok * DM;
    float s = 0.f;
    for (int i = threadIdx.x; i < DM; i += 256) { float v = xp[i]; xs[i] = v; s += v; }
    red[threadIdx.x] = s; __syncthreads();
    for (int st = 128; st; st >>= 1) { if (threadIdx.x < st) red[threadIdx.x] += red[threadIdx.x + st]; __syncthreads(); }
    float mu = red[0] * (1.f / DM);
    __syncthreads();
    float vs = 0.f;
    for (int i = threadIdx.x; i < DM; i += 256) { float d = xs[i] - mu; vs += d * d; }
    red[threadIdx.x] = vs; __syncthreads();
    for (int st = 128; st; st >>= 1) { if (threadIdx.x < st) red[threadIdx.x] += red[threadIdx.x + st]; __syncthreads(); }
    float rs = rsqrtf(red[0] * (1.f / DM) + 1e-5f);
    for (int i = threadIdx.x; i < DM; i += 256)
        out[(size_t)tok * DM + i] = (xs[i] - mu) * rs * sc[i] + bi[i];
}

// ------------- Phase-1 routers: Wc(64) WQr(32) WKr(32) WVr(32), one block/token -------------
__global__ void __launch_bounds__(256) route4_kernel(const float* __restrict__ n1,
                                                     const float* __restrict__ imp,
                                                     const float* __restrict__ Wc,
                                                     const float* __restrict__ WQr,
                                                     const float* __restrict__ WKr,
                                                     const float* __restrict__ WVr,
                                                     float* __restrict__ wpref) {
    const int tok = blockIdx.x;
    __shared__ float xs[DM];
    __shared__ float lg[160];
    __shared__ float mseg[4], sseg[4];
    for (int i = threadIdx.x; i < DM; i += 256) xs[i] = n1[(size_t)tok * DM + i];
    __syncthreads();
    const int t = threadIdx.x;
    if (t < 160) {
        const float* w; int col, n;
        if (t < 64)       { w = Wc;  col = t;       n = 64; }
        else if (t < 96)  { w = WQr; col = t - 64;  n = 32; }
        else if (t < 128) { w = WKr; col = t - 96;  n = 32; }
        else              { w = WVr; col = t - 128; n = 32; }
        float acc = 0.f;
        for (int d = 0; d < DM; d++) acc += xs[d] * w[d * n + col];
        lg[t] = acc;
    }
    __syncthreads();
    if (t < 4) {
        int o = (t == 0) ? 0 : (64 + 32 * (t - 1));
        int n = (t == 0) ? 64 : 32;
        float m = -1e30f;
        for (int i = 0; i < n; i++) m = fmaxf(m, lg[o + i]);
        float ss = 0.f;
        for (int i = 0; i < n; i++) ss += expf(lg[o + i] - m);
        mseg[t] = m; sseg[t] = ss;
    }
    __syncthreads();
    if (t < 160) {
        int seg = (t < 64) ? 0 : ((t < 96) ? 1 : ((t < 128) ? 2 : 3));
        float p = expf(lg[t] - mseg[seg]) / sseg[seg];
        wpref[(size_t)tok * 160 + t] = imp[tok] * p;
    }
}

// ------------- Phase-2 router: Wm(64) -------------
__global__ void __launch_bounds__(256) routem_kernel(const float* __restrict__ n2,
                                                     const float* __restrict__ imp,
                                                     const float* __restrict__ Wm,
                                                     float* __restrict__ wpref) {
    const int tok = blockIdx.x;
    __shared__ float xs[DM];
    __shared__ float lg[64];
    __shared__ float mm_, ss_;
    for (int i = threadIdx.x; i < DM; i += 256) xs[i] = n2[(size_t)tok * DM + i];
    __syncthreads();
    const int t = threadIdx.x;
    if (t < 64) {
        float acc = 0.f;
        for (int d = 0; d < DM; d++) acc += xs[d] * Wm[d * 64 + t];
        lg[t] = acc;
    }
    __syncthreads();
    if (t == 0) {
        float m = -1e30f;
        for (int i = 0; i < 64; i++) m = fmaxf(m, lg[i]);
        float ss = 0.f;
        for (int i = 0; i < 64; i++) ss += expf(lg[i] - m);
        mm_ = m; ss_ = ss;
    }
    __syncthreads();
    if (t < 64) {
        float p = expf(lg[t] - mm_) / ss_;
        wpref[(size_t)tok * 64 + t] = imp[tok] * p;
    }
}

// ------------- deterministic reduce over S -------------
__global__ void __launch_bounds__(256) reduce_pref(const float* __restrict__ wpref,
                                                   float* __restrict__ dense,
                                                   int ncols, int outoff) {
    const int b = blockIdx.x / ncols, c = blockIdx.x % ncols;
    __shared__ float red[256];
    float s = 0.f;
    for (int si = threadIdx.x; si < SD; si += 256)
        s += wpref[((size_t)(b * SD + si)) * ncols + c];
    red[threadIdx.x] = s; __syncthreads();
    for (int st = 128; st; st >>= 1) { if (threadIdx.x < st) red[threadIdx.x] += red[threadIdx.x + st]; __syncthreads(); }
    if (threadIdx.x == 0) dense[b * 224 + outoff + c] = red[0];
}

// ------------- top-k sparsify + renormalize -------------
__global__ void topk_kernel(const float* __restrict__ dense,
                            int* __restrict__ ridx, float* __restrict__ rw,
                            int r0, int nr) {
    const int t = threadIdx.x;
    if (t >= BD * nr) return;
    const int b = t / nr, r = r0 + (t % nr);
    const int offs[5] = {0, 64, 96, 128, 160};
    const int ns[5]   = {64, 32, 32, 32, 64};
    const int ks[5]   = {8, 4, 4, 4, 8};
    const float* dv = dense + b * 224 + offs[r];
    const int n = ns[r], k = ks[r];
    unsigned long long mask = 0;
    float vals[8]; int idxs[8];
    float ssum = 0.f;
    for (int kk = 0; kk < k; kk++) {
        float best = -1e30f; int bi = 0;
        for (int i = 0; i < n; i++)
            if (!((mask >> i) & 1ull) && dv[i] > best) { best = dv[i]; bi = i; }
        mask |= 1ull << bi;
        vals[kk] = best; idxs[kk] = bi; ssum += best;
    }
    float inv = 1.f / (ssum + 1e-8f);
    for (int kk = 0; kk < 8; kk++) {
        ridx[(b * 5 + r) * 8 + kk] = (kk < k) ? idxs[kk] : 0;
        rw[(b * 5 + r) * 8 + kk]   = (kk < k) ? vals[kk] * inv : 0.f;
    }
}

// ------------- mixture combine -------------
__global__ void __launch_bounds__(256) combine_kernel(const float* __restrict__ pool,
                                                      const int* __restrict__ ridx,
                                                      const float* __restrict__ rw,
                                                      int router, int kc,
                                                      float* __restrict__ out) {
    const size_t gid = (size_t)blockIdx.x * 256 + threadIdx.x;
    const int b = (int)(gid >> 17);
    const size_t dr = gid & 131071;
    const int* ii = ridx + (b * 5 + router) * 8;
    const float* ww = rw + (b * 5 + router) * 8;
    float acc = 0.f;
    for (int kk = 0; kk < kc; kk++)
        acc += ww[kk] * pool[((size_t)ii[kk] << 17) + dr];
    out[gid] = acc;
}

// ------------- generic batched fp32 GEMM -------------
__global__ void __launch_bounds__(256) mm64_kernel(const float* __restrict__ A,
                                                   const float* __restrict__ Bm,
                                                   const float* __restrict__ X,
                                                   float* __restrict__ C,
                                                   int N, int Kd,
                                                   long long sA, long long sB, long long sC, long long sX,
                                                   int hasX) {
    const int bz = blockIdx.z;
    const float* Ab = A + (size_t)bz * sA;
    const float* Bb = Bm + (size_t)bz * sB;
    float* Cb = C + (size_t)bz * sC;
    __shared__ float As[16][65];
    __shared__ float Bs[16][64];
    const int t = threadIdx.x;
    const int tx = t % 16, ty = t / 16;
    const int row0 = blockIdx.y * 64, col0 = blockIdx.x * 64;
    const int lc = t % 16, lr = t / 16;
    const int bn = t % 64, bk = t / 64;
    float acc[4][4] = {};
    for (int k0 = 0; k0 < Kd; k0 += 16) {
        #pragma unroll
        for (int i = 0; i < 4; i++)
            As[lc][lr + 16 * i] = Ab[(size_t)(row0 + lr + 16 * i) * Kd + k0 + lc];
        #pragma unroll
        for (int i = 0; i < 4; i++)
            Bs[bk + 4 * i][bn] = Bb[(size_t)(k0 + bk + 4 * i) * N + col0 + bn];
        __syncthreads();
        #pragma unroll
        for (int k = 0; k < 16; k++) {
            float a[4];
            #pragma unroll
            for (int i = 0; i < 4; i++) a[i] = As[k][ty * 4 + i];
            float4 bv = *(const float4*)&Bs[k][tx * 4];
            float b4[4] = {bv.x, bv.y, bv.z, bv.w};
            #pragma unroll
            for (int i = 0; i < 4; i++)
                #pragma unroll
                for (int j = 0; j < 4; j++) acc[i][j] += a[i] * b4[j];
        }
        __syncthreads();
    }
    #pragma unroll
    for (int i = 0; i < 4; i++) {
        const size_t r = row0 + ty * 4 + i;
        float4 v;
        float* vv = (float*)&v;
        #pragma unroll
        for (int j = 0; j < 4; j++) vv[j] = acc[i][j];
        if (hasX) {
            float4 xv = *(const float4*)&X[(size_t)bz * sX + r * N + col0 + tx * 4];
            v.x += xv.x; v.y += xv.y; v.z += xv.z; v.w += xv.w;
        }
        *(float4*)&Cb[r * N + col0 + tx * 4] = v;
    }
}

// ------------- flash attention, bf16 MFMA: block = (q-tile 64, head, batch), 4 waves -------------
__global__ void __launch_bounds__(256) attn_mfma_kernel(const float* __restrict__ Q,
                                                        const float* __restrict__ K,
                                                        const float* __restrict__ V,
                                                        float* __restrict__ O) {
    const int qt = blockIdx.x, hh = blockIdx.y, b = blockIdx.z;
    const int t = threadIdx.x;
    const int w = t >> 6;          // wave 0..3 -> q rows w*16..w*16+15
    const int l = t & 63;
    const int lq = l & 15;         // A-row / D-col index
    const int lg = l >> 4;         // quarter-wave

    __shared__ unsigned short ks[64 * 64];      // K tile, [key][d], pitch 64 bf16, XOR swizzled
    __shared__ unsigned short vt[64 * 64];      // V tile transposed, [d][key], XOR swizzled
    __shared__ unsigned short pl[4][16 * 64];   // per-wave P strip [q16][key64], XOR swizzled

    const size_t base = (size_t)b * SD * DM + (size_t)hh * DH;

    // ---- Q fragments (bf16), wave-private ----
    bf16x8 aq[2];
    {
        const int qrow = qt * 64 + w * 16 + lq;
        const float* qp = Q + base + (size_t)qrow * DM;
        #pragma unroll
        for (int c = 0; c < 2; c++) {
            union { unsigned short s[8]; bf16x8 v; } u;
            #pragma unroll
            for (int j = 0; j < 8; j++) u.s[j] = f2b(qp[lg * 8 + 32 * c + j]);
            aq[c] = u.v;
        }
    }

    f32x4 o_acc[4];
    #pragma unroll
    for (int dt = 0; dt < 4; dt++) o_acc[dt] = f32x4{0.f, 0.f, 0.f, 0.f};
    float m_r[4] = {-1e30f, -1e30f, -1e30f, -1e30f};
    float s_r[4] = {0.f, 0.f, 0.f, 0.f};

    const int ntile = qt + 1;
    for (int kt = 0; kt < ntile; kt++) {
        __syncthreads();   // prior-iter reads of ks/vt complete before overwrite
        // ---- stage K tile and V^T tile (fp32 -> bf16) ----
        #pragma unroll
        for (int p = 0; p < 8; p++) {
            const int i2 = t + 256 * p;          // 2048 float2 loads
            const int row = i2 >> 5;             // 0..63 (key)
            const int col = (i2 & 31) * 2;       // 0..62 (d)
            const float2 kf = *(const float2*)(K + base + (size_t)(kt * 64 + row) * DM + col);
            const float2 vf = *(const float2*)(V + base + (size_t)(kt * 64 + row) * DM + col);
            const unsigned kb = (unsigned)f2b(kf.x) | ((unsigned)f2b(kf.y) << 16);
            *(unsigned*)((char*)ks + ((row * 128 + col * 2) ^ ((row & 7) << 4))) = kb;
            *(unsigned short*)((char*)vt + ((col * 128 + row * 2) ^ (((col >> 1) & 7) << 4))) = f2b(vf.x);
            *(unsigned short*)((char*)vt + (((col + 1) * 128 + row * 2) ^ ((((col + 1) >> 1) & 7) << 4))) = f2b(vf.y);
        }
        __syncthreads();

        // ---- S strip: wave w computes 16q x 64k ----
        const f32x4 zero4 = {0.f, 0.f, 0.f, 0.f};
        f32x4 sacc[4];
        #pragma unroll
        for (int ct = 0; ct < 4; ct++) {
            const int krow = ct * 16 + lq;
            bf16x8 b0 = *(const bf16x8*)((const char*)ks + ((krow * 128 + lg * 16) ^ ((lq & 7) << 4)));
            bf16x8 b1 = *(const bf16x8*)((const char*)ks + ((krow * 128 + lg * 16 + 64) ^ ((lq & 7) << 4)));
            f32x4 s = __builtin_amdgcn_mfma_f32_16x16x32_bf16(aq[0], b0, zero4, 0, 0, 0);
            s = __builtin_amdgcn_mfma_f32_16x16x32_bf16(aq[1], b1, s, 0, 0, 0);
            sacc[ct] = s;
        }

        // ---- online softmax (rows = lg*4+j, cols = ct*16+lq) ----
        float tm[4];
        #pragma unroll
        for (int j = 0; j < 4; j++) {
            const int qg = qt * 64 + w * 16 + lg * 4 + j;
            float mx = -1e30f;
            #pragma unroll
            for (int ct = 0; ct < 4; ct++) {
                const int kg = kt * 64 + ct * 16 + lq;
                float v = sacc[ct][j] * 0.125f;
                v = (kg <= qg) ? v : -1e30f;
                sacc[ct][j] = v;
                mx = fmaxf(mx, v);
            }
            #pragma unroll
            for (int d = 1; d < 16; d <<= 1) mx = fmaxf(mx, __shfl_xor(mx, d));
            tm[j] = mx;
        }
        #pragma unroll
        for (int j = 0; j < 4; j++) {
            const float nm = fmaxf(m_r[j], tm[j]);
            const float so = __expf(m_r[j] - nm);
            m_r[j] = nm;
            float rs = 0.f;
            const int prow = lg * 4 + j;
            #pragma unroll
            for (int ct = 0; ct < 4; ct++) {
                const float p = __expf(sacc[ct][j] - nm);
                rs += p;
                const int byteoff = ((prow * 128) + (ct * 16 + lq) * 2) ^ ((prow & 7) << 4);
                *(unsigned short*)((char*)&pl[w][0] + byteoff) = f2b(p);
            }
            #pragma unroll
            for (int d = 1; d < 16; d <<= 1) rs += __shfl_xor(rs, d);
            s_r[j] = s_r[j] * so + rs;
            #pragma unroll
            for (int dt = 0; dt < 4; dt++) o_acc[dt][j] *= so;
        }
        asm volatile("s_waitcnt lgkmcnt(0)" ::: "memory");

        // ---- PV: O += P @ V ----
        #pragma unroll
        for (int c = 0; c < 2; c++) {
            bf16x8 pa = *(const bf16x8*)((const char*)&pl[w][0] +
                          ((lq * 128 + lg * 16 + 64 * c) ^ ((lq & 7) << 4)));
            #pragma unroll
            for (int dt = 0; dt < 4; dt++) {
                const int dd = dt * 16 + lq;
                bf16x8 bv = *(const bf16x8*)((const char*)vt +
                              ((dd * 128 + lg * 16 + 64 * c) ^ (((dd >> 1) & 7) << 4)));
                o_acc[dt] = __builtin_amdgcn_mfma_f32_16x16x32_bf16(pa, bv, o_acc[dt], 0, 0, 0);
            }
        }
    }

    // ---- write out ----
    #pragma unroll
    for (int j = 0; j < 4; j++) {
        const float inv = 1.f / s_r[j];
        const int qrow = qt * 64 + w * 16 + lg * 4 + j;
        float* op = O + base + (size_t)qrow * DM;
        #pragma unroll
        for (int dt = 0; dt < 4; dt++) op[dt * 16 + lq] = o_acc[dt][j] * inv;
    }
}

// ------------- knowledge: 16 tokens/block, top-8 over 16384 -------------
__global__ void __launch_bounds__(256) know_kernel(const float* __restrict__ Qm,
                                                   const float* __restrict__ kK,
                                                   const float* __restrict__ kV,
                                                   float* __restrict__ out) {
    const int t = threadIdx.x;
    const int tok0 = blockIdx.x * 16;
    __shared__ float qs[16][129];
    __shared__ float ks[128][65];
    __shared__ float cv[2048];
    __shared__ int   ci[2048];
    __shared__ float tw[16][8];
    __shared__ int   tix[16][8];
    for (int i = t; i < 16 * 128; i += 256) qs[i >> 7][i & 127] = Qm[(size_t)tok0 * 128 + i];
    const int tokL = t >> 4, sub = t & 15;
    float tv[8]; int ti_[8];
    #pragma unroll
    for (int kk = 0; kk < 8; kk++) { tv[kk] = -1e30f; ti_[kk] = 0; }
    auto insert = [&](float v, int gi) {
        float mn = tv[0]; int ms = 0;
        #pragma unroll
        for (int kk = 1; kk < 8; kk++) if (tv[kk] < mn) { mn = tv[kk]; ms = kk; }
        if (v > mn) { tv[ms] = v; ti_[ms] = gi; }
    };
    for (int tile = 0; tile < NK / 64; tile++) {
        __syncthreads();
        for (int i = t; i < 64 * 128; i += 256) {
            int j = i >> 7, r = i & 127;
            ks[r][j] = kK[((size_t)(tile * 64 + j) << 7) + r];
        }
        __syncthreads();
        float a0 = 0, a1 = 0, a2 = 0, a3 = 0;
        for (int r = 0; r < 128; r++) {
            float qvv = qs[tokL][r];
            a0 += qvv * ks[r][sub];
            a1 += qvv * ks[r][sub + 16];
            a2 += qvv * ks[r][sub + 32];
            a3 += qvv * ks[r][sub + 48];
        }
        const float scl = 0.0883883476483184f;
        insert(a0 * scl, tile * 64 + sub);
        insert(a1 * scl, tile * 64 + sub + 16);
        insert(a2 * scl, tile * 64 + sub + 32);
        insert(a3 * scl, tile * 64 + sub + 48);
    }
    #pragma unroll
    for (int kk = 0; kk < 8; kk++) { cv[t * 8 + kk] = tv[kk]; ci[t * 8 + kk] = ti_[kk]; }
    __syncthreads();
    if (sub == 0) {
        const int base = tokL * 128;
        float bv[8]; int bi[8];
        for (int kk = 0; kk < 8; kk++) {
            float best = -1e30f; int bs = 0;
            for (int s = 0; s < 128; s++) { float v = cv[base + s]; if (v > best) { best = v; bs = s; } }
            bv[kk] = best; bi[kk] = ci[base + bs]; cv[base + bs] = -1e31f;
        }
        float m = bv[0];
        for (int kk = 1; kk < 8; kk++) m = fmaxf(m, bv[kk]);
        float ssum = 0.f; float e[8];
        for (int kk = 0; kk < 8; kk++) { e[kk] = __expf(bv[kk] - m); ssum += e[kk]; }
        float inv = 1.f / ssum;
        for (int kk = 0; kk < 8; kk++) { tw[tokL][kk] = e[kk] * inv; tix[tokL][kk] = bi[kk]; }
    }
    __syncthreads();
    for (int i = 0; i < 16; i++) {
        const size_t ob = (size_t)(tok0 + i) * DM;
        for (int d = t; d < DM; d += 256) {
            float acc = 0.f;
            #pragma unroll
            for (int kk = 0; kk < 8; kk++)
                acc += tw[i][kk] * kV[((size_t)tix[i][kk] << 10) + d];
            out[ob + d] += acc;
        }
    }
}

extern "C" void kernel_launch(void* const* d_in, const int* in_sizes, int n_in,
                              void* d_out, int out_size, void* d_ws, size_t ws_size,
                              hipStream_t stream) {
    const float* x    = (const float*)d_in[0];
    const float* imp  = (const float*)d_in[1];
    const float* Wc   = (const float*)d_in[2];
    const float* WQr  = (const float*)d_in[3];
    const float* WKr  = (const float*)d_in[4];
    const float* WVr  = (const float*)d_in[5];
    const float* Wm   = (const float*)d_in[6];
    const float* cneu = (const float*)d_in[7];
    const float* epool= (const float*)d_in[8];
    const float* kK   = (const float*)d_in[9];
    const float* kV   = (const float*)d_in[10];
    const float* WO   = (const float*)d_in[11];
    const float* ln1s = (const float*)d_in[12];
    const float* ln1b = (const float*)d_in[13];
    const float* ln2s = (const float*)d_in[14];
    const float* ln2b = (const float*)d_in[15];
    float* out = (float*)d_out;

    float* ws = (float*)d_ws;
    size_t o = 0;
    float* n1    = ws + o; o += (size_t)BD * SD * DM;
    float* wpref = ws + o; o += (size_t)BD * SD * 160;
    float* dense = ws + o; o += (size_t)BD * 224;
    int*   ridx  = (int*)(ws + o); o += (size_t)BD * 5 * 8;
    float* rw    = ws + o; o += (size_t)BD * 5 * 8;
    float* scomp = ws + o; o += (size_t)BD * DM * RK;
    float* EQ    = ws + o; o += (size_t)BD * RK * DM;
    float* EK    = ws + o; o += (size_t)BD * RK * DM;
    float* EV    = ws + o; o += (size_t)BD * RK * DM;
    float* hbuf  = ws + o; o += (size_t)BD * SD * RK;
    float* Qb    = ws + o; o += (size_t)BD * SD * DM;
    float* Kb    = ws + o; o += (size_t)BD * SD * DM;
    float* Vb    = ws + o; o += (size_t)BD * SD * DM;
    float* attn  = ws + o; o += (size_t)BD * SD * DM;

    const int NTOK = BD * SD;

    ln_kernel<<<NTOK, 256, 0, stream>>>(x, ln1s, ln1b, n1);
    route4_kernel<<<NTOK, 256, 0, stream>>>(n1, imp, Wc, WQr, WKr, WVr, wpref);
    reduce_pref<<<BD * 160, 256, 0, stream>>>(wpref, dense, 160, 0);
    topk_kernel<<<1, 64, 0, stream>>>(dense, ridx, rw, 0, 4);
    combine_kernel<<<BD * (DM * RK) / 256, 256, 0, stream>>>(cneu, ridx, rw, 0, 8, scomp);
    combine_kernel<<<BD * (RK * DM) / 256, 256, 0, stream>>>(epool, ridx, rw, 1, 4, EQ);
    combine_kernel<<<BD * (RK * DM) / 256, 256, 0, stream>>>(epool, ridx, rw, 2, 4, EK);
    combine_kernel<<<BD * (RK * DM) / 256, 256, 0, stream>>>(epool, ridx, rw, 3, 4, EV);
    mm64_kernel<<<dim3(RK / 64, SD / 64, BD), 256, 0, stream>>>(
        n1, scomp, nullptr, hbuf, RK, DM,
        (long long)SD * DM, (long long)DM * RK, (long long)SD * RK, 0, 0);
    mm64_kernel<<<dim3(DM / 64, SD / 64, BD), 256, 0, stream>>>(
        hbuf, EQ, nullptr, Qb, DM, RK,
        (long long)SD * RK, (long long)RK * DM, (long long)SD * DM, 0, 0);
    mm64_kernel<<<dim3(DM / 64, SD / 64, BD), 256, 0, stream>>>(
        hbuf, EK, nullptr, Kb, DM, RK,
        (long long)SD * RK, (long long)RK * DM, (long long)SD * DM, 0, 0);
    mm64_kernel<<<dim3(DM / 64, SD / 64, BD), 256, 0, stream>>>(
        hbuf, EV, nullptr, Vb, DM, RK,
        (long long)SD * RK, (long long)RK * DM, (long long)SD * DM, 0, 0);
    attn_mfma_kernel<<<dim3(SD / 64, NH, BD), 256, 0, stream>>>(Qb, Kb, Vb, attn);
    mm64_kernel<<<dim3(DM / 64, (BD * SD) / 64, 1), 256, 0, stream>>>(
        attn, WO, x, out, DM, DM, 0, 0, 0, 0, 1);
    ln_kernel<<<NTOK, 256, 0, stream>>>(out, ln2s, ln2b, n1);
    routem_kernel<<<NTOK, 256, 0, stream>>>(n1, imp, Wm, wpref);
    reduce_pref<<<BD * 64, 256, 0, stream>>>(wpref, dense, 64, 160);
    topk_kernel<<<1, 64, 0, stream>>>(dense, ridx, rw, 4, 1);
    combine_kernel<<<BD * (DM * RK) / 256, 256, 0, stream>>>(cneu, ridx, rw, 4, 8, scomp);
    mm64_kernel<<<dim3(RK / 64, SD / 64, BD), 256, 0, stream>>>(
        n1, scomp, nullptr, hbuf, RK, DM,
        (long long)SD * DM, (long long)DM * RK, (long long)SD * RK, 0, 0);
    know_kernel<<<NTOK / 16, 256, 0, stream>>>(hbuf, kK, kV, out);
}

// Round 3
// 1517.400 us; speedup vs baseline: 4.3004x; 1.9522x over previous
//
#include <hip/hip_runtime.h>
#include <hip/hip_bf16.h>

#define BD 8
#define SD 1024
#define DM 1024
#define NH 16
#define DH 64
#define RK 128
#define NC 64
#define NE 32
#define NK 16384
#define KNOW_K 8

typedef __attribute__((ext_vector_type(8))) short bf16x8;
typedef __attribute__((ext_vector_type(4))) float f32x4;

__device__ __forceinline__ unsigned short f2b(float f) {
    unsigned u = __float_as_uint(f);
    unsigned r = (u + 0x7FFFu + ((u >> 16) & 1u)) >> 16;
    return (unsigned short)r;
}

// ---------------- LayerNorm: one block per token ----------------
__global__ void __launch_bounds__(256) ln_kernel(const float* __restrict__ x,
                                                 const float* __restrict__ sc,
                                                 const float* __restrict__ bi,
                                                 float* __restrict__ out) {
    const int tok = blockIdx.x;
    __shared__ float xs[DM];
    __shared__ float red[256];
    const float* xp = x + (size_t)tok * DM;
    float s = 0.f;
    for (int i = threadIdx.x; i < DM; i += 256) { float v = xp[i]; xs[i] = v; s += v; }
    red[threadIdx.x] = s; __syncthreads();
    for (int st = 128; st; st >>= 1) { if (threadIdx.x < st) red[threadIdx.x] += red[threadIdx.x + st]; __syncthreads(); }
    float mu = red[0] * (1.f / DM);
    __syncthreads();
    float vs = 0.f;
    for (int i = threadIdx.x; i < DM; i += 256) { float d = xs[i] - mu; vs += d * d; }
    red[threadIdx.x] = vs; __syncthreads();
    for (int st = 128; st; st >>= 1) { if (threadIdx.x < st) red[threadIdx.x] += red[threadIdx.x + st]; __syncthreads(); }
    float rs = rsqrtf(red[0] * (1.f / DM) + 1e-5f);
    for (int i = threadIdx.x; i < DM; i += 256)
        out[(size_t)tok * DM + i] = (xs[i] - mu) * rs * sc[i] + bi[i];
}

// ------------- Phase-1 routers -------------
__global__ void __launch_bounds__(256) route4_kernel(const float* __restrict__ n1,
                                                     const float* __restrict__ imp,
                                                     const float* __restrict__ Wc,
                                                     const float* __restrict__ WQr,
                                                     const float* __restrict__ WKr,
                                                     const float* __restrict__ WVr,
                                                     float* __restrict__ wpref) {
    const int tok = blockIdx.x;
    __shared__ float xs[DM];
    __shared__ float lg[160];
    __shared__ float mseg[4], sseg[4];
    for (int i = threadIdx.x; i < DM; i += 256) xs[i] = n1[(size_t)tok * DM + i];
    __syncthreads();
    const int t = threadIdx.x;
    if (t < 160) {
        const float* w; int col, n;
        if (t < 64)       { w = Wc;  col = t;       n = 64; }
        else if (t < 96)  { w = WQr; col = t - 64;  n = 32; }
        else if (t < 128) { w = WKr; col = t - 96;  n = 32; }
        else              { w = WVr; col = t - 128; n = 32; }
        float acc = 0.f;
        for (int d = 0; d < DM; d++) acc += xs[d] * w[d * n + col];
        lg[t] = acc;
    }
    __syncthreads();
    if (t < 4) {
        int o = (t == 0) ? 0 : (64 + 32 * (t - 1));
        int n = (t == 0) ? 64 : 32;
        float m = -1e30f;
        for (int i = 0; i < n; i++) m = fmaxf(m, lg[o + i]);
        float ss = 0.f;
        for (int i = 0; i < n; i++) ss += expf(lg[o + i] - m);
        mseg[t] = m; sseg[t] = ss;
    }
    __syncthreads();
    if (t < 160) {
        int seg = (t < 64) ? 0 : ((t < 96) ? 1 : ((t < 128) ? 2 : 3));
        float p = expf(lg[t] - mseg[seg]) / sseg[seg];
        wpref[(size_t)tok * 160 + t] = imp[tok] * p;
    }
}

// ------------- Phase-2 router -------------
__global__ void __launch_bounds__(256) routem_kernel(const float* __restrict__ n2,
                                                     const float* __restrict__ imp,
                                                     const float* __restrict__ Wm,
                                                     float* __restrict__ wpref) {
    const int tok = blockIdx.x;
    __shared__ float xs[DM];
    __shared__ float lg[64];
    __shared__ float mm_, ss_;
    for (int i = threadIdx.x; i < DM; i += 256) xs[i] = n2[(size_t)tok * DM + i];
    __syncthreads();
    const int t = threadIdx.x;
    if (t < 64) {
        float acc = 0.f;
        for (int d = 0; d < DM; d++) acc += xs[d] * Wm[d * 64 + t];
        lg[t] = acc;
    }
    __syncthreads();
    if (t == 0) {
        float m = -1e30f;
        for (int i = 0; i < 64; i++) m = fmaxf(m, lg[i]);
        float ss = 0.f;
        for (int i = 0; i < 64; i++) ss += expf(lg[i] - m);
        mm_ = m; ss_ = ss;
    }
    __syncthreads();
    if (t < 64) {
        float p = expf(lg[t] - mm_) / ss_;
        wpref[(size_t)tok * 64 + t] = imp[tok] * p;
    }
}

// ------------- deterministic reduce over S -------------
__global__ void __launch_bounds__(256) reduce_pref(const float* __restrict__ wpref,
                                                   float* __restrict__ dense,
                                                   int ncols, int outoff) {
    const int b = blockIdx.x / ncols, c = blockIdx.x % ncols;
    __shared__ float red[256];
    float s = 0.f;
    for (int si = threadIdx.x; si < SD; si += 256)
        s += wpref[((size_t)(b * SD + si)) * ncols + c];
    red[threadIdx.x] = s; __syncthreads();
    for (int st = 128; st; st >>= 1) { if (threadIdx.x < st) red[threadIdx.x] += red[threadIdx.x + st]; __syncthreads(); }
    if (threadIdx.x == 0) dense[b * 224 + outoff + c] = red[0];
}

// ------------- top-k sparsify + renormalize -------------
__global__ void topk_kernel(const float* __restrict__ dense,
                            int* __restrict__ ridx, float* __restrict__ rw,
                            int r0, int nr) {
    const int t = threadIdx.x;
    if (t >= BD * nr) return;
    const int b = t / nr, r = r0 + (t % nr);
    const int offs[5] = {0, 64, 96, 128, 160};
    const int ns[5]   = {64, 32, 32, 32, 64};
    const int ks[5]   = {8, 4, 4, 4, 8};
    const float* dv = dense + b * 224 + offs[r];
    const int n = ns[r], k = ks[r];
    unsigned long long mask = 0;
    float vals[8]; int idxs[8];
    float ssum = 0.f;
    for (int kk = 0; kk < k; kk++) {
        float best = -1e30f; int bi = 0;
        for (int i = 0; i < n; i++)
            if (!((mask >> i) & 1ull) && dv[i] > best) { best = dv[i]; bi = i; }
        mask |= 1ull << bi;
        vals[kk] = best; idxs[kk] = bi; ssum += best;
    }
    float inv = 1.f / (ssum + 1e-8f);
    for (int kk = 0; kk < 8; kk++) {
        ridx[(b * 5 + r) * 8 + kk] = (kk < k) ? idxs[kk] : 0;
        rw[(b * 5 + r) * 8 + kk]   = (kk < k) ? vals[kk] * inv : 0.f;
    }
}

// ------------- mixture combine -------------
__global__ void __launch_bounds__(256) combine_kernel(const float* __restrict__ pool,
                                                      const int* __restrict__ ridx,
                                                      const float* __restrict__ rw,
                                                      int router, int kc,
                                                      float* __restrict__ out) {
    const size_t gid = (size_t)blockIdx.x * 256 + threadIdx.x;
    const int b = (int)(gid >> 17);
    const size_t dr = gid & 131071;
    const int* ii = ridx + (b * 5 + router) * 8;
    const float* ww = rw + (b * 5 + router) * 8;
    float acc = 0.f;
    for (int kk = 0; kk < kc; kk++)
        acc += ww[kk] * pool[((size_t)ii[kk] << 17) + dr];
    out[gid] = acc;
}

// ------------- generic batched fp32 GEMM -------------
__global__ void __launch_bounds__(256) mm64_kernel(const float* __restrict__ A,
                                                   const float* __restrict__ Bm,
                                                   const float* __restrict__ X,
                                                   float* __restrict__ C,
                                                   int N, int Kd,
                                                   long long sA, long long sB, long long sC, long long sX,
                                                   int hasX) {
    const int bz = blockIdx.z;
    const float* Ab = A + (size_t)bz * sA;
    const float* Bb = Bm + (size_t)bz * sB;
    float* Cb = C + (size_t)bz * sC;
    __shared__ float As[16][65];
    __shared__ float Bs[16][64];
    const int t = threadIdx.x;
    const int tx = t % 16, ty = t / 16;
    const int row0 = blockIdx.y * 64, col0 = blockIdx.x * 64;
    const int lc = t % 16, lr = t / 16;
    const int bn = t % 64, bk = t / 64;
    float acc[4][4] = {};
    for (int k0 = 0; k0 < Kd; k0 += 16) {
        #pragma unroll
        for (int i = 0; i < 4; i++)
            As[lc][lr + 16 * i] = Ab[(size_t)(row0 + lr + 16 * i) * Kd + k0 + lc];
        #pragma unroll
        for (int i = 0; i < 4; i++)
            Bs[bk + 4 * i][bn] = Bb[(size_t)(k0 + bk + 4 * i) * N + col0 + bn];
        __syncthreads();
        #pragma unroll
        for (int k = 0; k < 16; k++) {
            float a[4];
            #pragma unroll
            for (int i = 0; i < 4; i++) a[i] = As[k][ty * 4 + i];
            float4 bv = *(const float4*)&Bs[k][tx * 4];
            float b4[4] = {bv.x, bv.y, bv.z, bv.w};
            #pragma unroll
            for (int i = 0; i < 4; i++)
                #pragma unroll
                for (int j = 0; j < 4; j++) acc[i][j] += a[i] * b4[j];
        }
        __syncthreads();
    }
    #pragma unroll
    for (int i = 0; i < 4; i++) {
        const size_t r = row0 + ty * 4 + i;
        float4 v;
        float* vv = (float*)&v;
        #pragma unroll
        for (int j = 0; j < 4; j++) vv[j] = acc[i][j];
        if (hasX) {
            float4 xv = *(const float4*)&X[(size_t)bz * sX + r * N + col0 + tx * 4];
            v.x += xv.x; v.y += xv.y; v.z += xv.z; v.w += xv.w;
        }
        *(float4*)&Cb[r * N + col0 + tx * 4] = v;
    }
}

// ------------- flash attention, bf16 MFMA -------------
__global__ void __launch_bounds__(256) attn_mfma_kernel(const float* __restrict__ Q,
                                                        const float* __restrict__ K,
                                                        const float* __restrict__ V,
                                                        float* __restrict__ O) {
    const int qt = blockIdx.x, hh = blockIdx.y, b = blockIdx.z;
    const int t = threadIdx.x;
    const int w = t >> 6;
    const int l = t & 63;
    const int lq = l & 15;
    const int lg = l >> 4;

    __shared__ unsigned short ks[64 * 64];
    __shared__ unsigned short vt[64 * 64];
    __shared__ unsigned short pl[4][16 * 64];

    const size_t base = (size_t)b * SD * DM + (size_t)hh * DH;

    bf16x8 aq[2];
    {
        const int qrow = qt * 64 + w * 16 + lq;
        const float* qp = Q + base + (size_t)qrow * DM;
        #pragma unroll
        for (int c = 0; c < 2; c++) {
            union { unsigned short s[8]; bf16x8 v; } u;
            #pragma unroll
            for (int j = 0; j < 8; j++) u.s[j] = f2b(qp[lg * 8 + 32 * c + j]);
            aq[c] = u.v;
        }
    }

    f32x4 o_acc[4];
    #pragma unroll
    for (int dt = 0; dt < 4; dt++) o_acc[dt] = f32x4{0.f, 0.f, 0.f, 0.f};
    float m_r[4] = {-1e30f, -1e30f, -1e30f, -1e30f};
    float s_r[4] = {0.f, 0.f, 0.f, 0.f};

    const int ntile = qt + 1;
    for (int kt = 0; kt < ntile; kt++) {
        __syncthreads();
        #pragma unroll
        for (int p = 0; p < 8; p++) {
            const int i2 = t + 256 * p;
            const int row = i2 >> 5;
            const int col = (i2 & 31) * 2;
            const float2 kf = *(const float2*)(K + base + (size_t)(kt * 64 + row) * DM + col);
            const float2 vf = *(const float2*)(V + base + (size_t)(kt * 64 + row) * DM + col);
            const unsigned kb = (unsigned)f2b(kf.x) | ((unsigned)f2b(kf.y) << 16);
            *(unsigned*)((char*)ks + ((row * 128 + col * 2) ^ ((row & 7) << 4))) = kb;
            *(unsigned short*)((char*)vt + ((col * 128 + row * 2) ^ (((col >> 1) & 7) << 4))) = f2b(vf.x);
            *(unsigned short*)((char*)vt + (((col + 1) * 128 + row * 2) ^ ((((col + 1) >> 1) & 7) << 4))) = f2b(vf.y);
        }
        __syncthreads();

        const f32x4 zero4 = {0.f, 0.f, 0.f, 0.f};
        f32x4 sacc[4];
        #pragma unroll
        for (int ct = 0; ct < 4; ct++) {
            const int krow = ct * 16 + lq;
            bf16x8 b0 = *(const bf16x8*)((const char*)ks + ((krow * 128 + lg * 16) ^ ((lq & 7) << 4)));
            bf16x8 b1 = *(const bf16x8*)((const char*)ks + ((krow * 128 + lg * 16 + 64) ^ ((lq & 7) << 4)));
            f32x4 s = __builtin_amdgcn_mfma_f32_16x16x32_bf16(aq[0], b0, zero4, 0, 0, 0);
            s = __builtin_amdgcn_mfma_f32_16x16x32_bf16(aq[1], b1, s, 0, 0, 0);
            sacc[ct] = s;
        }

        float tm[4];
        #pragma unroll
        for (int j = 0; j < 4; j++) {
            const int qg = qt * 64 + w * 16 + lg * 4 + j;
            float mx = -1e30f;
            #pragma unroll
            for (int ct = 0; ct < 4; ct++) {
                const int kg = kt * 64 + ct * 16 + lq;
                float v = sacc[ct][j] * 0.125f;
                v = (kg <= qg) ? v : -1e30f;
                sacc[ct][j] = v;
                mx = fmaxf(mx, v);
            }
            #pragma unroll
            for (int d = 1; d < 16; d <<= 1) mx = fmaxf(mx, __shfl_xor(mx, d));
            tm[j] = mx;
        }
        #pragma unroll
        for (int j = 0; j < 4; j++) {
            const float nm = fmaxf(m_r[j], tm[j]);
            const float so = __expf(m_r[j] - nm);
            m_r[j] = nm;
            float rs = 0.f;
            const int prow = lg * 4 + j;
            #pragma unroll
            for (int ct = 0; ct < 4; ct++) {
                const float p = __expf(sacc[ct][j] - nm);
                rs += p;
                const int byteoff = ((prow * 128) + (ct * 16 + lq) * 2) ^ ((prow & 7) << 4);
                *(unsigned short*)((char*)&pl[w][0] + byteoff) = f2b(p);
            }
            #pragma unroll
            for (int d = 1; d < 16; d <<= 1) rs += __shfl_xor(rs, d);
            s_r[j] = s_r[j] * so + rs;
            #pragma unroll
            for (int dt = 0; dt < 4; dt++) o_acc[dt][j] *= so;
        }
        asm volatile("s_waitcnt lgkmcnt(0)" ::: "memory");

        #pragma unroll
        for (int c = 0; c < 2; c++) {
            bf16x8 pa = *(const bf16x8*)((const char*)&pl[w][0] +
                          ((lq * 128 + lg * 16 + 64 * c) ^ ((lq & 7) << 4)));
            #pragma unroll
            for (int dt = 0; dt < 4; dt++) {
                const int dd = dt * 16 + lq;
                bf16x8 bv = *(const bf16x8*)((const char*)vt +
                              ((dd * 128 + lg * 16 + 64 * c) ^ (((dd >> 1) & 7) << 4)));
                o_acc[dt] = __builtin_amdgcn_mfma_f32_16x16x32_bf16(pa, bv, o_acc[dt], 0, 0, 0);
            }
        }
    }

    #pragma unroll
    for (int j = 0; j < 4; j++) {
        const float inv = 1.f / s_r[j];
        const int qrow = qt * 64 + w * 16 + lg * 4 + j;
        float* op = O + base + (size_t)qrow * DM;
        #pragma unroll
        for (int dt = 0; dt < 4; dt++) op[dt * 16 + lq] = o_acc[dt][j] * inv;
    }
}

// ------------- fp32 -> bf16 convert (with scale) -------------
__global__ void __launch_bounds__(256) cvt_bf16_kernel(const float* __restrict__ src,
                                                       unsigned short* __restrict__ dst,
                                                       float scale, int n4) {
    const int i = blockIdx.x * 256 + threadIdx.x;
    if (i >= n4) return;
    float4 v = ((const float4*)src)[i];
    unsigned r0 = (unsigned)f2b(v.x * scale) | ((unsigned)f2b(v.y * scale) << 16);
    unsigned r1 = (unsigned)f2b(v.z * scale) | ((unsigned)f2b(v.w * scale) << 16);
    uint2 o; o.x = r0; o.y = r1;
    ((uint2*)dst)[i] = o;
}

// ------------- knowledge scores: MFMA + packed per-lane top-8 -------------
// block: 512 thr = 8 waves; 32 tokens; wave w: token half (w&1), key quarter (w>>1)
__global__ void __launch_bounds__(512) know_score_kernel(const unsigned short* __restrict__ Qmb,
                                                         const unsigned short* __restrict__ kKb,
                                                         float* __restrict__ cand) {
    const int t = threadIdx.x;
    const int w = t >> 6, l = t & 63, lq = l & 15, lg = l >> 4;
    const int half = w & 1;
    const int quart = w >> 1;
    const int tok0 = blockIdx.x * 32;
    __shared__ unsigned short ks[4][64 * 128];   // 64 KB

    // Q fragments: token row = tok0 + half*16 + lq, d = c*32 + lg*8 + j
    bf16x8 aq[4];
    {
        const unsigned short* qp = Qmb + (size_t)(tok0 + half * 16 + lq) * 128 + lg * 8;
        #pragma unroll
        for (int c = 0; c < 4; c++) aq[c] = *(const bf16x8*)(qp + c * 32);
    }

    // packed top-8 per row (key idx in low 14 mantissa bits); distinct sentinels
    float tv[4][8];
    float mn[4];
    #pragma unroll
    for (int j = 0; j < 4; j++) {
        #pragma unroll
        for (int s = 0; s < 8; s++) tv[j][s] = __uint_as_float(0xF2000000u | (unsigned)s);
        mn[j] = __uint_as_float(0xF2000007u);
    }

    const int kq0 = quart * 4096;
    const int sb = t >> 7;          // staging buffer 0..3
    const int st = t & 127;         // thread within buffer

    for (int kt = 0; kt < 64; kt++) {
        __syncthreads();
        // stage 64 keys x 128 d (bf16) into ks[sb], XOR-swizzled
        const unsigned short* src = kKb + ((size_t)(sb * 4096 + kt * 64) << 7);
        #pragma unroll
        for (int c2 = 0; c2 < 8; c2++) {
            const int e = c2 * 1024 + st * 8;
            bf16x8 v = *(const bf16x8*)(src + e);
            const int row = e >> 7;
            *(bf16x8*)((char*)&ks[sb][0] + ((e * 2) ^ ((row & 7) << 4))) = v;
        }
        __syncthreads();

        const f32x4 z4 = {0.f, 0.f, 0.f, 0.f};
        #pragma unroll
        for (int ct = 0; ct < 4; ct++) {
            const int row = ct * 16 + lq;
            const char* kb = (const char*)&ks[quart][0] + row * 256;
            const int sw = (row & 7) << 4;
            f32x4 s = z4;
            #pragma unroll
            for (int c = 0; c < 4; c++) {
                bf16x8 bv = *(const bf16x8*)(kb + ((c * 64 + lg * 16) ^ sw));
                s = __builtin_amdgcn_mfma_f32_16x16x32_bf16(aq[c], bv, s, 0, 0, 0);
            }
            const unsigned keyb = (unsigned)(kq0 + kt * 64 + ct * 16 + lq);
            #pragma unroll
            for (int j = 0; j < 4; j++) {
                unsigned u = __float_as_uint(s[j]);
                float pv = __uint_as_float((u & 0xFFFFC000u) | keyb);
                if (pv > mn[j]) {
                    #pragma unroll
                    for (int ss = 0; ss < 8; ss++)
                        tv[j][ss] = (tv[j][ss] == mn[j]) ? pv : tv[j][ss];
                    float m0 = tv[j][0];
                    #pragma unroll
                    for (int ss = 1; ss < 8; ss++) m0 = fminf(m0, tv[j][ss]);
                    mn[j] = m0;
                }
            }
        }
    }
    // dump candidates: cand[tok][quart*128 + lq*8 + s]
    #pragma unroll
    for (int j = 0; j < 4; j++) {
        const int tok = tok0 + half * 16 + lg * 4 + j;
        float* cp = cand + ((size_t)tok << 9) + quart * 128 + lq * 8;
        #pragma unroll
        for (int ss = 0; ss < 8; ss++) cp[ss] = tv[j][ss];
    }
}

// ------------- knowledge merge + V gather: one wave per token -------------
__global__ void __launch_bounds__(256) know_out_kernel(const float* __restrict__ cand,
                                                       const float* __restrict__ kV,
                                                       float* __restrict__ out) {
    const int t = threadIdx.x, w = t >> 6, l = t & 63;
    const int tok = blockIdx.x * 4 + w;
    const float* cp = cand + ((size_t)tok << 9);
    float lv[8];
    #pragma unroll
    for (int i = 0; i < 8; i++) lv[i] = cp[i * 64 + l];

    float topv[8]; int topi[8];
    #pragma unroll
    for (int kk = 0; kk < 8; kk++) {
        float m = lv[0];
        #pragma unroll
        for (int i = 1; i < 8; i++) m = fmaxf(m, lv[i]);
        #pragma unroll
        for (int d = 1; d < 64; d <<= 1) m = fmaxf(m, __shfl_xor(m, d));
        topv[kk] = m;
        topi[kk] = (int)(__float_as_uint(m) & 0x3FFFu);
        #pragma unroll
        for (int i = 0; i < 8; i++) lv[i] = (lv[i] == m) ? -1e31f : lv[i];
    }
    const float mx = topv[0];
    float e[8]; float ssum = 0.f;
    #pragma unroll
    for (int kk = 0; kk < 8; kk++) { e[kk] = __expf(topv[kk] - mx); ssum += e[kk]; }
    const float inv = 1.f / ssum;

    float4 acc[4];
    #pragma unroll
    for (int ch = 0; ch < 4; ch++) acc[ch] = float4{0.f, 0.f, 0.f, 0.f};
    #pragma unroll
    for (int kk = 0; kk < 8; kk++) {
        const float wk = e[kk] * inv;
        const float* vp = kV + ((size_t)topi[kk] << 10);
        #pragma unroll
        for (int ch = 0; ch < 4; ch++) {
            float4 v = *(const float4*)(vp + ch * 256 + l * 4);
            acc[ch].x += wk * v.x; acc[ch].y += wk * v.y;
            acc[ch].z += wk * v.z; acc[ch].w += wk * v.w;
        }
    }
    float* op = out + ((size_t)tok << 10);
    #pragma unroll
    for (int ch = 0; ch < 4; ch++) {
        float4 o = *(const float4*)(op + ch * 256 + l * 4);
        o.x += acc[ch].x; o.y += acc[ch].y; o.z += acc[ch].z; o.w += acc[ch].w;
        *(float4*)(op + ch * 256 + l * 4) = o;
    }
}

extern "C" void kernel_launch(void* const* d_in, const int* in_sizes, int n_in,
                              void* d_out, int out_size, void* d_ws, size_t ws_size,
                              hipStream_t stream) {
    const float* x    = (const float*)d_in[0];
    const float* imp  = (const float*)d_in[1];
    const float* Wc   = (const float*)d_in[2];
    const float* WQr  = (const float*)d_in[3];
    const float* WKr  = (const float*)d_in[4];
    const float* WVr  = (const float*)d_in[5];
    const float* Wm   = (const float*)d_in[6];
    const float* cneu = (const float*)d_in[7];
    const float* epool= (const float*)d_in[8];
    const float* kK   = (const float*)d_in[9];
    const float* kV   = (const float*)d_in[10];
    const float* WO   = (const float*)d_in[11];
    const float* ln1s = (const float*)d_in[12];
    const float* ln1b = (const float*)d_in[13];
    const float* ln2s = (const float*)d_in[14];
    const float* ln2b = (const float*)d_in[15];
    float* out = (float*)d_out;

    float* ws = (float*)d_ws;
    size_t o = 0;
    float* n1    = ws + o; o += (size_t)BD * SD * DM;
    float* wpref = ws + o; o += (size_t)BD * SD * 160;
    float* dense = ws + o; o += (size_t)BD * 224;
    int*   ridx  = (int*)(ws + o); o += (size_t)BD * 5 * 8;
    float* rw    = ws + o; o += (size_t)BD * 5 * 8;
    float* scomp = ws + o; o += (size_t)BD * DM * RK;
    float* EQ    = ws + o; o += (size_t)BD * RK * DM;
    float* EK    = ws + o; o += (size_t)BD * RK * DM;
    float* EV    = ws + o; o += (size_t)BD * RK * DM;
    float* hbuf  = ws + o; o += (size_t)BD * SD * RK;
    float* Qb    = ws + o; o += (size_t)BD * SD * DM;
    float* Kb    = ws + o; o += (size_t)BD * SD * DM;
    float* Vb    = ws + o; o += (size_t)BD * SD * DM;
    float* attn  = ws + o; o += (size_t)BD * SD * DM;

    // reuse dead buffers for knowledge phase
    float* cand = Qb;                                  // 16 MB needed, 32 MB avail
    unsigned short* kKb = (unsigned short*)Vb;         // 4 MB
    unsigned short* Qmb = (unsigned short*)attn;       // 2 MB

    const int NTOK = BD * SD;

    ln_kernel<<<NTOK, 256, 0, stream>>>(x, ln1s, ln1b, n1);
    route4_kernel<<<NTOK, 256, 0, stream>>>(n1, imp, Wc, WQr, WKr, WVr, wpref);
    reduce_pref<<<BD * 160, 256, 0, stream>>>(wpref, dense, 160, 0);
    topk_kernel<<<1, 64, 0, stream>>>(dense, ridx, rw, 0, 4);
    combine_kernel<<<BD * (DM * RK) / 256, 256, 0, stream>>>(cneu, ridx, rw, 0, 8, scomp);
    combine_kernel<<<BD * (RK * DM) / 256, 256, 0, stream>>>(epool, ridx, rw, 1, 4, EQ);
    combine_kernel<<<BD * (RK * DM) / 256, 256, 0, stream>>>(epool, ridx, rw, 2, 4, EK);
    combine_kernel<<<BD * (RK * DM) / 256, 256, 0, stream>>>(epool, ridx, rw, 3, 4, EV);
    mm64_kernel<<<dim3(RK / 64, SD / 64, BD), 256, 0, stream>>>(
        n1, scomp, nullptr, hbuf, RK, DM,
        (long long)SD * DM, (long long)DM * RK, (long long)SD * RK, 0, 0);
    mm64_kernel<<<dim3(DM / 64, SD / 64, BD), 256, 0, stream>>>(
        hbuf, EQ, nullptr, Qb, DM, RK,
        (long long)SD * RK, (long long)RK * DM, (long long)SD * DM, 0, 0);
    mm64_kernel<<<dim3(DM / 64, SD / 64, BD), 256, 0, stream>>>(
        hbuf, EK, nullptr, Kb, DM, RK,
        (long long)SD * RK, (long long)RK * DM, (long long)SD * DM, 0, 0);
    mm64_kernel<<<dim3(DM / 64, SD / 64, BD), 256, 0, stream>>>(
        hbuf, EV, nullptr, Vb, DM, RK,
        (long long)SD * RK, (long long)RK * DM, (long long)SD * DM, 0, 0);
    attn_mfma_kernel<<<dim3(SD / 64, NH, BD), 256, 0, stream>>>(Qb, Kb, Vb, attn);
    mm64_kernel<<<dim3(DM / 64, (BD * SD) / 64, 1), 256, 0, stream>>>(
        attn, WO, x, out, DM, DM, 0, 0, 0, 0, 1);
    // kK -> bf16 (Vb dead after attention)
    cvt_bf16_kernel<<<(NK * RK / 4) / 256, 256, 0, stream>>>(kK, kKb, 1.0f, NK * RK / 4);
    ln_kernel<<<NTOK, 256, 0, stream>>>(out, ln2s, ln2b, n1);
    routem_kernel<<<NTOK, 256, 0, stream>>>(n1, imp, Wm, wpref);
    reduce_pref<<<BD * 64, 256, 0, stream>>>(wpref, dense, 64, 160);
    topk_kernel<<<1, 64, 0, stream>>>(dense, ridx, rw, 4, 1);
    combine_kernel<<<BD * (DM * RK) / 256, 256, 0, stream>>>(cneu, ridx, rw, 4, 8, scomp);
    mm64_kernel<<<dim3(RK / 64, SD / 64, BD), 256, 0, stream>>>(
        n1, scomp, nullptr, hbuf, RK, DM,
        (long long)SD * DM, (long long)DM * RK, (long long)SD * RK, 0, 0);
    // Qm -> bf16 with 1/sqrt(128) folded (attn dead after WO GEMM)
    cvt_bf16_kernel<<<(NTOK * RK / 4) / 256, 256, 0, stream>>>(
        hbuf, Qmb, 0.0883883476483184f, NTOK * RK / 4);
    know_score_kernel<<<NTOK / 32, 512, 0, stream>>>(Qmb, kKb, cand);
    know_out_kernel<<<NTOK / 4, 256, 0, stream>>>(cand, kV, out);
}

// Round 4
// 960.861 us; speedup vs baseline: 6.7912x; 1.5792x over previous
//
#include <hip/hip_runtime.h>
#include <hip/hip_bf16.h>

#define BD 8
#define SD 1024
#define DM 1024
#define NH 16
#define DH 64
#define RK 128
#define NK 16384

typedef __attribute__((ext_vector_type(8))) short bf16x8;
typedef __attribute__((ext_vector_type(4))) float f32x4;

__device__ __forceinline__ unsigned short f2b(float f) {
    unsigned u = __float_as_uint(f);
    unsigned r = (u + 0x7FFFu + ((u >> 16) & 1u)) >> 16;
    return (unsigned short)r;
}

// ---------------- LayerNorm: fp32 + bf16 outputs ----------------
__global__ void __launch_bounds__(256) ln_kernel(const float* __restrict__ x,
                                                 const float* __restrict__ sc,
                                                 const float* __restrict__ bi,
                                                 float* __restrict__ out,
                                                 unsigned short* __restrict__ outb) {
    const int tok = blockIdx.x;
    __shared__ float xs[DM];
    __shared__ float red[256];
    const float* xp = x + (size_t)tok * DM;
    float s = 0.f;
    for (int i = threadIdx.x; i < DM; i += 256) { float v = xp[i]; xs[i] = v; s += v; }
    red[threadIdx.x] = s; __syncthreads();
    for (int st = 128; st; st >>= 1) { if (threadIdx.x < st) red[threadIdx.x] += red[threadIdx.x + st]; __syncthreads(); }
    float mu = red[0] * (1.f / DM);
    __syncthreads();
    float vs = 0.f;
    for (int i = threadIdx.x; i < DM; i += 256) { float d = xs[i] - mu; vs += d * d; }
    red[threadIdx.x] = vs; __syncthreads();
    for (int st = 128; st; st >>= 1) { if (threadIdx.x < st) red[threadIdx.x] += red[threadIdx.x + st]; __syncthreads(); }
    float rs = rsqrtf(red[0] * (1.f / DM) + 1e-5f);
    for (int i = threadIdx.x; i < DM; i += 256) {
        float v = (xs[i] - mu) * rs * sc[i] + bi[i];
        out[(size_t)tok * DM + i] = v;
        outb[(size_t)tok * DM + i] = f2b(v);
    }
}

// ---------------- concat router weights into [1024][192] (pad zeros) ----------------
__global__ void __launch_bounds__(256) concatw_kernel(const float* __restrict__ Wc,
                                                      const float* __restrict__ WQr,
                                                      const float* __restrict__ WKr,
                                                      const float* __restrict__ WVr,
                                                      float* __restrict__ Wcat) {
    const int i = blockIdx.x * 256 + threadIdx.x;
    if (i >= 1024 * 192) return;
    const int d = i / 192, c = i % 192;
    float v = 0.f;
    if (c < 64)       v = Wc[d * 64 + c];
    else if (c < 96)  v = WQr[d * 32 + c - 64];
    else if (c < 128) v = WKr[d * 32 + c - 96];
    else if (c < 160) v = WVr[d * 32 + c - 128];
    Wcat[i] = v;
}

// ---------------- generic fp32 GEMM (router logits only) ----------------
__global__ void __launch_bounds__(256) mm64_kernel(const float* __restrict__ A,
                                                   const float* __restrict__ Bm,
                                                   float* __restrict__ C,
                                                   int N, int Kd) {
    __shared__ float As[16][65];
    __shared__ float Bs[16][64];
    const int t = threadIdx.x;
    const int tx = t % 16, ty = t / 16;
    const int row0 = blockIdx.y * 64, col0 = blockIdx.x * 64;
    const int lc = t % 16, lr = t / 16;
    const int bn = t % 64, bk = t / 64;
    float acc[4][4] = {};
    for (int k0 = 0; k0 < Kd; k0 += 16) {
        #pragma unroll
        for (int i = 0; i < 4; i++)
            As[lc][lr + 16 * i] = A[(size_t)(row0 + lr + 16 * i) * Kd + k0 + lc];
        #pragma unroll
        for (int i = 0; i < 4; i++)
            Bs[bk + 4 * i][bn] = Bm[(size_t)(k0 + bk + 4 * i) * N + col0 + bn];
        __syncthreads();
        #pragma unroll
        for (int k = 0; k < 16; k++) {
            float a[4];
            #pragma unroll
            for (int i = 0; i < 4; i++) a[i] = As[k][ty * 4 + i];
            float4 bv = *(const float4*)&Bs[k][tx * 4];
            float b4[4] = {bv.x, bv.y, bv.z, bv.w};
            #pragma unroll
            for (int i = 0; i < 4; i++)
                #pragma unroll
                for (int j = 0; j < 4; j++) acc[i][j] += a[i] * b4[j];
        }
        __syncthreads();
    }
    #pragma unroll
    for (int i = 0; i < 4; i++) {
        const size_t r = row0 + ty * 4 + i;
        float4 v;
        float* vv = (float*)&v;
        #pragma unroll
        for (int j = 0; j < 4; j++) vv[j] = acc[i][j];
        *(float4*)&C[r * N + col0 + tx * 4] = v;
    }
}

// ---------------- phase-1 softmax prefs: 4 segments/token ----------------
__global__ void __launch_bounds__(256) softpref_kernel(const float* __restrict__ lgt,
                                                       const float* __restrict__ imp,
                                                       float* __restrict__ wpref) {
    const int tok = blockIdx.x * 64 + (threadIdx.x >> 2);
    const int sg = threadIdx.x & 3;
    const int o = (sg == 0) ? 0 : (64 + 32 * (sg - 1));
    const int n = (sg == 0) ? 64 : 32;
    const float* lp = lgt + (size_t)tok * 192 + o;
    float m = -1e30f;
    for (int i = 0; i < n; i++) m = fmaxf(m, lp[i]);
    float ss = 0.f;
    for (int i = 0; i < n; i++) ss += __expf(lp[i] - m);
    const float scl = imp[tok] / ss;
    float* wp = wpref + (size_t)tok * 160 + o;
    for (int i = 0; i < n; i++) wp[i] = __expf(lp[i] - m) * scl;
}

// ---------------- phase-2 softmax prefs: one thread/token ----------------
__global__ void __launch_bounds__(256) softm_kernel(const float* __restrict__ lgt,
                                                    const float* __restrict__ imp,
                                                    float* __restrict__ wpref) {
    const int tok = blockIdx.x * 256 + threadIdx.x;
    const float* lp = lgt + (size_t)tok * 64;
    float m = -1e30f;
    for (int i = 0; i < 64; i++) m = fmaxf(m, lp[i]);
    float ss = 0.f;
    for (int i = 0; i < 64; i++) ss += __expf(lp[i] - m);
    const float scl = imp[tok] / ss;
    for (int i = 0; i < 64; i++) wpref[(size_t)tok * 64 + i] = __expf(lp[i] - m) * scl;
}

// ---------------- deterministic reduce over S ----------------
__global__ void __launch_bounds__(256) reduce_pref(const float* __restrict__ wpref,
                                                   float* __restrict__ dense,
                                                   int ncols, int outoff) {
    const int b = blockIdx.x / ncols, c = blockIdx.x % ncols;
    __shared__ float red[256];
    float s = 0.f;
    for (int si = threadIdx.x; si < SD; si += 256)
        s += wpref[((size_t)(b * SD + si)) * ncols + c];
    red[threadIdx.x] = s; __syncthreads();
    for (int st = 128; st; st >>= 1) { if (threadIdx.x < st) red[threadIdx.x] += red[threadIdx.x + st]; __syncthreads(); }
    if (threadIdx.x == 0) dense[b * 224 + outoff + c] = red[0];
}

// ---------------- top-k sparsify + renormalize ----------------
__global__ void topk_kernel(const float* __restrict__ dense,
                            int* __restrict__ ridx, float* __restrict__ rw,
                            int r0, int nr) {
    const int t = threadIdx.x;
    if (t >= BD * nr) return;
    const int b = t / nr, r = r0 + (t % nr);
    const int offs[5] = {0, 64, 96, 128, 160};
    const int ns[5]   = {64, 32, 32, 32, 64};
    const int ks[5]   = {8, 4, 4, 4, 8};
    const float* dv = dense + b * 224 + offs[r];
    const int n = ns[r], k = ks[r];
    unsigned long long mask = 0;
    float vals[8]; int idxs[8];
    float ssum = 0.f;
    for (int kk = 0; kk < k; kk++) {
        float best = -1e30f; int bi = 0;
        for (int i = 0; i < n; i++)
            if (!((mask >> i) & 1ull) && dv[i] > best) { best = dv[i]; bi = i; }
        mask |= 1ull << bi;
        vals[kk] = best; idxs[kk] = bi; ssum += best;
    }
    float inv = 1.f / (ssum + 1e-8f);
    for (int kk = 0; kk < 8; kk++) {
        ridx[(b * 5 + r) * 8 + kk] = (kk < k) ? idxs[kk] : 0;
        rw[(b * 5 + r) * 8 + kk]   = (kk < k) ? vals[kk] * inv : 0.f;
    }
}

// ---------------- mixture combine, float4 ----------------
__global__ void __launch_bounds__(256) combine4_kernel(const float* __restrict__ pool,
                                                       const int* __restrict__ ridx,
                                                       const float* __restrict__ rw,
                                                       int router, int kc,
                                                       float* __restrict__ out) {
    const size_t gid = (size_t)blockIdx.x * 256 + threadIdx.x;   // float4 index
    const int b = (int)(gid >> 15);
    const size_t dr = gid & 32767;
    const int* ii = ridx + (b * 5 + router) * 8;
    const float* ww = rw + (b * 5 + router) * 8;
    float4 acc = {0.f, 0.f, 0.f, 0.f};
    for (int kk = 0; kk < kc; kk++) {
        const float w = ww[kk];
        float4 v = ((const float4*)(pool + ((size_t)ii[kk] << 17)))[dr];
        acc.x += w * v.x; acc.y += w * v.y; acc.z += w * v.z; acc.w += w * v.w;
    }
    ((float4*)out)[gid] = acc;
}

// ---------------- tile transpose + fp32->bf16: src[R][C] -> dst[C][R] ----------------
__global__ void __launch_bounds__(256) tcvt_kernel(const float* __restrict__ src,
                                                   unsigned short* __restrict__ dst,
                                                   int R, int Cc,
                                                   long long sS, long long sD) {
    __shared__ float ls[64][65];
    const int r0 = blockIdx.y * 64, c0 = blockIdx.x * 64;
    const float* sp = src + (size_t)blockIdx.z * sS;
    unsigned short* dp = dst + (size_t)blockIdx.z * sD;
    const int t = threadIdx.x;
    #pragma unroll
    for (int p = 0; p < 16; p++) {
        const int e = p * 256 + t;
        const int r = e >> 6, c = e & 63;
        ls[r][c] = sp[(size_t)(r0 + r) * Cc + c0 + c];
    }
    __syncthreads();
    #pragma unroll
    for (int p = 0; p < 16; p++) {
        const int e = p * 256 + t;
        const int c = e >> 6, r = e & 63;
        dp[(size_t)(c0 + c) * R + r0 + r] = f2b(ls[r][c]);
    }
}

// ---------------- fp32 -> bf16 convert with scale ----------------
__global__ void __launch_bounds__(256) cvt_bf16_kernel(const float* __restrict__ src,
                                                       unsigned short* __restrict__ dst,
                                                       float scale, int n4) {
    const int i = blockIdx.x * 256 + threadIdx.x;
    if (i >= n4) return;
    float4 v = ((const float4*)src)[i];
    unsigned r0 = (unsigned)f2b(v.x * scale) | ((unsigned)f2b(v.y * scale) << 16);
    unsigned r1 = (unsigned)f2b(v.z * scale) | ((unsigned)f2b(v.w * scale) << 16);
    uint2 o; o.x = r0; o.y = r1;
    ((uint2*)dst)[i] = o;
}

// ---------------- bf16 MFMA GEMM: C = A[M][K] @ Bt[N][K]^T (+X), 128x128 tile ----------------
template<int OUTB, int HASX>
__global__ void __launch_bounds__(256) gemm_bf16(const unsigned short* __restrict__ A,
                                                 const unsigned short* __restrict__ Bt,
                                                 const float* __restrict__ X,
                                                 void* __restrict__ Cv,
                                                 int M, int N, int K,
                                                 long long sA, long long sB, long long sC) {
    const int bz = blockIdx.z;
    const unsigned short* Ab = A + (size_t)bz * sA;
    const unsigned short* Btb = Bt + (size_t)bz * sB;
    const int row0 = blockIdx.y * 128, col0 = blockIdx.x * 128;
    const int t = threadIdx.x;
    const int w = t >> 6, l = t & 63, lq = l & 15, lg = l >> 4;
    const int wr = w >> 1, wc = w & 1;
    __shared__ unsigned short As[128 * 64];
    __shared__ unsigned short Bs[128 * 64];
    f32x4 acc[4][4];
    #pragma unroll
    for (int mi = 0; mi < 4; mi++)
        #pragma unroll
        for (int ni = 0; ni < 4; ni++) acc[mi][ni] = f32x4{0.f, 0.f, 0.f, 0.f};

    for (int k0 = 0; k0 < K; k0 += 64) {
        __syncthreads();
        #pragma unroll
        for (int p = 0; p < 4; p++) {
            const int e = t * 8 + p * 2048;
            const int row = e >> 6, col = e & 63;
            bf16x8 va = *(const bf16x8*)(Ab + (size_t)(row0 + row) * K + k0 + col);
            *(bf16x8*)((char*)As + ((row * 128 + col * 2) ^ ((row & 7) << 4))) = va;
            bf16x8 vb = *(const bf16x8*)(Btb + (size_t)(col0 + row) * K + k0 + col);
            *(bf16x8*)((char*)Bs + ((row * 128 + col * 2) ^ ((row & 7) << 4))) = vb;
        }
        __syncthreads();
        #pragma unroll
        for (int kk = 0; kk < 2; kk++) {
            bf16x8 af[4], bg[4];
            #pragma unroll
            for (int mi = 0; mi < 4; mi++) {
                const int r = wr * 64 + mi * 16 + lq;
                af[mi] = *(const bf16x8*)((const char*)As + ((r * 128 + lg * 16 + kk * 64) ^ ((r & 7) << 4)));
            }
            #pragma unroll
            for (int ni = 0; ni < 4; ni++) {
                const int r = wc * 64 + ni * 16 + lq;
                bg[ni] = *(const bf16x8*)((const char*)Bs + ((r * 128 + lg * 16 + kk * 64) ^ ((r & 7) << 4)));
            }
            #pragma unroll
            for (int mi = 0; mi < 4; mi++)
                #pragma unroll
                for (int ni = 0; ni < 4; ni++)
                    acc[mi][ni] = __builtin_amdgcn_mfma_f32_16x16x32_bf16(af[mi], bg[ni], acc[mi][ni], 0, 0, 0);
        }
    }
    #pragma unroll
    for (int mi = 0; mi < 4; mi++) {
        #pragma unroll
        for (int j = 0; j < 4; j++) {
            const int row = row0 + wr * 64 + mi * 16 + lg * 4 + j;
            #pragma unroll
            for (int ni = 0; ni < 4; ni++) {
                const int col = col0 + wc * 64 + ni * 16 + lq;
                float v = acc[mi][ni][j];
                if (HASX) v += X[(size_t)row * N + col];
                if (OUTB) ((unsigned short*)Cv)[(size_t)bz * sC + (size_t)row * N + col] = f2b(v);
                else      ((float*)Cv)[(size_t)bz * sC + (size_t)row * N + col] = v;
            }
        }
    }
}

// ---------------- flash attention, bf16 in / bf16 out ----------------
__global__ void __launch_bounds__(256) attn_mfma_kernel(const unsigned short* __restrict__ Q,
                                                        const unsigned short* __restrict__ K,
                                                        const unsigned short* __restrict__ V,
                                                        unsigned short* __restrict__ O) {
    const int qt = blockIdx.x, hh = blockIdx.y, b = blockIdx.z;
    const int t = threadIdx.x;
    const int w = t >> 6;
    const int l = t & 63;
    const int lq = l & 15;
    const int lg = l >> 4;

    __shared__ unsigned short ks[64 * 64];
    __shared__ unsigned short vt[64 * 64];
    __shared__ unsigned short pl[4][16 * 64];

    const size_t base = (size_t)b * SD * DM + (size_t)hh * DH;

    bf16x8 aq[2];
    {
        const int qrow = qt * 64 + w * 16 + lq;
        const unsigned short* qp = Q + base + (size_t)qrow * DM + lg * 8;
        aq[0] = *(const bf16x8*)(qp);
        aq[1] = *(const bf16x8*)(qp + 32);
    }

    f32x4 o_acc[4];
    #pragma unroll
    for (int dt = 0; dt < 4; dt++) o_acc[dt] = f32x4{0.f, 0.f, 0.f, 0.f};
    float m_r[4] = {-1e30f, -1e30f, -1e30f, -1e30f};
    float s_r[4] = {0.f, 0.f, 0.f, 0.f};

    const int ntile = qt + 1;
    for (int kt = 0; kt < ntile; kt++) {
        __syncthreads();
        #pragma unroll
        for (int p = 0; p < 2; p++) {
            const int e8 = t + 256 * p;
            const int row = e8 >> 3;
            const int col = (e8 & 7) * 8;
            bf16x8 kv = *(const bf16x8*)(K + base + (size_t)(kt * 64 + row) * DM + col);
            *(bf16x8*)((char*)ks + ((row * 128 + col * 2) ^ ((row & 7) << 4))) = kv;
            bf16x8 vv = *(const bf16x8*)(V + base + (size_t)(kt * 64 + row) * DM + col);
            #pragma unroll
            for (int j2 = 0; j2 < 8; j2++) {
                const int d = col + j2;
                *(unsigned short*)((char*)vt + ((d * 128 + row * 2) ^ (((d >> 1) & 7) << 4))) =
                    (unsigned short)vv[j2];
            }
        }
        __syncthreads();

        const f32x4 zero4 = {0.f, 0.f, 0.f, 0.f};
        f32x4 sacc[4];
        #pragma unroll
        for (int ct = 0; ct < 4; ct++) {
            const int krow = ct * 16 + lq;
            bf16x8 b0 = *(const bf16x8*)((const char*)ks + ((krow * 128 + lg * 16) ^ ((lq & 7) << 4)));
            bf16x8 b1 = *(const bf16x8*)((const char*)ks + ((krow * 128 + lg * 16 + 64) ^ ((lq & 7) << 4)));
            f32x4 s = __builtin_amdgcn_mfma_f32_16x16x32_bf16(aq[0], b0, zero4, 0, 0, 0);
            s = __builtin_amdgcn_mfma_f32_16x16x32_bf16(aq[1], b1, s, 0, 0, 0);
            sacc[ct] = s;
        }

        float tm[4];
        #pragma unroll
        for (int j = 0; j < 4; j++) {
            const int qg = qt * 64 + w * 16 + lg * 4 + j;
            float mx = -1e30f;
            #pragma unroll
            for (int ct = 0; ct < 4; ct++) {
                const int kg = kt * 64 + ct * 16 + lq;
                float v = sacc[ct][j] * 0.125f;
                v = (kg <= qg) ? v : -1e30f;
                sacc[ct][j] = v;
                mx = fmaxf(mx, v);
            }
            #pragma unroll
            for (int d = 1; d < 16; d <<= 1) mx = fmaxf(mx, __shfl_xor(mx, d));
            tm[j] = mx;
        }
        #pragma unroll
        for (int j = 0; j < 4; j++) {
            const float nm = fmaxf(m_r[j], tm[j]);
            const float so = __expf(m_r[j] - nm);
            m_r[j] = nm;
            float rs = 0.f;
            const int prow = lg * 4 + j;
            #pragma unroll
            for (int ct = 0; ct < 4; ct++) {
                const float p = __expf(sacc[ct][j] - nm);
                rs += p;
                const int byteoff = ((prow * 128) + (ct * 16 + lq) * 2) ^ ((prow & 7) << 4);
                *(unsigned short*)((char*)&pl[w][0] + byteoff) = f2b(p);
            }
            #pragma unroll
            for (int d = 1; d < 16; d <<= 1) rs += __shfl_xor(rs, d);
            s_r[j] = s_r[j] * so + rs;
            #pragma unroll
            for (int dt = 0; dt < 4; dt++) o_acc[dt][j] *= so;
        }
        asm volatile("s_waitcnt lgkmcnt(0)" ::: "memory");

        #pragma unroll
        for (int c = 0; c < 2; c++) {
            bf16x8 pa = *(const bf16x8*)((const char*)&pl[w][0] +
                          ((lq * 128 + lg * 16 + 64 * c) ^ ((lq & 7) << 4)));
            #pragma unroll
            for (int dt = 0; dt < 4; dt++) {
                const int dd = dt * 16 + lq;
                bf16x8 bv = *(const bf16x8*)((const char*)vt +
                              ((dd * 128 + lg * 16 + 64 * c) ^ (((dd >> 1) & 7) << 4)));
                o_acc[dt] = __builtin_amdgcn_mfma_f32_16x16x32_bf16(pa, bv, o_acc[dt], 0, 0, 0);
            }
        }
    }

    #pragma unroll
    for (int j = 0; j < 4; j++) {
        const float inv = 1.f / s_r[j];
        const int qrow = qt * 64 + w * 16 + lg * 4 + j;
        unsigned short* op = O + base + (size_t)qrow * DM;
        #pragma unroll
        for (int dt = 0; dt < 4; dt++) op[dt * 16 + lq] = f2b(o_acc[dt][j] * inv);
    }
}

// ---------------- knowledge scores: MFMA + packed per-lane top-8 ----------------
__global__ void __launch_bounds__(512) know_score_kernel(const unsigned short* __restrict__ Qmb,
                                                         const unsigned short* __restrict__ kKb,
                                                         float* __restrict__ cand) {
    const int t = threadIdx.x;
    const int w = t >> 6, l = t & 63, lq = l & 15, lg = l >> 4;
    const int half = w & 1;
    const int quart = w >> 1;
    const int tok0 = blockIdx.x * 32;
    __shared__ unsigned short ks[4][64 * 128];

    bf16x8 aq[4];
    {
        const unsigned short* qp = Qmb + (size_t)(tok0 + half * 16 + lq) * 128 + lg * 8;
        #pragma unroll
        for (int c = 0; c < 4; c++) aq[c] = *(const bf16x8*)(qp + c * 32);
    }

    float tv[4][8];
    float mn[4];
    #pragma unroll
    for (int j = 0; j < 4; j++) {
        #pragma unroll
        for (int s = 0; s < 8; s++) tv[j][s] = __uint_as_float(0xF2000000u | (unsigned)s);
        mn[j] = __uint_as_float(0xF2000007u);
    }

    const int kq0 = quart * 4096;
    const int sb = t >> 7;
    const int st = t & 127;

    for (int kt = 0; kt < 64; kt++) {
        __syncthreads();
        const unsigned short* src = kKb + ((size_t)(sb * 4096 + kt * 64) << 7);
        #pragma unroll
        for (int c2 = 0; c2 < 8; c2++) {
            const int e = c2 * 1024 + st * 8;
            bf16x8 v = *(const bf16x8*)(src + e);
            const int row = e >> 7;
            *(bf16x8*)((char*)&ks[sb][0] + ((e * 2) ^ ((row & 7) << 4))) = v;
        }
        __syncthreads();

        const f32x4 z4 = {0.f, 0.f, 0.f, 0.f};
        #pragma unroll
        for (int ct = 0; ct < 4; ct++) {
            const int row = ct * 16 + lq;
            const char* kb = (const char*)&ks[quart][0] + row * 256;
            const int sw = (row & 7) << 4;
            f32x4 s = z4;
            #pragma unroll
            for (int c = 0; c < 4; c++) {
                bf16x8 bv = *(const bf16x8*)(kb + ((c * 64 + lg * 16) ^ sw));
                s = __builtin_amdgcn_mfma_f32_16x16x32_bf16(aq[c], bv, s, 0, 0, 0);
            }
            const unsigned keyb = (unsigned)(kq0 + kt * 64 + ct * 16 + lq);
            #pragma unroll
            for (int j = 0; j < 4; j++) {
                unsigned u = __float_as_uint(s[j]);
                float pv = __uint_as_float((u & 0xFFFFC000u) | keyb);
                if (pv > mn[j]) {
                    #pragma unroll
                    for (int ss = 0; ss < 8; ss++)
                        tv[j][ss] = (tv[j][ss] == mn[j]) ? pv : tv[j][ss];
                    float m0 = tv[j][0];
                    #pragma unroll
                    for (int ss = 1; ss < 8; ss++) m0 = fminf(m0, tv[j][ss]);
                    mn[j] = m0;
                }
            }
        }
    }
    #pragma unroll
    for (int j = 0; j < 4; j++) {
        const int tok = tok0 + half * 16 + lg * 4 + j;
        float* cp = cand + ((size_t)tok << 9) + quart * 128 + lq * 8;
        #pragma unroll
        for (int ss = 0; ss < 8; ss++) cp[ss] = tv[j][ss];
    }
}

// ---------------- knowledge merge + V gather ----------------
__global__ void __launch_bounds__(256) know_out_kernel(const float* __restrict__ cand,
                                                       const float* __restrict__ kV,
                                                       float* __restrict__ out) {
    const int t = threadIdx.x, w = t >> 6, l = t & 63;
    const int tok = blockIdx.x * 4 + w;
    const float* cp = cand + ((size_t)tok << 9);
    float lv[8];
    #pragma unroll
    for (int i = 0; i < 8; i++) lv[i] = cp[i * 64 + l];

    float topv[8]; int topi[8];
    #pragma unroll
    for (int kk = 0; kk < 8; kk++) {
        float m = lv[0];
        #pragma unroll
        for (int i = 1; i < 8; i++) m = fmaxf(m, lv[i]);
        #pragma unroll
        for (int d = 1; d < 64; d <<= 1) m = fmaxf(m, __shfl_xor(m, d));
        topv[kk] = m;
        topi[kk] = (int)(__float_as_uint(m) & 0x3FFFu);
        #pragma unroll
        for (int i = 0; i < 8; i++) lv[i] = (lv[i] == m) ? -1e31f : lv[i];
    }
    const float mx = topv[0];
    float e[8]; float ssum = 0.f;
    #pragma unroll
    for (int kk = 0; kk < 8; kk++) { e[kk] = __expf(topv[kk] - mx); ssum += e[kk]; }
    const float inv = 1.f / ssum;

    float4 acc[4];
    #pragma unroll
    for (int ch = 0; ch < 4; ch++) acc[ch] = float4{0.f, 0.f, 0.f, 0.f};
    #pragma unroll
    for (int kk = 0; kk < 8; kk++) {
        const float wk = e[kk] * inv;
        const float* vp = kV + ((size_t)topi[kk] << 10);
        #pragma unroll
        for (int ch = 0; ch < 4; ch++) {
            float4 v = *(const float4*)(vp + ch * 256 + l * 4);
            acc[ch].x += wk * v.x; acc[ch].y += wk * v.y;
            acc[ch].z += wk * v.z; acc[ch].w += wk * v.w;
        }
    }
    float* op = out + ((size_t)tok << 10);
    #pragma unroll
    for (int ch = 0; ch < 4; ch++) {
        float4 o = *(const float4*)(op + ch * 256 + l * 4);
        o.x += acc[ch].x; o.y += acc[ch].y; o.z += acc[ch].z; o.w += acc[ch].w;
        *(float4*)(op + ch * 256 + l * 4) = o;
    }
}

extern "C" void kernel_launch(void* const* d_in, const int* in_sizes, int n_in,
                              void* d_out, int out_size, void* d_ws, size_t ws_size,
                              hipStream_t stream) {
    const float* x    = (const float*)d_in[0];
    const float* imp  = (const float*)d_in[1];
    const float* Wc   = (const float*)d_in[2];
    const float* WQr  = (const float*)d_in[3];
    const float* WKr  = (const float*)d_in[4];
    const float* WVr  = (const float*)d_in[5];
    const float* Wm   = (const float*)d_in[6];
    const float* cneu = (const float*)d_in[7];
    const float* epool= (const float*)d_in[8];
    const float* kK   = (const float*)d_in[9];
    const float* kV   = (const float*)d_in[10];
    const float* WO   = (const float*)d_in[11];
    const float* ln1s = (const float*)d_in[12];
    const float* ln1b = (const float*)d_in[13];
    const float* ln2s = (const float*)d_in[14];
    const float* ln2b = (const float*)d_in[15];
    float* out = (float*)d_out;

    float* ws = (float*)d_ws;
    size_t o = 0;
    float* n1    = ws + o; o += (size_t)BD * SD * DM;            // fp32, reused as n2
    unsigned short* n1b = (unsigned short*)(ws + o); o += (size_t)BD * SD * DM / 2;  // bf16, reused as n2b
    float* lgt   = ws + o; o += (size_t)BD * SD * 192;
    float* wpref = ws + o; o += (size_t)BD * SD * 160;
    float* dense = ws + o; o += (size_t)BD * 224;
    int*   ridx  = (int*)(ws + o); o += (size_t)BD * 5 * 8;
    float* rw    = ws + o; o += (size_t)BD * 5 * 8;
    float* Wcat  = ws + o; o += (size_t)1024 * 192;
    float* scomp = ws + o; o += (size_t)BD * DM * RK;            // fp32, reused for sc_m
    unsigned short* scompT = (unsigned short*)(ws + o); o += (size_t)BD * RK * DM / 2;
    float* EQ    = ws + o; o += (size_t)BD * RK * DM;
    float* EK    = ws + o; o += (size_t)BD * RK * DM;
    float* EV    = ws + o; o += (size_t)BD * RK * DM;
    unsigned short* EQt = (unsigned short*)(ws + o); o += (size_t)BD * RK * DM / 2;
    unsigned short* EKt = (unsigned short*)(ws + o); o += (size_t)BD * RK * DM / 2;
    unsigned short* EVt = (unsigned short*)(ws + o); o += (size_t)BD * RK * DM / 2;
    unsigned short* hb  = (unsigned short*)(ws + o); o += (size_t)BD * SD * RK / 2;
    unsigned short* Qb16 = (unsigned short*)(ws + o); o += (size_t)BD * SD * DM / 2;
    unsigned short* Kb16 = (unsigned short*)(ws + o); o += (size_t)BD * SD * DM / 2;
    unsigned short* Vb16 = (unsigned short*)(ws + o); o += (size_t)BD * SD * DM / 2;
    unsigned short* attnb = (unsigned short*)(ws + o); o += (size_t)BD * SD * DM / 2;
    unsigned short* WOt = (unsigned short*)(ws + o); o += (size_t)DM * DM / 2;
    unsigned short* kKb = (unsigned short*)(ws + o); o += (size_t)NK * RK / 2;
    unsigned short* Qmb = (unsigned short*)(ws + o); o += (size_t)BD * SD * RK / 2;
    float* cand = ws + o; o += (size_t)BD * SD * 512;

    const int NTOK = BD * SD;

    // independent prep
    concatw_kernel<<<768, 256, 0, stream>>>(Wc, WQr, WKr, WVr, Wcat);
    tcvt_kernel<<<dim3(16, 16, 1), 256, 0, stream>>>(WO, WOt, DM, DM, 0, 0);
    cvt_bf16_kernel<<<(NK * RK / 4) / 256, 256, 0, stream>>>(kK, kKb, 0.0883883476483184f, NK * RK / 4);

    // phase 1
    ln_kernel<<<NTOK, 256, 0, stream>>>(x, ln1s, ln1b, n1, n1b);
    mm64_kernel<<<dim3(3, NTOK / 64, 1), 256, 0, stream>>>(n1, Wcat, lgt, 192, DM);
    softpref_kernel<<<NTOK / 64, 256, 0, stream>>>(lgt, imp, wpref);
    reduce_pref<<<BD * 160, 256, 0, stream>>>(wpref, dense, 160, 0);
    topk_kernel<<<1, 64, 0, stream>>>(dense, ridx, rw, 0, 4);
    combine4_kernel<<<1024, 256, 0, stream>>>(cneu, ridx, rw, 0, 8, scomp);
    combine4_kernel<<<1024, 256, 0, stream>>>(epool, ridx, rw, 1, 4, EQ);
    combine4_kernel<<<1024, 256, 0, stream>>>(epool, ridx, rw, 2, 4, EK);
    combine4_kernel<<<1024, 256, 0, stream>>>(epool, ridx, rw, 3, 4, EV);
    tcvt_kernel<<<dim3(2, 16, BD), 256, 0, stream>>>(scomp, scompT, DM, RK,
        (long long)DM * RK, (long long)RK * DM);
    tcvt_kernel<<<dim3(16, 2, BD), 256, 0, stream>>>(EQ, EQt, RK, DM,
        (long long)RK * DM, (long long)RK * DM);
    tcvt_kernel<<<dim3(16, 2, BD), 256, 0, stream>>>(EK, EKt, RK, DM,
        (long long)RK * DM, (long long)RK * DM);
    tcvt_kernel<<<dim3(16, 2, BD), 256, 0, stream>>>(EV, EVt, RK, DM,
        (long long)RK * DM, (long long)RK * DM);
    // h = n1 @ scomp  -> bf16
    gemm_bf16<1, 0><<<dim3(1, 8, BD), 256, 0, stream>>>(n1b, scompT, nullptr, hb,
        SD, RK, DM, (long long)SD * DM, (long long)RK * DM, (long long)SD * RK);
    // Q/K/V = h @ E -> bf16
    gemm_bf16<1, 0><<<dim3(8, 8, BD), 256, 0, stream>>>(hb, EQt, nullptr, Qb16,
        SD, DM, RK, (long long)SD * RK, (long long)DM * RK, (long long)SD * DM);
    gemm_bf16<1, 0><<<dim3(8, 8, BD), 256, 0, stream>>>(hb, EKt, nullptr, Kb16,
        SD, DM, RK, (long long)SD * RK, (long long)DM * RK, (long long)SD * DM);
    gemm_bf16<1, 0><<<dim3(8, 8, BD), 256, 0, stream>>>(hb, EVt, nullptr, Vb16,
        SD, DM, RK, (long long)SD * RK, (long long)DM * RK, (long long)SD * DM);
    attn_mfma_kernel<<<dim3(SD / 64, NH, BD), 256, 0, stream>>>(Qb16, Kb16, Vb16, attnb);
    // out = x + attn @ WO
    gemm_bf16<0, 1><<<dim3(8, 64, 1), 256, 0, stream>>>(attnb, WOt, x, out,
        NTOK, DM, DM, 0, 0, 0);

    // phase 2
    ln_kernel<<<NTOK, 256, 0, stream>>>(out, ln2s, ln2b, n1, n1b);
    mm64_kernel<<<dim3(1, NTOK / 64, 1), 256, 0, stream>>>(n1, Wm, lgt, 64, DM);
    softm_kernel<<<NTOK / 256, 256, 0, stream>>>(lgt, imp, wpref);
    reduce_pref<<<BD * 64, 256, 0, stream>>>(wpref, dense, 64, 160);
    topk_kernel<<<1, 64, 0, stream>>>(dense, ridx, rw, 4, 1);
    combine4_kernel<<<1024, 256, 0, stream>>>(cneu, ridx, rw, 4, 8, scomp);
    tcvt_kernel<<<dim3(2, 16, BD), 256, 0, stream>>>(scomp, scompT, DM, RK,
        (long long)DM * RK, (long long)RK * DM);
    // Qm = n2 @ sc_m -> bf16 (1/sqrt(128) folded into kKb)
    gemm_bf16<1, 0><<<dim3(1, 8, BD), 256, 0, stream>>>(n1b, scompT, nullptr, Qmb,
        SD, RK, DM, (long long)SD * DM, (long long)RK * DM, (long long)SD * RK);
    know_score_kernel<<<NTOK / 32, 512, 0, stream>>>(Qmb, kKb, cand);
    know_out_kernel<<<NTOK / 4, 256, 0, stream>>>(cand, kV, out);
}

// Round 5
// 916.637 us; speedup vs baseline: 7.1188x; 1.0482x over previous
//
#include <hip/hip_runtime.h>
#include <hip/hip_bf16.h>

#define BD 8
#define SD 1024
#define DM 1024
#define NH 16
#define DH 64
#define RK 128
#define NK 16384

typedef __attribute__((ext_vector_type(8))) short bf16x8;
typedef __attribute__((ext_vector_type(4))) float f32x4;

__device__ __forceinline__ unsigned short f2b(float f) {
    unsigned u = __float_as_uint(f);
    unsigned r = (u + 0x7FFFu + ((u >> 16) & 1u)) >> 16;
    return (unsigned short)r;
}

// ---------------- LayerNorm: fp32 + bf16 outputs ----------------
__global__ void __launch_bounds__(256) ln_kernel(const float* __restrict__ x,
                                                 const float* __restrict__ sc,
                                                 const float* __restrict__ bi,
                                                 float* __restrict__ out,
                                                 unsigned short* __restrict__ outb) {
    const int tok = blockIdx.x;
    __shared__ float xs[DM];
    __shared__ float red[256];
    const float* xp = x + (size_t)tok * DM;
    float s = 0.f;
    for (int i = threadIdx.x; i < DM; i += 256) { float v = xp[i]; xs[i] = v; s += v; }
    red[threadIdx.x] = s; __syncthreads();
    for (int st = 128; st; st >>= 1) { if (threadIdx.x < st) red[threadIdx.x] += red[threadIdx.x + st]; __syncthreads(); }
    float mu = red[0] * (1.f / DM);
    __syncthreads();
    float vs = 0.f;
    for (int i = threadIdx.x; i < DM; i += 256) { float d = xs[i] - mu; vs += d * d; }
    red[threadIdx.x] = vs; __syncthreads();
    for (int st = 128; st; st >>= 1) { if (threadIdx.x < st) red[threadIdx.x] += red[threadIdx.x + st]; __syncthreads(); }
    float rs = rsqrtf(red[0] * (1.f / DM) + 1e-5f);
    for (int i = threadIdx.x; i < DM; i += 256) {
        float v = (xs[i] - mu) * rs * sc[i] + bi[i];
        out[(size_t)tok * DM + i] = v;
        outb[(size_t)tok * DM + i] = f2b(v);
    }
}

// ---------------- concat router weights into [1024][192] ----------------
__global__ void __launch_bounds__(256) concatw_kernel(const float* __restrict__ Wc,
                                                      const float* __restrict__ WQr,
                                                      const float* __restrict__ WKr,
                                                      const float* __restrict__ WVr,
                                                      float* __restrict__ Wcat) {
    const int i = blockIdx.x * 256 + threadIdx.x;
    if (i >= 1024 * 192) return;
    const int d = i / 192, c = i % 192;
    float v = 0.f;
    if (c < 64)       v = Wc[d * 64 + c];
    else if (c < 96)  v = WQr[d * 32 + c - 64];
    else if (c < 128) v = WKr[d * 32 + c - 96];
    else if (c < 160) v = WVr[d * 32 + c - 128];
    Wcat[i] = v;
}

// ---------------- fp32 GEMM (router logits only) ----------------
__global__ void __launch_bounds__(256) mm64_kernel(const float* __restrict__ A,
                                                   const float* __restrict__ Bm,
                                                   float* __restrict__ C,
                                                   int N, int Kd) {
    __shared__ float As[16][65];
    __shared__ float Bs[16][64];
    const int t = threadIdx.x;
    const int tx = t % 16, ty = t / 16;
    const int row0 = blockIdx.y * 64, col0 = blockIdx.x * 64;
    const int lc = t % 16, lr = t / 16;
    const int bn = t % 64, bk = t / 64;
    float acc[4][4] = {};
    for (int k0 = 0; k0 < Kd; k0 += 16) {
        #pragma unroll
        for (int i = 0; i < 4; i++)
            As[lc][lr + 16 * i] = A[(size_t)(row0 + lr + 16 * i) * Kd + k0 + lc];
        #pragma unroll
        for (int i = 0; i < 4; i++)
            Bs[bk + 4 * i][bn] = Bm[(size_t)(k0 + bk + 4 * i) * N + col0 + bn];
        __syncthreads();
        #pragma unroll
        for (int k = 0; k < 16; k++) {
            float a[4];
            #pragma unroll
            for (int i = 0; i < 4; i++) a[i] = As[k][ty * 4 + i];
            float4 bv = *(const float4*)&Bs[k][tx * 4];
            float b4[4] = {bv.x, bv.y, bv.z, bv.w};
            #pragma unroll
            for (int i = 0; i < 4; i++)
                #pragma unroll
                for (int j = 0; j < 4; j++) acc[i][j] += a[i] * b4[j];
        }
        __syncthreads();
    }
    #pragma unroll
    for (int i = 0; i < 4; i++) {
        const size_t r = row0 + ty * 4 + i;
        float4 v;
        float* vv = (float*)&v;
        #pragma unroll
        for (int j = 0; j < 4; j++) vv[j] = acc[i][j];
        *(float4*)&C[r * N + col0 + tx * 4] = v;
    }
}

// ---------------- phase-1 softmax prefs ----------------
__global__ void __launch_bounds__(256) softpref_kernel(const float* __restrict__ lgt,
                                                       const float* __restrict__ imp,
                                                       float* __restrict__ wpref) {
    const int tok = blockIdx.x * 64 + (threadIdx.x >> 2);
    const int sg = threadIdx.x & 3;
    const int o = (sg == 0) ? 0 : (64 + 32 * (sg - 1));
    const int n = (sg == 0) ? 64 : 32;
    const float* lp = lgt + (size_t)tok * 192 + o;
    float m = -1e30f;
    for (int i = 0; i < n; i++) m = fmaxf(m, lp[i]);
    float ss = 0.f;
    for (int i = 0; i < n; i++) ss += __expf(lp[i] - m);
    const float scl = imp[tok] / ss;
    float* wp = wpref + (size_t)tok * 160 + o;
    for (int i = 0; i < n; i++) wp[i] = __expf(lp[i] - m) * scl;
}

// ---------------- phase-2 softmax prefs ----------------
__global__ void __launch_bounds__(256) softm_kernel(const float* __restrict__ lgt,
                                                    const float* __restrict__ imp,
                                                    float* __restrict__ wpref) {
    const int tok = blockIdx.x * 256 + threadIdx.x;
    const float* lp = lgt + (size_t)tok * 64;
    float m = -1e30f;
    for (int i = 0; i < 64; i++) m = fmaxf(m, lp[i]);
    float ss = 0.f;
    for (int i = 0; i < 64; i++) ss += __expf(lp[i] - m);
    const float scl = imp[tok] / ss;
    for (int i = 0; i < 64; i++) wpref[(size_t)tok * 64 + i] = __expf(lp[i] - m) * scl;
}

// ---------------- deterministic reduce over S ----------------
__global__ void __launch_bounds__(256) reduce_pref(const float* __restrict__ wpref,
                                                   float* __restrict__ dense,
                                                   int ncols, int outoff) {
    const int b = blockIdx.x / ncols, c = blockIdx.x % ncols;
    __shared__ float red[256];
    float s = 0.f;
    for (int si = threadIdx.x; si < SD; si += 256)
        s += wpref[((size_t)(b * SD + si)) * ncols + c];
    red[threadIdx.x] = s; __syncthreads();
    for (int st = 128; st; st >>= 1) { if (threadIdx.x < st) red[threadIdx.x] += red[threadIdx.x + st]; __syncthreads(); }
    if (threadIdx.x == 0) dense[b * 224 + outoff + c] = red[0];
}

// ---------------- top-k sparsify + renormalize ----------------
__global__ void topk_kernel(const float* __restrict__ dense,
                            int* __restrict__ ridx, float* __restrict__ rw,
                            int r0, int nr) {
    const int t = threadIdx.x;
    if (t >= BD * nr) return;
    const int b = t / nr, r = r0 + (t % nr);
    const int offs[5] = {0, 64, 96, 128, 160};
    const int ns[5]   = {64, 32, 32, 32, 64};
    const int ks[5]   = {8, 4, 4, 4, 8};
    const float* dv = dense + b * 224 + offs[r];
    const int n = ns[r], k = ks[r];
    unsigned long long mask = 0;
    float vals[8]; int idxs[8];
    float ssum = 0.f;
    for (int kk = 0; kk < k; kk++) {
        float best = -1e30f; int bi = 0;
        for (int i = 0; i < n; i++)
            if (!((mask >> i) & 1ull) && dv[i] > best) { best = dv[i]; bi = i; }
        mask |= 1ull << bi;
        vals[kk] = best; idxs[kk] = bi; ssum += best;
    }
    float inv = 1.f / (ssum + 1e-8f);
    for (int kk = 0; kk < 8; kk++) {
        ridx[(b * 5 + r) * 8 + kk] = (kk < k) ? idxs[kk] : 0;
        rw[(b * 5 + r) * 8 + kk]   = (kk < k) ? vals[kk] * inv : 0.f;
    }
}

// ---------------- fused mixture + transpose + bf16: outT[c][r] = sum w*pool[i][r][c] ----------------
__global__ void __launch_bounds__(256) combine_t_kernel(const float* __restrict__ pool,
                                                        const int* __restrict__ ridx,
                                                        const float* __restrict__ rw,
                                                        int router, int kc,
                                                        unsigned short* __restrict__ outT,
                                                        int Rp, int Cp) {
    const int b = blockIdx.z;
    const int r0 = blockIdx.y * 64, c0 = blockIdx.x * 64;
    __shared__ float ls[64][65];
    const int* ii = ridx + (b * 5 + router) * 8;
    const float* ww = rw + (b * 5 + router) * 8;
    const int t = threadIdx.x;
    const int rr = t >> 4, cc = (t & 15) * 4;
    #pragma unroll
    for (int p = 0; p < 4; p++) {
        const int r = rr + p * 16;
        float4 acc = {0.f, 0.f, 0.f, 0.f};
        for (int kk = 0; kk < kc; kk++) {
            const float w = ww[kk];
            float4 v = *(const float4*)&pool[((size_t)ii[kk] * Rp + r0 + r) * Cp + c0 + cc];
            acc.x += w * v.x; acc.y += w * v.y; acc.z += w * v.z; acc.w += w * v.w;
        }
        ls[r][cc] = acc.x; ls[r][cc + 1] = acc.y; ls[r][cc + 2] = acc.z; ls[r][cc + 3] = acc.w;
    }
    __syncthreads();
    unsigned short* op = outT + (size_t)b * Rp * Cp;
    #pragma unroll
    for (int q = 0; q < 2; q++) {
        const int c = (t >> 3) + q * 32;
        const int r8 = (t & 7) * 8;
        union { unsigned short s[8]; bf16x8 v; } u;
        #pragma unroll
        for (int j = 0; j < 8; j++) u.s[j] = f2b(ls[r8 + j][c]);
        *(bf16x8*)(op + (size_t)(c0 + c) * Rp + r0 + r8) = u.v;
    }
}

// ---------------- tile transpose + fp32->bf16 (WO only) ----------------
__global__ void __launch_bounds__(256) tcvt_kernel(const float* __restrict__ src,
                                                   unsigned short* __restrict__ dst,
                                                   int R, int Cc) {
    __shared__ float ls[64][65];
    const int r0 = blockIdx.y * 64, c0 = blockIdx.x * 64;
    const int t = threadIdx.x;
    #pragma unroll
    for (int p = 0; p < 16; p++) {
        const int e = p * 256 + t;
        const int r = e >> 6, c = e & 63;
        ls[r][c] = src[(size_t)(r0 + r) * Cc + c0 + c];
    }
    __syncthreads();
    #pragma unroll
    for (int p = 0; p < 16; p++) {
        const int e = p * 256 + t;
        const int c = e >> 6, r = e & 63;
        dst[(size_t)(c0 + c) * R + r0 + r] = f2b(ls[r][c]);
    }
}

// ---------------- fp32 -> bf16 convert with scale ----------------
__global__ void __launch_bounds__(256) cvt_bf16_kernel(const float* __restrict__ src,
                                                       unsigned short* __restrict__ dst,
                                                       float scale, int n4) {
    const int i = blockIdx.x * 256 + threadIdx.x;
    if (i >= n4) return;
    float4 v = ((const float4*)src)[i];
    unsigned r0 = (unsigned)f2b(v.x * scale) | ((unsigned)f2b(v.y * scale) << 16);
    unsigned r1 = (unsigned)f2b(v.z * scale) | ((unsigned)f2b(v.w * scale) << 16);
    uint2 o; o.x = r0; o.y = r1;
    ((uint2*)dst)[i] = o;
}

// ---------------- bf16 MFMA GEMM: C = A[M][K] @ Bt[N][K]^T (+X), 128x128 tile ----------------
template<int OUTB, int HASX>
__global__ void __launch_bounds__(256) gemm_bf16(const unsigned short* __restrict__ A,
                                                 const unsigned short* __restrict__ Bt,
                                                 const float* __restrict__ X,
                                                 void* __restrict__ Cv,
                                                 int M, int N, int K,
                                                 long long sA, long long sB, long long sC) {
    const int bz = blockIdx.z;
    const unsigned short* Ab = A + (size_t)bz * sA;
    const unsigned short* Btb = Bt + (size_t)bz * sB;
    const int row0 = blockIdx.y * 128, col0 = blockIdx.x * 128;
    const int t = threadIdx.x;
    const int w = t >> 6, l = t & 63, lq = l & 15, lg = l >> 4;
    const int wr = w >> 1, wc = w & 1;
    __shared__ unsigned short As[128 * 64];
    __shared__ unsigned short Bs[128 * 64];
    f32x4 acc[4][4];
    #pragma unroll
    for (int mi = 0; mi < 4; mi++)
        #pragma unroll
        for (int ni = 0; ni < 4; ni++) acc[mi][ni] = f32x4{0.f, 0.f, 0.f, 0.f};

    for (int k0 = 0; k0 < K; k0 += 64) {
        __syncthreads();
        #pragma unroll
        for (int p = 0; p < 4; p++) {
            const int e = t * 8 + p * 2048;
            const int row = e >> 6, col = e & 63;
            bf16x8 va = *(const bf16x8*)(Ab + (size_t)(row0 + row) * K + k0 + col);
            *(bf16x8*)((char*)As + ((row * 128 + col * 2) ^ ((row & 7) << 4))) = va;
            bf16x8 vb = *(const bf16x8*)(Btb + (size_t)(col0 + row) * K + k0 + col);
            *(bf16x8*)((char*)Bs + ((row * 128 + col * 2) ^ ((row & 7) << 4))) = vb;
        }
        __syncthreads();
        #pragma unroll
        for (int kk = 0; kk < 2; kk++) {
            bf16x8 af[4], bg[4];
            #pragma unroll
            for (int mi = 0; mi < 4; mi++) {
                const int r = wr * 64 + mi * 16 + lq;
                af[mi] = *(const bf16x8*)((const char*)As + ((r * 128 + lg * 16 + kk * 64) ^ ((r & 7) << 4)));
            }
            #pragma unroll
            for (int ni = 0; ni < 4; ni++) {
                const int r = wc * 64 + ni * 16 + lq;
                bg[ni] = *(const bf16x8*)((const char*)Bs + ((r * 128 + lg * 16 + kk * 64) ^ ((r & 7) << 4)));
            }
            #pragma unroll
            for (int mi = 0; mi < 4; mi++)
                #pragma unroll
                for (int ni = 0; ni < 4; ni++)
                    acc[mi][ni] = __builtin_amdgcn_mfma_f32_16x16x32_bf16(af[mi], bg[ni], acc[mi][ni], 0, 0, 0);
        }
    }
    #pragma unroll
    for (int mi = 0; mi < 4; mi++) {
        #pragma unroll
        for (int j = 0; j < 4; j++) {
            const int row = row0 + wr * 64 + mi * 16 + lg * 4 + j;
            #pragma unroll
            for (int ni = 0; ni < 4; ni++) {
                const int col = col0 + wc * 64 + ni * 16 + lq;
                float v = acc[mi][ni][j];
                if (HASX) v += X[(size_t)row * N + col];
                if (OUTB) ((unsigned short*)Cv)[(size_t)bz * sC + (size_t)row * N + col] = f2b(v);
                else      ((float*)Cv)[(size_t)bz * sC + (size_t)row * N + col] = v;
            }
        }
    }
}

// ---------------- flash attention, 128-row Q tiles, 8 waves ----------------
__global__ void __launch_bounds__(512) attn_mfma_kernel(const unsigned short* __restrict__ Q,
                                                        const unsigned short* __restrict__ K,
                                                        const unsigned short* __restrict__ V,
                                                        unsigned short* __restrict__ O) {
    const int qt = blockIdx.x, hh = blockIdx.y, b = blockIdx.z;
    const int t = threadIdx.x;
    const int w = t >> 6;
    const int l = t & 63;
    const int lq = l & 15;
    const int lg = l >> 4;

    __shared__ unsigned short ks[64 * 64];
    __shared__ unsigned short vt[64 * 64];
    __shared__ unsigned short pl[8][16 * 64];

    const size_t base = (size_t)b * SD * DM + (size_t)hh * DH;

    bf16x8 aq[2];
    {
        const int qrow = qt * 128 + w * 16 + lq;
        const unsigned short* qp = Q + base + (size_t)qrow * DM + lg * 8;
        aq[0] = *(const bf16x8*)(qp);
        aq[1] = *(const bf16x8*)(qp + 32);
    }

    f32x4 o_acc[4];
    #pragma unroll
    for (int dt = 0; dt < 4; dt++) o_acc[dt] = f32x4{0.f, 0.f, 0.f, 0.f};
    float m_r[4] = {-1e30f, -1e30f, -1e30f, -1e30f};
    float s_r[4] = {0.f, 0.f, 0.f, 0.f};

    const int ntile = 2 * qt + 2;
    const int mymax = qt * 128 + w * 16 + 15;
    const int srow = t >> 3, scol = (t & 7) * 8;
    for (int kt = 0; kt < ntile; kt++) {
        __syncthreads();
        {
            bf16x8 kv = *(const bf16x8*)(K + base + (size_t)(kt * 64 + srow) * DM + scol);
            *(bf16x8*)((char*)ks + ((srow * 128 + scol * 2) ^ ((srow & 7) << 4))) = kv;
            bf16x8 vv = *(const bf16x8*)(V + base + (size_t)(kt * 64 + srow) * DM + scol);
            #pragma unroll
            for (int j2 = 0; j2 < 8; j2++) {
                const int d = scol + j2;
                *(unsigned short*)((char*)vt + ((d * 128 + srow * 2) ^ (((d >> 1) & 7) << 4))) =
                    (unsigned short)vv[j2];
            }
        }
        __syncthreads();
        if (kt * 64 > mymax) continue;

        const f32x4 zero4 = {0.f, 0.f, 0.f, 0.f};
        f32x4 sacc[4];
        #pragma unroll
        for (int ct = 0; ct < 4; ct++) {
            const int krow = ct * 16 + lq;
            bf16x8 b0 = *(const bf16x8*)((const char*)ks + ((krow * 128 + lg * 16) ^ ((lq & 7) << 4)));
            bf16x8 b1 = *(const bf16x8*)((const char*)ks + ((krow * 128 + lg * 16 + 64) ^ ((lq & 7) << 4)));
            f32x4 s = __builtin_amdgcn_mfma_f32_16x16x32_bf16(aq[0], b0, zero4, 0, 0, 0);
            s = __builtin_amdgcn_mfma_f32_16x16x32_bf16(aq[1], b1, s, 0, 0, 0);
            sacc[ct] = s;
        }

        float tm[4];
        #pragma unroll
        for (int j = 0; j < 4; j++) {
            const int qg = qt * 128 + w * 16 + lg * 4 + j;
            float mx = -1e30f;
            #pragma unroll
            for (int ct = 0; ct < 4; ct++) {
                const int kg = kt * 64 + ct * 16 + lq;
                float v = sacc[ct][j] * 0.125f;
                v = (kg <= qg) ? v : -1e30f;
                sacc[ct][j] = v;
                mx = fmaxf(mx, v);
            }
            #pragma unroll
            for (int d = 1; d < 16; d <<= 1) mx = fmaxf(mx, __shfl_xor(mx, d));
            tm[j] = mx;
        }
        #pragma unroll
        for (int j = 0; j < 4; j++) {
            const float nm = fmaxf(m_r[j], tm[j]);
            const float so = __expf(m_r[j] - nm);
            m_r[j] = nm;
            float rs = 0.f;
            const int prow = lg * 4 + j;
            #pragma unroll
            for (int ct = 0; ct < 4; ct++) {
                const float p = __expf(sacc[ct][j] - nm);
                rs += p;
                const int byteoff = ((prow * 128) + (ct * 16 + lq) * 2) ^ ((prow & 7) << 4);
                *(unsigned short*)((char*)&pl[w][0] + byteoff) = f2b(p);
            }
            #pragma unroll
            for (int d = 1; d < 16; d <<= 1) rs += __shfl_xor(rs, d);
            s_r[j] = s_r[j] * so + rs;
            #pragma unroll
            for (int dt = 0; dt < 4; dt++) o_acc[dt][j] *= so;
        }
        asm volatile("s_waitcnt lgkmcnt(0)" ::: "memory");

        #pragma unroll
        for (int c = 0; c < 2; c++) {
            bf16x8 pa = *(const bf16x8*)((const char*)&pl[w][0] +
                          ((lq * 128 + lg * 16 + 64 * c) ^ ((lq & 7) << 4)));
            #pragma unroll
            for (int dt = 0; dt < 4; dt++) {
                const int dd = dt * 16 + lq;
                bf16x8 bv = *(const bf16x8*)((const char*)vt +
                              ((dd * 128 + lg * 16 + 64 * c) ^ (((dd >> 1) & 7) << 4)));
                o_acc[dt] = __builtin_amdgcn_mfma_f32_16x16x32_bf16(pa, bv, o_acc[dt], 0, 0, 0);
            }
        }
    }

    #pragma unroll
    for (int j = 0; j < 4; j++) {
        const float inv = 1.f / s_r[j];
        const int qrow = qt * 128 + w * 16 + lg * 4 + j;
        unsigned short* op = O + base + (size_t)qrow * DM;
        #pragma unroll
        for (int dt = 0; dt < 4; dt++) op[dt * 16 + lq] = f2b(o_acc[dt][j] * inv);
    }
}

// ---------------- knowledge scores: barrier-free wave-private tiles, branchless top-8 ----------------
// 512 blocks x 16 tokens; wave w owns keys [w*2048, (w+1)*2048) with private 8KB LDS tile
__global__ void __launch_bounds__(512) know_score_kernel(const unsigned short* __restrict__ Qmb,
                                                         const unsigned short* __restrict__ kKb,
                                                         float* __restrict__ cand) {
    const int t = threadIdx.x;
    const int w = t >> 6, l = t & 63, lq = l & 15, lg = l >> 4;
    const int tok0 = blockIdx.x * 16;
    __shared__ unsigned short ks[8][32 * 128];   // 64 KB, wave-private tiles

    bf16x8 aq[4];
    {
        const unsigned short* qp = Qmb + (size_t)(tok0 + lq) * 128 + lg * 8;
        #pragma unroll
        for (int c = 0; c < 4; c++) aq[c] = *(const bf16x8*)(qp + c * 32);
    }

    float tv[4][8];
    float mn[4];
    #pragma unroll
    for (int j = 0; j < 4; j++) {
        #pragma unroll
        for (int s = 0; s < 8; s++) tv[j][s] = __uint_as_float(0xF2000000u | (unsigned)s);
        mn[j] = __uint_as_float(0xF2000007u);
    }

    const unsigned short* gsrc = kKb + (((size_t)w * 2048) << 7) + l * 8;
    unsigned short* myks = &ks[w][0];

    bf16x8 vreg[8];
    #pragma unroll
    for (int p = 0; p < 8; p++) vreg[p] = *(const bf16x8*)(gsrc + p * 512);

    for (int kt = 0; kt < 64; kt++) {
        // stage current tile regs -> private LDS (same-wave DS ops are in-order; no barriers)
        #pragma unroll
        for (int p = 0; p < 8; p++) {
            const int e = p * 512 + l * 8;
            const int row = e >> 7;
            *(bf16x8*)((char*)myks + ((e * 2) ^ ((row & 7) << 4))) = vreg[p];
        }
        // prefetch next tile into regs (latency hides under compute below)
        if (kt < 63) {
            const unsigned short* src2 = gsrc + (size_t)(kt + 1) * 4096;
            #pragma unroll
            for (int p = 0; p < 8; p++) vreg[p] = *(const bf16x8*)(src2 + p * 512);
        }
        #pragma unroll
        for (int ct = 0; ct < 2; ct++) {
            const int row = ct * 16 + lq;
            const char* kb = (const char*)myks + row * 256;
            const int sw = (row & 7) << 4;
            f32x4 s = {0.f, 0.f, 0.f, 0.f};
            #pragma unroll
            for (int c = 0; c < 4; c++) {
                bf16x8 bv = *(const bf16x8*)(kb + ((c * 64 + lg * 16) ^ sw));
                s = __builtin_amdgcn_mfma_f32_16x16x32_bf16(aq[c], bv, s, 0, 0, 0);
            }
            const unsigned keyb = (unsigned)(w * 2048 + kt * 32 + ct * 16 + lq);
            #pragma unroll
            for (int j = 0; j < 4; j++) {
                unsigned u = __float_as_uint(s[j]);
                float pv = __uint_as_float((u & 0xFFFFC000u) | keyb);
                pv = fmaxf(pv, mn[j]);            // pv<=mn -> replace min with itself (no-op)
                #pragma unroll
                for (int ss = 0; ss < 8; ss++)
                    tv[j][ss] = (tv[j][ss] == mn[j]) ? pv : tv[j][ss];
                float a0 = fminf(tv[j][0], tv[j][1]);
                float a1 = fminf(tv[j][2], tv[j][3]);
                float a2 = fminf(tv[j][4], tv[j][5]);
                float a3 = fminf(tv[j][6], tv[j][7]);
                mn[j] = fminf(fminf(a0, a1), fminf(a2, a3));
            }
        }
    }
    #pragma unroll
    for (int j = 0; j < 4; j++) {
        const int tok = tok0 + lg * 4 + j;
        float* cp = cand + ((size_t)tok << 10) + w * 128 + lq * 8;
        #pragma unroll
        for (int ss = 0; ss < 8; ss++) cp[ss] = tv[j][ss];
    }
}

// ---------------- knowledge merge + V gather: one wave per token, 1024 candidates ----------------
__global__ void __launch_bounds__(256) know_out_kernel(const float* __restrict__ cand,
                                                       const float* __restrict__ kV,
                                                       float* __restrict__ out) {
    const int t = threadIdx.x, w = t >> 6, l = t & 63;
    const int tok = blockIdx.x * 4 + w;
    const float* cp = cand + ((size_t)tok << 10);
    float lv[16];
    #pragma unroll
    for (int i = 0; i < 16; i++) lv[i] = cp[i * 64 + l];

    float topv[8]; int topi[8];
    #pragma unroll
    for (int kk = 0; kk < 8; kk++) {
        float m = lv[0];
        #pragma unroll
        for (int i = 1; i < 16; i++) m = fmaxf(m, lv[i]);
        #pragma unroll
        for (int d = 1; d < 64; d <<= 1) m = fmaxf(m, __shfl_xor(m, d));
        topv[kk] = m;
        topi[kk] = (int)(__float_as_uint(m) & 0x3FFFu);
        #pragma unroll
        for (int i = 0; i < 16; i++) lv[i] = (lv[i] == m) ? -1e31f : lv[i];
    }
    const float mx = topv[0];
    float e[8]; float ssum = 0.f;
    #pragma unroll
    for (int kk = 0; kk < 8; kk++) { e[kk] = __expf(topv[kk] - mx); ssum += e[kk]; }
    const float inv = 1.f / ssum;

    float4 acc[4];
    #pragma unroll
    for (int ch = 0; ch < 4; ch++) acc[ch] = float4{0.f, 0.f, 0.f, 0.f};
    #pragma unroll
    for (int kk = 0; kk < 8; kk++) {
        const float wk = e[kk] * inv;
        const float* vp = kV + ((size_t)topi[kk] << 10);
        #pragma unroll
        for (int ch = 0; ch < 4; ch++) {
            float4 v = *(const float4*)(vp + ch * 256 + l * 4);
            acc[ch].x += wk * v.x; acc[ch].y += wk * v.y;
            acc[ch].z += wk * v.z; acc[ch].w += wk * v.w;
        }
    }
    float* op = out + ((size_t)tok << 10);
    #pragma unroll
    for (int ch = 0; ch < 4; ch++) {
        float4 o = *(const float4*)(op + ch * 256 + l * 4);
        o.x += acc[ch].x; o.y += acc[ch].y; o.z += acc[ch].z; o.w += acc[ch].w;
        *(float4*)(op + ch * 256 + l * 4) = o;
    }
}

extern "C" void kernel_launch(void* const* d_in, const int* in_sizes, int n_in,
                              void* d_out, int out_size, void* d_ws, size_t ws_size,
                              hipStream_t stream) {
    const float* x    = (const float*)d_in[0];
    const float* imp  = (const float*)d_in[1];
    const float* Wc   = (const float*)d_in[2];
    const float* WQr  = (const float*)d_in[3];
    const float* WKr  = (const float*)d_in[4];
    const float* WVr  = (const float*)d_in[5];
    const float* Wm   = (const float*)d_in[6];
    const float* cneu = (const float*)d_in[7];
    const float* epool= (const float*)d_in[8];
    const float* kK   = (const float*)d_in[9];
    const float* kV   = (const float*)d_in[10];
    const float* WO   = (const float*)d_in[11];
    const float* ln1s = (const float*)d_in[12];
    const float* ln1b = (const float*)d_in[13];
    const float* ln2s = (const float*)d_in[14];
    const float* ln2b = (const float*)d_in[15];
    float* out = (float*)d_out;

    float* ws = (float*)d_ws;
    size_t o = 0;
    float* n1    = ws + o; o += (size_t)BD * SD * DM;
    unsigned short* n1b = (unsigned short*)(ws + o); o += (size_t)BD * SD * DM / 2;
    float* lgt   = ws + o; o += (size_t)BD * SD * 192;
    float* wpref = ws + o; o += (size_t)BD * SD * 160;
    float* dense = ws + o; o += (size_t)BD * 224;
    int*   ridx  = (int*)(ws + o); o += (size_t)BD * 5 * 8;
    float* rw    = ws + o; o += (size_t)BD * 5 * 8;
    float* Wcat  = ws + o; o += (size_t)1024 * 192;
    unsigned short* scompT = (unsigned short*)(ws + o); o += (size_t)BD * RK * DM / 2;
    unsigned short* EQt = (unsigned short*)(ws + o); o += (size_t)BD * RK * DM / 2;
    unsigned short* EKt = (unsigned short*)(ws + o); o += (size_t)BD * RK * DM / 2;
    unsigned short* EVt = (unsigned short*)(ws + o); o += (size_t)BD * RK * DM / 2;
    unsigned short* hb  = (unsigned short*)(ws + o); o += (size_t)BD * SD * RK / 2;
    unsigned short* Qb16 = (unsigned short*)(ws + o); o += (size_t)BD * SD * DM / 2;
    unsigned short* Kb16 = (unsigned short*)(ws + o); o += (size_t)BD * SD * DM / 2;
    unsigned short* Vb16 = (unsigned short*)(ws + o); o += (size_t)BD * SD * DM / 2;
    unsigned short* attnb = (unsigned short*)(ws + o); o += (size_t)BD * SD * DM / 2;
    unsigned short* WOt = (unsigned short*)(ws + o); o += (size_t)DM * DM / 2;
    unsigned short* kKb = (unsigned short*)(ws + o); o += (size_t)NK * RK / 2;
    unsigned short* Qmb = (unsigned short*)(ws + o); o += (size_t)BD * SD * RK / 2;
    float* cand = ws + o; o += (size_t)BD * SD * 1024;

    const int NTOK = BD * SD;

    // independent prep
    concatw_kernel<<<768, 256, 0, stream>>>(Wc, WQr, WKr, WVr, Wcat);
    tcvt_kernel<<<dim3(16, 16, 1), 256, 0, stream>>>(WO, WOt, DM, DM);
    cvt_bf16_kernel<<<(NK * RK / 4) / 256, 256, 0, stream>>>(kK, kKb, 0.0883883476483184f, NK * RK / 4);

    // phase 1
    ln_kernel<<<NTOK, 256, 0, stream>>>(x, ln1s, ln1b, n1, n1b);
    mm64_kernel<<<dim3(3, NTOK / 64, 1), 256, 0, stream>>>(n1, Wcat, lgt, 192, DM);
    softpref_kernel<<<NTOK / 64, 256, 0, stream>>>(lgt, imp, wpref);
    reduce_pref<<<BD * 160, 256, 0, stream>>>(wpref, dense, 160, 0);
    topk_kernel<<<1, 64, 0, stream>>>(dense, ridx, rw, 0, 4);
    combine_t_kernel<<<dim3(2, 16, BD), 256, 0, stream>>>(cneu, ridx, rw, 0, 8, scompT, DM, RK);
    combine_t_kernel<<<dim3(16, 2, BD), 256, 0, stream>>>(epool, ridx, rw, 1, 4, EQt, RK, DM);
    combine_t_kernel<<<dim3(16, 2, BD), 256, 0, stream>>>(epool, ridx, rw, 2, 4, EKt, RK, DM);
    combine_t_kernel<<<dim3(16, 2, BD), 256, 0, stream>>>(epool, ridx, rw, 3, 4, EVt, RK, DM);
    gemm_bf16<1, 0><<<dim3(1, 8, BD), 256, 0, stream>>>(n1b, scompT, nullptr, hb,
        SD, RK, DM, (long long)SD * DM, (long long)RK * DM, (long long)SD * RK);
    gemm_bf16<1, 0><<<dim3(8, 8, BD), 256, 0, stream>>>(hb, EQt, nullptr, Qb16,
        SD, DM, RK, (long long)SD * RK, (long long)DM * RK, (long long)SD * DM);
    gemm_bf16<1, 0><<<dim3(8, 8, BD), 256, 0, stream>>>(hb, EKt, nullptr, Kb16,
        SD, DM, RK, (long long)SD * RK, (long long)DM * RK, (long long)SD * DM);
    gemm_bf16<1, 0><<<dim3(8, 8, BD), 256, 0, stream>>>(hb, EVt, nullptr, Vb16,
        SD, DM, RK, (long long)SD * RK, (long long)DM * RK, (long long)SD * DM);
    attn_mfma_kernel<<<dim3(SD / 128, NH, BD), 512, 0, stream>>>(Qb16, Kb16, Vb16, attnb);
    gemm_bf16<0, 1><<<dim3(8, 64, 1), 256, 0, stream>>>(attnb, WOt, x, out,
        NTOK, DM, DM, 0, 0, 0);

    // phase 2
    ln_kernel<<<NTOK, 256, 0, stream>>>(out, ln2s, ln2b, n1, n1b);
    mm64_kernel<<<dim3(1, NTOK / 64, 1), 256, 0, stream>>>(n1, Wm, lgt, 64, DM);
    softm_kernel<<<NTOK / 256, 256, 0, stream>>>(lgt, imp, wpref);
    reduce_pref<<<BD * 64, 256, 0, stream>>>(wpref, dense, 64, 160);
    topk_kernel<<<1, 64, 0, stream>>>(dense, ridx, rw, 4, 1);
    combine_t_kernel<<<dim3(2, 16, BD), 256, 0, stream>>>(cneu, ridx, rw, 4, 8, scompT, DM, RK);
    gemm_bf16<1, 0><<<dim3(1, 8, BD), 256, 0, stream>>>(n1b, scompT, nullptr, Qmb,
        SD, RK, DM, (long long)SD * DM, (long long)RK * DM, (long long)SD * RK);
    know_score_kernel<<<NTOK / 16, 512, 0, stream>>>(Qmb, kKb, cand);
    know_out_kernel<<<NTOK / 4, 256, 0, stream>>>(cand, kV, out);
}

// Round 6
// 872.508 us; speedup vs baseline: 7.4789x; 1.0506x over previous
//
#include <hip/hip_runtime.h>
#include <hip/hip_bf16.h>

#define BD 8
#define SD 1024
#define DM 1024
#define NH 16
#define DH 64
#define RK 128
#define NK 16384

typedef __attribute__((ext_vector_type(8))) short bf16x8;
typedef __attribute__((ext_vector_type(4))) float f32x4;

__device__ __forceinline__ unsigned short f2b(float f) {
    unsigned u = __float_as_uint(f);
    unsigned r = (u + 0x7FFFu + ((u >> 16) & 1u)) >> 16;
    return (unsigned short)r;
}

// ---------------- LayerNorm: fp32 + bf16 outputs ----------------
__global__ void __launch_bounds__(256) ln_kernel(const float* __restrict__ x,
                                                 const float* __restrict__ sc,
                                                 const float* __restrict__ bi,
                                                 float* __restrict__ out,
                                                 unsigned short* __restrict__ outb) {
    const int tok = blockIdx.x;
    __shared__ float xs[DM];
    __shared__ float red[256];
    const float* xp = x + (size_t)tok * DM;
    float s = 0.f;
    for (int i = threadIdx.x; i < DM; i += 256) { float v = xp[i]; xs[i] = v; s += v; }
    red[threadIdx.x] = s; __syncthreads();
    for (int st = 128; st; st >>= 1) { if (threadIdx.x < st) red[threadIdx.x] += red[threadIdx.x + st]; __syncthreads(); }
    float mu = red[0] * (1.f / DM);
    __syncthreads();
    float vs = 0.f;
    for (int i = threadIdx.x; i < DM; i += 256) { float d = xs[i] - mu; vs += d * d; }
    red[threadIdx.x] = vs; __syncthreads();
    for (int st = 128; st; st >>= 1) { if (threadIdx.x < st) red[threadIdx.x] += red[threadIdx.x + st]; __syncthreads(); }
    float rs = rsqrtf(red[0] * (1.f / DM) + 1e-5f);
    for (int i = threadIdx.x; i < DM; i += 256) {
        float v = (xs[i] - mu) * rs * sc[i] + bi[i];
        out[(size_t)tok * DM + i] = v;
        outb[(size_t)tok * DM + i] = f2b(v);
    }
}

// ---------------- concat router weights into [1024][192] ----------------
__global__ void __launch_bounds__(256) concatw_kernel(const float* __restrict__ Wc,
                                                      const float* __restrict__ WQr,
                                                      const float* __restrict__ WKr,
                                                      const float* __restrict__ WVr,
                                                      float* __restrict__ Wcat) {
    const int i = blockIdx.x * 256 + threadIdx.x;
    if (i >= 1024 * 192) return;
    const int d = i / 192, c = i % 192;
    float v = 0.f;
    if (c < 64)       v = Wc[d * 64 + c];
    else if (c < 96)  v = WQr[d * 32 + c - 64];
    else if (c < 128) v = WKr[d * 32 + c - 96];
    else if (c < 160) v = WVr[d * 32 + c - 128];
    Wcat[i] = v;
}

// ---------------- fp32 GEMM (router logits only) ----------------
__global__ void __launch_bounds__(256) mm64_kernel(const float* __restrict__ A,
                                                   const float* __restrict__ Bm,
                                                   float* __restrict__ C,
                                                   int N, int Kd) {
    __shared__ float As[16][65];
    __shared__ float Bs[16][64];
    const int t = threadIdx.x;
    const int tx = t % 16, ty = t / 16;
    const int row0 = blockIdx.y * 64, col0 = blockIdx.x * 64;
    const int lc = t % 16, lr = t / 16;
    const int bn = t % 64, bk = t / 64;
    float acc[4][4] = {};
    for (int k0 = 0; k0 < Kd; k0 += 16) {
        #pragma unroll
        for (int i = 0; i < 4; i++)
            As[lc][lr + 16 * i] = A[(size_t)(row0 + lr + 16 * i) * Kd + k0 + lc];
        #pragma unroll
        for (int i = 0; i < 4; i++)
            Bs[bk + 4 * i][bn] = Bm[(size_t)(k0 + bk + 4 * i) * N + col0 + bn];
        __syncthreads();
        #pragma unroll
        for (int k = 0; k < 16; k++) {
            float a[4];
            #pragma unroll
            for (int i = 0; i < 4; i++) a[i] = As[k][ty * 4 + i];
            float4 bv = *(const float4*)&Bs[k][tx * 4];
            float b4[4] = {bv.x, bv.y, bv.z, bv.w};
            #pragma unroll
            for (int i = 0; i < 4; i++)
                #pragma unroll
                for (int j = 0; j < 4; j++) acc[i][j] += a[i] * b4[j];
        }
        __syncthreads();
    }
    #pragma unroll
    for (int i = 0; i < 4; i++) {
        const size_t r = row0 + ty * 4 + i;
        float4 v;
        float* vv = (float*)&v;
        #pragma unroll
        for (int j = 0; j < 4; j++) vv[j] = acc[i][j];
        *(float4*)&C[r * N + col0 + tx * 4] = v;
    }
}

// ---------------- phase-1 softmax prefs ----------------
__global__ void __launch_bounds__(256) softpref_kernel(const float* __restrict__ lgt,
                                                       const float* __restrict__ imp,
                                                       float* __restrict__ wpref) {
    const int tok = blockIdx.x * 64 + (threadIdx.x >> 2);
    const int sg = threadIdx.x & 3;
    const int o = (sg == 0) ? 0 : (64 + 32 * (sg - 1));
    const int n = (sg == 0) ? 64 : 32;
    const float* lp = lgt + (size_t)tok * 192 + o;
    float m = -1e30f;
    for (int i = 0; i < n; i++) m = fmaxf(m, lp[i]);
    float ss = 0.f;
    for (int i = 0; i < n; i++) ss += __expf(lp[i] - m);
    const float scl = imp[tok] / ss;
    float* wp = wpref + (size_t)tok * 160 + o;
    for (int i = 0; i < n; i++) wp[i] = __expf(lp[i] - m) * scl;
}

// ---------------- phase-2 softmax prefs ----------------
__global__ void __launch_bounds__(256) softm_kernel(const float* __restrict__ lgt,
                                                    const float* __restrict__ imp,
                                                    float* __restrict__ wpref) {
    const int tok = blockIdx.x * 256 + threadIdx.x;
    const float* lp = lgt + (size_t)tok * 64;
    float m = -1e30f;
    for (int i = 0; i < 64; i++) m = fmaxf(m, lp[i]);
    float ss = 0.f;
    for (int i = 0; i < 64; i++) ss += __expf(lp[i] - m);
    const float scl = imp[tok] / ss;
    for (int i = 0; i < 64; i++) wpref[(size_t)tok * 64 + i] = __expf(lp[i] - m) * scl;
}

// ---------------- deterministic reduce over S ----------------
__global__ void __launch_bounds__(256) reduce_pref(const float* __restrict__ wpref,
                                                   float* __restrict__ dense,
                                                   int ncols, int outoff) {
    const int b = blockIdx.x / ncols, c = blockIdx.x % ncols;
    __shared__ float red[256];
    float s = 0.f;
    for (int si = threadIdx.x; si < SD; si += 256)
        s += wpref[((size_t)(b * SD + si)) * ncols + c];
    red[threadIdx.x] = s; __syncthreads();
    for (int st = 128; st; st >>= 1) { if (threadIdx.x < st) red[threadIdx.x] += red[threadIdx.x + st]; __syncthreads(); }
    if (threadIdx.x == 0) dense[b * 224 + outoff + c] = red[0];
}

// ---------------- top-k sparsify + renormalize ----------------
__global__ void topk_kernel(const float* __restrict__ dense,
                            int* __restrict__ ridx, float* __restrict__ rw,
                            int r0, int nr) {
    const int t = threadIdx.x;
    if (t >= BD * nr) return;
    const int b = t / nr, r = r0 + (t % nr);
    const int offs[5] = {0, 64, 96, 128, 160};
    const int ns[5]   = {64, 32, 32, 32, 64};
    const int ks[5]   = {8, 4, 4, 4, 8};
    const float* dv = dense + b * 224 + offs[r];
    const int n = ns[r], k = ks[r];
    unsigned long long mask = 0;
    float vals[8]; int idxs[8];
    float ssum = 0.f;
    for (int kk = 0; kk < k; kk++) {
        float best = -1e30f; int bi = 0;
        for (int i = 0; i < n; i++)
            if (!((mask >> i) & 1ull) && dv[i] > best) { best = dv[i]; bi = i; }
        mask |= 1ull << bi;
        vals[kk] = best; idxs[kk] = bi; ssum += best;
    }
    float inv = 1.f / (ssum + 1e-8f);
    for (int kk = 0; kk < 8; kk++) {
        ridx[(b * 5 + r) * 8 + kk] = (kk < k) ? idxs[kk] : 0;
        rw[(b * 5 + r) * 8 + kk]   = (kk < k) ? vals[kk] * inv : 0.f;
    }
}

// ---------------- fused mixture + transpose + bf16 ----------------
__global__ void __launch_bounds__(256) combine_t_kernel(const float* __restrict__ pool,
                                                        const int* __restrict__ ridx,
                                                        const float* __restrict__ rw,
                                                        int router, int kc,
                                                        unsigned short* __restrict__ outT,
                                                        int Rp, int Cp) {
    const int b = blockIdx.z;
    const int r0 = blockIdx.y * 64, c0 = blockIdx.x * 64;
    __shared__ float ls[64][65];
    const int* ii = ridx + (b * 5 + router) * 8;
    const float* ww = rw + (b * 5 + router) * 8;
    const int t = threadIdx.x;
    const int rr = t >> 4, cc = (t & 15) * 4;
    #pragma unroll
    for (int p = 0; p < 4; p++) {
        const int r = rr + p * 16;
        float4 acc = {0.f, 0.f, 0.f, 0.f};
        for (int kk = 0; kk < kc; kk++) {
            const float w = ww[kk];
            float4 v = *(const float4*)&pool[((size_t)ii[kk] * Rp + r0 + r) * Cp + c0 + cc];
            acc.x += w * v.x; acc.y += w * v.y; acc.z += w * v.z; acc.w += w * v.w;
        }
        ls[r][cc] = acc.x; ls[r][cc + 1] = acc.y; ls[r][cc + 2] = acc.z; ls[r][cc + 3] = acc.w;
    }
    __syncthreads();
    unsigned short* op = outT + (size_t)b * Rp * Cp;
    #pragma unroll
    for (int q = 0; q < 2; q++) {
        const int c = (t >> 3) + q * 32;
        const int r8 = (t & 7) * 8;
        union { unsigned short s[8]; bf16x8 v; } u;
        #pragma unroll
        for (int j = 0; j < 8; j++) u.s[j] = f2b(ls[r8 + j][c]);
        *(bf16x8*)(op + (size_t)(c0 + c) * Rp + r0 + r8) = u.v;
    }
}

// ---------------- tile transpose + fp32->bf16 (WO only) ----------------
__global__ void __launch_bounds__(256) tcvt_kernel(const float* __restrict__ src,
                                                   unsigned short* __restrict__ dst,
                                                   int R, int Cc) {
    __shared__ float ls[64][65];
    const int r0 = blockIdx.y * 64, c0 = blockIdx.x * 64;
    const int t = threadIdx.x;
    #pragma unroll
    for (int p = 0; p < 16; p++) {
        const int e = p * 256 + t;
        const int r = e >> 6, c = e & 63;
        ls[r][c] = src[(size_t)(r0 + r) * Cc + c0 + c];
    }
    __syncthreads();
    #pragma unroll
    for (int p = 0; p < 16; p++) {
        const int e = p * 256 + t;
        const int c = e >> 6, r = e & 63;
        dst[(size_t)(c0 + c) * R + r0 + r] = f2b(ls[r][c]);
    }
}

// ---------------- fp32 -> bf16 convert with scale ----------------
__global__ void __launch_bounds__(256) cvt_bf16_kernel(const float* __restrict__ src,
                                                       unsigned short* __restrict__ dst,
                                                       float scale, int n4) {
    const int i = blockIdx.x * 256 + threadIdx.x;
    if (i >= n4) return;
    float4 v = ((const float4*)src)[i];
    unsigned r0 = (unsigned)f2b(v.x * scale) | ((unsigned)f2b(v.y * scale) << 16);
    unsigned r1 = (unsigned)f2b(v.z * scale) | ((unsigned)f2b(v.w * scale) << 16);
    uint2 o; o.x = r0; o.y = r1;
    ((uint2*)dst)[i] = o;
}

// ---------------- bf16 MFMA GEMM: C = A[M][K] @ Bt[N][K]^T (+X), 128x128 tile ----------------
template<int OUTB, int HASX>
__global__ void __launch_bounds__(256) gemm_bf16(const unsigned short* __restrict__ A,
                                                 const unsigned short* __restrict__ Bt,
                                                 const float* __restrict__ X,
                                                 void* __restrict__ Cv,
                                                 int M, int N, int K,
                                                 long long sA, long long sB, long long sC) {
    const int bz = blockIdx.z;
    const unsigned short* Ab = A + (size_t)bz * sA;
    const unsigned short* Btb = Bt + (size_t)bz * sB;
    const int row0 = blockIdx.y * 128, col0 = blockIdx.x * 128;
    const int t = threadIdx.x;
    const int w = t >> 6, l = t & 63, lq = l & 15, lg = l >> 4;
    const int wr = w >> 1, wc = w & 1;
    __shared__ unsigned short As[128 * 64];
    __shared__ unsigned short Bs[128 * 64];
    f32x4 acc[4][4];
    #pragma unroll
    for (int mi = 0; mi < 4; mi++)
        #pragma unroll
        for (int ni = 0; ni < 4; ni++) acc[mi][ni] = f32x4{0.f, 0.f, 0.f, 0.f};

    for (int k0 = 0; k0 < K; k0 += 64) {
        __syncthreads();
        #pragma unroll
        for (int p = 0; p < 4; p++) {
            const int e = t * 8 + p * 2048;
            const int row = e >> 6, col = e & 63;
            bf16x8 va = *(const bf16x8*)(Ab + (size_t)(row0 + row) * K + k0 + col);
            *(bf16x8*)((char*)As + ((row * 128 + col * 2) ^ ((row & 7) << 4))) = va;
            bf16x8 vb = *(const bf16x8*)(Btb + (size_t)(col0 + row) * K + k0 + col);
            *(bf16x8*)((char*)Bs + ((row * 128 + col * 2) ^ ((row & 7) << 4))) = vb;
        }
        __syncthreads();
        #pragma unroll
        for (int kk = 0; kk < 2; kk++) {
            bf16x8 af[4], bg[4];
            #pragma unroll
            for (int mi = 0; mi < 4; mi++) {
                const int r = wr * 64 + mi * 16 + lq;
                af[mi] = *(const bf16x8*)((const char*)As + ((r * 128 + lg * 16 + kk * 64) ^ ((r & 7) << 4)));
            }
            #pragma unroll
            for (int ni = 0; ni < 4; ni++) {
                const int r = wc * 64 + ni * 16 + lq;
                bg[ni] = *(const bf16x8*)((const char*)Bs + ((r * 128 + lg * 16 + kk * 64) ^ ((r & 7) << 4)));
            }
            #pragma unroll
            for (int mi = 0; mi < 4; mi++)
                #pragma unroll
                for (int ni = 0; ni < 4; ni++)
                    acc[mi][ni] = __builtin_amdgcn_mfma_f32_16x16x32_bf16(af[mi], bg[ni], acc[mi][ni], 0, 0, 0);
        }
    }
    #pragma unroll
    for (int mi = 0; mi < 4; mi++) {
        #pragma unroll
        for (int j = 0; j < 4; j++) {
            const int row = row0 + wr * 64 + mi * 16 + lg * 4 + j;
            #pragma unroll
            for (int ni = 0; ni < 4; ni++) {
                const int col = col0 + wc * 64 + ni * 16 + lq;
                float v = acc[mi][ni][j];
                if (HASX) v += X[(size_t)row * N + col];
                if (OUTB) ((unsigned short*)Cv)[(size_t)bz * sC + (size_t)row * N + col] = f2b(v);
                else      ((float*)Cv)[(size_t)bz * sC + (size_t)row * N + col] = v;
            }
        }
    }
}

// ---------------- flash attention, 128-row Q tiles, 8 waves ----------------
__global__ void __launch_bounds__(512) attn_mfma_kernel(const unsigned short* __restrict__ Q,
                                                        const unsigned short* __restrict__ K,
                                                        const unsigned short* __restrict__ V,
                                                        unsigned short* __restrict__ O) {
    const int qt = blockIdx.x, hh = blockIdx.y, b = blockIdx.z;
    const int t = threadIdx.x;
    const int w = t >> 6;
    const int l = t & 63;
    const int lq = l & 15;
    const int lg = l >> 4;

    __shared__ unsigned short ks[64 * 64];
    __shared__ unsigned short vt[64 * 64];
    __shared__ unsigned short pl[8][16 * 64];

    const size_t base = (size_t)b * SD * DM + (size_t)hh * DH;

    bf16x8 aq[2];
    {
        const int qrow = qt * 128 + w * 16 + lq;
        const unsigned short* qp = Q + base + (size_t)qrow * DM + lg * 8;
        aq[0] = *(const bf16x8*)(qp);
        aq[1] = *(const bf16x8*)(qp + 32);
    }

    f32x4 o_acc[4];
    #pragma unroll
    for (int dt = 0; dt < 4; dt++) o_acc[dt] = f32x4{0.f, 0.f, 0.f, 0.f};
    float m_r[4] = {-1e30f, -1e30f, -1e30f, -1e30f};
    float s_r[4] = {0.f, 0.f, 0.f, 0.f};

    const int ntile = 2 * qt + 2;
    const int mymax = qt * 128 + w * 16 + 15;
    const int srow = t >> 3, scol = (t & 7) * 8;
    for (int kt = 0; kt < ntile; kt++) {
        __syncthreads();
        {
            bf16x8 kv = *(const bf16x8*)(K + base + (size_t)(kt * 64 + srow) * DM + scol);
            *(bf16x8*)((char*)ks + ((srow * 128 + scol * 2) ^ ((srow & 7) << 4))) = kv;
            bf16x8 vv = *(const bf16x8*)(V + base + (size_t)(kt * 64 + srow) * DM + scol);
            #pragma unroll
            for (int j2 = 0; j2 < 8; j2++) {
                const int d = scol + j2;
                *(unsigned short*)((char*)vt + ((d * 128 + srow * 2) ^ (((d >> 1) & 7) << 4))) =
                    (unsigned short)vv[j2];
            }
        }
        __syncthreads();
        if (kt * 64 > mymax) continue;

        const f32x4 zero4 = {0.f, 0.f, 0.f, 0.f};
        f32x4 sacc[4];
        #pragma unroll
        for (int ct = 0; ct < 4; ct++) {
            const int krow = ct * 16 + lq;
            bf16x8 b0 = *(const bf16x8*)((const char*)ks + ((krow * 128 + lg * 16) ^ ((lq & 7) << 4)));
            bf16x8 b1 = *(const bf16x8*)((const char*)ks + ((krow * 128 + lg * 16 + 64) ^ ((lq & 7) << 4)));
            f32x4 s = __builtin_amdgcn_mfma_f32_16x16x32_bf16(aq[0], b0, zero4, 0, 0, 0);
            s = __builtin_amdgcn_mfma_f32_16x16x32_bf16(aq[1], b1, s, 0, 0, 0);
            sacc[ct] = s;
        }

        float tm[4];
        #pragma unroll
        for (int j = 0; j < 4; j++) {
            const int qg = qt * 128 + w * 16 + lg * 4 + j;
            float mx = -1e30f;
            #pragma unroll
            for (int ct = 0; ct < 4; ct++) {
                const int kg = kt * 64 + ct * 16 + lq;
                float v = sacc[ct][j] * 0.125f;
                v = (kg <= qg) ? v : -1e30f;
                sacc[ct][j] = v;
                mx = fmaxf(mx, v);
            }
            #pragma unroll
            for (int d = 1; d < 16; d <<= 1) mx = fmaxf(mx, __shfl_xor(mx, d));
            tm[j] = mx;
        }
        #pragma unroll
        for (int j = 0; j < 4; j++) {
            const float nm = fmaxf(m_r[j], tm[j]);
            const float so = __expf(m_r[j] - nm);
            m_r[j] = nm;
            float rs = 0.f;
            const int prow = lg * 4 + j;
            #pragma unroll
            for (int ct = 0; ct < 4; ct++) {
                const float p = __expf(sacc[ct][j] - nm);
                rs += p;
                const int byteoff = ((prow * 128) + (ct * 16 + lq) * 2) ^ ((prow & 7) << 4);
                *(unsigned short*)((char*)&pl[w][0] + byteoff) = f2b(p);
            }
            #pragma unroll
            for (int d = 1; d < 16; d <<= 1) rs += __shfl_xor(rs, d);
            s_r[j] = s_r[j] * so + rs;
            #pragma unroll
            for (int dt = 0; dt < 4; dt++) o_acc[dt][j] *= so;
        }
        asm volatile("s_waitcnt lgkmcnt(0)" ::: "memory");

        #pragma unroll
        for (int c = 0; c < 2; c++) {
            bf16x8 pa = *(const bf16x8*)((const char*)&pl[w][0] +
                          ((lq * 128 + lg * 16 + 64 * c) ^ ((lq & 7) << 4)));
            #pragma unroll
            for (int dt = 0; dt < 4; dt++) {
                const int dd = dt * 16 + lq;
                bf16x8 bv = *(const bf16x8*)((const char*)vt +
                              ((dd * 128 + lg * 16 + 64 * c) ^ (((dd >> 1) & 7) << 4)));
                o_acc[dt] = __builtin_amdgcn_mfma_f32_16x16x32_bf16(pa, bv, o_acc[dt], 0, 0, 0);
            }
        }
    }

    #pragma unroll
    for (int j = 0; j < 4; j++) {
        const float inv = 1.f / s_r[j];
        const int qrow = qt * 128 + w * 16 + lg * 4 + j;
        unsigned short* op = O + base + (size_t)qrow * DM;
        #pragma unroll
        for (int dt = 0; dt < 4; dt++) op[dt * 16 + lq] = f2b(o_acc[dt][j] * inv);
    }
}

// ---------------- knowledge scores: sorted-list + bitonic batch merge ----------------
// 512 blocks x 16 tokens; wave w owns keys [w*2048,(w+1)*2048), private 8KB LDS tile.
// Per (lane, token-row): sorted-desc top-8 list; every 2 kt merge a sorted-4 batch
// via pointwise-max (bitonic valley) + 12-CE cleanup. ~9.5 VALU/score vs ~26.
#define CE(a, b) { float hi_ = fmaxf(a, b), lo_ = fminf(a, b); a = hi_; b = lo_; }
__global__ void __launch_bounds__(512, 4) know_score_kernel(const unsigned short* __restrict__ Qmb,
                                                            const unsigned short* __restrict__ kKb,
                                                            float* __restrict__ cand) {
    const int t = threadIdx.x;
    const int w = t >> 6, l = t & 63, lq = l & 15, lg = l >> 4;
    const int tok0 = blockIdx.x * 16;
    __shared__ unsigned short ks[8][32 * 128];   // 64 KB, wave-private tiles

    bf16x8 aq[4];
    {
        const unsigned short* qp = Qmb + (size_t)(tok0 + lq) * 128 + lg * 8;
        #pragma unroll
        for (int c = 0; c < 4; c++) aq[c] = *(const bf16x8*)(qp + c * 32);
    }

    // sorted-descending top-8 lists (distinct negative sentinels; larger mantissa = more negative)
    float L[4][8];
    #pragma unroll
    for (int j = 0; j < 4; j++)
        #pragma unroll
        for (int s = 0; s < 8; s++) L[j][s] = __uint_as_float(0xF2000000u | (unsigned)s);

    const unsigned short* gsrc = kKb + (((size_t)w * 2048) << 7) + l * 8;
    unsigned short* myks = &ks[w][0];

    bf16x8 vreg[8];
    #pragma unroll
    for (int p = 0; p < 8; p++) vreg[p] = *(const bf16x8*)(gsrc + p * 512);

    for (int t2 = 0; t2 < 32; t2++) {
        float B[4][4];
        #pragma unroll
        for (int sub = 0; sub < 2; sub++) {
            const int kt = t2 * 2 + sub;
            // stage current tile regs -> private LDS (same-wave DS ops in order; no barriers)
            #pragma unroll
            for (int p = 0; p < 8; p++) {
                const int e = p * 512 + l * 8;
                const int row = e >> 7;
                *(bf16x8*)((char*)myks + ((e * 2) ^ ((row & 7) << 4))) = vreg[p];
            }
            if (kt < 63) {
                const unsigned short* src2 = gsrc + (size_t)(kt + 1) * 4096;
                #pragma unroll
                for (int p = 0; p < 8; p++) vreg[p] = *(const bf16x8*)(src2 + p * 512);
            }
            #pragma unroll
            for (int ct = 0; ct < 2; ct++) {
                const int row = ct * 16 + lq;
                const char* kb = (const char*)myks + row * 256;
                const int sw = (row & 7) << 4;
                f32x4 s = {0.f, 0.f, 0.f, 0.f};
                #pragma unroll
                for (int c = 0; c < 4; c++) {
                    bf16x8 bv = *(const bf16x8*)(kb + ((c * 64 + lg * 16) ^ sw));
                    s = __builtin_amdgcn_mfma_f32_16x16x32_bf16(aq[c], bv, s, 0, 0, 0);
                }
                const unsigned keyb = (unsigned)(w * 2048 + kt * 32 + ct * 16 + lq);
                #pragma unroll
                for (int j = 0; j < 4; j++) {
                    unsigned u = __float_as_uint(s[j]);
                    B[j][sub * 2 + ct] = __uint_as_float((u & 0xFFFFC000u) | keyb);
                }
            }
        }
        #pragma unroll
        for (int j = 0; j < 4; j++) {
            // sort-4 descending
            CE(B[j][0], B[j][2]); CE(B[j][1], B[j][3]);
            CE(B[j][0], B[j][1]); CE(B[j][2], B[j][3]);
            CE(B[j][1], B[j][2]);
            // merge: top-8 of (L desc-8) U (B desc-4) -> bitonic valley
            L[j][4] = fmaxf(L[j][4], B[j][3]);
            L[j][5] = fmaxf(L[j][5], B[j][2]);
            L[j][6] = fmaxf(L[j][6], B[j][1]);
            L[j][7] = fmaxf(L[j][7], B[j][0]);
            // bitonic cleanup -> sorted descending
            CE(L[j][0], L[j][4]); CE(L[j][1], L[j][5]); CE(L[j][2], L[j][6]); CE(L[j][3], L[j][7]);
            CE(L[j][0], L[j][2]); CE(L[j][1], L[j][3]); CE(L[j][4], L[j][6]); CE(L[j][5], L[j][7]);
            CE(L[j][0], L[j][1]); CE(L[j][2], L[j][3]); CE(L[j][4], L[j][5]); CE(L[j][6], L[j][7]);
        }
    }
    #pragma unroll
    for (int j = 0; j < 4; j++) {
        const int tok = tok0 + lg * 4 + j;
        float* cp = cand + ((size_t)tok << 10) + w * 128 + lq * 8;
        #pragma unroll
        for (int ss = 0; ss < 8; ss++) cp[ss] = L[j][ss];
    }
}
#undef CE

// ---------------- knowledge merge + V gather: one wave per token, 1024 candidates ----------------
__global__ void __launch_bounds__(256) know_out_kernel(const float* __restrict__ cand,
                                                       const float* __restrict__ kV,
                                                       float* __restrict__ out) {
    const int t = threadIdx.x, w = t >> 6, l = t & 63;
    const int tok = blockIdx.x * 4 + w;
    const float* cp = cand + ((size_t)tok << 10);
    float lv[16];
    #pragma unroll
    for (int i = 0; i < 16; i++) lv[i] = cp[i * 64 + l];

    float topv[8]; int topi[8];
    #pragma unroll
    for (int kk = 0; kk < 8; kk++) {
        float m = lv[0];
        #pragma unroll
        for (int i = 1; i < 16; i++) m = fmaxf(m, lv[i]);
        #pragma unroll
        for (int d = 1; d < 64; d <<= 1) m = fmaxf(m, __shfl_xor(m, d));
        topv[kk] = m;
        topi[kk] = (int)(__float_as_uint(m) & 0x3FFFu);
        #pragma unroll
        for (int i = 0; i < 16; i++) lv[i] = (lv[i] == m) ? -1e31f : lv[i];
    }
    const float mx = topv[0];
    float e[8]; float ssum = 0.f;
    #pragma unroll
    for (int kk = 0; kk < 8; kk++) { e[kk] = __expf(topv[kk] - mx); ssum += e[kk]; }
    const float inv = 1.f / ssum;

    float4 acc[4];
    #pragma unroll
    for (int ch = 0; ch < 4; ch++) acc[ch] = float4{0.f, 0.f, 0.f, 0.f};
    #pragma unroll
    for (int kk = 0; kk < 8; kk++) {
        const float wk = e[kk] * inv;
        const float* vp = kV + ((size_t)topi[kk] << 10);
        #pragma unroll
        for (int ch = 0; ch < 4; ch++) {
            float4 v = *(const float4*)(vp + ch * 256 + l * 4);
            acc[ch].x += wk * v.x; acc[ch].y += wk * v.y;
            acc[ch].z += wk * v.z; acc[ch].w += wk * v.w;
        }
    }
    float* op = out + ((size_t)tok << 10);
    #pragma unroll
    for (int ch = 0; ch < 4; ch++) {
        float4 o = *(const float4*)(op + ch * 256 + l * 4);
        o.x += acc[ch].x; o.y += acc[ch].y; o.z += acc[ch].z; o.w += acc[ch].w;
        *(float4*)(op + ch * 256 + l * 4) = o;
    }
}

extern "C" void kernel_launch(void* const* d_in, const int* in_sizes, int n_in,
                              void* d_out, int out_size, void* d_ws, size_t ws_size,
                              hipStream_t stream) {
    const float* x    = (const float*)d_in[0];
    const float* imp  = (const float*)d_in[1];
    const float* Wc   = (const float*)d_in[2];
    const float* WQr  = (const float*)d_in[3];
    const float* WKr  = (const float*)d_in[4];
    const float* WVr  = (const float*)d_in[5];
    const float* Wm   = (const float*)d_in[6];
    const float* cneu = (const float*)d_in[7];
    const float* epool= (const float*)d_in[8];
    const float* kK   = (const float*)d_in[9];
    const float* kV   = (const float*)d_in[10];
    const float* WO   = (const float*)d_in[11];
    const float* ln1s = (const float*)d_in[12];
    const float* ln1b = (const float*)d_in[13];
    const float* ln2s = (const float*)d_in[14];
    const float* ln2b = (const float*)d_in[15];
    float* out = (float*)d_out;

    float* ws = (float*)d_ws;
    size_t o = 0;
    float* n1    = ws + o; o += (size_t)BD * SD * DM;
    unsigned short* n1b = (unsigned short*)(ws + o); o += (size_t)BD * SD * DM / 2;
    float* lgt   = ws + o; o += (size_t)BD * SD * 192;
    float* wpref = ws + o; o += (size_t)BD * SD * 160;
    float* dense = ws + o; o += (size_t)BD * 224;
    int*   ridx  = (int*)(ws + o); o += (size_t)BD * 5 * 8;
    float* rw    = ws + o; o += (size_t)BD * 5 * 8;
    float* Wcat  = ws + o; o += (size_t)1024 * 192;
    unsigned short* scompT = (unsigned short*)(ws + o); o += (size_t)BD * RK * DM / 2;
    unsigned short* EQt = (unsigned short*)(ws + o); o += (size_t)BD * RK * DM / 2;
    unsigned short* EKt = (unsigned short*)(ws + o); o += (size_t)BD * RK * DM / 2;
    unsigned short* EVt = (unsigned short*)(ws + o); o += (size_t)BD * RK * DM / 2;
    unsigned short* hb  = (unsigned short*)(ws + o); o += (size_t)BD * SD * RK / 2;
    unsigned short* Qb16 = (unsigned short*)(ws + o); o += (size_t)BD * SD * DM / 2;
    unsigned short* Kb16 = (unsigned short*)(ws + o); o += (size_t)BD * SD * DM / 2;
    unsigned short* Vb16 = (unsigned short*)(ws + o); o += (size_t)BD * SD * DM / 2;
    unsigned short* attnb = (unsigned short*)(ws + o); o += (size_t)BD * SD * DM / 2;
    unsigned short* WOt = (unsigned short*)(ws + o); o += (size_t)DM * DM / 2;
    unsigned short* kKb = (unsigned short*)(ws + o); o += (size_t)NK * RK / 2;
    unsigned short* Qmb = (unsigned short*)(ws + o); o += (size_t)BD * SD * RK / 2;
    float* cand = ws + o; o += (size_t)BD * SD * 1024;

    const int NTOK = BD * SD;

    // independent prep
    concatw_kernel<<<768, 256, 0, stream>>>(Wc, WQr, WKr, WVr, Wcat);
    tcvt_kernel<<<dim3(16, 16, 1), 256, 0, stream>>>(WO, WOt, DM, DM);
    cvt_bf16_kernel<<<(NK * RK / 4) / 256, 256, 0, stream>>>(kK, kKb, 0.0883883476483184f, NK * RK / 4);

    // phase 1
    ln_kernel<<<NTOK, 256, 0, stream>>>(x, ln1s, ln1b, n1, n1b);
    mm64_kernel<<<dim3(3, NTOK / 64, 1), 256, 0, stream>>>(n1, Wcat, lgt, 192, DM);
    softpref_kernel<<<NTOK / 64, 256, 0, stream>>>(lgt, imp, wpref);
    reduce_pref<<<BD * 160, 256, 0, stream>>>(wpref, dense, 160, 0);
    topk_kernel<<<1, 64, 0, stream>>>(dense, ridx, rw, 0, 4);
    combine_t_kernel<<<dim3(2, 16, BD), 256, 0, stream>>>(cneu, ridx, rw, 0, 8, scompT, DM, RK);
    combine_t_kernel<<<dim3(16, 2, BD), 256, 0, stream>>>(epool, ridx, rw, 1, 4, EQt, RK, DM);
    combine_t_kernel<<<dim3(16, 2, BD), 256, 0, stream>>>(epool, ridx, rw, 2, 4, EKt, RK, DM);
    combine_t_kernel<<<dim3(16, 2, BD), 256, 0, stream>>>(epool, ridx, rw, 3, 4, EVt, RK, DM);
    gemm_bf16<1, 0><<<dim3(1, 8, BD), 256, 0, stream>>>(n1b, scompT, nullptr, hb,
        SD, RK, DM, (long long)SD * DM, (long long)RK * DM, (long long)SD * RK);
    gemm_bf16<1, 0><<<dim3(8, 8, BD), 256, 0, stream>>>(hb, EQt, nullptr, Qb16,
        SD, DM, RK, (long long)SD * RK, (long long)DM * RK, (long long)SD * DM);
    gemm_bf16<1, 0><<<dim3(8, 8, BD), 256, 0, stream>>>(hb, EKt, nullptr, Kb16,
        SD, DM, RK, (long long)SD * RK, (long long)DM * RK, (long long)SD * DM);
    gemm_bf16<1, 0><<<dim3(8, 8, BD), 256, 0, stream>>>(hb, EVt, nullptr, Vb16,
        SD, DM, RK, (long long)SD * RK, (long long)DM * RK, (long long)SD * DM);
    attn_mfma_kernel<<<dim3(SD / 128, NH, BD), 512, 0, stream>>>(Qb16, Kb16, Vb16, attnb);
    gemm_bf16<0, 1><<<dim3(8, 64, 1), 256, 0, stream>>>(attnb, WOt, x, out,
        NTOK, DM, DM, 0, 0, 0);

    // phase 2
    ln_kernel<<<NTOK, 256, 0, stream>>>(out, ln2s, ln2b, n1, n1b);
    mm64_kernel<<<dim3(1, NTOK / 64, 1), 256, 0, stream>>>(n1, Wm, lgt, 64, DM);
    softm_kernel<<<NTOK / 256, 256, 0, stream>>>(lgt, imp, wpref);
    reduce_pref<<<BD * 64, 256, 0, stream>>>(wpref, dense, 64, 160);
    topk_kernel<<<1, 64, 0, stream>>>(dense, ridx, rw, 4, 1);
    combine_t_kernel<<<dim3(2, 16, BD), 256, 0, stream>>>(cneu, ridx, rw, 4, 8, scompT, DM, RK);
    gemm_bf16<1, 0><<<dim3(1, 8, BD), 256, 0, stream>>>(n1b, scompT, nullptr, Qmb,
        SD, RK, DM, (long long)SD * DM, (long long)RK * DM, (long long)SD * RK);
    know_score_kernel<<<NTOK / 16, 512, 0, stream>>>(Qmb, kKb, cand);
    know_out_kernel<<<NTOK / 4, 256, 0, stream>>>(cand, kV, out);
}

// Round 8
// 822.491 us; speedup vs baseline: 7.9337x; 1.0608x over previous
//
#include <hip/hip_runtime.h>
#include <hip/hip_bf16.h>

#define BD 8
#define SD 1024
#define DM 1024
#define NH 16
#define DH 64
#define RK 128
#define NK 16384

typedef __attribute__((ext_vector_type(8))) short bf16x8;
typedef __attribute__((ext_vector_type(4))) float f32x4;

__device__ __forceinline__ unsigned short f2b(float f) {
    unsigned u = __float_as_uint(f);
    unsigned r = (u + 0x7FFFu + ((u >> 16) & 1u)) >> 16;
    return (unsigned short)r;
}

// ---------------- LayerNorm: fp32 + bf16 outputs ----------------
__global__ void __launch_bounds__(256) ln_kernel(const float* __restrict__ x,
                                                 const float* __restrict__ sc,
                                                 const float* __restrict__ bi,
                                                 float* __restrict__ out,
                                                 unsigned short* __restrict__ outb) {
    const int tok = blockIdx.x;
    __shared__ float xs[DM];
    __shared__ float red[256];
    const float* xp = x + (size_t)tok * DM;
    float s = 0.f;
    for (int i = threadIdx.x; i < DM; i += 256) { float v = xp[i]; xs[i] = v; s += v; }
    red[threadIdx.x] = s; __syncthreads();
    for (int st = 128; st; st >>= 1) { if (threadIdx.x < st) red[threadIdx.x] += red[threadIdx.x + st]; __syncthreads(); }
    float mu = red[0] * (1.f / DM);
    __syncthreads();
    float vs = 0.f;
    for (int i = threadIdx.x; i < DM; i += 256) { float d = xs[i] - mu; vs += d * d; }
    red[threadIdx.x] = vs; __syncthreads();
    for (int st = 128; st; st >>= 1) { if (threadIdx.x < st) red[threadIdx.x] += red[threadIdx.x + st]; __syncthreads(); }
    float rs = rsqrtf(red[0] * (1.f / DM) + 1e-5f);
    for (int i = threadIdx.x; i < DM; i += 256) {
        float v = (xs[i] - mu) * rs * sc[i] + bi[i];
        out[(size_t)tok * DM + i] = v;
        outb[(size_t)tok * DM + i] = f2b(v);
    }
}

// ---------------- concat router weights into [1024][192] ----------------
__global__ void __launch_bounds__(256) concatw_kernel(const float* __restrict__ Wc,
                                                      const float* __restrict__ WQr,
                                                      const float* __restrict__ WKr,
                                                      const float* __restrict__ WVr,
                                                      float* __restrict__ Wcat) {
    const int i = blockIdx.x * 256 + threadIdx.x;
    if (i >= 1024 * 192) return;
    const int d = i / 192, c = i % 192;
    float v = 0.f;
    if (c < 64)       v = Wc[d * 64 + c];
    else if (c < 96)  v = WQr[d * 32 + c - 64];
    else if (c < 128) v = WKr[d * 32 + c - 96];
    else if (c < 160) v = WVr[d * 32 + c - 128];
    Wcat[i] = v;
}

// ---------------- fp32 GEMM (router logits only) ----------------
__global__ void __launch_bounds__(256) mm64_kernel(const float* __restrict__ A,
                                                   const float* __restrict__ Bm,
                                                   float* __restrict__ C,
                                                   int N, int Kd) {
    __shared__ float As[16][65];
    __shared__ float Bs[16][64];
    const int t = threadIdx.x;
    const int tx = t % 16, ty = t / 16;
    const int row0 = blockIdx.y * 64, col0 = blockIdx.x * 64;
    const int lc = t % 16, lr = t / 16;
    const int bn = t % 64, bk = t / 64;
    float acc[4][4] = {};
    for (int k0 = 0; k0 < Kd; k0 += 16) {
        #pragma unroll
        for (int i = 0; i < 4; i++)
            As[lc][lr + 16 * i] = A[(size_t)(row0 + lr + 16 * i) * Kd + k0 + lc];
        #pragma unroll
        for (int i = 0; i < 4; i++)
            Bs[bk + 4 * i][bn] = Bm[(size_t)(k0 + bk + 4 * i) * N + col0 + bn];
        __syncthreads();
        #pragma unroll
        for (int k = 0; k < 16; k++) {
            float a[4];
            #pragma unroll
            for (int i = 0; i < 4; i++) a[i] = As[k][ty * 4 + i];
            float4 bv = *(const float4*)&Bs[k][tx * 4];
            float b4[4] = {bv.x, bv.y, bv.z, bv.w};
            #pragma unroll
            for (int i = 0; i < 4; i++)
                #pragma unroll
                for (int j = 0; j < 4; j++) acc[i][j] += a[i] * b4[j];
        }
        __syncthreads();
    }
    #pragma unroll
    for (int i = 0; i < 4; i++) {
        const size_t r = row0 + ty * 4 + i;
        float4 v;
        float* vv = (float*)&v;
        #pragma unroll
        for (int j = 0; j < 4; j++) vv[j] = acc[i][j];
        *(float4*)&C[r * N + col0 + tx * 4] = v;
    }
}

// ---------------- phase-1 softmax prefs ----------------
__global__ void __launch_bounds__(256) softpref_kernel(const float* __restrict__ lgt,
                                                       const float* __restrict__ imp,
                                                       float* __restrict__ wpref) {
    const int tok = blockIdx.x * 64 + (threadIdx.x >> 2);
    const int sg = threadIdx.x & 3;
    const int o = (sg == 0) ? 0 : (64 + 32 * (sg - 1));
    const int n = (sg == 0) ? 64 : 32;
    const float* lp = lgt + (size_t)tok * 192 + o;
    float m = -1e30f;
    for (int i = 0; i < n; i++) m = fmaxf(m, lp[i]);
    float ss = 0.f;
    for (int i = 0; i < n; i++) ss += __expf(lp[i] - m);
    const float scl = imp[tok] / ss;
    float* wp = wpref + (size_t)tok * 160 + o;
    for (int i = 0; i < n; i++) wp[i] = __expf(lp[i] - m) * scl;
}

// ---------------- phase-2 softmax prefs ----------------
__global__ void __launch_bounds__(256) softm_kernel(const float* __restrict__ lgt,
                                                    const float* __restrict__ imp,
                                                    float* __restrict__ wpref) {
    const int tok = blockIdx.x * 256 + threadIdx.x;
    const float* lp = lgt + (size_t)tok * 64;
    float m = -1e30f;
    for (int i = 0; i < 64; i++) m = fmaxf(m, lp[i]);
    float ss = 0.f;
    for (int i = 0; i < 64; i++) ss += __expf(lp[i] - m);
    const float scl = imp[tok] / ss;
    for (int i = 0; i < 64; i++) wpref[(size_t)tok * 64 + i] = __expf(lp[i] - m) * scl;
}

// ---------------- deterministic reduce over S ----------------
__global__ void __launch_bounds__(256) reduce_pref(const float* __restrict__ wpref,
                                                   float* __restrict__ dense,
                                                   int ncols, int outoff) {
    const int b = blockIdx.x / ncols, c = blockIdx.x % ncols;
    __shared__ float red[256];
    float s = 0.f;
    for (int si = threadIdx.x; si < SD; si += 256)
        s += wpref[((size_t)(b * SD + si)) * ncols + c];
    red[threadIdx.x] = s; __syncthreads();
    for (int st = 128; st; st >>= 1) { if (threadIdx.x < st) red[threadIdx.x] += red[threadIdx.x + st]; __syncthreads(); }
    if (threadIdx.x == 0) dense[b * 224 + outoff + c] = red[0];
}

// ---------------- top-k sparsify + renormalize ----------------
__global__ void topk_kernel(const float* __restrict__ dense,
                            int* __restrict__ ridx, float* __restrict__ rw,
                            int r0, int nr) {
    const int t = threadIdx.x;
    if (t >= BD * nr) return;
    const int b = t / nr, r = r0 + (t % nr);
    const int offs[5] = {0, 64, 96, 128, 160};
    const int ns[5]   = {64, 32, 32, 32, 64};
    const int ks[5]   = {8, 4, 4, 4, 8};
    const float* dv = dense + b * 224 + offs[r];
    const int n = ns[r], k = ks[r];
    unsigned long long mask = 0;
    float vals[8]; int idxs[8];
    float ssum = 0.f;
    for (int kk = 0; kk < k; kk++) {
        float best = -1e30f; int bi = 0;
        for (int i = 0; i < n; i++)
            if (!((mask >> i) & 1ull) && dv[i] > best) { best = dv[i]; bi = i; }
        mask |= 1ull << bi;
        vals[kk] = best; idxs[kk] = bi; ssum += best;
    }
    float inv = 1.f / (ssum + 1e-8f);
    for (int kk = 0; kk < 8; kk++) {
        ridx[(b * 5 + r) * 8 + kk] = (kk < k) ? idxs[kk] : 0;
        rw[(b * 5 + r) * 8 + kk]   = (kk < k) ? vals[kk] * inv : 0.f;
    }
}

// ---------------- fused mixture + transpose + bf16 ----------------
__global__ void __launch_bounds__(256) combine_t_kernel(const float* __restrict__ pool,
                                                        const int* __restrict__ ridx,
                                                        const float* __restrict__ rw,
                                                        int router, int kc,
                                                        unsigned short* __restrict__ outT,
                                                        int Rp, int Cp) {
    const int b = blockIdx.z;
    const int r0 = blockIdx.y * 64, c0 = blockIdx.x * 64;
    __shared__ float ls[64][65];
    const int* ii = ridx + (b * 5 + router) * 8;
    const float* ww = rw + (b * 5 + router) * 8;
    const int t = threadIdx.x;
    const int rr = t >> 4, cc = (t & 15) * 4;
    #pragma unroll
    for (int p = 0; p < 4; p++) {
        const int r = rr + p * 16;
        float4 acc = {0.f, 0.f, 0.f, 0.f};
        for (int kk = 0; kk < kc; kk++) {
            const float w = ww[kk];
            float4 v = *(const float4*)&pool[((size_t)ii[kk] * Rp + r0 + r) * Cp + c0 + cc];
            acc.x += w * v.x; acc.y += w * v.y; acc.z += w * v.z; acc.w += w * v.w;
        }
        ls[r][cc] = acc.x; ls[r][cc + 1] = acc.y; ls[r][cc + 2] = acc.z; ls[r][cc + 3] = acc.w;
    }
    __syncthreads();
    unsigned short* op = outT + (size_t)b * Rp * Cp;
    #pragma unroll
    for (int q = 0; q < 2; q++) {
        const int c = (t >> 3) + q * 32;
        const int r8 = (t & 7) * 8;
        union { unsigned short s[8]; bf16x8 v; } u;
        #pragma unroll
        for (int j = 0; j < 8; j++) u.s[j] = f2b(ls[r8 + j][c]);
        *(bf16x8*)(op + (size_t)(c0 + c) * Rp + r0 + r8) = u.v;
    }
}

// ---------------- tile transpose + fp32->bf16 (WO only) ----------------
__global__ void __launch_bounds__(256) tcvt_kernel(const float* __restrict__ src,
                                                   unsigned short* __restrict__ dst,
                                                   int R, int Cc) {
    __shared__ float ls[64][65];
    const int r0 = blockIdx.y * 64, c0 = blockIdx.x * 64;
    const int t = threadIdx.x;
    #pragma unroll
    for (int p = 0; p < 16; p++) {
        const int e = p * 256 + t;
        const int r = e >> 6, c = e & 63;
        ls[r][c] = src[(size_t)(r0 + r) * Cc + c0 + c];
    }
    __syncthreads();
    #pragma unroll
    for (int p = 0; p < 16; p++) {
        const int e = p * 256 + t;
        const int c = e >> 6, r = e & 63;
        dst[(size_t)(c0 + c) * R + r0 + r] = f2b(ls[r][c]);
    }
}

// ---------------- fp32 -> bf16 convert with scale ----------------
__global__ void __launch_bounds__(256) cvt_bf16_kernel(const float* __restrict__ src,
                                                       unsigned short* __restrict__ dst,
                                                       float scale, int n4) {
    const int i = blockIdx.x * 256 + threadIdx.x;
    if (i >= n4) return;
    float4 v = ((const float4*)src)[i];
    unsigned r0 = (unsigned)f2b(v.x * scale) | ((unsigned)f2b(v.y * scale) << 16);
    unsigned r1 = (unsigned)f2b(v.z * scale) | ((unsigned)f2b(v.w * scale) << 16);
    uint2 o; o.x = r0; o.y = r1;
    ((uint2*)dst)[i] = o;
}

// ---------------- bf16 MFMA GEMM: C = A[M][K] @ Bt[N][K]^T (+X), 128x128 tile ----------------
template<int OUTB, int HASX>
__global__ void __launch_bounds__(256) gemm_bf16(const unsigned short* __restrict__ A,
                                                 const unsigned short* __restrict__ Bt,
                                                 const float* __restrict__ X,
                                                 void* __restrict__ Cv,
                                                 int M, int N, int K,
                                                 long long sA, long long sB, long long sC) {
    const int bz = blockIdx.z;
    const unsigned short* Ab = A + (size_t)bz * sA;
    const unsigned short* Btb = Bt + (size_t)bz * sB;
    const int row0 = blockIdx.y * 128, col0 = blockIdx.x * 128;
    const int t = threadIdx.x;
    const int w = t >> 6, l = t & 63, lq = l & 15, lg = l >> 4;
    const int wr = w >> 1, wc = w & 1;
    __shared__ unsigned short As[128 * 64];
    __shared__ unsigned short Bs[128 * 64];
    f32x4 acc[4][4];
    #pragma unroll
    for (int mi = 0; mi < 4; mi++)
        #pragma unroll
        for (int ni = 0; ni < 4; ni++) acc[mi][ni] = f32x4{0.f, 0.f, 0.f, 0.f};

    for (int k0 = 0; k0 < K; k0 += 64) {
        __syncthreads();
        #pragma unroll
        for (int p = 0; p < 4; p++) {
            const int e = t * 8 + p * 2048;
            const int row = e >> 6, col = e & 63;
            bf16x8 va = *(const bf16x8*)(Ab + (size_t)(row0 + row) * K + k0 + col);
            *(bf16x8*)((char*)As + ((row * 128 + col * 2) ^ ((row & 7) << 4))) = va;
            bf16x8 vb = *(const bf16x8*)(Btb + (size_t)(col0 + row) * K + k0 + col);
            *(bf16x8*)((char*)Bs + ((row * 128 + col * 2) ^ ((row & 7) << 4))) = vb;
        }
        __syncthreads();
        #pragma unroll
        for (int kk = 0; kk < 2; kk++) {
            bf16x8 af[4], bg[4];
            #pragma unroll
            for (int mi = 0; mi < 4; mi++) {
                const int r = wr * 64 + mi * 16 + lq;
                af[mi] = *(const bf16x8*)((const char*)As + ((r * 128 + lg * 16 + kk * 64) ^ ((r & 7) << 4)));
            }
            #pragma unroll
            for (int ni = 0; ni < 4; ni++) {
                const int r = wc * 64 + ni * 16 + lq;
                bg[ni] = *(const bf16x8*)((const char*)Bs + ((r * 128 + lg * 16 + kk * 64) ^ ((r & 7) << 4)));
            }
            #pragma unroll
            for (int mi = 0; mi < 4; mi++)
                #pragma unroll
                for (int ni = 0; ni < 4; ni++)
                    acc[mi][ni] = __builtin_amdgcn_mfma_f32_16x16x32_bf16(af[mi], bg[ni], acc[mi][ni], 0, 0, 0);
        }
    }
    #pragma unroll
    for (int mi = 0; mi < 4; mi++) {
        #pragma unroll
        for (int j = 0; j < 4; j++) {
            const int row = row0 + wr * 64 + mi * 16 + lg * 4 + j;
            #pragma unroll
            for (int ni = 0; ni < 4; ni++) {
                const int col = col0 + wc * 64 + ni * 16 + lq;
                float v = acc[mi][ni][j];
                if (HASX) v += X[(size_t)row * N + col];
                if (OUTB) ((unsigned short*)Cv)[(size_t)bz * sC + (size_t)row * N + col] = f2b(v);
                else      ((float*)Cv)[(size_t)bz * sC + (size_t)row * N + col] = v;
            }
        }
    }
}

// ---------------- flash attention: paired q-tiles (qt, 15-qt), dbuf K/V, 1 barrier/tile ----------------
#define SWZV(d) (((((d) >> 1) ^ ((d) >> 3)) & 7) << 4)
__global__ void __launch_bounds__(256) attn_mfma_kernel(const unsigned short* __restrict__ Q,
                                                        const unsigned short* __restrict__ K,
                                                        const unsigned short* __restrict__ V,
                                                        unsigned short* __restrict__ O) {
    const int qt = blockIdx.x, hh = blockIdx.y, b = blockIdx.z;
    const int t = threadIdx.x;
    const int w = t >> 6, l = t & 63, lq = l & 15, lg = l >> 4;

    __shared__ unsigned short ks[2][64 * 64];
    __shared__ unsigned short vt[2][64 * 64];
    __shared__ unsigned short pl[4][16 * 64];

    const size_t base = (size_t)b * SD * DM + (size_t)hh * DH;
    const int qA = qt;          // light tile
    const int qB = 15 - qt;     // heavy tile

    bf16x8 aqA[2], aqB[2];
    {
        const unsigned short* qp = Q + base + (size_t)(qA * 64 + w * 16 + lq) * DM + lg * 8;
        aqA[0] = *(const bf16x8*)qp; aqA[1] = *(const bf16x8*)(qp + 32);
        const unsigned short* qp2 = Q + base + (size_t)(qB * 64 + w * 16 + lq) * DM + lg * 8;
        aqB[0] = *(const bf16x8*)qp2; aqB[1] = *(const bf16x8*)(qp2 + 32);
    }

    f32x4 oA[4], oB[4];
    #pragma unroll
    for (int dt = 0; dt < 4; dt++) { oA[dt] = f32x4{0.f,0.f,0.f,0.f}; oB[dt] = f32x4{0.f,0.f,0.f,0.f}; }
    float mA[4] = {-1e30f,-1e30f,-1e30f,-1e30f}, sA[4] = {0.f,0.f,0.f,0.f};
    float mB[4] = {-1e30f,-1e30f,-1e30f,-1e30f}, sB[4] = {0.f,0.f,0.f,0.f};

    const int ntile = 16 - qt;            // tiles needed by heavy tile B
    const int srow = t >> 3;              // 0..31
    const int scol = (t & 7) * 8;

    int cur = 0;

    // prologue: stage tile 0 into buf 0
    #pragma unroll
    for (int p = 0; p < 2; p++) {
        const int row = srow + 32 * p;
        bf16x8 kv = *(const bf16x8*)(K + base + (size_t)row * DM + scol);
        *(bf16x8*)((char*)&ks[0][0] + ((row * 128 + scol * 2) ^ ((row & 7) << 4))) = kv;
        bf16x8 vv = *(const bf16x8*)(V + base + (size_t)row * DM + scol);
        #pragma unroll
        for (int j2 = 0; j2 < 8; j2++) {
            const int d = scol + j2;
            *(unsigned short*)((char*)&vt[0][0] + ((d * 128 + row * 2) ^ SWZV(d))) = (unsigned short)vv[j2];
        }
    }
    __syncthreads();

    auto compute = [&](int q0, const bf16x8* aq, f32x4* o_, float* m_, float* s_, int kt) {
        const f32x4 zero4 = {0.f, 0.f, 0.f, 0.f};
        f32x4 sacc[4];
        #pragma unroll
        for (int ct = 0; ct < 4; ct++) {
            const int krow = ct * 16 + lq;
            bf16x8 b0 = *(const bf16x8*)((const char*)&ks[cur][0] + ((krow * 128 + lg * 16) ^ ((lq & 7) << 4)));
            bf16x8 b1 = *(const bf16x8*)((const char*)&ks[cur][0] + ((krow * 128 + lg * 16 + 64) ^ ((lq & 7) << 4)));
            f32x4 s = __builtin_amdgcn_mfma_f32_16x16x32_bf16(aq[0], b0, zero4, 0, 0, 0);
            s = __builtin_amdgcn_mfma_f32_16x16x32_bf16(aq[1], b1, s, 0, 0, 0);
            sacc[ct] = s;
        }
        float tm[4];
        #pragma unroll
        for (int j = 0; j < 4; j++) {
            const int qg = q0 * 64 + w * 16 + lg * 4 + j;
            float mx = -1e30f;
            #pragma unroll
            for (int ct = 0; ct < 4; ct++) {
                const int kg = kt * 64 + ct * 16 + lq;
                float v = sacc[ct][j] * 0.125f;
                v = (kg <= qg) ? v : -1e30f;
                sacc[ct][j] = v;
                mx = fmaxf(mx, v);
            }
            #pragma unroll
            for (int d = 1; d < 16; d <<= 1) mx = fmaxf(mx, __shfl_xor(mx, d));
            tm[j] = mx;
        }
        #pragma unroll
        for (int j = 0; j < 4; j++) {
            const float nm = fmaxf(m_[j], tm[j]);
            const float so = __expf(m_[j] - nm);
            m_[j] = nm;
            float rs = 0.f;
            const int prow = lg * 4 + j;
            #pragma unroll
            for (int ct = 0; ct < 4; ct++) {
                const float p = __expf(sacc[ct][j] - nm);
                rs += p;
                const int byteoff = ((prow * 128) + (ct * 16 + lq) * 2) ^ ((prow & 7) << 4);
                *(unsigned short*)((char*)&pl[w][0] + byteoff) = f2b(p);
            }
            #pragma unroll
            for (int d = 1; d < 16; d <<= 1) rs += __shfl_xor(rs, d);
            s_[j] = s_[j] * so + rs;
            #pragma unroll
            for (int dt = 0; dt < 4; dt++) o_[dt][j] *= so;
        }
        asm volatile("s_waitcnt lgkmcnt(0)" ::: "memory");
        __builtin_amdgcn_sched_barrier(0);
        #pragma unroll
        for (int c = 0; c < 2; c++) {
            bf16x8 pa = *(const bf16x8*)((const char*)&pl[w][0] +
                          ((lq * 128 + lg * 16 + 64 * c) ^ ((lq & 7) << 4)));
            #pragma unroll
            for (int dt = 0; dt < 4; dt++) {
                const int dd = dt * 16 + lq;
                bf16x8 bv = *(const bf16x8*)((const char*)&vt[cur][0] +
                              ((dd * 128 + lg * 16 + 64 * c) ^ SWZV(dd)));
                o_[dt] = __builtin_amdgcn_mfma_f32_16x16x32_bf16(pa, bv, o_[dt], 0, 0, 0);
            }
        }
    };

    const int mymaxA = qA * 64 + w * 16 + 15;
    for (int kt = 0; kt < ntile; kt++) {
        // T14: issue next-tile global loads early (hide HBM latency under compute)
        bf16x8 kN[2], vN[2];
        const bool pre = (kt + 1 < ntile);
        if (pre) {
            #pragma unroll
            for (int p = 0; p < 2; p++) {
                const int row = srow + 32 * p;
                kN[p] = *(const bf16x8*)(K + base + (size_t)((kt + 1) * 64 + row) * DM + scol);
                vN[p] = *(const bf16x8*)(V + base + (size_t)((kt + 1) * 64 + row) * DM + scol);
            }
        }
        compute(qB, aqB, oB, mB, sB, kt);
        if (kt * 64 <= mymaxA) compute(qA, aqA, oA, mA, sA, kt);
        if (pre) {
            #pragma unroll
            for (int p = 0; p < 2; p++) {
                const int row = srow + 32 * p;
                *(bf16x8*)((char*)&ks[cur ^ 1][0] + ((row * 128 + scol * 2) ^ ((row & 7) << 4))) = kN[p];
                #pragma unroll
                for (int j2 = 0; j2 < 8; j2++) {
                    const int d = scol + j2;
                    *(unsigned short*)((char*)&vt[cur ^ 1][0] + ((d * 128 + row * 2) ^ SWZV(d))) =
                        (unsigned short)vN[p][j2];
                }
            }
        }
        __syncthreads();
        cur ^= 1;
    }

    #pragma unroll
    for (int j = 0; j < 4; j++) {
        const float invA = 1.f / sA[j];
        const float invB = 1.f / sB[j];
        const int rowA = qA * 64 + w * 16 + lg * 4 + j;
        const int rowB = qB * 64 + w * 16 + lg * 4 + j;
        unsigned short* opA = O + base + (size_t)rowA * DM;
        unsigned short* opB = O + base + (size_t)rowB * DM;
        #pragma unroll
        for (int dt = 0; dt < 4; dt++) {
            opA[dt * 16 + lq] = f2b(oA[dt][j] * invA);
            opB[dt * 16 + lq] = f2b(oB[dt][j] * invB);
        }
    }
}
#undef SWZV

// ---------------- knowledge scores: sorted-list + bitonic batch merge ----------------
#define CE(a, b) { float hi_ = fmaxf(a, b), lo_ = fminf(a, b); a = hi_; b = lo_; }
__global__ void __launch_bounds__(512, 4) know_score_kernel(const unsigned short* __restrict__ Qmb,
                                                            const unsigned short* __restrict__ kKb,
                                                            float* __restrict__ cand) {
    const int t = threadIdx.x;
    const int w = t >> 6, l = t & 63, lq = l & 15, lg = l >> 4;
    const int tok0 = blockIdx.x * 16;
    __shared__ unsigned short ks[8][32 * 128];

    bf16x8 aq[4];
    {
        const unsigned short* qp = Qmb + (size_t)(tok0 + lq) * 128 + lg * 8;
        #pragma unroll
        for (int c = 0; c < 4; c++) aq[c] = *(const bf16x8*)(qp + c * 32);
    }

    float L[4][8];
    #pragma unroll
    for (int j = 0; j < 4; j++)
        #pragma unroll
        for (int s = 0; s < 8; s++) L[j][s] = __uint_as_float(0xF2000000u | (unsigned)s);

    const unsigned short* gsrc = kKb + (((size_t)w * 2048) << 7) + l * 8;
    unsigned short* myks = &ks[w][0];

    bf16x8 vreg[8];
    #pragma unroll
    for (int p = 0; p < 8; p++) vreg[p] = *(const bf16x8*)(gsrc + p * 512);

    for (int t2 = 0; t2 < 32; t2++) {
        float B[4][4];
        #pragma unroll
        for (int sub = 0; sub < 2; sub++) {
            const int kt = t2 * 2 + sub;
            #pragma unroll
            for (int p = 0; p < 8; p++) {
                const int e = p * 512 + l * 8;
                const int row = e >> 7;
                *(bf16x8*)((char*)myks + ((e * 2) ^ ((row & 7) << 4))) = vreg[p];
            }
            if (kt < 63) {
                const unsigned short* src2 = gsrc + (size_t)(kt + 1) * 4096;
                #pragma unroll
                for (int p = 0; p < 8; p++) vreg[p] = *(const bf16x8*)(src2 + p * 512);
            }
            #pragma unroll
            for (int ct = 0; ct < 2; ct++) {
                const int row = ct * 16 + lq;
                const char* kb = (const char*)myks + row * 256;
                const int sw = (row & 7) << 4;
                f32x4 s = {0.f, 0.f, 0.f, 0.f};
                #pragma unroll
                for (int c = 0; c < 4; c++) {
                    bf16x8 bv = *(const bf16x8*)(kb + ((c * 64 + lg * 16) ^ sw));
                    s = __builtin_amdgcn_mfma_f32_16x16x32_bf16(aq[c], bv, s, 0, 0, 0);
                }
                const unsigned keyb = (unsigned)(w * 2048 + kt * 32 + ct * 16 + lq);
                #pragma unroll
                for (int j = 0; j < 4; j++) {
                    unsigned u = __float_as_uint(s[j]);
                    B[j][sub * 2 + ct] = __uint_as_float((u & 0xFFFFC000u) | keyb);
                }
            }
        }
        #pragma unroll
        for (int j = 0; j < 4; j++) {
            CE(B[j][0], B[j][2]); CE(B[j][1], B[j][3]);
            CE(B[j][0], B[j][1]); CE(B[j][2], B[j][3]);
            CE(B[j][1], B[j][2]);
            L[j][4] = fmaxf(L[j][4], B[j][3]);
            L[j][5] = fmaxf(L[j][5], B[j][2]);
            L[j][6] = fmaxf(L[j][6], B[j][1]);
            L[j][7] = fmaxf(L[j][7], B[j][0]);
            CE(L[j][0], L[j][4]); CE(L[j][1], L[j][5]); CE(L[j][2], L[j][6]); CE(L[j][3], L[j][7]);
            CE(L[j][0], L[j][2]); CE(L[j][1], L[j][3]); CE(L[j][4], L[j][6]); CE(L[j][5], L[j][7]);
            CE(L[j][0], L[j][1]); CE(L[j][2], L[j][3]); CE(L[j][4], L[j][5]); CE(L[j][6], L[j][7]);
        }
    }
    #pragma unroll
    for (int j = 0; j < 4; j++) {
        const int tok = tok0 + lg * 4 + j;
        float* cp = cand + ((size_t)tok << 10) + w * 128 + lq * 8;
        #pragma unroll
        for (int ss = 0; ss < 8; ss++) cp[ss] = L[j][ss];
    }
}
#undef CE

// ---------------- knowledge merge + V gather ----------------
__global__ void __launch_bounds__(256) know_out_kernel(const float* __restrict__ cand,
                                                       const float* __restrict__ kV,
                                                       float* __restrict__ out) {
    const int t = threadIdx.x, w = t >> 6, l = t & 63;
    const int tok = blockIdx.x * 4 + w;
    const float* cp = cand + ((size_t)tok << 10);
    float lv[16];
    #pragma unroll
    for (int i = 0; i < 16; i++) lv[i] = cp[i * 64 + l];

    float topv[8]; int topi[8];
    #pragma unroll
    for (int kk = 0; kk < 8; kk++) {
        float m = lv[0];
        #pragma unroll
        for (int i = 1; i < 16; i++) m = fmaxf(m, lv[i]);
        #pragma unroll
        for (int d = 1; d < 64; d <<= 1) m = fmaxf(m, __shfl_xor(m, d));
        topv[kk] = m;
        topi[kk] = (int)(__float_as_uint(m) & 0x3FFFu);
        #pragma unroll
        for (int i = 0; i < 16; i++) lv[i] = (lv[i] == m) ? -1e31f : lv[i];
    }
    const float mx = topv[0];
    float e[8]; float ssum = 0.f;
    #pragma unroll
    for (int kk = 0; kk < 8; kk++) { e[kk] = __expf(topv[kk] - mx); ssum += e[kk]; }
    const float inv = 1.f / ssum;

    float4 acc[4];
    #pragma unroll
    for (int ch = 0; ch < 4; ch++) acc[ch] = float4{0.f, 0.f, 0.f, 0.f};
    #pragma unroll
    for (int kk = 0; kk < 8; kk++) {
        const float wk = e[kk] * inv;
        const float* vp = kV + ((size_t)topi[kk] << 10);
        #pragma unroll
        for (int ch = 0; ch < 4; ch++) {
            float4 v = *(const float4*)(vp + ch * 256 + l * 4);
            acc[ch].x += wk * v.x; acc[ch].y += wk * v.y;
            acc[ch].z += wk * v.z; acc[ch].w += wk * v.w;
        }
    }
    float* op = out + ((size_t)tok << 10);
    #pragma unroll
    for (int ch = 0; ch < 4; ch++) {
        float4 o = *(const float4*)(op + ch * 256 + l * 4);
        o.x += acc[ch].x; o.y += acc[ch].y; o.z += acc[ch].z; o.w += acc[ch].w;
        *(float4*)(op + ch * 256 + l * 4) = o;
    }
}

extern "C" void kernel_launch(void* const* d_in, const int* in_sizes, int n_in,
                              void* d_out, int out_size, void* d_ws, size_t ws_size,
                              hipStream_t stream) {
    const float* x    = (const float*)d_in[0];
    const float* imp  = (const float*)d_in[1];
    const float* Wc   = (const float*)d_in[2];
    const float* WQr  = (const float*)d_in[3];
    const float* WKr  = (const float*)d_in[4];
    const float* WVr  = (const float*)d_in[5];
    const float* Wm   = (const float*)d_in[6];
    const float* cneu = (const float*)d_in[7];
    const float* epool= (const float*)d_in[8];
    const float* kK   = (const float*)d_in[9];
    const float* kV   = (const float*)d_in[10];
    const float* WO   = (const float*)d_in[11];
    const float* ln1s = (const float*)d_in[12];
    const float* ln1b = (const float*)d_in[13];
    const float* ln2s = (const float*)d_in[14];
    const float* ln2b = (const float*)d_in[15];
    float* out = (float*)d_out;

    float* ws = (float*)d_ws;
    size_t o = 0;
    float* n1    = ws + o; o += (size_t)BD * SD * DM;
    unsigned short* n1b = (unsigned short*)(ws + o); o += (size_t)BD * SD * DM / 2;
    float* lgt   = ws + o; o += (size_t)BD * SD * 192;
    float* wpref = ws + o; o += (size_t)BD * SD * 160;
    float* dense = ws + o; o += (size_t)BD * 224;
    int*   ridx  = (int*)(ws + o); o += (size_t)BD * 5 * 8;
    float* rw    = ws + o; o += (size_t)BD * 5 * 8;
    float* Wcat  = ws + o; o += (size_t)1024 * 192;
    unsigned short* scompT = (unsigned short*)(ws + o); o += (size_t)BD * RK * DM / 2;
    unsigned short* EQt = (unsigned short*)(ws + o); o += (size_t)BD * RK * DM / 2;
    unsigned short* EKt = (unsigned short*)(ws + o); o += (size_t)BD * RK * DM / 2;
    unsigned short* EVt = (unsigned short*)(ws + o); o += (size_t)BD * RK * DM / 2;
    unsigned short* hb  = (unsigned short*)(ws + o); o += (size_t)BD * SD * RK / 2;
    unsigned short* Qb16 = (unsigned short*)(ws + o); o += (size_t)BD * SD * DM / 2;
    unsigned short* Kb16 = (unsigned short*)(ws + o); o += (size_t)BD * SD * DM / 2;
    unsigned short* Vb16 = (unsigned short*)(ws + o); o += (size_t)BD * SD * DM / 2;
    unsigned short* attnb = (unsigned short*)(ws + o); o += (size_t)BD * SD * DM / 2;
    unsigned short* WOt = (unsigned short*)(ws + o); o += (size_t)DM * DM / 2;
    unsigned short* kKb = (unsigned short*)(ws + o); o += (size_t)NK * RK / 2;
    unsigned short* Qmb = (unsigned short*)(ws + o); o += (size_t)BD * SD * RK / 2;
    float* cand = ws + o; o += (size_t)BD * SD * 1024;

    const int NTOK = BD * SD;

    // independent prep
    concatw_kernel<<<768, 256, 0, stream>>>(Wc, WQr, WKr, WVr, Wcat);
    tcvt_kernel<<<dim3(16, 16, 1), 256, 0, stream>>>(WO, WOt, DM, DM);
    cvt_bf16_kernel<<<(NK * RK / 4) / 256, 256, 0, stream>>>(kK, kKb, 0.0883883476483184f, NK * RK / 4);

    // phase 1
    ln_kernel<<<NTOK, 256, 0, stream>>>(x, ln1s, ln1b, n1, n1b);
    mm64_kernel<<<dim3(3, NTOK / 64, 1), 256, 0, stream>>>(n1, Wcat, lgt, 192, DM);
    softpref_kernel<<<NTOK / 64, 256, 0, stream>>>(lgt, imp, wpref);
    reduce_pref<<<BD * 160, 256, 0, stream>>>(wpref, dense, 160, 0);
    topk_kernel<<<1, 64, 0, stream>>>(dense, ridx, rw, 0, 4);
    combine_t_kernel<<<dim3(2, 16, BD), 256, 0, stream>>>(cneu, ridx, rw, 0, 8, scompT, DM, RK);
    combine_t_kernel<<<dim3(16, 2, BD), 256, 0, stream>>>(epool, ridx, rw, 1, 4, EQt, RK, DM);
    combine_t_kernel<<<dim3(16, 2, BD), 256, 0, stream>>>(epool, ridx, rw, 2, 4, EKt, RK, DM);
    combine_t_kernel<<<dim3(16, 2, BD), 256, 0, stream>>>(epool, ridx, rw, 3, 4, EVt, RK, DM);
    gemm_bf16<1, 0><<<dim3(1, 8, BD), 256, 0, stream>>>(n1b, scompT, nullptr, hb,
        SD, RK, DM, (long long)SD * DM, (long long)RK * DM, (long long)SD * RK);
    gemm_bf16<1, 0><<<dim3(8, 8, BD), 256, 0, stream>>>(hb, EQt, nullptr, Qb16,
        SD, DM, RK, (long long)SD * RK, (long long)DM * RK, (long long)SD * DM);
    gemm_bf16<1, 0><<<dim3(8, 8, BD), 256, 0, stream>>>(hb, EKt, nullptr, Kb16,
        SD, DM, RK, (long long)SD * RK, (long long)DM * RK, (long long)SD * DM);
    gemm_bf16<1, 0><<<dim3(8, 8, BD), 256, 0, stream>>>(hb, EVt, nullptr, Vb16,
        SD, DM, RK, (long long)SD * RK, (long long)DM * RK, (long long)SD * DM);
    attn_mfma_kernel<<<dim3(8, NH, BD), 256, 0, stream>>>(Qb16, Kb16, Vb16, attnb);
    gemm_bf16<0, 1><<<dim3(8, 64, 1), 256, 0, stream>>>(attnb, WOt, x, out,
        NTOK, DM, DM, 0, 0, 0);

    // phase 2
    ln_kernel<<<NTOK, 256, 0, stream>>>(out, ln2s, ln2b, n1, n1b);
    mm64_kernel<<<dim3(1, NTOK / 64, 1), 256, 0, stream>>>(n1, Wm, lgt, 64, DM);
    softm_kernel<<<NTOK / 256, 256, 0, stream>>>(lgt, imp, wpref);
    reduce_pref<<<BD * 64, 256, 0, stream>>>(wpref, dense, 64, 160);
    topk_kernel<<<1, 64, 0, stream>>>(dense, ridx, rw, 4, 1);
    combine_t_kernel<<<dim3(2, 16, BD), 256, 0, stream>>>(cneu, ridx, rw, 4, 8, scompT, DM, RK);
    gemm_bf16<1, 0><<<dim3(1, 8, BD), 256, 0, stream>>>(n1b, scompT, nullptr, Qmb,
        SD, RK, DM, (long long)SD * DM, (long long)RK * DM, (long long)SD * RK);
    know_score_kernel<<<NTOK / 16, 512, 0, stream>>>(Qmb, kKb, cand);
    know_out_kernel<<<NTOK / 4, 256, 0, stream>>>(cand, kV, out);
}

// Round 9
// 819.088 us; speedup vs baseline: 7.9666x; 1.0042x over previous
//
#include <hip/hip_runtime.h>
#include <hip/hip_bf16.h>

#define BD 8
#define SD 1024
#define DM 1024
#define NH 16
#define DH 64
#define RK 128
#define NK 16384

typedef __attribute__((ext_vector_type(8))) short bf16x8;
typedef __attribute__((ext_vector_type(4))) float f32x4;

__device__ __forceinline__ unsigned short f2b(float f) {
    unsigned u = __float_as_uint(f);
    unsigned r = (u + 0x7FFFu + ((u >> 16) & 1u)) >> 16;
    return (unsigned short)r;
}
__device__ __forceinline__ float b2f(unsigned short h) {
    return __uint_as_float(((unsigned)h) << 16);
}

// ---------------- LayerNorm: bf16 hi/lo outputs (split for fp32-accurate logits) ----------------
__global__ void __launch_bounds__(256) ln_kernel(const float* __restrict__ x,
                                                 const float* __restrict__ sc,
                                                 const float* __restrict__ bi,
                                                 unsigned short* __restrict__ outh,
                                                 unsigned short* __restrict__ outl) {
    const int tok = blockIdx.x;
    __shared__ float xs[DM];
    __shared__ float red[256];
    const float* xp = x + (size_t)tok * DM;
    float s = 0.f;
    for (int i = threadIdx.x; i < DM; i += 256) { float v = xp[i]; xs[i] = v; s += v; }
    red[threadIdx.x] = s; __syncthreads();
    for (int st = 128; st; st >>= 1) { if (threadIdx.x < st) red[threadIdx.x] += red[threadIdx.x + st]; __syncthreads(); }
    float mu = red[0] * (1.f / DM);
    __syncthreads();
    float vs = 0.f;
    for (int i = threadIdx.x; i < DM; i += 256) { float d = xs[i] - mu; vs += d * d; }
    red[threadIdx.x] = vs; __syncthreads();
    for (int st = 128; st; st >>= 1) { if (threadIdx.x < st) red[threadIdx.x] += red[threadIdx.x + st]; __syncthreads(); }
    float rs = rsqrtf(red[0] * (1.f / DM) + 1e-5f);
    for (int i = threadIdx.x; i < DM; i += 256) {
        float v = (xs[i] - mu) * rs * sc[i] + bi[i];
        unsigned short h = f2b(v);
        outh[(size_t)tok * DM + i] = h;
        outl[(size_t)tok * DM + i] = f2b(v - b2f(h));
    }
}

// ---------------- router weights -> transposed hi/lo bf16 [256][1024] ----------------
// rows 0..63 Wc, 64..95 WQr, 96..127 WKr, 128..159 WVr, 160..191 zero, 192..255 Wm
__global__ void __launch_bounds__(256) concatw_kernel(const float* __restrict__ Wc,
                                                      const float* __restrict__ WQr,
                                                      const float* __restrict__ WKr,
                                                      const float* __restrict__ WVr,
                                                      const float* __restrict__ Wm,
                                                      unsigned short* __restrict__ WTh,
                                                      unsigned short* __restrict__ WTl) {
    const int i = blockIdx.x * 256 + threadIdx.x;   // 256*1024
    const int c = i >> 10, d = i & 1023;
    float v = 0.f;
    if (c < 64)       v = Wc[d * 64 + c];
    else if (c < 96)  v = WQr[d * 32 + c - 64];
    else if (c < 128) v = WKr[d * 32 + c - 96];
    else if (c < 160) v = WVr[d * 32 + c - 128];
    else if (c >= 192) v = Wm[d * 64 + c - 192];
    unsigned short h = f2b(v);
    WTh[i] = h;
    WTl[i] = f2b(v - b2f(h));
}

// ---------------- split-bf16 logits GEMM: C_fp32 = (Ah+Al) @ (Bh+Bl)^T, 128x64 tile ----------------
__global__ void __launch_bounds__(256) gemm_split(const unsigned short* __restrict__ Ah,
                                                  const unsigned short* __restrict__ Al,
                                                  const unsigned short* __restrict__ Bh,
                                                  const unsigned short* __restrict__ Bl,
                                                  float* __restrict__ C,
                                                  int N, int K) {
    const int row0 = blockIdx.y * 128, col0 = blockIdx.x * 64;
    const int t = threadIdx.x;
    const int w = t >> 6, l = t & 63, lq = l & 15, lg = l >> 4;
    __shared__ unsigned short sAh[128 * 64];
    __shared__ unsigned short sAl[128 * 64];
    __shared__ unsigned short sBh[64 * 64];
    __shared__ unsigned short sBl[64 * 64];
    f32x4 acc[2][4];
    #pragma unroll
    for (int mi = 0; mi < 2; mi++)
        #pragma unroll
        for (int ni = 0; ni < 4; ni++) acc[mi][ni] = f32x4{0.f, 0.f, 0.f, 0.f};

    for (int k0 = 0; k0 < K; k0 += 64) {
        __syncthreads();
        #pragma unroll
        for (int p = 0; p < 4; p++) {
            const int e = t * 8 + p * 2048;
            const int row = e >> 6, col = e & 63;
            const int sw = (e * 2) ^ ((row & 7) << 4);
            *(bf16x8*)((char*)sAh + sw) = *(const bf16x8*)(Ah + (size_t)(row0 + row) * K + k0 + col);
            *(bf16x8*)((char*)sAl + sw) = *(const bf16x8*)(Al + (size_t)(row0 + row) * K + k0 + col);
        }
        #pragma unroll
        for (int p = 0; p < 2; p++) {
            const int e = t * 8 + p * 2048;
            const int row = e >> 6, col = e & 63;
            const int sw = (e * 2) ^ ((row & 7) << 4);
            *(bf16x8*)((char*)sBh + sw) = *(const bf16x8*)(Bh + (size_t)(col0 + row) * K + k0 + col);
            *(bf16x8*)((char*)sBl + sw) = *(const bf16x8*)(Bl + (size_t)(col0 + row) * K + k0 + col);
        }
        __syncthreads();
        #pragma unroll
        for (int kk = 0; kk < 2; kk++) {
            bf16x8 ah[2], al[2], bh[4], bl[4];
            #pragma unroll
            for (int mi = 0; mi < 2; mi++) {
                const int r = w * 32 + mi * 16 + lq;
                const int off = (r * 128 + lg * 16 + kk * 64) ^ ((r & 7) << 4);
                ah[mi] = *(const bf16x8*)((const char*)sAh + off);
                al[mi] = *(const bf16x8*)((const char*)sAl + off);
            }
            #pragma unroll
            for (int ni = 0; ni < 4; ni++) {
                const int r = ni * 16 + lq;
                const int off = (r * 128 + lg * 16 + kk * 64) ^ ((r & 7) << 4);
                bh[ni] = *(const bf16x8*)((const char*)sBh + off);
                bl[ni] = *(const bf16x8*)((const char*)sBl + off);
            }
            #pragma unroll
            for (int mi = 0; mi < 2; mi++)
                #pragma unroll
                for (int ni = 0; ni < 4; ni++) {
                    acc[mi][ni] = __builtin_amdgcn_mfma_f32_16x16x32_bf16(ah[mi], bh[ni], acc[mi][ni], 0, 0, 0);
                    acc[mi][ni] = __builtin_amdgcn_mfma_f32_16x16x32_bf16(ah[mi], bl[ni], acc[mi][ni], 0, 0, 0);
                    acc[mi][ni] = __builtin_amdgcn_mfma_f32_16x16x32_bf16(al[mi], bh[ni], acc[mi][ni], 0, 0, 0);
                }
        }
    }
    #pragma unroll
    for (int mi = 0; mi < 2; mi++)
        #pragma unroll
        for (int j = 0; j < 4; j++) {
            const int row = row0 + w * 32 + mi * 16 + lg * 4 + j;
            #pragma unroll
            for (int ni = 0; ni < 4; ni++)
                C[(size_t)row * N + col0 + ni * 16 + lq] = acc[mi][ni][j];
        }
}

// ---------------- phase-1 softmax prefs ----------------
__global__ void __launch_bounds__(256) softpref_kernel(const float* __restrict__ lgt,
                                                       const float* __restrict__ imp,
                                                       float* __restrict__ wpref) {
    const int tok = blockIdx.x * 64 + (threadIdx.x >> 2);
    const int sg = threadIdx.x & 3;
    const int o = (sg == 0) ? 0 : (64 + 32 * (sg - 1));
    const int n = (sg == 0) ? 64 : 32;
    const float* lp = lgt + (size_t)tok * 192 + o;
    float m = -1e30f;
    for (int i = 0; i < n; i++) m = fmaxf(m, lp[i]);
    float ss = 0.f;
    for (int i = 0; i < n; i++) ss += __expf(lp[i] - m);
    const float scl = imp[tok] / ss;
    float* wp = wpref + (size_t)tok * 160 + o;
    for (int i = 0; i < n; i++) wp[i] = __expf(lp[i] - m) * scl;
}

// ---------------- phase-2 softmax prefs ----------------
__global__ void __launch_bounds__(256) softm_kernel(const float* __restrict__ lgt,
                                                    const float* __restrict__ imp,
                                                    float* __restrict__ wpref) {
    const int tok = blockIdx.x * 256 + threadIdx.x;
    const float* lp = lgt + (size_t)tok * 64;
    float m = -1e30f;
    for (int i = 0; i < 64; i++) m = fmaxf(m, lp[i]);
    float ss = 0.f;
    for (int i = 0; i < 64; i++) ss += __expf(lp[i] - m);
    const float scl = imp[tok] / ss;
    for (int i = 0; i < 64; i++) wpref[(size_t)tok * 64 + i] = __expf(lp[i] - m) * scl;
}

// ---------------- deterministic reduce over S ----------------
__global__ void __launch_bounds__(256) reduce_pref(const float* __restrict__ wpref,
                                                   float* __restrict__ dense,
                                                   int ncols, int outoff) {
    const int b = blockIdx.x / ncols, c = blockIdx.x % ncols;
    __shared__ float red[256];
    float s = 0.f;
    for (int si = threadIdx.x; si < SD; si += 256)
        s += wpref[((size_t)(b * SD + si)) * ncols + c];
    red[threadIdx.x] = s; __syncthreads();
    for (int st = 128; st; st >>= 1) { if (threadIdx.x < st) red[threadIdx.x] += red[threadIdx.x + st]; __syncthreads(); }
    if (threadIdx.x == 0) dense[b * 224 + outoff + c] = red[0];
}

// ---------------- top-k sparsify + renormalize ----------------
__global__ void topk_kernel(const float* __restrict__ dense,
                            int* __restrict__ ridx, float* __restrict__ rw,
                            int r0, int nr) {
    const int t = threadIdx.x;
    if (t >= BD * nr) return;
    const int b = t / nr, r = r0 + (t % nr);
    const int offs[5] = {0, 64, 96, 128, 160};
    const int ns[5]   = {64, 32, 32, 32, 64};
    const int ks[5]   = {8, 4, 4, 4, 8};
    const float* dv = dense + b * 224 + offs[r];
    const int n = ns[r], k = ks[r];
    unsigned long long mask = 0;
    float vals[8]; int idxs[8];
    float ssum = 0.f;
    for (int kk = 0; kk < k; kk++) {
        float best = -1e30f; int bi = 0;
        for (int i = 0; i < n; i++)
            if (!((mask >> i) & 1ull) && dv[i] > best) { best = dv[i]; bi = i; }
        mask |= 1ull << bi;
        vals[kk] = best; idxs[kk] = bi; ssum += best;
    }
    float inv = 1.f / (ssum + 1e-8f);
    for (int kk = 0; kk < 8; kk++) {
        ridx[(b * 5 + r) * 8 + kk] = (kk < k) ? idxs[kk] : 0;
        rw[(b * 5 + r) * 8 + kk]   = (kk < k) ? vals[kk] * inv : 0.f;
    }
}

// ---------------- fused mixture + transpose + bf16 ----------------
__global__ void __launch_bounds__(256) combine_t_kernel(const float* __restrict__ pool,
                                                        const int* __restrict__ ridx,
                                                        const float* __restrict__ rw,
                                                        int router, int kc,
                                                        unsigned short* __restrict__ outT,
                                                        int Rp, int Cp) {
    const int b = blockIdx.z;
    const int r0 = blockIdx.y * 64, c0 = blockIdx.x * 64;
    __shared__ float ls[64][65];
    const int* ii = ridx + (b * 5 + router) * 8;
    const float* ww = rw + (b * 5 + router) * 8;
    const int t = threadIdx.x;
    const int rr = t >> 4, cc = (t & 15) * 4;
    #pragma unroll
    for (int p = 0; p < 4; p++) {
        const int r = rr + p * 16;
        float4 acc = {0.f, 0.f, 0.f, 0.f};
        for (int kk = 0; kk < kc; kk++) {
            const float w = ww[kk];
            float4 v = *(const float4*)&pool[((size_t)ii[kk] * Rp + r0 + r) * Cp + c0 + cc];
            acc.x += w * v.x; acc.y += w * v.y; acc.z += w * v.z; acc.w += w * v.w;
        }
        ls[r][cc] = acc.x; ls[r][cc + 1] = acc.y; ls[r][cc + 2] = acc.z; ls[r][cc + 3] = acc.w;
    }
    __syncthreads();
    unsigned short* op = outT + (size_t)b * Rp * Cp;
    #pragma unroll
    for (int q = 0; q < 2; q++) {
        const int c = (t >> 3) + q * 32;
        const int r8 = (t & 7) * 8;
        union { unsigned short s[8]; bf16x8 v; } u;
        #pragma unroll
        for (int j = 0; j < 8; j++) u.s[j] = f2b(ls[r8 + j][c]);
        *(bf16x8*)(op + (size_t)(c0 + c) * Rp + r0 + r8) = u.v;
    }
}

// ---------------- tile transpose + fp32->bf16 (WO only) ----------------
__global__ void __launch_bounds__(256) tcvt_kernel(const float* __restrict__ src,
                                                   unsigned short* __restrict__ dst,
                                                   int R, int Cc) {
    __shared__ float ls[64][65];
    const int r0 = blockIdx.y * 64, c0 = blockIdx.x * 64;
    const int t = threadIdx.x;
    #pragma unroll
    for (int p = 0; p < 16; p++) {
        const int e = p * 256 + t;
        const int r = e >> 6, c = e & 63;
        ls[r][c] = src[(size_t)(r0 + r) * Cc + c0 + c];
    }
    __syncthreads();
    #pragma unroll
    for (int p = 0; p < 16; p++) {
        const int e = p * 256 + t;
        const int c = e >> 6, r = e & 63;
        dst[(size_t)(c0 + c) * R + r0 + r] = f2b(ls[r][c]);
    }
}

// ---------------- fp32 -> bf16 convert with scale ----------------
__global__ void __launch_bounds__(256) cvt_bf16_kernel(const float* __restrict__ src,
                                                       unsigned short* __restrict__ dst,
                                                       float scale, int n4) {
    const int i = blockIdx.x * 256 + threadIdx.x;
    if (i >= n4) return;
    float4 v = ((const float4*)src)[i];
    unsigned r0 = (unsigned)f2b(v.x * scale) | ((unsigned)f2b(v.y * scale) << 16);
    unsigned r1 = (unsigned)f2b(v.z * scale) | ((unsigned)f2b(v.w * scale) << 16);
    uint2 o; o.x = r0; o.y = r1;
    ((uint2*)dst)[i] = o;
}

// ---------------- bf16 MFMA GEMM: C = A[M][K] @ Bt[N][K]^T (+X), 128x128 tile ----------------
template<int OUTB, int HASX>
__global__ void __launch_bounds__(256) gemm_bf16(const unsigned short* __restrict__ A,
                                                 const unsigned short* __restrict__ Bt,
                                                 const float* __restrict__ X,
                                                 void* __restrict__ Cv,
                                                 int M, int N, int K,
                                                 long long sA, long long sB, long long sC) {
    const int bz = blockIdx.z;
    const unsigned short* Ab = A + (size_t)bz * sA;
    const unsigned short* Btb = Bt + (size_t)bz * sB;
    const int row0 = blockIdx.y * 128, col0 = blockIdx.x * 128;
    const int t = threadIdx.x;
    const int w = t >> 6, l = t & 63, lq = l & 15, lg = l >> 4;
    const int wr = w >> 1, wc = w & 1;
    __shared__ unsigned short As[128 * 64];
    __shared__ unsigned short Bs[128 * 64];
    f32x4 acc[4][4];
    #pragma unroll
    for (int mi = 0; mi < 4; mi++)
        #pragma unroll
        for (int ni = 0; ni < 4; ni++) acc[mi][ni] = f32x4{0.f, 0.f, 0.f, 0.f};

    for (int k0 = 0; k0 < K; k0 += 64) {
        __syncthreads();
        #pragma unroll
        for (int p = 0; p < 4; p++) {
            const int e = t * 8 + p * 2048;
            const int row = e >> 6, col = e & 63;
            bf16x8 va = *(const bf16x8*)(Ab + (size_t)(row0 + row) * K + k0 + col);
            *(bf16x8*)((char*)As + ((row * 128 + col * 2) ^ ((row & 7) << 4))) = va;
            bf16x8 vb = *(const bf16x8*)(Btb + (size_t)(col0 + row) * K + k0 + col);
            *(bf16x8*)((char*)Bs + ((row * 128 + col * 2) ^ ((row & 7) << 4))) = vb;
        }
        __syncthreads();
        #pragma unroll
        for (int kk = 0; kk < 2; kk++) {
            bf16x8 af[4], bg[4];
            #pragma unroll
            for (int mi = 0; mi < 4; mi++) {
                const int r = wr * 64 + mi * 16 + lq;
                af[mi] = *(const bf16x8*)((const char*)As + ((r * 128 + lg * 16 + kk * 64) ^ ((r & 7) << 4)));
            }
            #pragma unroll
            for (int ni = 0; ni < 4; ni++) {
                const int r = wc * 64 + ni * 16 + lq;
                bg[ni] = *(const bf16x8*)((const char*)Bs + ((r * 128 + lg * 16 + kk * 64) ^ ((r & 7) << 4)));
            }
            #pragma unroll
            for (int mi = 0; mi < 4; mi++)
                #pragma unroll
                for (int ni = 0; ni < 4; ni++)
                    acc[mi][ni] = __builtin_amdgcn_mfma_f32_16x16x32_bf16(af[mi], bg[ni], acc[mi][ni], 0, 0, 0);
        }
    }
    #pragma unroll
    for (int mi = 0; mi < 4; mi++) {
        #pragma unroll
        for (int j = 0; j < 4; j++) {
            const int row = row0 + wr * 64 + mi * 16 + lg * 4 + j;
            #pragma unroll
            for (int ni = 0; ni < 4; ni++) {
                const int col = col0 + wc * 64 + ni * 16 + lq;
                float v = acc[mi][ni][j];
                if (HASX) v += X[(size_t)row * N + col];
                if (OUTB) ((unsigned short*)Cv)[(size_t)bz * sC + (size_t)row * N + col] = f2b(v);
                else      ((float*)Cv)[(size_t)bz * sC + (size_t)row * N + col] = v;
            }
        }
    }
}

// ---------------- flash attention: paired q-tiles (qt, 15-qt), dbuf K/V, 1 barrier/tile ----------------
#define SWZV(d) (((((d) >> 1) ^ ((d) >> 3)) & 7) << 4)
__global__ void __launch_bounds__(256) attn_mfma_kernel(const unsigned short* __restrict__ Q,
                                                        const unsigned short* __restrict__ K,
                                                        const unsigned short* __restrict__ V,
                                                        unsigned short* __restrict__ O) {
    const int qt = blockIdx.x, hh = blockIdx.y, b = blockIdx.z;
    const int t = threadIdx.x;
    const int w = t >> 6, l = t & 63, lq = l & 15, lg = l >> 4;

    __shared__ unsigned short ks[2][64 * 64];
    __shared__ unsigned short vt[2][64 * 64];
    __shared__ unsigned short pl[4][16 * 64];

    const size_t base = (size_t)b * SD * DM + (size_t)hh * DH;
    const int qA = qt;
    const int qB = 15 - qt;

    bf16x8 aqA[2], aqB[2];
    {
        const unsigned short* qp = Q + base + (size_t)(qA * 64 + w * 16 + lq) * DM + lg * 8;
        aqA[0] = *(const bf16x8*)qp; aqA[1] = *(const bf16x8*)(qp + 32);
        const unsigned short* qp2 = Q + base + (size_t)(qB * 64 + w * 16 + lq) * DM + lg * 8;
        aqB[0] = *(const bf16x8*)qp2; aqB[1] = *(const bf16x8*)(qp2 + 32);
    }

    f32x4 oA[4], oB[4];
    #pragma unroll
    for (int dt = 0; dt < 4; dt++) { oA[dt] = f32x4{0.f,0.f,0.f,0.f}; oB[dt] = f32x4{0.f,0.f,0.f,0.f}; }
    float mA[4] = {-1e30f,-1e30f,-1e30f,-1e30f}, sA[4] = {0.f,0.f,0.f,0.f};
    float mB[4] = {-1e30f,-1e30f,-1e30f,-1e30f}, sB[4] = {0.f,0.f,0.f,0.f};

    const int ntile = 16 - qt;
    const int srow = t >> 3;
    const int scol = (t & 7) * 8;

    int cur = 0;

    #pragma unroll
    for (int p = 0; p < 2; p++) {
        const int row = srow + 32 * p;
        bf16x8 kv = *(const bf16x8*)(K + base + (size_t)row * DM + scol);
        *(bf16x8*)((char*)&ks[0][0] + ((row * 128 + scol * 2) ^ ((row & 7) << 4))) = kv;
        bf16x8 vv = *(const bf16x8*)(V + base + (size_t)row * DM + scol);
        #pragma unroll
        for (int j2 = 0; j2 < 8; j2++) {
            const int d = scol + j2;
            *(unsigned short*)((char*)&vt[0][0] + ((d * 128 + row * 2) ^ SWZV(d))) = (unsigned short)vv[j2];
        }
    }
    __syncthreads();

    auto compute = [&](int q0, const bf16x8* aq, f32x4* o_, float* m_, float* s_, int kt) {
        const f32x4 zero4 = {0.f, 0.f, 0.f, 0.f};
        f32x4 sacc[4];
        #pragma unroll
        for (int ct = 0; ct < 4; ct++) {
            const int krow = ct * 16 + lq;
            bf16x8 b0 = *(const bf16x8*)((const char*)&ks[cur][0] + ((krow * 128 + lg * 16) ^ ((lq & 7) << 4)));
            bf16x8 b1 = *(const bf16x8*)((const char*)&ks[cur][0] + ((krow * 128 + lg * 16 + 64) ^ ((lq & 7) << 4)));
            f32x4 s = __builtin_amdgcn_mfma_f32_16x16x32_bf16(aq[0], b0, zero4, 0, 0, 0);
            s = __builtin_amdgcn_mfma_f32_16x16x32_bf16(aq[1], b1, s, 0, 0, 0);
            sacc[ct] = s;
        }
        float tm[4];
        #pragma unroll
        for (int j = 0; j < 4; j++) {
            const int qg = q0 * 64 + w * 16 + lg * 4 + j;
            float mx = -1e30f;
            #pragma unroll
            for (int ct = 0; ct < 4; ct++) {
                const int kg = kt * 64 + ct * 16 + lq;
                float v = sacc[ct][j] * 0.125f;
                v = (kg <= qg) ? v : -1e30f;
                sacc[ct][j] = v;
                mx = fmaxf(mx, v);
            }
            #pragma unroll
            for (int d = 1; d < 16; d <<= 1) mx = fmaxf(mx, __shfl_xor(mx, d));
            tm[j] = mx;
        }
        #pragma unroll
        for (int j = 0; j < 4; j++) {
            const float nm = fmaxf(m_[j], tm[j]);
            const float so = __expf(m_[j] - nm);
            m_[j] = nm;
            float rs = 0.f;
            const int prow = lg * 4 + j;
            #pragma unroll
            for (int ct = 0; ct < 4; ct++) {
                const float p = __expf(sacc[ct][j] - nm);
                rs += p;
                const int byteoff = ((prow * 128) + (ct * 16 + lq) * 2) ^ ((prow & 7) << 4);
                *(unsigned short*)((char*)&pl[w][0] + byteoff) = f2b(p);
            }
            #pragma unroll
            for (int d = 1; d < 16; d <<= 1) rs += __shfl_xor(rs, d);
            s_[j] = s_[j] * so + rs;
            #pragma unroll
            for (int dt = 0; dt < 4; dt++) o_[dt][j] *= so;
        }
        asm volatile("s_waitcnt lgkmcnt(0)" ::: "memory");
        __builtin_amdgcn_sched_barrier(0);
        #pragma unroll
        for (int c = 0; c < 2; c++) {
            bf16x8 pa = *(const bf16x8*)((const char*)&pl[w][0] +
                          ((lq * 128 + lg * 16 + 64 * c) ^ ((lq & 7) << 4)));
            #pragma unroll
            for (int dt = 0; dt < 4; dt++) {
                const int dd = dt * 16 + lq;
                bf16x8 bv = *(const bf16x8*)((const char*)&vt[cur][0] +
                              ((dd * 128 + lg * 16 + 64 * c) ^ SWZV(dd)));
                o_[dt] = __builtin_amdgcn_mfma_f32_16x16x32_bf16(pa, bv, o_[dt], 0, 0, 0);
            }
        }
    };

    const int mymaxA = qA * 64 + w * 16 + 15;
    for (int kt = 0; kt < ntile; kt++) {
        bf16x8 kN[2], vN[2];
        const bool pre = (kt + 1 < ntile);
        if (pre) {
            #pragma unroll
            for (int p = 0; p < 2; p++) {
                const int row = srow + 32 * p;
                kN[p] = *(const bf16x8*)(K + base + (size_t)((kt + 1) * 64 + row) * DM + scol);
                vN[p] = *(const bf16x8*)(V + base + (size_t)((kt + 1) * 64 + row) * DM + scol);
            }
        }
        compute(qB, aqB, oB, mB, sB, kt);
        if (kt * 64 <= mymaxA) compute(qA, aqA, oA, mA, sA, kt);
        if (pre) {
            #pragma unroll
            for (int p = 0; p < 2; p++) {
                const int row = srow + 32 * p;
                *(bf16x8*)((char*)&ks[cur ^ 1][0] + ((row * 128 + scol * 2) ^ ((row & 7) << 4))) = kN[p];
                #pragma unroll
                for (int j2 = 0; j2 < 8; j2++) {
                    const int d = scol + j2;
                    *(unsigned short*)((char*)&vt[cur ^ 1][0] + ((d * 128 + row * 2) ^ SWZV(d))) =
                        (unsigned short)vN[p][j2];
                }
            }
        }
        __syncthreads();
        cur ^= 1;
    }

    #pragma unroll
    for (int j = 0; j < 4; j++) {
        const float invA = 1.f / sA[j];
        const float invB = 1.f / sB[j];
        const int rowA = qA * 64 + w * 16 + lg * 4 + j;
        const int rowB = qB * 64 + w * 16 + lg * 4 + j;
        unsigned short* opA = O + base + (size_t)rowA * DM;
        unsigned short* opB = O + base + (size_t)rowB * DM;
        #pragma unroll
        for (int dt = 0; dt < 4; dt++) {
            opA[dt * 16 + lq] = f2b(oA[dt][j] * invA);
            opB[dt * 16 + lq] = f2b(oB[dt][j] * invB);
        }
    }
}
#undef SWZV

// ---------------- knowledge scores: direct-from-L2 B-frags, no LDS, 32 tokens/block ----------------
// 256 blocks x 512 thr; wave w: token-group tg=w&1 (16 tokens), key-quarter q=w>>1 (4096 keys)
#define CE(a, b) { float hi_ = fmaxf(a, b), lo_ = fminf(a, b); a = hi_; b = lo_; }
__global__ void __launch_bounds__(512, 2) know_score_kernel(const unsigned short* __restrict__ Qmb,
                                                            const unsigned short* __restrict__ kKb,
                                                            float* __restrict__ cand) {
    const int t = threadIdx.x;
    const int w = t >> 6, l = t & 63, lq = l & 15, lg = l >> 4;
    const int tg = w & 1, q = w >> 1;
    const int tok0 = blockIdx.x * 32;

    bf16x8 aq[4];
    {
        const unsigned short* qp = Qmb + (size_t)(tok0 + tg * 16 + lq) * 128 + lg * 8;
        #pragma unroll
        for (int c = 0; c < 4; c++) aq[c] = *(const bf16x8*)(qp + c * 32);
    }

    float L[4][8];
    #pragma unroll
    for (int j = 0; j < 4; j++)
        #pragma unroll
        for (int s = 0; s < 8; s++) L[j][s] = __uint_as_float(0xF2000000u | (unsigned)s);

    const unsigned short* kwb = kKb + (((size_t)q * 4096) << 7) + (size_t)lq * 128 + lg * 8;

    auto LD = [&](int kt, bf16x8* f) {
        const unsigned short* p = kwb + ((size_t)kt << 12);   // kt*32*128
        #pragma unroll
        for (int ct = 0; ct < 2; ct++)
            #pragma unroll
            for (int c = 0; c < 4; c++)
                f[ct * 4 + c] = *(const bf16x8*)(p + ct * 2048 + c * 32);
    };

    float B[4][4];
    auto SCORE = [&](const bf16x8* f, int kt, int sub) {
        #pragma unroll
        for (int ct = 0; ct < 2; ct++) {
            f32x4 s = {0.f, 0.f, 0.f, 0.f};
            #pragma unroll
            for (int c = 0; c < 4; c++)
                s = __builtin_amdgcn_mfma_f32_16x16x32_bf16(aq[c], f[ct * 4 + c], s, 0, 0, 0);
            const unsigned keyb = (unsigned)(q * 4096 + kt * 32 + ct * 16 + lq);
            #pragma unroll
            for (int j = 0; j < 4; j++) {
                unsigned u = __float_as_uint(s[j]);
                B[j][sub * 2 + ct] = __uint_as_float((u & 0xFFFFC000u) | keyb);
            }
        }
    };

    bf16x8 fA[8], fB[8];
    LD(0, fA);
    for (int t2 = 0; t2 < 64; t2++) {
        LD(2 * t2 + 1, fB);
        SCORE(fA, 2 * t2, 0);
        if (t2 < 63) LD(2 * t2 + 2, fA);
        SCORE(fB, 2 * t2 + 1, 1);
        #pragma unroll
        for (int j = 0; j < 4; j++) {
            CE(B[j][0], B[j][2]); CE(B[j][1], B[j][3]);
            CE(B[j][0], B[j][1]); CE(B[j][2], B[j][3]);
            CE(B[j][1], B[j][2]);
            L[j][4] = fmaxf(L[j][4], B[j][3]);
            L[j][5] = fmaxf(L[j][5], B[j][2]);
            L[j][6] = fmaxf(L[j][6], B[j][1]);
            L[j][7] = fmaxf(L[j][7], B[j][0]);
            CE(L[j][0], L[j][4]); CE(L[j][1], L[j][5]); CE(L[j][2], L[j][6]); CE(L[j][3], L[j][7]);
            CE(L[j][0], L[j][2]); CE(L[j][1], L[j][3]); CE(L[j][4], L[j][6]); CE(L[j][5], L[j][7]);
            CE(L[j][0], L[j][1]); CE(L[j][2], L[j][3]); CE(L[j][4], L[j][5]); CE(L[j][6], L[j][7]);
        }
    }
    #pragma unroll
    for (int j = 0; j < 4; j++) {
        const int tok = tok0 + tg * 16 + lg * 4 + j;
        float* cp = cand + ((size_t)tok << 9) + q * 128 + lq * 8;
        #pragma unroll
        for (int ss = 0; ss < 8; ss++) cp[ss] = L[j][ss];
    }
}
#undef CE

// ---------------- knowledge merge + V gather: one wave per token, 512 candidates ----------------
__global__ void __launch_bounds__(256) know_out_kernel(const float* __restrict__ cand,
                                                       const float* __restrict__ kV,
                                                       float* __restrict__ out) {
    const int t = threadIdx.x, w = t >> 6, l = t & 63;
    const int tok = blockIdx.x * 4 + w;
    const float* cp = cand + ((size_t)tok << 9);
    float lv[8];
    #pragma unroll
    for (int i = 0; i < 8; i++) lv[i] = cp[i * 64 + l];

    float topv[8]; int topi[8];
    #pragma unroll
    for (int kk = 0; kk < 8; kk++) {
        float m = lv[0];
        #pragma unroll
        for (int i = 1; i < 8; i++) m = fmaxf(m, lv[i]);
        #pragma unroll
        for (int d = 1; d < 64; d <<= 1) m = fmaxf(m, __shfl_xor(m, d));
        topv[kk] = m;
        topi[kk] = (int)(__float_as_uint(m) & 0x3FFFu);
        #pragma unroll
        for (int i = 0; i < 8; i++) lv[i] = (lv[i] == m) ? -1e31f : lv[i];
    }
    const float mx = topv[0];
    float e[8]; float ssum = 0.f;
    #pragma unroll
    for (int kk = 0; kk < 8; kk++) { e[kk] = __expf(topv[kk] - mx); ssum += e[kk]; }
    const float inv = 1.f / ssum;

    float4 acc[4];
    #pragma unroll
    for (int ch = 0; ch < 4; ch++) acc[ch] = float4{0.f, 0.f, 0.f, 0.f};
    #pragma unroll
    for (int kk = 0; kk < 8; kk++) {
        const float wk = e[kk] * inv;
        const float* vp = kV + ((size_t)topi[kk] << 10);
        #pragma unroll
        for (int ch = 0; ch < 4; ch++) {
            float4 v = *(const float4*)(vp + ch * 256 + l * 4);
            acc[ch].x += wk * v.x; acc[ch].y += wk * v.y;
            acc[ch].z += wk * v.z; acc[ch].w += wk * v.w;
        }
    }
    float* op = out + ((size_t)tok << 10);
    #pragma unroll
    for (int ch = 0; ch < 4; ch++) {
        float4 o = *(const float4*)(op + ch * 256 + l * 4);
        o.x += acc[ch].x; o.y += acc[ch].y; o.z += acc[ch].z; o.w += acc[ch].w;
        *(float4*)(op + ch * 256 + l * 4) = o;
    }
}

extern "C" void kernel_launch(void* const* d_in, const int* in_sizes, int n_in,
                              void* d_out, int out_size, void* d_ws, size_t ws_size,
                              hipStream_t stream) {
    const float* x    = (const float*)d_in[0];
    const float* imp  = (const float*)d_in[1];
    const float* Wc   = (const float*)d_in[2];
    const float* WQr  = (const float*)d_in[3];
    const float* WKr  = (const float*)d_in[4];
    const float* WVr  = (const float*)d_in[5];
    const float* Wm   = (const float*)d_in[6];
    const float* cneu = (const float*)d_in[7];
    const float* epool= (const float*)d_in[8];
    const float* kK   = (const float*)d_in[9];
    const float* kV   = (const float*)d_in[10];
    const float* WO   = (const float*)d_in[11];
    const float* ln1s = (const float*)d_in[12];
    const float* ln1b = (const float*)d_in[13];
    const float* ln2s = (const float*)d_in[14];
    const float* ln2b = (const float*)d_in[15];
    float* out = (float*)d_out;

    float* ws = (float*)d_ws;
    size_t o = 0;
    unsigned short* n1h = (unsigned short*)(ws + o); o += (size_t)BD * SD * DM / 2;
    unsigned short* n1l = (unsigned short*)(ws + o); o += (size_t)BD * SD * DM / 2;
    float* lgt   = ws + o; o += (size_t)BD * SD * 192;
    float* wpref = ws + o; o += (size_t)BD * SD * 160;
    float* dense = ws + o; o += (size_t)BD * 224;
    int*   ridx  = (int*)(ws + o); o += (size_t)BD * 5 * 8;
    float* rw    = ws + o; o += (size_t)BD * 5 * 8;
    unsigned short* WTh = (unsigned short*)(ws + o); o += (size_t)256 * 1024 / 2;
    unsigned short* WTl = (unsigned short*)(ws + o); o += (size_t)256 * 1024 / 2;
    unsigned short* scompT = (unsigned short*)(ws + o); o += (size_t)BD * RK * DM / 2;
    unsigned short* EQt = (unsigned short*)(ws + o); o += (size_t)BD * RK * DM / 2;
    unsigned short* EKt = (unsigned short*)(ws + o); o += (size_t)BD * RK * DM / 2;
    unsigned short* EVt = (unsigned short*)(ws + o); o += (size_t)BD * RK * DM / 2;
    unsigned short* hb  = (unsigned short*)(ws + o); o += (size_t)BD * SD * RK / 2;
    unsigned short* Qb16 = (unsigned short*)(ws + o); o += (size_t)BD * SD * DM / 2;
    unsigned short* Kb16 = (unsigned short*)(ws + o); o += (size_t)BD * SD * DM / 2;
    unsigned short* Vb16 = (unsigned short*)(ws + o); o += (size_t)BD * SD * DM / 2;
    unsigned short* attnb = (unsigned short*)(ws + o); o += (size_t)BD * SD * DM / 2;
    unsigned short* WOt = (unsigned short*)(ws + o); o += (size_t)DM * DM / 2;
    unsigned short* kKb = (unsigned short*)(ws + o); o += (size_t)NK * RK / 2;
    unsigned short* Qmb = (unsigned short*)(ws + o); o += (size_t)BD * SD * RK / 2;
    float* cand = ws + o; o += (size_t)BD * SD * 512;

    const int NTOK = BD * SD;

    // independent prep
    concatw_kernel<<<1024, 256, 0, stream>>>(Wc, WQr, WKr, WVr, Wm, WTh, WTl);
    tcvt_kernel<<<dim3(16, 16, 1), 256, 0, stream>>>(WO, WOt, DM, DM);
    cvt_bf16_kernel<<<(NK * RK / 4) / 256, 256, 0, stream>>>(kK, kKb, 0.0883883476483184f, NK * RK / 4);

    // phase 1
    ln_kernel<<<NTOK, 256, 0, stream>>>(x, ln1s, ln1b, n1h, n1l);
    gemm_split<<<dim3(3, NTOK / 128), 256, 0, stream>>>(n1h, n1l, WTh, WTl, lgt, 192, DM);
    softpref_kernel<<<NTOK / 64, 256, 0, stream>>>(lgt, imp, wpref);
    reduce_pref<<<BD * 160, 256, 0, stream>>>(wpref, dense, 160, 0);
    topk_kernel<<<1, 64, 0, stream>>>(dense, ridx, rw, 0, 4);
    combine_t_kernel<<<dim3(2, 16, BD), 256, 0, stream>>>(cneu, ridx, rw, 0, 8, scompT, DM, RK);
    combine_t_kernel<<<dim3(16, 2, BD), 256, 0, stream>>>(epool, ridx, rw, 1, 4, EQt, RK, DM);
    combine_t_kernel<<<dim3(16, 2, BD), 256, 0, stream>>>(epool, ridx, rw, 2, 4, EKt, RK, DM);
    combine_t_kernel<<<dim3(16, 2, BD), 256, 0, stream>>>(epool, ridx, rw, 3, 4, EVt, RK, DM);
    gemm_bf16<1, 0><<<dim3(1, 8, BD), 256, 0, stream>>>(n1h, scompT, nullptr, hb,
        SD, RK, DM, (long long)SD * DM, (long long)RK * DM, (long long)SD * RK);
    gemm_bf16<1, 0><<<dim3(8, 8, BD), 256, 0, stream>>>(hb, EQt, nullptr, Qb16,
        SD, DM, RK, (long long)SD * RK, (long long)DM * RK, (long long)SD * DM);
    gemm_bf16<1, 0><<<dim3(8, 8, BD), 256, 0, stream>>>(hb, EKt, nullptr, Kb16,
        SD, DM, RK, (long long)SD * RK, (long long)DM * RK, (long long)SD * DM);
    gemm_bf16<1, 0><<<dim3(8, 8, BD), 256, 0, stream>>>(hb, EVt, nullptr, Vb16,
        SD, DM, RK, (long long)SD * RK, (long long)DM * RK, (long long)SD * DM);
    attn_mfma_kernel<<<dim3(8, NH, BD), 256, 0, stream>>>(Qb16, Kb16, Vb16, attnb);
    gemm_bf16<0, 1><<<dim3(8, 64, 1), 256, 0, stream>>>(attnb, WOt, x, out,
        NTOK, DM, DM, 0, 0, 0);

    // phase 2
    ln_kernel<<<NTOK, 256, 0, stream>>>(out, ln2s, ln2b, n1h, n1l);
    gemm_split<<<dim3(1, NTOK / 128), 256, 0, stream>>>(n1h, n1l,
        WTh + (size_t)192 * 1024, WTl + (size_t)192 * 1024, lgt, 64, DM);
    softm_kernel<<<NTOK / 256, 256, 0, stream>>>(lgt, imp, wpref);
    reduce_pref<<<BD * 64, 256, 0, stream>>>(wpref, dense, 64, 160);
    topk_kernel<<<1, 64, 0, stream>>>(dense, ridx, rw, 4, 1);
    combine_t_kernel<<<dim3(2, 16, BD), 256, 0, stream>>>(cneu, ridx, rw, 4, 8, scompT, DM, RK);
    gemm_bf16<1, 0><<<dim3(1, 8, BD), 256, 0, stream>>>(n1h, scompT, nullptr, Qmb,
        SD, RK, DM, (long long)SD * DM, (long long)RK * DM, (long long)SD * RK);
    know_score_kernel<<<NTOK / 32, 512, 0, stream>>>(Qmb, kKb, cand);
    know_out_kernel<<<NTOK / 4, 256, 0, stream>>>(cand, kV, out);
}

// Round 10
// 691.504 us; speedup vs baseline: 9.4365x; 1.1845x over previous
//
#include <hip/hip_runtime.h>
#include <hip/hip_bf16.h>

#define BD 8
#define SD 1024
#define DM 1024
#define NH 16
#define DH 64
#define RK 128
#define NK 16384

typedef __attribute__((ext_vector_type(8))) short bf16x8;
typedef __attribute__((ext_vector_type(4))) float f32x4;

__device__ __forceinline__ unsigned short f2b(float f) {
    unsigned u = __float_as_uint(f);
    unsigned r = (u + 0x7FFFu + ((u >> 16) & 1u)) >> 16;
    return (unsigned short)r;
}
__device__ __forceinline__ float b2f(unsigned short h) {
    return __uint_as_float(((unsigned)h) << 16);
}

// ---------------- LayerNorm: bf16 hi/lo outputs ----------------
__global__ void __launch_bounds__(256) ln_kernel(const float* __restrict__ x,
                                                 const float* __restrict__ sc,
                                                 const float* __restrict__ bi,
                                                 unsigned short* __restrict__ outh,
                                                 unsigned short* __restrict__ outl) {
    const int tok = blockIdx.x;
    __shared__ float xs[DM];
    __shared__ float red[256];
    const float* xp = x + (size_t)tok * DM;
    float s = 0.f;
    for (int i = threadIdx.x; i < DM; i += 256) { float v = xp[i]; xs[i] = v; s += v; }
    red[threadIdx.x] = s; __syncthreads();
    for (int st = 128; st; st >>= 1) { if (threadIdx.x < st) red[threadIdx.x] += red[threadIdx.x + st]; __syncthreads(); }
    float mu = red[0] * (1.f / DM);
    __syncthreads();
    float vs = 0.f;
    for (int i = threadIdx.x; i < DM; i += 256) { float d = xs[i] - mu; vs += d * d; }
    red[threadIdx.x] = vs; __syncthreads();
    for (int st = 128; st; st >>= 1) { if (threadIdx.x < st) red[threadIdx.x] += red[threadIdx.x + st]; __syncthreads(); }
    float rs = rsqrtf(red[0] * (1.f / DM) + 1e-5f);
    for (int i = threadIdx.x; i < DM; i += 256) {
        float v = (xs[i] - mu) * rs * sc[i] + bi[i];
        unsigned short h = f2b(v);
        outh[(size_t)tok * DM + i] = h;
        outl[(size_t)tok * DM + i] = f2b(v - b2f(h));
    }
}

// ---------------- router weights -> transposed hi/lo bf16 [256][1024] ----------------
__global__ void __launch_bounds__(256) concatw_kernel(const float* __restrict__ Wc,
                                                      const float* __restrict__ WQr,
                                                      const float* __restrict__ WKr,
                                                      const float* __restrict__ WVr,
                                                      const float* __restrict__ Wm,
                                                      unsigned short* __restrict__ WTh,
                                                      unsigned short* __restrict__ WTl) {
    const int i = blockIdx.x * 256 + threadIdx.x;
    const int c = i >> 10, d = i & 1023;
    float v = 0.f;
    if (c < 64)       v = Wc[d * 64 + c];
    else if (c < 96)  v = WQr[d * 32 + c - 64];
    else if (c < 128) v = WKr[d * 32 + c - 96];
    else if (c < 160) v = WVr[d * 32 + c - 128];
    else if (c >= 192) v = Wm[d * 64 + c - 192];
    unsigned short h = f2b(v);
    WTh[i] = h;
    WTl[i] = f2b(v - b2f(h));
}

// ---------------- split-bf16 logits GEMM ----------------
__global__ void __launch_bounds__(256) gemm_split(const unsigned short* __restrict__ Ah,
                                                  const unsigned short* __restrict__ Al,
                                                  const unsigned short* __restrict__ Bh,
                                                  const unsigned short* __restrict__ Bl,
                                                  float* __restrict__ C,
                                                  int N, int K) {
    const int row0 = blockIdx.y * 128, col0 = blockIdx.x * 64;
    const int t = threadIdx.x;
    const int w = t >> 6, l = t & 63, lq = l & 15, lg = l >> 4;
    __shared__ unsigned short sAh[128 * 64];
    __shared__ unsigned short sAl[128 * 64];
    __shared__ unsigned short sBh[64 * 64];
    __shared__ unsigned short sBl[64 * 64];
    f32x4 acc[2][4];
    #pragma unroll
    for (int mi = 0; mi < 2; mi++)
        #pragma unroll
        for (int ni = 0; ni < 4; ni++) acc[mi][ni] = f32x4{0.f, 0.f, 0.f, 0.f};

    for (int k0 = 0; k0 < K; k0 += 64) {
        __syncthreads();
        #pragma unroll
        for (int p = 0; p < 4; p++) {
            const int e = t * 8 + p * 2048;
            const int row = e >> 6, col = e & 63;
            const int sw = (e * 2) ^ ((row & 7) << 4);
            *(bf16x8*)((char*)sAh + sw) = *(const bf16x8*)(Ah + (size_t)(row0 + row) * K + k0 + col);
            *(bf16x8*)((char*)sAl + sw) = *(const bf16x8*)(Al + (size_t)(row0 + row) * K + k0 + col);
        }
        #pragma unroll
        for (int p = 0; p < 2; p++) {
            const int e = t * 8 + p * 2048;
            const int row = e >> 6, col = e & 63;
            const int sw = (e * 2) ^ ((row & 7) << 4);
            *(bf16x8*)((char*)sBh + sw) = *(const bf16x8*)(Bh + (size_t)(col0 + row) * K + k0 + col);
            *(bf16x8*)((char*)sBl + sw) = *(const bf16x8*)(Bl + (size_t)(col0 + row) * K + k0 + col);
        }
        __syncthreads();
        #pragma unroll
        for (int kk = 0; kk < 2; kk++) {
            bf16x8 ah[2], al[2], bh[4], bl[4];
            #pragma unroll
            for (int mi = 0; mi < 2; mi++) {
                const int r = w * 32 + mi * 16 + lq;
                const int off = (r * 128 + lg * 16 + kk * 64) ^ ((r & 7) << 4);
                ah[mi] = *(const bf16x8*)((const char*)sAh + off);
                al[mi] = *(const bf16x8*)((const char*)sAl + off);
            }
            #pragma unroll
            for (int ni = 0; ni < 4; ni++) {
                const int r = ni * 16 + lq;
                const int off = (r * 128 + lg * 16 + kk * 64) ^ ((r & 7) << 4);
                bh[ni] = *(const bf16x8*)((const char*)sBh + off);
                bl[ni] = *(const bf16x8*)((const char*)sBl + off);
            }
            #pragma unroll
            for (int mi = 0; mi < 2; mi++)
                #pragma unroll
                for (int ni = 0; ni < 4; ni++) {
                    acc[mi][ni] = __builtin_amdgcn_mfma_f32_16x16x32_bf16(ah[mi], bh[ni], acc[mi][ni], 0, 0, 0);
                    acc[mi][ni] = __builtin_amdgcn_mfma_f32_16x16x32_bf16(ah[mi], bl[ni], acc[mi][ni], 0, 0, 0);
                    acc[mi][ni] = __builtin_amdgcn_mfma_f32_16x16x32_bf16(al[mi], bh[ni], acc[mi][ni], 0, 0, 0);
                }
        }
    }
    #pragma unroll
    for (int mi = 0; mi < 2; mi++)
        #pragma unroll
        for (int j = 0; j < 4; j++) {
            const int row = row0 + w * 32 + mi * 16 + lg * 4 + j;
            #pragma unroll
            for (int ni = 0; ni < 4; ni++)
                C[(size_t)row * N + col0 + ni * 16 + lq] = acc[mi][ni][j];
        }
}

// ---------------- phase-1 softmax prefs ----------------
__global__ void __launch_bounds__(256) softpref_kernel(const float* __restrict__ lgt,
                                                       const float* __restrict__ imp,
                                                       float* __restrict__ wpref) {
    const int tok = blockIdx.x * 64 + (threadIdx.x >> 2);
    const int sg = threadIdx.x & 3;
    const int o = (sg == 0) ? 0 : (64 + 32 * (sg - 1));
    const int n = (sg == 0) ? 64 : 32;
    const float* lp = lgt + (size_t)tok * 192 + o;
    float m = -1e30f;
    for (int i = 0; i < n; i++) m = fmaxf(m, lp[i]);
    float ss = 0.f;
    for (int i = 0; i < n; i++) ss += __expf(lp[i] - m);
    const float scl = imp[tok] / ss;
    float* wp = wpref + (size_t)tok * 160 + o;
    for (int i = 0; i < n; i++) wp[i] = __expf(lp[i] - m) * scl;
}

// ---------------- phase-2 softmax prefs ----------------
__global__ void __launch_bounds__(256) softm_kernel(const float* __restrict__ lgt,
                                                    const float* __restrict__ imp,
                                                    float* __restrict__ wpref) {
    const int tok = blockIdx.x * 256 + threadIdx.x;
    const float* lp = lgt + (size_t)tok * 64;
    float m = -1e30f;
    for (int i = 0; i < 64; i++) m = fmaxf(m, lp[i]);
    float ss = 0.f;
    for (int i = 0; i < 64; i++) ss += __expf(lp[i] - m);
    const float scl = imp[tok] / ss;
    for (int i = 0; i < 64; i++) wpref[(size_t)tok * 64 + i] = __expf(lp[i] - m) * scl;
}

// ---------------- deterministic reduce over S ----------------
__global__ void __launch_bounds__(256) reduce_pref(const float* __restrict__ wpref,
                                                   float* __restrict__ dense,
                                                   int ncols, int outoff) {
    const int b = blockIdx.x / ncols, c = blockIdx.x % ncols;
    __shared__ float red[256];
    float s = 0.f;
    for (int si = threadIdx.x; si < SD; si += 256)
        s += wpref[((size_t)(b * SD + si)) * ncols + c];
    red[threadIdx.x] = s; __syncthreads();
    for (int st = 128; st; st >>= 1) { if (threadIdx.x < st) red[threadIdx.x] += red[threadIdx.x + st]; __syncthreads(); }
    if (threadIdx.x == 0) dense[b * 224 + outoff + c] = red[0];
}

// ---------------- top-k sparsify + renormalize ----------------
__global__ void topk_kernel(const float* __restrict__ dense,
                            int* __restrict__ ridx, float* __restrict__ rw,
                            int r0, int nr) {
    const int t = threadIdx.x;
    if (t >= BD * nr) return;
    const int b = t / nr, r = r0 + (t % nr);
    const int offs[5] = {0, 64, 96, 128, 160};
    const int ns[5]   = {64, 32, 32, 32, 64};
    const int ks[5]   = {8, 4, 4, 4, 8};
    const float* dv = dense + b * 224 + offs[r];
    const int n = ns[r], k = ks[r];
    unsigned long long mask = 0;
    float vals[8]; int idxs[8];
    float ssum = 0.f;
    for (int kk = 0; kk < k; kk++) {
        float best = -1e30f; int bi = 0;
        for (int i = 0; i < n; i++)
            if (!((mask >> i) & 1ull) && dv[i] > best) { best = dv[i]; bi = i; }
        mask |= 1ull << bi;
        vals[kk] = best; idxs[kk] = bi; ssum += best;
    }
    float inv = 1.f / (ssum + 1e-8f);
    for (int kk = 0; kk < 8; kk++) {
        ridx[(b * 5 + r) * 8 + kk] = (kk < k) ? idxs[kk] : 0;
        rw[(b * 5 + r) * 8 + kk]   = (kk < k) ? vals[kk] * inv : 0.f;
    }
}

// ---------------- fused mixture + transpose + bf16 ----------------
__global__ void __launch_bounds__(256) combine_t_kernel(const float* __restrict__ pool,
                                                        const int* __restrict__ ridx,
                                                        const float* __restrict__ rw,
                                                        int router, int kc,
                                                        unsigned short* __restrict__ outT,
                                                        int Rp, int Cp) {
    const int b = blockIdx.z;
    const int r0 = blockIdx.y * 64, c0 = blockIdx.x * 64;
    __shared__ float ls[64][65];
    const int* ii = ridx + (b * 5 + router) * 8;
    const float* ww = rw + (b * 5 + router) * 8;
    const int t = threadIdx.x;
    const int rr = t >> 4, cc = (t & 15) * 4;
    #pragma unroll
    for (int p = 0; p < 4; p++) {
        const int r = rr + p * 16;
        float4 acc = {0.f, 0.f, 0.f, 0.f};
        for (int kk = 0; kk < kc; kk++) {
            const float w = ww[kk];
            float4 v = *(const float4*)&pool[((size_t)ii[kk] * Rp + r0 + r) * Cp + c0 + cc];
            acc.x += w * v.x; acc.y += w * v.y; acc.z += w * v.z; acc.w += w * v.w;
        }
        ls[r][cc] = acc.x; ls[r][cc + 1] = acc.y; ls[r][cc + 2] = acc.z; ls[r][cc + 3] = acc.w;
    }
    __syncthreads();
    unsigned short* op = outT + (size_t)b * Rp * Cp;
    #pragma unroll
    for (int q = 0; q < 2; q++) {
        const int c = (t >> 3) + q * 32;
        const int r8 = (t & 7) * 8;
        union { unsigned short s[8]; bf16x8 v; } u;
        #pragma unroll
        for (int j = 0; j < 8; j++) u.s[j] = f2b(ls[r8 + j][c]);
        *(bf16x8*)(op + (size_t)(c0 + c) * Rp + r0 + r8) = u.v;
    }
}

// ---------------- tile transpose + fp32->bf16 (WO only) ----------------
__global__ void __launch_bounds__(256) tcvt_kernel(const float* __restrict__ src,
                                                   unsigned short* __restrict__ dst,
                                                   int R, int Cc) {
    __shared__ float ls[64][65];
    const int r0 = blockIdx.y * 64, c0 = blockIdx.x * 64;
    const int t = threadIdx.x;
    #pragma unroll
    for (int p = 0; p < 16; p++) {
        const int e = p * 256 + t;
        const int r = e >> 6, c = e & 63;
        ls[r][c] = src[(size_t)(r0 + r) * Cc + c0 + c];
    }
    __syncthreads();
    #pragma unroll
    for (int p = 0; p < 16; p++) {
        const int e = p * 256 + t;
        const int c = e >> 6, r = e & 63;
        dst[(size_t)(c0 + c) * R + r0 + r] = f2b(ls[r][c]);
    }
}

// ---------------- fp32 -> bf16 convert with scale ----------------
__global__ void __launch_bounds__(256) cvt_bf16_kernel(const float* __restrict__ src,
                                                       unsigned short* __restrict__ dst,
                                                       float scale, int n4) {
    const int i = blockIdx.x * 256 + threadIdx.x;
    if (i >= n4) return;
    float4 v = ((const float4*)src)[i];
    unsigned r0 = (unsigned)f2b(v.x * scale) | ((unsigned)f2b(v.y * scale) << 16);
    unsigned r1 = (unsigned)f2b(v.z * scale) | ((unsigned)f2b(v.w * scale) << 16);
    uint2 o; o.x = r0; o.y = r1;
    ((uint2*)dst)[i] = o;
}

// ---------------- bf16 MFMA GEMM: C = A[M][K] @ Bt[N][K]^T (+X), 128x128 tile ----------------
template<int OUTB, int HASX>
__global__ void __launch_bounds__(256) gemm_bf16(const unsigned short* __restrict__ A,
                                                 const unsigned short* __restrict__ Bt,
                                                 const float* __restrict__ X,
                                                 void* __restrict__ Cv,
                                                 int M, int N, int K,
                                                 long long sA, long long sB, long long sC) {
    const int bz = blockIdx.z;
    const unsigned short* Ab = A + (size_t)bz * sA;
    const unsigned short* Btb = Bt + (size_t)bz * sB;
    const int row0 = blockIdx.y * 128, col0 = blockIdx.x * 128;
    const int t = threadIdx.x;
    const int w = t >> 6, l = t & 63, lq = l & 15, lg = l >> 4;
    const int wr = w >> 1, wc = w & 1;
    __shared__ unsigned short As[128 * 64];
    __shared__ unsigned short Bs[128 * 64];
    f32x4 acc[4][4];
    #pragma unroll
    for (int mi = 0; mi < 4; mi++)
        #pragma unroll
        for (int ni = 0; ni < 4; ni++) acc[mi][ni] = f32x4{0.f, 0.f, 0.f, 0.f};

    for (int k0 = 0; k0 < K; k0 += 64) {
        __syncthreads();
        #pragma unroll
        for (int p = 0; p < 4; p++) {
            const int e = t * 8 + p * 2048;
            const int row = e >> 6, col = e & 63;
            bf16x8 va = *(const bf16x8*)(Ab + (size_t)(row0 + row) * K + k0 + col);
            *(bf16x8*)((char*)As + ((row * 128 + col * 2) ^ ((row & 7) << 4))) = va;
            bf16x8 vb = *(const bf16x8*)(Btb + (size_t)(col0 + row) * K + k0 + col);
            *(bf16x8*)((char*)Bs + ((row * 128 + col * 2) ^ ((row & 7) << 4))) = vb;
        }
        __syncthreads();
        #pragma unroll
        for (int kk = 0; kk < 2; kk++) {
            bf16x8 af[4], bg[4];
            #pragma unroll
            for (int mi = 0; mi < 4; mi++) {
                const int r = wr * 64 + mi * 16 + lq;
                af[mi] = *(const bf16x8*)((const char*)As + ((r * 128 + lg * 16 + kk * 64) ^ ((r & 7) << 4)));
            }
            #pragma unroll
            for (int ni = 0; ni < 4; ni++) {
                const int r = wc * 64 + ni * 16 + lq;
                bg[ni] = *(const bf16x8*)((const char*)Bs + ((r * 128 + lg * 16 + kk * 64) ^ ((r & 7) << 4)));
            }
            #pragma unroll
            for (int mi = 0; mi < 4; mi++)
                #pragma unroll
                for (int ni = 0; ni < 4; ni++)
                    acc[mi][ni] = __builtin_amdgcn_mfma_f32_16x16x32_bf16(af[mi], bg[ni], acc[mi][ni], 0, 0, 0);
        }
    }
    #pragma unroll
    for (int mi = 0; mi < 4; mi++) {
        #pragma unroll
        for (int j = 0; j < 4; j++) {
            const int row = row0 + wr * 64 + mi * 16 + lg * 4 + j;
            #pragma unroll
            for (int ni = 0; ni < 4; ni++) {
                const int col = col0 + wc * 64 + ni * 16 + lq;
                float v = acc[mi][ni][j];
                if (HASX) v += X[(size_t)row * N + col];
                if (OUTB) ((unsigned short*)Cv)[(size_t)bz * sC + (size_t)row * N + col] = f2b(v);
                else      ((float*)Cv)[(size_t)bz * sC + (size_t)row * N + col] = v;
            }
        }
    }
}

// ---------------- flash attention: paired q-tiles (qt, 15-qt), dbuf K/V, 1 barrier/tile ----------------
#define SWZV(d) (((((d) >> 1) ^ ((d) >> 3)) & 7) << 4)
__global__ void __launch_bounds__(256) attn_mfma_kernel(const unsigned short* __restrict__ Q,
                                                        const unsigned short* __restrict__ K,
                                                        const unsigned short* __restrict__ V,
                                                        unsigned short* __restrict__ O) {
    const int qt = blockIdx.x, hh = blockIdx.y, b = blockIdx.z;
    const int t = threadIdx.x;
    const int w = t >> 6, l = t & 63, lq = l & 15, lg = l >> 4;

    __shared__ unsigned short ks[2][64 * 64];
    __shared__ unsigned short vt[2][64 * 64];
    __shared__ unsigned short pl[4][16 * 64];

    const size_t base = (size_t)b * SD * DM + (size_t)hh * DH;
    const int qA = qt;
    const int qB = 15 - qt;

    bf16x8 aqA[2], aqB[2];
    {
        const unsigned short* qp = Q + base + (size_t)(qA * 64 + w * 16 + lq) * DM + lg * 8;
        aqA[0] = *(const bf16x8*)qp; aqA[1] = *(const bf16x8*)(qp + 32);
        const unsigned short* qp2 = Q + base + (size_t)(qB * 64 + w * 16 + lq) * DM + lg * 8;
        aqB[0] = *(const bf16x8*)qp2; aqB[1] = *(const bf16x8*)(qp2 + 32);
    }

    f32x4 oA[4], oB[4];
    #pragma unroll
    for (int dt = 0; dt < 4; dt++) { oA[dt] = f32x4{0.f,0.f,0.f,0.f}; oB[dt] = f32x4{0.f,0.f,0.f,0.f}; }
    float mA[4] = {-1e30f,-1e30f,-1e30f,-1e30f}, sA[4] = {0.f,0.f,0.f,0.f};
    float mB[4] = {-1e30f,-1e30f,-1e30f,-1e30f}, sB[4] = {0.f,0.f,0.f,0.f};

    const int ntile = 16 - qt;
    const int srow = t >> 3;
    const int scol = (t & 7) * 8;

    int cur = 0;

    #pragma unroll
    for (int p = 0; p < 2; p++) {
        const int row = srow + 32 * p;
        bf16x8 kv = *(const bf16x8*)(K + base + (size_t)row * DM + scol);
        *(bf16x8*)((char*)&ks[0][0] + ((row * 128 + scol * 2) ^ ((row & 7) << 4))) = kv;
        bf16x8 vv = *(const bf16x8*)(V + base + (size_t)row * DM + scol);
        #pragma unroll
        for (int j2 = 0; j2 < 8; j2++) {
            const int d = scol + j2;
            *(unsigned short*)((char*)&vt[0][0] + ((d * 128 + row * 2) ^ SWZV(d))) = (unsigned short)vv[j2];
        }
    }
    __syncthreads();

    auto compute = [&](int q0, const bf16x8* aq, f32x4* o_, float* m_, float* s_, int kt) {
        const f32x4 zero4 = {0.f, 0.f, 0.f, 0.f};
        f32x4 sacc[4];
        #pragma unroll
        for (int ct = 0; ct < 4; ct++) {
            const int krow = ct * 16 + lq;
            bf16x8 b0 = *(const bf16x8*)((const char*)&ks[cur][0] + ((krow * 128 + lg * 16) ^ ((lq & 7) << 4)));
            bf16x8 b1 = *(const bf16x8*)((const char*)&ks[cur][0] + ((krow * 128 + lg * 16 + 64) ^ ((lq & 7) << 4)));
            f32x4 s = __builtin_amdgcn_mfma_f32_16x16x32_bf16(aq[0], b0, zero4, 0, 0, 0);
            s = __builtin_amdgcn_mfma_f32_16x16x32_bf16(aq[1], b1, s, 0, 0, 0);
            sacc[ct] = s;
        }
        float tm[4];
        #pragma unroll
        for (int j = 0; j < 4; j++) {
            const int qg = q0 * 64 + w * 16 + lg * 4 + j;
            float mx = -1e30f;
            #pragma unroll
            for (int ct = 0; ct < 4; ct++) {
                const int kg = kt * 64 + ct * 16 + lq;
                float v = sacc[ct][j] * 0.125f;
                v = (kg <= qg) ? v : -1e30f;
                sacc[ct][j] = v;
                mx = fmaxf(mx, v);
            }
            #pragma unroll
            for (int d = 1; d < 16; d <<= 1) mx = fmaxf(mx, __shfl_xor(mx, d));
            tm[j] = mx;
        }
        #pragma unroll
        for (int j = 0; j < 4; j++) {
            const float nm = fmaxf(m_[j], tm[j]);
            const float so = __expf(m_[j] - nm);
            m_[j] = nm;
            float rs = 0.f;
            const int prow = lg * 4 + j;
            #pragma unroll
            for (int ct = 0; ct < 4; ct++) {
                const float p = __expf(sacc[ct][j] - nm);
                rs += p;
                const int byteoff = ((prow * 128) + (ct * 16 + lq) * 2) ^ ((prow & 7) << 4);
                *(unsigned short*)((char*)&pl[w][0] + byteoff) = f2b(p);
            }
            #pragma unroll
            for (int d = 1; d < 16; d <<= 1) rs += __shfl_xor(rs, d);
            s_[j] = s_[j] * so + rs;
            #pragma unroll
            for (int dt = 0; dt < 4; dt++) o_[dt][j] *= so;
        }
        asm volatile("s_waitcnt lgkmcnt(0)" ::: "memory");
        __builtin_amdgcn_sched_barrier(0);
        #pragma unroll
        for (int c = 0; c < 2; c++) {
            bf16x8 pa = *(const bf16x8*)((const char*)&pl[w][0] +
                          ((lq * 128 + lg * 16 + 64 * c) ^ ((lq & 7) << 4)));
            #pragma unroll
            for (int dt = 0; dt < 4; dt++) {
                const int dd = dt * 16 + lq;
                bf16x8 bv = *(const bf16x8*)((const char*)&vt[cur][0] +
                              ((dd * 128 + lg * 16 + 64 * c) ^ SWZV(dd)));
                o_[dt] = __builtin_amdgcn_mfma_f32_16x16x32_bf16(pa, bv, o_[dt], 0, 0, 0);
            }
        }
    };

    const int mymaxA = qA * 64 + w * 16 + 15;
    for (int kt = 0; kt < ntile; kt++) {
        bf16x8 kN[2], vN[2];
        const bool pre = (kt + 1 < ntile);
        if (pre) {
            #pragma unroll
            for (int p = 0; p < 2; p++) {
                const int row = srow + 32 * p;
                kN[p] = *(const bf16x8*)(K + base + (size_t)((kt + 1) * 64 + row) * DM + scol);
                vN[p] = *(const bf16x8*)(V + base + (size_t)((kt + 1) * 64 + row) * DM + scol);
            }
        }
        compute(qB, aqB, oB, mB, sB, kt);
        if (kt * 64 <= mymaxA) compute(qA, aqA, oA, mA, sA, kt);
        if (pre) {
            #pragma unroll
            for (int p = 0; p < 2; p++) {
                const int row = srow + 32 * p;
                *(bf16x8*)((char*)&ks[cur ^ 1][0] + ((row * 128 + scol * 2) ^ ((row & 7) << 4))) = kN[p];
                #pragma unroll
                for (int j2 = 0; j2 < 8; j2++) {
                    const int d = scol + j2;
                    *(unsigned short*)((char*)&vt[cur ^ 1][0] + ((d * 128 + row * 2) ^ SWZV(d))) =
                        (unsigned short)vN[p][j2];
                }
            }
        }
        __syncthreads();
        cur ^= 1;
    }

    #pragma unroll
    for (int j = 0; j < 4; j++) {
        const float invA = 1.f / sA[j];
        const float invB = 1.f / sB[j];
        const int rowA = qA * 64 + w * 16 + lg * 4 + j;
        const int rowB = qB * 64 + w * 16 + lg * 4 + j;
        unsigned short* opA = O + base + (size_t)rowA * DM;
        unsigned short* opB = O + base + (size_t)rowB * DM;
        #pragma unroll
        for (int dt = 0; dt < 4; dt++) {
            opA[dt * 16 + lq] = f2b(oA[dt][j] * invA);
            opB[dt * 16 + lq] = f2b(oB[dt][j] * invB);
        }
    }
}
#undef SWZV

// ---------------- knowledge scores: wave-private LDS tiles + bitonic merge (r8 proven) ----------------
#define CE(a, b) { float hi_ = fmaxf(a, b), lo_ = fminf(a, b); a = hi_; b = lo_; }
__global__ void __launch_bounds__(512, 4) know_score_kernel(const unsigned short* __restrict__ Qmb,
                                                            const unsigned short* __restrict__ kKb,
                                                            float* __restrict__ cand) {
    const int t = threadIdx.x;
    const int w = t >> 6, l = t & 63, lq = l & 15, lg = l >> 4;
    const int tok0 = blockIdx.x * 16;
    __shared__ unsigned short ks[8][32 * 128];

    bf16x8 aq[4];
    {
        const unsigned short* qp = Qmb + (size_t)(tok0 + lq) * 128 + lg * 8;
        #pragma unroll
        for (int c = 0; c < 4; c++) aq[c] = *(const bf16x8*)(qp + c * 32);
    }

    float L[4][8];
    #pragma unroll
    for (int j = 0; j < 4; j++)
        #pragma unroll
        for (int s = 0; s < 8; s++) L[j][s] = __uint_as_float(0xF2000000u | (unsigned)s);

    const unsigned short* gsrc = kKb + (((size_t)w * 2048) << 7) + l * 8;
    unsigned short* myks = &ks[w][0];

    bf16x8 vreg[8];
    #pragma unroll
    for (int p = 0; p < 8; p++) vreg[p] = *(const bf16x8*)(gsrc + p * 512);

    for (int t2 = 0; t2 < 32; t2++) {
        float B[4][4];
        #pragma unroll
        for (int sub = 0; sub < 2; sub++) {
            const int kt = t2 * 2 + sub;
            #pragma unroll
            for (int p = 0; p < 8; p++) {
                const int e = p * 512 + l * 8;
                const int row = e >> 7;
                *(bf16x8*)((char*)myks + ((e * 2) ^ ((row & 7) << 4))) = vreg[p];
            }
            if (kt < 63) {
                const unsigned short* src2 = gsrc + (size_t)(kt + 1) * 4096;
                #pragma unroll
                for (int p = 0; p < 8; p++) vreg[p] = *(const bf16x8*)(src2 + p * 512);
            }
            #pragma unroll
            for (int ct = 0; ct < 2; ct++) {
                const int row = ct * 16 + lq;
                const char* kb = (const char*)myks + row * 256;
                const int sw = (row & 7) << 4;
                f32x4 s = {0.f, 0.f, 0.f, 0.f};
                #pragma unroll
                for (int c = 0; c < 4; c++) {
                    bf16x8 bv = *(const bf16x8*)(kb + ((c * 64 + lg * 16) ^ sw));
                    s = __builtin_amdgcn_mfma_f32_16x16x32_bf16(aq[c], bv, s, 0, 0, 0);
                }
                const unsigned keyb = (unsigned)(w * 2048 + kt * 32 + ct * 16 + lq);
                #pragma unroll
                for (int j = 0; j < 4; j++) {
                    unsigned u = __float_as_uint(s[j]);
                    B[j][sub * 2 + ct] = __uint_as_float((u & 0xFFFFC000u) | keyb);
                }
            }
        }
        #pragma unroll
        for (int j = 0; j < 4; j++) {
            CE(B[j][0], B[j][2]); CE(B[j][1], B[j][3]);
            CE(B[j][0], B[j][1]); CE(B[j][2], B[j][3]);
            CE(B[j][1], B[j][2]);
            L[j][4] = fmaxf(L[j][4], B[j][3]);
            L[j][5] = fmaxf(L[j][5], B[j][2]);
            L[j][6] = fmaxf(L[j][6], B[j][1]);
            L[j][7] = fmaxf(L[j][7], B[j][0]);
            CE(L[j][0], L[j][4]); CE(L[j][1], L[j][5]); CE(L[j][2], L[j][6]); CE(L[j][3], L[j][7]);
            CE(L[j][0], L[j][2]); CE(L[j][1], L[j][3]); CE(L[j][4], L[j][6]); CE(L[j][5], L[j][7]);
            CE(L[j][0], L[j][1]); CE(L[j][2], L[j][3]); CE(L[j][4], L[j][5]); CE(L[j][6], L[j][7]);
        }
    }
    #pragma unroll
    for (int j = 0; j < 4; j++) {
        const int tok = tok0 + lg * 4 + j;
        float* cp = cand + ((size_t)tok << 10) + w * 128 + lq * 8;
        #pragma unroll
        for (int ss = 0; ss < 8; ss++) cp[ss] = L[j][ss];
    }
}
#undef CE

// ---------------- knowledge merge + V gather: one wave per token, 1024 candidates ----------------
__global__ void __launch_bounds__(256) know_out_kernel(const float* __restrict__ cand,
                                                       const float* __restrict__ kV,
                                                       float* __restrict__ out) {
    const int t = threadIdx.x, w = t >> 6, l = t & 63;
    const int tok = blockIdx.x * 4 + w;
    const float* cp = cand + ((size_t)tok << 10);
    float lv[16];
    #pragma unroll
    for (int i = 0; i < 16; i++) lv[i] = cp[i * 64 + l];

    float topv[8]; int topi[8];
    #pragma unroll
    for (int kk = 0; kk < 8; kk++) {
        float m = lv[0];
        #pragma unroll
        for (int i = 1; i < 16; i++) m = fmaxf(m, lv[i]);
        #pragma unroll
        for (int d = 1; d < 64; d <<= 1) m = fmaxf(m, __shfl_xor(m, d));
        topv[kk] = m;
        topi[kk] = (int)(__float_as_uint(m) & 0x3FFFu);
        #pragma unroll
        for (int i = 0; i < 16; i++) lv[i] = (lv[i] == m) ? -1e31f : lv[i];
    }
    const float mx = topv[0];
    float e[8]; float ssum = 0.f;
    #pragma unroll
    for (int kk = 0; kk < 8; kk++) { e[kk] = __expf(topv[kk] - mx); ssum += e[kk]; }
    const float inv = 1.f / ssum;

    float4 acc[4];
    #pragma unroll
    for (int ch = 0; ch < 4; ch++) acc[ch] = float4{0.f, 0.f, 0.f, 0.f};
    #pragma unroll
    for (int kk = 0; kk < 8; kk++) {
        const float wk = e[kk] * inv;
        const float* vp = kV + ((size_t)topi[kk] << 10);
        #pragma unroll
        for (int ch = 0; ch < 4; ch++) {
            float4 v = *(const float4*)(vp + ch * 256 + l * 4);
            acc[ch].x += wk * v.x; acc[ch].y += wk * v.y;
            acc[ch].z += wk * v.z; acc[ch].w += wk * v.w;
        }
    }
    float* op = out + ((size_t)tok << 10);
    #pragma unroll
    for (int ch = 0; ch < 4; ch++) {
        float4 o = *(const float4*)(op + ch * 256 + l * 4);
        o.x += acc[ch].x; o.y += acc[ch].y; o.z += acc[ch].z; o.w += acc[ch].w;
        *(float4*)(op + ch * 256 + l * 4) = o;
    }
}

extern "C" void kernel_launch(void* const* d_in, const int* in_sizes, int n_in,
                              void* d_out, int out_size, void* d_ws, size_t ws_size,
                              hipStream_t stream) {
    const float* x    = (const float*)d_in[0];
    const float* imp  = (const float*)d_in[1];
    const float* Wc   = (const float*)d_in[2];
    const float* WQr  = (const float*)d_in[3];
    const float* WKr  = (const float*)d_in[4];
    const float* WVr  = (const float*)d_in[5];
    const float* Wm   = (const float*)d_in[6];
    const float* cneu = (const float*)d_in[7];
    const float* epool= (const float*)d_in[8];
    const float* kK   = (const float*)d_in[9];
    const float* kV   = (const float*)d_in[10];
    const float* WO   = (const float*)d_in[11];
    const float* ln1s = (const float*)d_in[12];
    const float* ln1b = (const float*)d_in[13];
    const float* ln2s = (const float*)d_in[14];
    const float* ln2b = (const float*)d_in[15];
    float* out = (float*)d_out;

    float* ws = (float*)d_ws;
    size_t o = 0;
    unsigned short* n1h = (unsigned short*)(ws + o); o += (size_t)BD * SD * DM / 2;
    unsigned short* n1l = (unsigned short*)(ws + o); o += (size_t)BD * SD * DM / 2;
    float* lgt   = ws + o; o += (size_t)BD * SD * 192;
    float* wpref = ws + o; o += (size_t)BD * SD * 160;
    float* dense = ws + o; o += (size_t)BD * 224;
    int*   ridx  = (int*)(ws + o); o += (size_t)BD * 5 * 8;
    float* rw    = ws + o; o += (size_t)BD * 5 * 8;
    unsigned short* WTh = (unsigned short*)(ws + o); o += (size_t)256 * 1024 / 2;
    unsigned short* WTl = (unsigned short*)(ws + o); o += (size_t)256 * 1024 / 2;
    unsigned short* scompT = (unsigned short*)(ws + o); o += (size_t)BD * RK * DM / 2;
    unsigned short* EQt = (unsigned short*)(ws + o); o += (size_t)BD * RK * DM / 2;
    unsigned short* EKt = (unsigned short*)(ws + o); o += (size_t)BD * RK * DM / 2;
    unsigned short* EVt = (unsigned short*)(ws + o); o += (size_t)BD * RK * DM / 2;
    unsigned short* hb  = (unsigned short*)(ws + o); o += (size_t)BD * SD * RK / 2;
    unsigned short* Qb16 = (unsigned short*)(ws + o); o += (size_t)BD * SD * DM / 2;
    unsigned short* Kb16 = (unsigned short*)(ws + o); o += (size_t)BD * SD * DM / 2;
    unsigned short* Vb16 = (unsigned short*)(ws + o); o += (size_t)BD * SD * DM / 2;
    unsigned short* attnb = (unsigned short*)(ws + o); o += (size_t)BD * SD * DM / 2;
    unsigned short* WOt = (unsigned short*)(ws + o); o += (size_t)DM * DM / 2;
    unsigned short* kKb = (unsigned short*)(ws + o); o += (size_t)NK * RK / 2;
    unsigned short* Qmb = (unsigned short*)(ws + o); o += (size_t)BD * SD * RK / 2;
    float* cand = ws + o; o += (size_t)BD * SD * 1024;

    const int NTOK = BD * SD;

    // independent prep
    concatw_kernel<<<1024, 256, 0, stream>>>(Wc, WQr, WKr, WVr, Wm, WTh, WTl);
    tcvt_kernel<<<dim3(16, 16, 1), 256, 0, stream>>>(WO, WOt, DM, DM);
    cvt_bf16_kernel<<<(NK * RK / 4) / 256, 256, 0, stream>>>(kK, kKb, 0.0883883476483184f, NK * RK / 4);

    // phase 1
    ln_kernel<<<NTOK, 256, 0, stream>>>(x, ln1s, ln1b, n1h, n1l);
    gemm_split<<<dim3(3, NTOK / 128), 256, 0, stream>>>(n1h, n1l, WTh, WTl, lgt, 192, DM);
    softpref_kernel<<<NTOK / 64, 256, 0, stream>>>(lgt, imp, wpref);
    reduce_pref<<<BD * 160, 256, 0, stream>>>(wpref, dense, 160, 0);
    topk_kernel<<<1, 64, 0, stream>>>(dense, ridx, rw, 0, 4);
    combine_t_kernel<<<dim3(2, 16, BD), 256, 0, stream>>>(cneu, ridx, rw, 0, 8, scompT, DM, RK);
    combine_t_kernel<<<dim3(16, 2, BD), 256, 0, stream>>>(epool, ridx, rw, 1, 4, EQt, RK, DM);
    combine_t_kernel<<<dim3(16, 2, BD), 256, 0, stream>>>(epool, ridx, rw, 2, 4, EKt, RK, DM);
    combine_t_kernel<<<dim3(16, 2, BD), 256, 0, stream>>>(epool, ridx, rw, 3, 4, EVt, RK, DM);
    gemm_bf16<1, 0><<<dim3(1, 8, BD), 256, 0, stream>>>(n1h, scompT, nullptr, hb,
        SD, RK, DM, (long long)SD * DM, (long long)RK * DM, (long long)SD * RK);
    gemm_bf16<1, 0><<<dim3(8, 8, BD), 256, 0, stream>>>(hb, EQt, nullptr, Qb16,
        SD, DM, RK, (long long)SD * RK, (long long)DM * RK, (long long)SD * DM);
    gemm_bf16<1, 0><<<dim3(8, 8, BD), 256, 0, stream>>>(hb, EKt, nullptr, Kb16,
        SD, DM, RK, (long long)SD * RK, (long long)DM * RK, (long long)SD * DM);
    gemm_bf16<1, 0><<<dim3(8, 8, BD), 256, 0, stream>>>(hb, EVt, nullptr, Vb16,
        SD, DM, RK, (long long)SD * RK, (long long)DM * RK, (long long)SD * DM);
    attn_mfma_kernel<<<dim3(8, NH, BD), 256, 0, stream>>>(Qb16, Kb16, Vb16, attnb);
    gemm_bf16<0, 1><<<dim3(8, 64, 1), 256, 0, stream>>>(attnb, WOt, x, out,
        NTOK, DM, DM, 0, 0, 0);

    // phase 2
    ln_kernel<<<NTOK, 256, 0, stream>>>(out, ln2s, ln2b, n1h, n1l);
    gemm_split<<<dim3(1, NTOK / 128), 256, 0, stream>>>(n1h, n1l,
        WTh + (size_t)192 * 1024, WTl + (size_t)192 * 1024, lgt, 64, DM);
    softm_kernel<<<NTOK / 256, 256, 0, stream>>>(lgt, imp, wpref);
    reduce_pref<<<BD * 64, 256, 0, stream>>>(wpref, dense, 64, 160);
    topk_kernel<<<1, 64, 0, stream>>>(dense, ridx, rw, 4, 1);
    combine_t_kernel<<<dim3(2, 16, BD), 256, 0, stream>>>(cneu, ridx, rw, 4, 8, scompT, DM, RK);
    gemm_bf16<1, 0><<<dim3(1, 8, BD), 256, 0, stream>>>(n1h, scompT, nullptr, Qmb,
        SD, RK, DM, (long long)SD * DM, (long long)RK * DM, (long long)SD * RK);
    know_score_kernel<<<NTOK / 16, 512, 0, stream>>>(Qmb, kKb, cand);
    know_out_kernel<<<NTOK / 4, 256, 0, stream>>>(cand, kV, out);
}

// Round 11
// 689.117 us; speedup vs baseline: 9.4692x; 1.0035x over previous
//
#include <hip/hip_runtime.h>
#include <hip/hip_bf16.h>

#define BD 8
#define SD 1024
#define DM 1024
#define NH 16
#define DH 64
#define RK 128
#define NK 16384

typedef __attribute__((ext_vector_type(8))) short bf16x8;
typedef __attribute__((ext_vector_type(4))) float f32x4;

__device__ __forceinline__ unsigned short f2b(float f) {
    unsigned u = __float_as_uint(f);
    unsigned r = (u + 0x7FFFu + ((u >> 16) & 1u)) >> 16;
    return (unsigned short)r;
}
__device__ __forceinline__ float b2f(unsigned short h) {
    return __uint_as_float(((unsigned)h) << 16);
}

// ---------------- LayerNorm: bf16 hi/lo outputs ----------------
__global__ void __launch_bounds__(256) ln_kernel(const float* __restrict__ x,
                                                 const float* __restrict__ sc,
                                                 const float* __restrict__ bi,
                                                 unsigned short* __restrict__ outh,
                                                 unsigned short* __restrict__ outl) {
    const int tok = blockIdx.x;
    __shared__ float xs[DM];
    __shared__ float red[256];
    const float* xp = x + (size_t)tok * DM;
    float s = 0.f;
    for (int i = threadIdx.x; i < DM; i += 256) { float v = xp[i]; xs[i] = v; s += v; }
    red[threadIdx.x] = s; __syncthreads();
    for (int st = 128; st; st >>= 1) { if (threadIdx.x < st) red[threadIdx.x] += red[threadIdx.x + st]; __syncthreads(); }
    float mu = red[0] * (1.f / DM);
    __syncthreads();
    float vs = 0.f;
    for (int i = threadIdx.x; i < DM; i += 256) { float d = xs[i] - mu; vs += d * d; }
    red[threadIdx.x] = vs; __syncthreads();
    for (int st = 128; st; st >>= 1) { if (threadIdx.x < st) red[threadIdx.x] += red[threadIdx.x + st]; __syncthreads(); }
    float rs = rsqrtf(red[0] * (1.f / DM) + 1e-5f);
    for (int i = threadIdx.x; i < DM; i += 256) {
        float v = (xs[i] - mu) * rs * sc[i] + bi[i];
        unsigned short h = f2b(v);
        outh[(size_t)tok * DM + i] = h;
        outl[(size_t)tok * DM + i] = f2b(v - b2f(h));
    }
}

// ---------------- router weights -> transposed hi/lo bf16 [256][1024] ----------------
__global__ void __launch_bounds__(256) concatw_kernel(const float* __restrict__ Wc,
                                                      const float* __restrict__ WQr,
                                                      const float* __restrict__ WKr,
                                                      const float* __restrict__ WVr,
                                                      const float* __restrict__ Wm,
                                                      unsigned short* __restrict__ WTh,
                                                      unsigned short* __restrict__ WTl) {
    const int i = blockIdx.x * 256 + threadIdx.x;
    const int c = i >> 10, d = i & 1023;
    float v = 0.f;
    if (c < 64)       v = Wc[d * 64 + c];
    else if (c < 96)  v = WQr[d * 32 + c - 64];
    else if (c < 128) v = WKr[d * 32 + c - 96];
    else if (c < 160) v = WVr[d * 32 + c - 128];
    else if (c >= 192) v = Wm[d * 64 + c - 192];
    unsigned short h = f2b(v);
    WTh[i] = h;
    WTl[i] = f2b(v - b2f(h));
}

// ---------------- split-bf16 logits GEMM ----------------
__global__ void __launch_bounds__(256) gemm_split(const unsigned short* __restrict__ Ah,
                                                  const unsigned short* __restrict__ Al,
                                                  const unsigned short* __restrict__ Bh,
                                                  const unsigned short* __restrict__ Bl,
                                                  float* __restrict__ C,
                                                  int N, int K) {
    const int row0 = blockIdx.y * 128, col0 = blockIdx.x * 64;
    const int t = threadIdx.x;
    const int w = t >> 6, l = t & 63, lq = l & 15, lg = l >> 4;
    __shared__ unsigned short sAh[128 * 64];
    __shared__ unsigned short sAl[128 * 64];
    __shared__ unsigned short sBh[64 * 64];
    __shared__ unsigned short sBl[64 * 64];
    f32x4 acc[2][4];
    #pragma unroll
    for (int mi = 0; mi < 2; mi++)
        #pragma unroll
        for (int ni = 0; ni < 4; ni++) acc[mi][ni] = f32x4{0.f, 0.f, 0.f, 0.f};

    for (int k0 = 0; k0 < K; k0 += 64) {
        __syncthreads();
        #pragma unroll
        for (int p = 0; p < 4; p++) {
            const int e = t * 8 + p * 2048;
            const int row = e >> 6, col = e & 63;
            const int sw = (e * 2) ^ ((row & 7) << 4);
            *(bf16x8*)((char*)sAh + sw) = *(const bf16x8*)(Ah + (size_t)(row0 + row) * K + k0 + col);
            *(bf16x8*)((char*)sAl + sw) = *(const bf16x8*)(Al + (size_t)(row0 + row) * K + k0 + col);
        }
        #pragma unroll
        for (int p = 0; p < 2; p++) {
            const int e = t * 8 + p * 2048;
            const int row = e >> 6, col = e & 63;
            const int sw = (e * 2) ^ ((row & 7) << 4);
            *(bf16x8*)((char*)sBh + sw) = *(const bf16x8*)(Bh + (size_t)(col0 + row) * K + k0 + col);
            *(bf16x8*)((char*)sBl + sw) = *(const bf16x8*)(Bl + (size_t)(col0 + row) * K + k0 + col);
        }
        __syncthreads();
        #pragma unroll
        for (int kk = 0; kk < 2; kk++) {
            bf16x8 ah[2], al[2], bh[4], bl[4];
            #pragma unroll
            for (int mi = 0; mi < 2; mi++) {
                const int r = w * 32 + mi * 16 + lq;
                const int off = (r * 128 + lg * 16 + kk * 64) ^ ((r & 7) << 4);
                ah[mi] = *(const bf16x8*)((const char*)sAh + off);
                al[mi] = *(const bf16x8*)((const char*)sAl + off);
            }
            #pragma unroll
            for (int ni = 0; ni < 4; ni++) {
                const int r = ni * 16 + lq;
                const int off = (r * 128 + lg * 16 + kk * 64) ^ ((r & 7) << 4);
                bh[ni] = *(const bf16x8*)((const char*)sBh + off);
                bl[ni] = *(const bf16x8*)((const char*)sBl + off);
            }
            #pragma unroll
            for (int mi = 0; mi < 2; mi++)
                #pragma unroll
                for (int ni = 0; ni < 4; ni++) {
                    acc[mi][ni] = __builtin_amdgcn_mfma_f32_16x16x32_bf16(ah[mi], bh[ni], acc[mi][ni], 0, 0, 0);
                    acc[mi][ni] = __builtin_amdgcn_mfma_f32_16x16x32_bf16(ah[mi], bl[ni], acc[mi][ni], 0, 0, 0);
                    acc[mi][ni] = __builtin_amdgcn_mfma_f32_16x16x32_bf16(al[mi], bh[ni], acc[mi][ni], 0, 0, 0);
                }
        }
    }
    #pragma unroll
    for (int mi = 0; mi < 2; mi++)
        #pragma unroll
        for (int j = 0; j < 4; j++) {
            const int row = row0 + w * 32 + mi * 16 + lg * 4 + j;
            #pragma unroll
            for (int ni = 0; ni < 4; ni++)
                C[(size_t)row * N + col0 + ni * 16 + lq] = acc[mi][ni][j];
        }
}

// ---------------- phase-1 softmax prefs ----------------
__global__ void __launch_bounds__(256) softpref_kernel(const float* __restrict__ lgt,
                                                       const float* __restrict__ imp,
                                                       float* __restrict__ wpref) {
    const int tok = blockIdx.x * 64 + (threadIdx.x >> 2);
    const int sg = threadIdx.x & 3;
    const int o = (sg == 0) ? 0 : (64 + 32 * (sg - 1));
    const int n = (sg == 0) ? 64 : 32;
    const float* lp = lgt + (size_t)tok * 192 + o;
    float m = -1e30f;
    for (int i = 0; i < n; i++) m = fmaxf(m, lp[i]);
    float ss = 0.f;
    for (int i = 0; i < n; i++) ss += __expf(lp[i] - m);
    const float scl = imp[tok] / ss;
    float* wp = wpref + (size_t)tok * 160 + o;
    for (int i = 0; i < n; i++) wp[i] = __expf(lp[i] - m) * scl;
}

// ---------------- phase-2 softmax prefs ----------------
__global__ void __launch_bounds__(256) softm_kernel(const float* __restrict__ lgt,
                                                    const float* __restrict__ imp,
                                                    float* __restrict__ wpref) {
    const int tok = blockIdx.x * 256 + threadIdx.x;
    const float* lp = lgt + (size_t)tok * 64;
    float m = -1e30f;
    for (int i = 0; i < 64; i++) m = fmaxf(m, lp[i]);
    float ss = 0.f;
    for (int i = 0; i < 64; i++) ss += __expf(lp[i] - m);
    const float scl = imp[tok] / ss;
    for (int i = 0; i < 64; i++) wpref[(size_t)tok * 64 + i] = __expf(lp[i] - m) * scl;
}

// ---------------- deterministic reduce over S ----------------
__global__ void __launch_bounds__(256) reduce_pref(const float* __restrict__ wpref,
                                                   float* __restrict__ dense,
                                                   int ncols, int outoff) {
    const int b = blockIdx.x / ncols, c = blockIdx.x % ncols;
    __shared__ float red[256];
    float s = 0.f;
    for (int si = threadIdx.x; si < SD; si += 256)
        s += wpref[((size_t)(b * SD + si)) * ncols + c];
    red[threadIdx.x] = s; __syncthreads();
    for (int st = 128; st; st >>= 1) { if (threadIdx.x < st) red[threadIdx.x] += red[threadIdx.x + st]; __syncthreads(); }
    if (threadIdx.x == 0) dense[b * 224 + outoff + c] = red[0];
}

// ---------------- top-k sparsify + renormalize ----------------
__global__ void topk_kernel(const float* __restrict__ dense,
                            int* __restrict__ ridx, float* __restrict__ rw,
                            int r0, int nr) {
    const int t = threadIdx.x;
    if (t >= BD * nr) return;
    const int b = t / nr, r = r0 + (t % nr);
    const int offs[5] = {0, 64, 96, 128, 160};
    const int ns[5]   = {64, 32, 32, 32, 64};
    const int ks[5]   = {8, 4, 4, 4, 8};
    const float* dv = dense + b * 224 + offs[r];
    const int n = ns[r], k = ks[r];
    unsigned long long mask = 0;
    float vals[8]; int idxs[8];
    float ssum = 0.f;
    for (int kk = 0; kk < k; kk++) {
        float best = -1e30f; int bi = 0;
        for (int i = 0; i < n; i++)
            if (!((mask >> i) & 1ull) && dv[i] > best) { best = dv[i]; bi = i; }
        mask |= 1ull << bi;
        vals[kk] = best; idxs[kk] = bi; ssum += best;
    }
    float inv = 1.f / (ssum + 1e-8f);
    for (int kk = 0; kk < 8; kk++) {
        ridx[(b * 5 + r) * 8 + kk] = (kk < k) ? idxs[kk] : 0;
        rw[(b * 5 + r) * 8 + kk]   = (kk < k) ? vals[kk] * inv : 0.f;
    }
}

// ---------------- fused mixture + transpose + bf16 ----------------
__global__ void __launch_bounds__(256) combine_t_kernel(const float* __restrict__ pool,
                                                        const int* __restrict__ ridx,
                                                        const float* __restrict__ rw,
                                                        int router, int kc,
                                                        unsigned short* __restrict__ outT,
                                                        int Rp, int Cp) {
    const int b = blockIdx.z;
    const int r0 = blockIdx.y * 64, c0 = blockIdx.x * 64;
    __shared__ float ls[64][65];
    const int* ii = ridx + (b * 5 + router) * 8;
    const float* ww = rw + (b * 5 + router) * 8;
    const int t = threadIdx.x;
    const int rr = t >> 4, cc = (t & 15) * 4;
    #pragma unroll
    for (int p = 0; p < 4; p++) {
        const int r = rr + p * 16;
        float4 acc = {0.f, 0.f, 0.f, 0.f};
        for (int kk = 0; kk < kc; kk++) {
            const float w = ww[kk];
            float4 v = *(const float4*)&pool[((size_t)ii[kk] * Rp + r0 + r) * Cp + c0 + cc];
            acc.x += w * v.x; acc.y += w * v.y; acc.z += w * v.z; acc.w += w * v.w;
        }
        ls[r][cc] = acc.x; ls[r][cc + 1] = acc.y; ls[r][cc + 2] = acc.z; ls[r][cc + 3] = acc.w;
    }
    __syncthreads();
    unsigned short* op = outT + (size_t)b * Rp * Cp;
    #pragma unroll
    for (int q = 0; q < 2; q++) {
        const int c = (t >> 3) + q * 32;
        const int r8 = (t & 7) * 8;
        union { unsigned short s[8]; bf16x8 v; } u;
        #pragma unroll
        for (int j = 0; j < 8; j++) u.s[j] = f2b(ls[r8 + j][c]);
        *(bf16x8*)(op + (size_t)(c0 + c) * Rp + r0 + r8) = u.v;
    }
}

// ---------------- tile transpose + fp32->bf16 (WO only) ----------------
__global__ void __launch_bounds__(256) tcvt_kernel(const float* __restrict__ src,
                                                   unsigned short* __restrict__ dst,
                                                   int R, int Cc) {
    __shared__ float ls[64][65];
    const int r0 = blockIdx.y * 64, c0 = blockIdx.x * 64;
    const int t = threadIdx.x;
    #pragma unroll
    for (int p = 0; p < 16; p++) {
        const int e = p * 256 + t;
        const int r = e >> 6, c = e & 63;
        ls[r][c] = src[(size_t)(r0 + r) * Cc + c0 + c];
    }
    __syncthreads();
    #pragma unroll
    for (int p = 0; p < 16; p++) {
        const int e = p * 256 + t;
        const int c = e >> 6, r = e & 63;
        dst[(size_t)(c0 + c) * R + r0 + r] = f2b(ls[r][c]);
    }
}

// ---------------- fp32 -> bf16 convert with scale ----------------
__global__ void __launch_bounds__(256) cvt_bf16_kernel(const float* __restrict__ src,
                                                       unsigned short* __restrict__ dst,
                                                       float scale, int n4) {
    const int i = blockIdx.x * 256 + threadIdx.x;
    if (i >= n4) return;
    float4 v = ((const float4*)src)[i];
    unsigned r0 = (unsigned)f2b(v.x * scale) | ((unsigned)f2b(v.y * scale) << 16);
    unsigned r1 = (unsigned)f2b(v.z * scale) | ((unsigned)f2b(v.w * scale) << 16);
    uint2 o; o.x = r0; o.y = r1;
    ((uint2*)dst)[i] = o;
}

// ---------------- bf16 MFMA GEMM: C = A[M][K] @ Bt[N][K]^T (+X), 128x128 tile ----------------
template<int OUTB, int HASX>
__global__ void __launch_bounds__(256) gemm_bf16(const unsigned short* __restrict__ A,
                                                 const unsigned short* __restrict__ Bt,
                                                 const float* __restrict__ X,
                                                 void* __restrict__ Cv,
                                                 int M, int N, int K,
                                                 long long sA, long long sB, long long sC) {
    const int bz = blockIdx.z;
    const unsigned short* Ab = A + (size_t)bz * sA;
    const unsigned short* Btb = Bt + (size_t)bz * sB;
    const int row0 = blockIdx.y * 128, col0 = blockIdx.x * 128;
    const int t = threadIdx.x;
    const int w = t >> 6, l = t & 63, lq = l & 15, lg = l >> 4;
    const int wr = w >> 1, wc = w & 1;
    __shared__ unsigned short As[128 * 64];
    __shared__ unsigned short Bs[128 * 64];
    f32x4 acc[4][4];
    #pragma unroll
    for (int mi = 0; mi < 4; mi++)
        #pragma unroll
        for (int ni = 0; ni < 4; ni++) acc[mi][ni] = f32x4{0.f, 0.f, 0.f, 0.f};

    for (int k0 = 0; k0 < K; k0 += 64) {
        __syncthreads();
        #pragma unroll
        for (int p = 0; p < 4; p++) {
            const int e = t * 8 + p * 2048;
            const int row = e >> 6, col = e & 63;
            bf16x8 va = *(const bf16x8*)(Ab + (size_t)(row0 + row) * K + k0 + col);
            *(bf16x8*)((char*)As + ((row * 128 + col * 2) ^ ((row & 7) << 4))) = va;
            bf16x8 vb = *(const bf16x8*)(Btb + (size_t)(col0 + row) * K + k0 + col);
            *(bf16x8*)((char*)Bs + ((row * 128 + col * 2) ^ ((row & 7) << 4))) = vb;
        }
        __syncthreads();
        #pragma unroll
        for (int kk = 0; kk < 2; kk++) {
            bf16x8 af[4], bg[4];
            #pragma unroll
            for (int mi = 0; mi < 4; mi++) {
                const int r = wr * 64 + mi * 16 + lq;
                af[mi] = *(const bf16x8*)((const char*)As + ((r * 128 + lg * 16 + kk * 64) ^ ((r & 7) << 4)));
            }
            #pragma unroll
            for (int ni = 0; ni < 4; ni++) {
                const int r = wc * 64 + ni * 16 + lq;
                bg[ni] = *(const bf16x8*)((const char*)Bs + ((r * 128 + lg * 16 + kk * 64) ^ ((r & 7) << 4)));
            }
            #pragma unroll
            for (int mi = 0; mi < 4; mi++)
                #pragma unroll
                for (int ni = 0; ni < 4; ni++)
                    acc[mi][ni] = __builtin_amdgcn_mfma_f32_16x16x32_bf16(af[mi], bg[ni], acc[mi][ni], 0, 0, 0);
        }
    }
    #pragma unroll
    for (int mi = 0; mi < 4; mi++) {
        #pragma unroll
        for (int j = 0; j < 4; j++) {
            const int row = row0 + wr * 64 + mi * 16 + lg * 4 + j;
            #pragma unroll
            for (int ni = 0; ni < 4; ni++) {
                const int col = col0 + wc * 64 + ni * 16 + lq;
                float v = acc[mi][ni][j];
                if (HASX) v += X[(size_t)row * N + col];
                if (OUTB) ((unsigned short*)Cv)[(size_t)bz * sC + (size_t)row * N + col] = f2b(v);
                else      ((float*)Cv)[(size_t)bz * sC + (size_t)row * N + col] = v;
            }
        }
    }
}

// ---------------- flash attention: paired q-tiles (qt, 15-qt), dbuf K/V, 1 barrier/tile ----------------
#define SWZV(d) (((((d) >> 1) ^ ((d) >> 3)) & 7) << 4)
__global__ void __launch_bounds__(256) attn_mfma_kernel(const unsigned short* __restrict__ Q,
                                                        const unsigned short* __restrict__ K,
                                                        const unsigned short* __restrict__ V,
                                                        unsigned short* __restrict__ O) {
    const int qt = blockIdx.x, hh = blockIdx.y, b = blockIdx.z;
    const int t = threadIdx.x;
    const int w = t >> 6, l = t & 63, lq = l & 15, lg = l >> 4;

    __shared__ unsigned short ks[2][64 * 64];
    __shared__ unsigned short vt[2][64 * 64];
    __shared__ unsigned short pl[4][16 * 64];

    const size_t base = (size_t)b * SD * DM + (size_t)hh * DH;
    const int qA = qt;
    const int qB = 15 - qt;

    bf16x8 aqA[2], aqB[2];
    {
        const unsigned short* qp = Q + base + (size_t)(qA * 64 + w * 16 + lq) * DM + lg * 8;
        aqA[0] = *(const bf16x8*)qp; aqA[1] = *(const bf16x8*)(qp + 32);
        const unsigned short* qp2 = Q + base + (size_t)(qB * 64 + w * 16 + lq) * DM + lg * 8;
        aqB[0] = *(const bf16x8*)qp2; aqB[1] = *(const bf16x8*)(qp2 + 32);
    }

    f32x4 oA[4], oB[4];
    #pragma unroll
    for (int dt = 0; dt < 4; dt++) { oA[dt] = f32x4{0.f,0.f,0.f,0.f}; oB[dt] = f32x4{0.f,0.f,0.f,0.f}; }
    float mA[4] = {-1e30f,-1e30f,-1e30f,-1e30f}, sA[4] = {0.f,0.f,0.f,0.f};
    float mB[4] = {-1e30f,-1e30f,-1e30f,-1e30f}, sB[4] = {0.f,0.f,0.f,0.f};

    const int ntile = 16 - qt;
    const int srow = t >> 3;
    const int scol = (t & 7) * 8;

    int cur = 0;

    #pragma unroll
    for (int p = 0; p < 2; p++) {
        const int row = srow + 32 * p;
        bf16x8 kv = *(const bf16x8*)(K + base + (size_t)row * DM + scol);
        *(bf16x8*)((char*)&ks[0][0] + ((row * 128 + scol * 2) ^ ((row & 7) << 4))) = kv;
        bf16x8 vv = *(const bf16x8*)(V + base + (size_t)row * DM + scol);
        #pragma unroll
        for (int j2 = 0; j2 < 8; j2++) {
            const int d = scol + j2;
            *(unsigned short*)((char*)&vt[0][0] + ((d * 128 + row * 2) ^ SWZV(d))) = (unsigned short)vv[j2];
        }
    }
    __syncthreads();

    auto compute = [&](int q0, const bf16x8* aq, f32x4* o_, float* m_, float* s_, int kt) {
        const f32x4 zero4 = {0.f, 0.f, 0.f, 0.f};
        f32x4 sacc[4];
        #pragma unroll
        for (int ct = 0; ct < 4; ct++) {
            const int krow = ct * 16 + lq;
            bf16x8 b0 = *(const bf16x8*)((const char*)&ks[cur][0] + ((krow * 128 + lg * 16) ^ ((lq & 7) << 4)));
            bf16x8 b1 = *(const bf16x8*)((const char*)&ks[cur][0] + ((krow * 128 + lg * 16 + 64) ^ ((lq & 7) << 4)));
            f32x4 s = __builtin_amdgcn_mfma_f32_16x16x32_bf16(aq[0], b0, zero4, 0, 0, 0);
            s = __builtin_amdgcn_mfma_f32_16x16x32_bf16(aq[1], b1, s, 0, 0, 0);
            sacc[ct] = s;
        }
        float tm[4];
        #pragma unroll
        for (int j = 0; j < 4; j++) {
            const int qg = q0 * 64 + w * 16 + lg * 4 + j;
            float mx = -1e30f;
            #pragma unroll
            for (int ct = 0; ct < 4; ct++) {
                const int kg = kt * 64 + ct * 16 + lq;
                float v = sacc[ct][j] * 0.125f;
                v = (kg <= qg) ? v : -1e30f;
                sacc[ct][j] = v;
                mx = fmaxf(mx, v);
            }
            #pragma unroll
            for (int d = 1; d < 16; d <<= 1) mx = fmaxf(mx, __shfl_xor(mx, d));
            tm[j] = mx;
        }
        #pragma unroll
        for (int j = 0; j < 4; j++) {
            const float nm = fmaxf(m_[j], tm[j]);
            const float so = __expf(m_[j] - nm);
            m_[j] = nm;
            float rs = 0.f;
            const int prow = lg * 4 + j;
            #pragma unroll
            for (int ct = 0; ct < 4; ct++) {
                const float p = __expf(sacc[ct][j] - nm);
                rs += p;
                const int byteoff = ((prow * 128) + (ct * 16 + lq) * 2) ^ ((prow & 7) << 4);
                *(unsigned short*)((char*)&pl[w][0] + byteoff) = f2b(p);
            }
            #pragma unroll
            for (int d = 1; d < 16; d <<= 1) rs += __shfl_xor(rs, d);
            s_[j] = s_[j] * so + rs;
            #pragma unroll
            for (int dt = 0; dt < 4; dt++) o_[dt][j] *= so;
        }
        asm volatile("s_waitcnt lgkmcnt(0)" ::: "memory");
        __builtin_amdgcn_sched_barrier(0);
        #pragma unroll
        for (int c = 0; c < 2; c++) {
            bf16x8 pa = *(const bf16x8*)((const char*)&pl[w][0] +
                          ((lq * 128 + lg * 16 + 64 * c) ^ ((lq & 7) << 4)));
            #pragma unroll
            for (int dt = 0; dt < 4; dt++) {
                const int dd = dt * 16 + lq;
                bf16x8 bv = *(const bf16x8*)((const char*)&vt[cur][0] +
                              ((dd * 128 + lg * 16 + 64 * c) ^ SWZV(dd)));
                o_[dt] = __builtin_amdgcn_mfma_f32_16x16x32_bf16(pa, bv, o_[dt], 0, 0, 0);
            }
        }
    };

    const int mymaxA = qA * 64 + w * 16 + 15;
    for (int kt = 0; kt < ntile; kt++) {
        bf16x8 kN[2], vN[2];
        const bool pre = (kt + 1 < ntile);
        if (pre) {
            #pragma unroll
            for (int p = 0; p < 2; p++) {
                const int row = srow + 32 * p;
                kN[p] = *(const bf16x8*)(K + base + (size_t)((kt + 1) * 64 + row) * DM + scol);
                vN[p] = *(const bf16x8*)(V + base + (size_t)((kt + 1) * 64 + row) * DM + scol);
            }
        }
        compute(qB, aqB, oB, mB, sB, kt);
        if (kt * 64 <= mymaxA) compute(qA, aqA, oA, mA, sA, kt);
        if (pre) {
            #pragma unroll
            for (int p = 0; p < 2; p++) {
                const int row = srow + 32 * p;
                *(bf16x8*)((char*)&ks[cur ^ 1][0] + ((row * 128 + scol * 2) ^ ((row & 7) << 4))) = kN[p];
                #pragma unroll
                for (int j2 = 0; j2 < 8; j2++) {
                    const int d = scol + j2;
                    *(unsigned short*)((char*)&vt[cur ^ 1][0] + ((d * 128 + row * 2) ^ SWZV(d))) =
                        (unsigned short)vN[p][j2];
                }
            }
        }
        __syncthreads();
        cur ^= 1;
    }

    #pragma unroll
    for (int j = 0; j < 4; j++) {
        const float invA = 1.f / sA[j];
        const float invB = 1.f / sB[j];
        const int rowA = qA * 64 + w * 16 + lg * 4 + j;
        const int rowB = qB * 64 + w * 16 + lg * 4 + j;
        unsigned short* opA = O + base + (size_t)rowA * DM;
        unsigned short* opB = O + base + (size_t)rowB * DM;
        #pragma unroll
        for (int dt = 0; dt < 4; dt++) {
            opA[dt * 16 + lq] = f2b(oA[dt][j] * invA);
            opB[dt * 16 + lq] = f2b(oB[dt][j] * invB);
        }
    }
}
#undef SWZV

// ---------------- knowledge scores: 16-key wave-private LDS tiles (32KB/block -> 4 blocks/CU) ----------------
#define CE(a, b) { float hi_ = fmaxf(a, b), lo_ = fminf(a, b); a = hi_; b = lo_; }
__global__ void __launch_bounds__(512, 4) know_score_kernel(const unsigned short* __restrict__ Qmb,
                                                            const unsigned short* __restrict__ kKb,
                                                            float* __restrict__ cand) {
    const int t = threadIdx.x;
    const int w = t >> 6, l = t & 63, lq = l & 15, lg = l >> 4;
    const int tok0 = blockIdx.x * 16;
    __shared__ unsigned short ks[8][16 * 128];   // 32 KB total

    bf16x8 aq[4];
    {
        const unsigned short* qp = Qmb + (size_t)(tok0 + lq) * 128 + lg * 8;
        #pragma unroll
        for (int c = 0; c < 4; c++) aq[c] = *(const bf16x8*)(qp + c * 32);
    }

    float L[4][8];
    #pragma unroll
    for (int j = 0; j < 4; j++)
        #pragma unroll
        for (int s = 0; s < 8; s++) L[j][s] = __uint_as_float(0xF2000000u | (unsigned)s);

    const unsigned short* gsrc = kKb + (((size_t)w * 2048) << 7) + l * 8;
    unsigned short* myks = &ks[w][0];

    bf16x8 vreg[4];
    #pragma unroll
    for (int p = 0; p < 4; p++) vreg[p] = *(const bf16x8*)(gsrc + p * 512);

    for (int t4 = 0; t4 < 32; t4++) {
        float B[4][4];
        #pragma unroll
        for (int sub = 0; sub < 4; sub++) {
            const int kt = t4 * 4 + sub;
            // stage 16 keys (same-wave DS order; no barriers)
            #pragma unroll
            for (int p = 0; p < 4; p++) {
                const int e = p * 512 + l * 8;
                const int row = e >> 7;   // 0..15
                *(bf16x8*)((char*)myks + ((e * 2) ^ ((row & 7) << 4))) = vreg[p];
            }
            // prefetch next 16-key tile
            if (kt < 127) {
                const unsigned short* src2 = gsrc + (size_t)(kt + 1) * 2048;
                #pragma unroll
                for (int p = 0; p < 4; p++) vreg[p] = *(const bf16x8*)(src2 + p * 512);
            }
            // score: row = lq
            {
                const char* kb = (const char*)myks + lq * 256;
                const int sw = (lq & 7) << 4;
                f32x4 s = {0.f, 0.f, 0.f, 0.f};
                #pragma unroll
                for (int c = 0; c < 4; c++) {
                    bf16x8 bv = *(const bf16x8*)(kb + ((c * 64 + lg * 16) ^ sw));
                    s = __builtin_amdgcn_mfma_f32_16x16x32_bf16(aq[c], bv, s, 0, 0, 0);
                }
                const unsigned keyb = (unsigned)(w * 2048 + kt * 16 + lq);
                #pragma unroll
                for (int j = 0; j < 4; j++) {
                    unsigned u = __float_as_uint(s[j]);
                    B[j][sub] = __uint_as_float((u & 0xFFFFC000u) | keyb);
                }
            }
        }
        #pragma unroll
        for (int j = 0; j < 4; j++) {
            CE(B[j][0], B[j][2]); CE(B[j][1], B[j][3]);
            CE(B[j][0], B[j][1]); CE(B[j][2], B[j][3]);
            CE(B[j][1], B[j][2]);
            L[j][4] = fmaxf(L[j][4], B[j][3]);
            L[j][5] = fmaxf(L[j][5], B[j][2]);
            L[j][6] = fmaxf(L[j][6], B[j][1]);
            L[j][7] = fmaxf(L[j][7], B[j][0]);
            CE(L[j][0], L[j][4]); CE(L[j][1], L[j][5]); CE(L[j][2], L[j][6]); CE(L[j][3], L[j][7]);
            CE(L[j][0], L[j][2]); CE(L[j][1], L[j][3]); CE(L[j][4], L[j][6]); CE(L[j][5], L[j][7]);
            CE(L[j][0], L[j][1]); CE(L[j][2], L[j][3]); CE(L[j][4], L[j][5]); CE(L[j][6], L[j][7]);
        }
    }
    #pragma unroll
    for (int j = 0; j < 4; j++) {
        const int tok = tok0 + lg * 4 + j;
        float* cp = cand + ((size_t)tok << 10) + w * 128 + lq * 8;
        #pragma unroll
        for (int ss = 0; ss < 8; ss++) cp[ss] = L[j][ss];
    }
}
#undef CE

// ---------------- knowledge merge + V gather: one wave per token, 1024 candidates ----------------
__global__ void __launch_bounds__(256) know_out_kernel(const float* __restrict__ cand,
                                                       const float* __restrict__ kV,
                                                       float* __restrict__ out) {
    const int t = threadIdx.x, w = t >> 6, l = t & 63;
    const int tok = blockIdx.x * 4 + w;
    const float* cp = cand + ((size_t)tok << 10);
    float lv[16];
    #pragma unroll
    for (int i = 0; i < 16; i++) lv[i] = cp[i * 64 + l];

    float topv[8]; int topi[8];
    #pragma unroll
    for (int kk = 0; kk < 8; kk++) {
        float m = lv[0];
        #pragma unroll
        for (int i = 1; i < 16; i++) m = fmaxf(m, lv[i]);
        #pragma unroll
        for (int d = 1; d < 64; d <<= 1) m = fmaxf(m, __shfl_xor(m, d));
        topv[kk] = m;
        topi[kk] = (int)(__float_as_uint(m) & 0x3FFFu);
        #pragma unroll
        for (int i = 0; i < 16; i++) lv[i] = (lv[i] == m) ? -1e31f : lv[i];
    }
    const float mx = topv[0];
    float e[8]; float ssum = 0.f;
    #pragma unroll
    for (int kk = 0; kk < 8; kk++) { e[kk] = __expf(topv[kk] - mx); ssum += e[kk]; }
    const float inv = 1.f / ssum;

    float4 acc[4];
    #pragma unroll
    for (int ch = 0; ch < 4; ch++) acc[ch] = float4{0.f, 0.f, 0.f, 0.f};
    #pragma unroll
    for (int kk = 0; kk < 8; kk++) {
        const float wk = e[kk] * inv;
        const float* vp = kV + ((size_t)topi[kk] << 10);
        #pragma unroll
        for (int ch = 0; ch < 4; ch++) {
            float4 v = *(const float4*)(vp + ch * 256 + l * 4);
            acc[ch].x += wk * v.x; acc[ch].y += wk * v.y;
            acc[ch].z += wk * v.z; acc[ch].w += wk * v.w;
        }
    }
    float* op = out + ((size_t)tok << 10);
    #pragma unroll
    for (int ch = 0; ch < 4; ch++) {
        float4 o = *(const float4*)(op + ch * 256 + l * 4);
        o.x += acc[ch].x; o.y += acc[ch].y; o.z += acc[ch].z; o.w += acc[ch].w;
        *(float4*)(op + ch * 256 + l * 4) = o;
    }
}

extern "C" void kernel_launch(void* const* d_in, const int* in_sizes, int n_in,
                              void* d_out, int out_size, void* d_ws, size_t ws_size,
                              hipStream_t stream) {
    const float* x    = (const float*)d_in[0];
    const float* imp  = (const float*)d_in[1];
    const float* Wc   = (const float*)d_in[2];
    const float* WQr  = (const float*)d_in[3];
    const float* WKr  = (const float*)d_in[4];
    const float* WVr  = (const float*)d_in[5];
    const float* Wm   = (const float*)d_in[6];
    const float* cneu = (const float*)d_in[7];
    const float* epool= (const float*)d_in[8];
    const float* kK   = (const float*)d_in[9];
    const float* kV   = (const float*)d_in[10];
    const float* WO   = (const float*)d_in[11];
    const float* ln1s = (const float*)d_in[12];
    const float* ln1b = (const float*)d_in[13];
    const float* ln2s = (const float*)d_in[14];
    const float* ln2b = (const float*)d_in[15];
    float* out = (float*)d_out;

    float* ws = (float*)d_ws;
    size_t o = 0;
    unsigned short* n1h = (unsigned short*)(ws + o); o += (size_t)BD * SD * DM / 2;
    unsigned short* n1l = (unsigned short*)(ws + o); o += (size_t)BD * SD * DM / 2;
    float* lgt   = ws + o; o += (size_t)BD * SD * 192;
    float* wpref = ws + o; o += (size_t)BD * SD * 160;
    float* dense = ws + o; o += (size_t)BD * 224;
    int*   ridx  = (int*)(ws + o); o += (size_t)BD * 5 * 8;
    float* rw    = ws + o; o += (size_t)BD * 5 * 8;
    unsigned short* WTh = (unsigned short*)(ws + o); o += (size_t)256 * 1024 / 2;
    unsigned short* WTl = (unsigned short*)(ws + o); o += (size_t)256 * 1024 / 2;
    unsigned short* scompT = (unsigned short*)(ws + o); o += (size_t)BD * RK * DM / 2;
    unsigned short* EQt = (unsigned short*)(ws + o); o += (size_t)BD * RK * DM / 2;
    unsigned short* EKt = (unsigned short*)(ws + o); o += (size_t)BD * RK * DM / 2;
    unsigned short* EVt = (unsigned short*)(ws + o); o += (size_t)BD * RK * DM / 2;
    unsigned short* hb  = (unsigned short*)(ws + o); o += (size_t)BD * SD * RK / 2;
    unsigned short* Qb16 = (unsigned short*)(ws + o); o += (size_t)BD * SD * DM / 2;
    unsigned short* Kb16 = (unsigned short*)(ws + o); o += (size_t)BD * SD * DM / 2;
    unsigned short* Vb16 = (unsigned short*)(ws + o); o += (size_t)BD * SD * DM / 2;
    unsigned short* attnb = (unsigned short*)(ws + o); o += (size_t)BD * SD * DM / 2;
    unsigned short* WOt = (unsigned short*)(ws + o); o += (size_t)DM * DM / 2;
    unsigned short* kKb = (unsigned short*)(ws + o); o += (size_t)NK * RK / 2;
    unsigned short* Qmb = (unsigned short*)(ws + o); o += (size_t)BD * SD * RK / 2;
    float* cand = ws + o; o += (size_t)BD * SD * 1024;

    const int NTOK = BD * SD;

    // independent prep
    concatw_kernel<<<1024, 256, 0, stream>>>(Wc, WQr, WKr, WVr, Wm, WTh, WTl);
    tcvt_kernel<<<dim3(16, 16, 1), 256, 0, stream>>>(WO, WOt, DM, DM);
    cvt_bf16_kernel<<<(NK * RK / 4) / 256, 256, 0, stream>>>(kK, kKb, 0.0883883476483184f, NK * RK / 4);

    // phase 1
    ln_kernel<<<NTOK, 256, 0, stream>>>(x, ln1s, ln1b, n1h, n1l);
    gemm_split<<<dim3(3, NTOK / 128), 256, 0, stream>>>(n1h, n1l, WTh, WTl, lgt, 192, DM);
    softpref_kernel<<<NTOK / 64, 256, 0, stream>>>(lgt, imp, wpref);
    reduce_pref<<<BD * 160, 256, 0, stream>>>(wpref, dense, 160, 0);
    topk_kernel<<<1, 64, 0, stream>>>(dense, ridx, rw, 0, 4);
    combine_t_kernel<<<dim3(2, 16, BD), 256, 0, stream>>>(cneu, ridx, rw, 0, 8, scompT, DM, RK);
    combine_t_kernel<<<dim3(16, 2, BD), 256, 0, stream>>>(epool, ridx, rw, 1, 4, EQt, RK, DM);
    combine_t_kernel<<<dim3(16, 2, BD), 256, 0, stream>>>(epool, ridx, rw, 2, 4, EKt, RK, DM);
    combine_t_kernel<<<dim3(16, 2, BD), 256, 0, stream>>>(epool, ridx, rw, 3, 4, EVt, RK, DM);
    gemm_bf16<1, 0><<<dim3(1, 8, BD), 256, 0, stream>>>(n1h, scompT, nullptr, hb,
        SD, RK, DM, (long long)SD * DM, (long long)RK * DM, (long long)SD * RK);
    gemm_bf16<1, 0><<<dim3(8, 8, BD), 256, 0, stream>>>(hb, EQt, nullptr, Qb16,
        SD, DM, RK, (long long)SD * RK, (long long)DM * RK, (long long)SD * DM);
    gemm_bf16<1, 0><<<dim3(8, 8, BD), 256, 0, stream>>>(hb, EKt, nullptr, Kb16,
        SD, DM, RK, (long long)SD * RK, (long long)DM * RK, (long long)SD * DM);
    gemm_bf16<1, 0><<<dim3(8, 8, BD), 256, 0, stream>>>(hb, EVt, nullptr, Vb16,
        SD, DM, RK, (long long)SD * RK, (long long)DM * RK, (long long)SD * DM);
    attn_mfma_kernel<<<dim3(8, NH, BD), 256, 0, stream>>>(Qb16, Kb16, Vb16, attnb);
    gemm_bf16<0, 1><<<dim3(8, 64, 1), 256, 0, stream>>>(attnb, WOt, x, out,
        NTOK, DM, DM, 0, 0, 0);

    // phase 2
    ln_kernel<<<NTOK, 256, 0, stream>>>(out, ln2s, ln2b, n1h, n1l);
    gemm_split<<<dim3(1, NTOK / 128), 256, 0, stream>>>(n1h, n1l,
        WTh + (size_t)192 * 1024, WTl + (size_t)192 * 1024, lgt, 64, DM);
    softm_kernel<<<NTOK / 256, 256, 0, stream>>>(lgt, imp, wpref);
    reduce_pref<<<BD * 64, 256, 0, stream>>>(wpref, dense, 64, 160);
    topk_kernel<<<1, 64, 0, stream>>>(dense, ridx, rw, 4, 1);
    combine_t_kernel<<<dim3(2, 16, BD), 256, 0, stream>>>(cneu, ridx, rw, 4, 8, scompT, DM, RK);
    gemm_bf16<1, 0><<<dim3(1, 8, BD), 256, 0, stream>>>(n1h, scompT, nullptr, Qmb,
        SD, RK, DM, (long long)SD * DM, (long long)RK * DM, (long long)SD * RK);
    know_score_kernel<<<NTOK / 16, 512, 0, stream>>>(Qmb, kKb, cand);
    know_out_kernel<<<NTOK / 4, 256, 0, stream>>>(cand, kV, out);
}

// Round 12
// 675.993 us; speedup vs baseline: 9.6530x; 1.0194x over previous
//
#include <hip/hip_runtime.h>
#include <hip/hip_bf16.h>

#define BD 8
#define SD 1024
#define DM 1024
#define NH 16
#define DH 64
#define RK 128
#define NK 16384

typedef __attribute__((ext_vector_type(8))) short bf16x8;
typedef __attribute__((ext_vector_type(4))) float f32x4;

__device__ __forceinline__ unsigned short f2b(float f) {
    unsigned u = __float_as_uint(f);
    unsigned r = (u + 0x7FFFu + ((u >> 16) & 1u)) >> 16;
    return (unsigned short)r;
}
__device__ __forceinline__ float b2f(unsigned short h) {
    return __uint_as_float(((unsigned)h) << 16);
}

// ---------------- LayerNorm: bf16 hi/lo outputs ----------------
__global__ void __launch_bounds__(256) ln_kernel(const float* __restrict__ x,
                                                 const float* __restrict__ sc,
                                                 const float* __restrict__ bi,
                                                 unsigned short* __restrict__ outh,
                                                 unsigned short* __restrict__ outl) {
    const int tok = blockIdx.x;
    __shared__ float xs[DM];
    __shared__ float red[256];
    const float* xp = x + (size_t)tok * DM;
    float s = 0.f;
    for (int i = threadIdx.x; i < DM; i += 256) { float v = xp[i]; xs[i] = v; s += v; }
    red[threadIdx.x] = s; __syncthreads();
    for (int st = 128; st; st >>= 1) { if (threadIdx.x < st) red[threadIdx.x] += red[threadIdx.x + st]; __syncthreads(); }
    float mu = red[0] * (1.f / DM);
    __syncthreads();
    float vs = 0.f;
    for (int i = threadIdx.x; i < DM; i += 256) { float d = xs[i] - mu; vs += d * d; }
    red[threadIdx.x] = vs; __syncthreads();
    for (int st = 128; st; st >>= 1) { if (threadIdx.x < st) red[threadIdx.x] += red[threadIdx.x + st]; __syncthreads(); }
    float rs = rsqrtf(red[0] * (1.f / DM) + 1e-5f);
    for (int i = threadIdx.x; i < DM; i += 256) {
        float v = (xs[i] - mu) * rs * sc[i] + bi[i];
        unsigned short h = f2b(v);
        outh[(size_t)tok * DM + i] = h;
        outl[(size_t)tok * DM + i] = f2b(v - b2f(h));
    }
}

// ---------------- router weights -> transposed hi/lo bf16 [256][1024] ----------------
__global__ void __launch_bounds__(256) concatw_kernel(const float* __restrict__ Wc,
                                                      const float* __restrict__ WQr,
                                                      const float* __restrict__ WKr,
                                                      const float* __restrict__ WVr,
                                                      const float* __restrict__ Wm,
                                                      unsigned short* __restrict__ WTh,
                                                      unsigned short* __restrict__ WTl) {
    const int i = blockIdx.x * 256 + threadIdx.x;
    const int c = i >> 10, d = i & 1023;
    float v = 0.f;
    if (c < 64)       v = Wc[d * 64 + c];
    else if (c < 96)  v = WQr[d * 32 + c - 64];
    else if (c < 128) v = WKr[d * 32 + c - 96];
    else if (c < 160) v = WVr[d * 32 + c - 128];
    else if (c >= 192) v = Wm[d * 64 + c - 192];
    unsigned short h = f2b(v);
    WTh[i] = h;
    WTl[i] = f2b(v - b2f(h));
}

// ---------------- split-bf16 logits GEMM ----------------
__global__ void __launch_bounds__(256) gemm_split(const unsigned short* __restrict__ Ah,
                                                  const unsigned short* __restrict__ Al,
                                                  const unsigned short* __restrict__ Bh,
                                                  const unsigned short* __restrict__ Bl,
                                                  float* __restrict__ C,
                                                  int N, int K) {
    const int row0 = blockIdx.y * 128, col0 = blockIdx.x * 64;
    const int t = threadIdx.x;
    const int w = t >> 6, l = t & 63, lq = l & 15, lg = l >> 4;
    __shared__ unsigned short sAh[128 * 64];
    __shared__ unsigned short sAl[128 * 64];
    __shared__ unsigned short sBh[64 * 64];
    __shared__ unsigned short sBl[64 * 64];
    f32x4 acc[2][4];
    #pragma unroll
    for (int mi = 0; mi < 2; mi++)
        #pragma unroll
        for (int ni = 0; ni < 4; ni++) acc[mi][ni] = f32x4{0.f, 0.f, 0.f, 0.f};

    for (int k0 = 0; k0 < K; k0 += 64) {
        __syncthreads();
        #pragma unroll
        for (int p = 0; p < 4; p++) {
            const int e = t * 8 + p * 2048;
            const int row = e >> 6, col = e & 63;
            const int sw = (e * 2) ^ ((row & 7) << 4);
            *(bf16x8*)((char*)sAh + sw) = *(const bf16x8*)(Ah + (size_t)(row0 + row) * K + k0 + col);
            *(bf16x8*)((char*)sAl + sw) = *(const bf16x8*)(Al + (size_t)(row0 + row) * K + k0 + col);
        }
        #pragma unroll
        for (int p = 0; p < 2; p++) {
            const int e = t * 8 + p * 2048;
            const int row = e >> 6, col = e & 63;
            const int sw = (e * 2) ^ ((row & 7) << 4);
            *(bf16x8*)((char*)sBh + sw) = *(const bf16x8*)(Bh + (size_t)(col0 + row) * K + k0 + col);
            *(bf16x8*)((char*)sBl + sw) = *(const bf16x8*)(Bl + (size_t)(col0 + row) * K + k0 + col);
        }
        __syncthreads();
        #pragma unroll
        for (int kk = 0; kk < 2; kk++) {
            bf16x8 ah[2], al[2], bh[4], bl[4];
            #pragma unroll
            for (int mi = 0; mi < 2; mi++) {
                const int r = w * 32 + mi * 16 + lq;
                const int off = (r * 128 + lg * 16 + kk * 64) ^ ((r & 7) << 4);
                ah[mi] = *(const bf16x8*)((const char*)sAh + off);
                al[mi] = *(const bf16x8*)((const char*)sAl + off);
            }
            #pragma unroll
            for (int ni = 0; ni < 4; ni++) {
                const int r = ni * 16 + lq;
                const int off = (r * 128 + lg * 16 + kk * 64) ^ ((r & 7) << 4);
                bh[ni] = *(const bf16x8*)((const char*)sBh + off);
                bl[ni] = *(const bf16x8*)((const char*)sBl + off);
            }
            #pragma unroll
            for (int mi = 0; mi < 2; mi++)
                #pragma unroll
                for (int ni = 0; ni < 4; ni++) {
                    acc[mi][ni] = __builtin_amdgcn_mfma_f32_16x16x32_bf16(ah[mi], bh[ni], acc[mi][ni], 0, 0, 0);
                    acc[mi][ni] = __builtin_amdgcn_mfma_f32_16x16x32_bf16(ah[mi], bl[ni], acc[mi][ni], 0, 0, 0);
                    acc[mi][ni] = __builtin_amdgcn_mfma_f32_16x16x32_bf16(al[mi], bh[ni], acc[mi][ni], 0, 0, 0);
                }
        }
    }
    #pragma unroll
    for (int mi = 0; mi < 2; mi++)
        #pragma unroll
        for (int j = 0; j < 4; j++) {
            const int row = row0 + w * 32 + mi * 16 + lg * 4 + j;
            #pragma unroll
            for (int ni = 0; ni < 4; ni++)
                C[(size_t)row * N + col0 + ni * 16 + lq] = acc[mi][ni][j];
        }
}

// ---------------- phase-1 softmax prefs ----------------
__global__ void __launch_bounds__(256) softpref_kernel(const float* __restrict__ lgt,
                                                       const float* __restrict__ imp,
                                                       float* __restrict__ wpref) {
    const int tok = blockIdx.x * 64 + (threadIdx.x >> 2);
    const int sg = threadIdx.x & 3;
    const int o = (sg == 0) ? 0 : (64 + 32 * (sg - 1));
    const int n = (sg == 0) ? 64 : 32;
    const float* lp = lgt + (size_t)tok * 192 + o;
    float m = -1e30f;
    for (int i = 0; i < n; i++) m = fmaxf(m, lp[i]);
    float ss = 0.f;
    for (int i = 0; i < n; i++) ss += __expf(lp[i] - m);
    const float scl = imp[tok] / ss;
    float* wp = wpref + (size_t)tok * 160 + o;
    for (int i = 0; i < n; i++) wp[i] = __expf(lp[i] - m) * scl;
}

// ---------------- phase-2 softmax prefs ----------------
__global__ void __launch_bounds__(256) softm_kernel(const float* __restrict__ lgt,
                                                    const float* __restrict__ imp,
                                                    float* __restrict__ wpref) {
    const int tok = blockIdx.x * 256 + threadIdx.x;
    const float* lp = lgt + (size_t)tok * 64;
    float m = -1e30f;
    for (int i = 0; i < 64; i++) m = fmaxf(m, lp[i]);
    float ss = 0.f;
    for (int i = 0; i < 64; i++) ss += __expf(lp[i] - m);
    const float scl = imp[tok] / ss;
    for (int i = 0; i < 64; i++) wpref[(size_t)tok * 64 + i] = __expf(lp[i] - m) * scl;
}

// ---------------- deterministic reduce over S ----------------
__global__ void __launch_bounds__(256) reduce_pref(const float* __restrict__ wpref,
                                                   float* __restrict__ dense,
                                                   int ncols, int outoff) {
    const int b = blockIdx.x / ncols, c = blockIdx.x % ncols;
    __shared__ float red[256];
    float s = 0.f;
    for (int si = threadIdx.x; si < SD; si += 256)
        s += wpref[((size_t)(b * SD + si)) * ncols + c];
    red[threadIdx.x] = s; __syncthreads();
    for (int st = 128; st; st >>= 1) { if (threadIdx.x < st) red[threadIdx.x] += red[threadIdx.x + st]; __syncthreads(); }
    if (threadIdx.x == 0) dense[b * 224 + outoff + c] = red[0];
}

// ---------------- top-k sparsify + renormalize ----------------
__global__ void topk_kernel(const float* __restrict__ dense,
                            int* __restrict__ ridx, float* __restrict__ rw,
                            int r0, int nr) {
    const int t = threadIdx.x;
    if (t >= BD * nr) return;
    const int b = t / nr, r = r0 + (t % nr);
    const int offs[5] = {0, 64, 96, 128, 160};
    const int ns[5]   = {64, 32, 32, 32, 64};
    const int ks[5]   = {8, 4, 4, 4, 8};
    const float* dv = dense + b * 224 + offs[r];
    const int n = ns[r], k = ks[r];
    unsigned long long mask = 0;
    float vals[8]; int idxs[8];
    float ssum = 0.f;
    for (int kk = 0; kk < k; kk++) {
        float best = -1e30f; int bi = 0;
        for (int i = 0; i < n; i++)
            if (!((mask >> i) & 1ull) && dv[i] > best) { best = dv[i]; bi = i; }
        mask |= 1ull << bi;
        vals[kk] = best; idxs[kk] = bi; ssum += best;
    }
    float inv = 1.f / (ssum + 1e-8f);
    for (int kk = 0; kk < 8; kk++) {
        ridx[(b * 5 + r) * 8 + kk] = (kk < k) ? idxs[kk] : 0;
        rw[(b * 5 + r) * 8 + kk]   = (kk < k) ? vals[kk] * inv : 0.f;
    }
}

// ---------------- fused mixture + transpose + bf16 (out batch stride param) ----------------
__global__ void __launch_bounds__(256) combine_t_kernel(const float* __restrict__ pool,
                                                        const int* __restrict__ ridx,
                                                        const float* __restrict__ rw,
                                                        int router, int kc,
                                                        unsigned short* __restrict__ outT,
                                                        int Rp, int Cp, long long sOut) {
    const int b = blockIdx.z;
    const int r0 = blockIdx.y * 64, c0 = blockIdx.x * 64;
    __shared__ float ls[64][65];
    const int* ii = ridx + (b * 5 + router) * 8;
    const float* ww = rw + (b * 5 + router) * 8;
    const int t = threadIdx.x;
    const int rr = t >> 4, cc = (t & 15) * 4;
    #pragma unroll
    for (int p = 0; p < 4; p++) {
        const int r = rr + p * 16;
        float4 acc = {0.f, 0.f, 0.f, 0.f};
        for (int kk = 0; kk < kc; kk++) {
            const float w = ww[kk];
            float4 v = *(const float4*)&pool[((size_t)ii[kk] * Rp + r0 + r) * Cp + c0 + cc];
            acc.x += w * v.x; acc.y += w * v.y; acc.z += w * v.z; acc.w += w * v.w;
        }
        ls[r][cc] = acc.x; ls[r][cc + 1] = acc.y; ls[r][cc + 2] = acc.z; ls[r][cc + 3] = acc.w;
    }
    __syncthreads();
    unsigned short* op = outT + (size_t)b * sOut;
    #pragma unroll
    for (int q = 0; q < 2; q++) {
        const int c = (t >> 3) + q * 32;
        const int r8 = (t & 7) * 8;
        union { unsigned short s[8]; bf16x8 v; } u;
        #pragma unroll
        for (int j = 0; j < 8; j++) u.s[j] = f2b(ls[r8 + j][c]);
        *(bf16x8*)(op + (size_t)(c0 + c) * Rp + r0 + r8) = u.v;
    }
}

// ---------------- tile transpose + fp32->bf16 (WO only) ----------------
__global__ void __launch_bounds__(256) tcvt_kernel(const float* __restrict__ src,
                                                   unsigned short* __restrict__ dst,
                                                   int R, int Cc) {
    __shared__ float ls[64][65];
    const int r0 = blockIdx.y * 64, c0 = blockIdx.x * 64;
    const int t = threadIdx.x;
    #pragma unroll
    for (int p = 0; p < 16; p++) {
        const int e = p * 256 + t;
        const int r = e >> 6, c = e & 63;
        ls[r][c] = src[(size_t)(r0 + r) * Cc + c0 + c];
    }
    __syncthreads();
    #pragma unroll
    for (int p = 0; p < 16; p++) {
        const int e = p * 256 + t;
        const int c = e >> 6, r = e & 63;
        dst[(size_t)(c0 + c) * R + r0 + r] = f2b(ls[r][c]);
    }
}

// ---------------- fp32 -> bf16 convert with scale ----------------
__global__ void __launch_bounds__(256) cvt_bf16_kernel(const float* __restrict__ src,
                                                       unsigned short* __restrict__ dst,
                                                       float scale, int n4) {
    const int i = blockIdx.x * 256 + threadIdx.x;
    if (i >= n4) return;
    float4 v = ((const float4*)src)[i];
    unsigned r0 = (unsigned)f2b(v.x * scale) | ((unsigned)f2b(v.y * scale) << 16);
    unsigned r1 = (unsigned)f2b(v.z * scale) | ((unsigned)f2b(v.w * scale) << 16);
    uint2 o; o.x = r0; o.y = r1;
    ((uint2*)dst)[i] = o;
}

// ---------------- bf16 MFMA GEMM: C = A[M][K] @ Bt[N][K]^T (+X), 128x128 tile ----------------
template<int OUTB, int HASX>
__global__ void __launch_bounds__(256) gemm_bf16(const unsigned short* __restrict__ A,
                                                 const unsigned short* __restrict__ Bt,
                                                 const float* __restrict__ X,
                                                 void* __restrict__ Cv,
                                                 int M, int N, int K,
                                                 long long sA, long long sB, long long sC) {
    const int bz = blockIdx.z;
    const unsigned short* Ab = A + (size_t)bz * sA;
    const unsigned short* Btb = Bt + (size_t)bz * sB;
    const int row0 = blockIdx.y * 128, col0 = blockIdx.x * 128;
    const int t = threadIdx.x;
    const int w = t >> 6, l = t & 63, lq = l & 15, lg = l >> 4;
    const int wr = w >> 1, wc = w & 1;
    __shared__ unsigned short As[128 * 64];
    __shared__ unsigned short Bs[128 * 64];
    f32x4 acc[4][4];
    #pragma unroll
    for (int mi = 0; mi < 4; mi++)
        #pragma unroll
        for (int ni = 0; ni < 4; ni++) acc[mi][ni] = f32x4{0.f, 0.f, 0.f, 0.f};

    for (int k0 = 0; k0 < K; k0 += 64) {
        __syncthreads();
        #pragma unroll
        for (int p = 0; p < 4; p++) {
            const int e = t * 8 + p * 2048;
            const int row = e >> 6, col = e & 63;
            bf16x8 va = *(const bf16x8*)(Ab + (size_t)(row0 + row) * K + k0 + col);
            *(bf16x8*)((char*)As + ((row * 128 + col * 2) ^ ((row & 7) << 4))) = va;
            bf16x8 vb = *(const bf16x8*)(Btb + (size_t)(col0 + row) * K + k0 + col);
            *(bf16x8*)((char*)Bs + ((row * 128 + col * 2) ^ ((row & 7) << 4))) = vb;
        }
        __syncthreads();
        #pragma unroll
        for (int kk = 0; kk < 2; kk++) {
            bf16x8 af[4], bg[4];
            #pragma unroll
            for (int mi = 0; mi < 4; mi++) {
                const int r = wr * 64 + mi * 16 + lq;
                af[mi] = *(const bf16x8*)((const char*)As + ((r * 128 + lg * 16 + kk * 64) ^ ((r & 7) << 4)));
            }
            #pragma unroll
            for (int ni = 0; ni < 4; ni++) {
                const int r = wc * 64 + ni * 16 + lq;
                bg[ni] = *(const bf16x8*)((const char*)Bs + ((r * 128 + lg * 16 + kk * 64) ^ ((r & 7) << 4)));
            }
            #pragma unroll
            for (int mi = 0; mi < 4; mi++)
                #pragma unroll
                for (int ni = 0; ni < 4; ni++)
                    acc[mi][ni] = __builtin_amdgcn_mfma_f32_16x16x32_bf16(af[mi], bg[ni], acc[mi][ni], 0, 0, 0);
        }
    }
    #pragma unroll
    for (int mi = 0; mi < 4; mi++) {
        #pragma unroll
        for (int j = 0; j < 4; j++) {
            const int row = row0 + wr * 64 + mi * 16 + lg * 4 + j;
            #pragma unroll
            for (int ni = 0; ni < 4; ni++) {
                const int col = col0 + wc * 64 + ni * 16 + lq;
                float v = acc[mi][ni][j];
                if (HASX) v += X[(size_t)row * N + col];
                if (OUTB) ((unsigned short*)Cv)[(size_t)bz * sC + (size_t)row * N + col] = f2b(v);
                else      ((float*)Cv)[(size_t)bz * sC + (size_t)row * N + col] = v;
            }
        }
    }
}

// ---------------- narrow GEMM for h/Qm: BM=64, N=128 fixed, bf16 out ----------------
__global__ void __launch_bounds__(256) gemm_h(const unsigned short* __restrict__ A,
                                              const unsigned short* __restrict__ Bt,
                                              unsigned short* __restrict__ C,
                                              int K,
                                              long long sA, long long sB, long long sC) {
    const int bz = blockIdx.z;
    const unsigned short* Ab = A + (size_t)bz * sA;
    const unsigned short* Btb = Bt + (size_t)bz * sB;
    const int row0 = blockIdx.y * 64;
    const int t = threadIdx.x;
    const int w = t >> 6, l = t & 63, lq = l & 15, lg = l >> 4;
    __shared__ unsigned short As[64 * 64];
    __shared__ unsigned short Bs[128 * 64];
    f32x4 acc[8];
    #pragma unroll
    for (int ni = 0; ni < 8; ni++) acc[ni] = f32x4{0.f, 0.f, 0.f, 0.f};

    for (int k0 = 0; k0 < K; k0 += 64) {
        __syncthreads();
        #pragma unroll
        for (int p = 0; p < 2; p++) {
            const int e = t * 8 + p * 2048;
            const int row = e >> 6, col = e & 63;
            bf16x8 va = *(const bf16x8*)(Ab + (size_t)(row0 + row) * K + k0 + col);
            *(bf16x8*)((char*)As + ((row * 128 + col * 2) ^ ((row & 7) << 4))) = va;
        }
        #pragma unroll
        for (int p = 0; p < 4; p++) {
            const int e = t * 8 + p * 2048;
            const int row = e >> 6, col = e & 63;
            bf16x8 vb = *(const bf16x8*)(Btb + (size_t)row * K + k0 + col);
            *(bf16x8*)((char*)Bs + ((row * 128 + col * 2) ^ ((row & 7) << 4))) = vb;
        }
        __syncthreads();
        #pragma unroll
        for (int kk = 0; kk < 2; kk++) {
            const int ra = w * 16 + lq;
            bf16x8 af = *(const bf16x8*)((const char*)As + ((ra * 128 + lg * 16 + kk * 64) ^ ((ra & 7) << 4)));
            #pragma unroll
            for (int ni = 0; ni < 8; ni++) {
                const int r = ni * 16 + lq;
                bf16x8 bg = *(const bf16x8*)((const char*)Bs + ((r * 128 + lg * 16 + kk * 64) ^ ((r & 7) << 4)));
                acc[ni] = __builtin_amdgcn_mfma_f32_16x16x32_bf16(af, bg, acc[ni], 0, 0, 0);
            }
        }
    }
    #pragma unroll
    for (int j = 0; j < 4; j++) {
        const int row = row0 + w * 16 + lg * 4 + j;
        #pragma unroll
        for (int ni = 0; ni < 8; ni++)
            C[(size_t)bz * sC + (size_t)row * 128 + ni * 16 + lq] = f2b(acc[ni][j]);
    }
}

// ---------------- flash attention: paired q-tiles, dbuf K/V, strided QKV input ----------------
#define SWZV(d) (((((d) >> 1) ^ ((d) >> 3)) & 7) << 4)
__global__ void __launch_bounds__(256) attn_mfma_kernel(const unsigned short* __restrict__ Q,
                                                        const unsigned short* __restrict__ K,
                                                        const unsigned short* __restrict__ V,
                                                        unsigned short* __restrict__ O,
                                                        int ldq) {
    const int qt = blockIdx.x, hh = blockIdx.y, b = blockIdx.z;
    const int t = threadIdx.x;
    const int w = t >> 6, l = t & 63, lq = l & 15, lg = l >> 4;

    __shared__ unsigned short ks[2][64 * 64];
    __shared__ unsigned short vt[2][64 * 64];
    __shared__ unsigned short pl[4][16 * 64];

    const size_t base = (size_t)b * SD * ldq + (size_t)hh * DH;
    const size_t obase = (size_t)b * SD * DM + (size_t)hh * DH;
    const int qA = qt;
    const int qB = 15 - qt;

    bf16x8 aqA[2], aqB[2];
    {
        const unsigned short* qp = Q + base + (size_t)(qA * 64 + w * 16 + lq) * ldq + lg * 8;
        aqA[0] = *(const bf16x8*)qp; aqA[1] = *(const bf16x8*)(qp + 32);
        const unsigned short* qp2 = Q + base + (size_t)(qB * 64 + w * 16 + lq) * ldq + lg * 8;
        aqB[0] = *(const bf16x8*)qp2; aqB[1] = *(const bf16x8*)(qp2 + 32);
    }

    f32x4 oA[4], oB[4];
    #pragma unroll
    for (int dt = 0; dt < 4; dt++) { oA[dt] = f32x4{0.f,0.f,0.f,0.f}; oB[dt] = f32x4{0.f,0.f,0.f,0.f}; }
    float mA[4] = {-1e30f,-1e30f,-1e30f,-1e30f}, sA[4] = {0.f,0.f,0.f,0.f};
    float mB[4] = {-1e30f,-1e30f,-1e30f,-1e30f}, sB[4] = {0.f,0.f,0.f,0.f};

    const int ntile = 16 - qt;
    const int srow = t >> 3;
    const int scol = (t & 7) * 8;

    int cur = 0;

    #pragma unroll
    for (int p = 0; p < 2; p++) {
        const int row = srow + 32 * p;
        bf16x8 kv = *(const bf16x8*)(K + base + (size_t)row * ldq + scol);
        *(bf16x8*)((char*)&ks[0][0] + ((row * 128 + scol * 2) ^ ((row & 7) << 4))) = kv;
        bf16x8 vv = *(const bf16x8*)(V + base + (size_t)row * ldq + scol);
        #pragma unroll
        for (int j2 = 0; j2 < 8; j2++) {
            const int d = scol + j2;
            *(unsigned short*)((char*)&vt[0][0] + ((d * 128 + row * 2) ^ SWZV(d))) = (unsigned short)vv[j2];
        }
    }
    __syncthreads();

    auto compute = [&](int q0, const bf16x8* aq, f32x4* o_, float* m_, float* s_, int kt) {
        const f32x4 zero4 = {0.f, 0.f, 0.f, 0.f};
        f32x4 sacc[4];
        #pragma unroll
        for (int ct = 0; ct < 4; ct++) {
            const int krow = ct * 16 + lq;
            bf16x8 b0 = *(const bf16x8*)((const char*)&ks[cur][0] + ((krow * 128 + lg * 16) ^ ((lq & 7) << 4)));
            bf16x8 b1 = *(const bf16x8*)((const char*)&ks[cur][0] + ((krow * 128 + lg * 16 + 64) ^ ((lq & 7) << 4)));
            f32x4 s = __builtin_amdgcn_mfma_f32_16x16x32_bf16(aq[0], b0, zero4, 0, 0, 0);
            s = __builtin_amdgcn_mfma_f32_16x16x32_bf16(aq[1], b1, s, 0, 0, 0);
            sacc[ct] = s;
        }
        float tm[4];
        #pragma unroll
        for (int j = 0; j < 4; j++) {
            const int qg = q0 * 64 + w * 16 + lg * 4 + j;
            float mx = -1e30f;
            #pragma unroll
            for (int ct = 0; ct < 4; ct++) {
                const int kg = kt * 64 + ct * 16 + lq;
                float v = sacc[ct][j] * 0.125f;
                v = (kg <= qg) ? v : -1e30f;
                sacc[ct][j] = v;
                mx = fmaxf(mx, v);
            }
            #pragma unroll
            for (int d = 1; d < 16; d <<= 1) mx = fmaxf(mx, __shfl_xor(mx, d));
            tm[j] = mx;
        }
        #pragma unroll
        for (int j = 0; j < 4; j++) {
            const float nm = fmaxf(m_[j], tm[j]);
            const float so = __expf(m_[j] - nm);
            m_[j] = nm;
            float rs = 0.f;
            const int prow = lg * 4 + j;
            #pragma unroll
            for (int ct = 0; ct < 4; ct++) {
                const float p = __expf(sacc[ct][j] - nm);
                rs += p;
                const int byteoff = ((prow * 128) + (ct * 16 + lq) * 2) ^ ((prow & 7) << 4);
                *(unsigned short*)((char*)&pl[w][0] + byteoff) = f2b(p);
            }
            #pragma unroll
            for (int d = 1; d < 16; d <<= 1) rs += __shfl_xor(rs, d);
            s_[j] = s_[j] * so + rs;
            #pragma unroll
            for (int dt = 0; dt < 4; dt++) o_[dt][j] *= so;
        }
        asm volatile("s_waitcnt lgkmcnt(0)" ::: "memory");
        __builtin_amdgcn_sched_barrier(0);
        #pragma unroll
        for (int c = 0; c < 2; c++) {
            bf16x8 pa = *(const bf16x8*)((const char*)&pl[w][0] +
                          ((lq * 128 + lg * 16 + 64 * c) ^ ((lq & 7) << 4)));
            #pragma unroll
            for (int dt = 0; dt < 4; dt++) {
                const int dd = dt * 16 + lq;
                bf16x8 bv = *(const bf16x8*)((const char*)&vt[cur][0] +
                              ((dd * 128 + lg * 16 + 64 * c) ^ SWZV(dd)));
                o_[dt] = __builtin_amdgcn_mfma_f32_16x16x32_bf16(pa, bv, o_[dt], 0, 0, 0);
            }
        }
    };

    const int mymaxA = qA * 64 + w * 16 + 15;
    for (int kt = 0; kt < ntile; kt++) {
        bf16x8 kN[2], vN[2];
        const bool pre = (kt + 1 < ntile);
        if (pre) {
            #pragma unroll
            for (int p = 0; p < 2; p++) {
                const int row = srow + 32 * p;
                kN[p] = *(const bf16x8*)(K + base + (size_t)((kt + 1) * 64 + row) * ldq + scol);
                vN[p] = *(const bf16x8*)(V + base + (size_t)((kt + 1) * 64 + row) * ldq + scol);
            }
        }
        compute(qB, aqB, oB, mB, sB, kt);
        if (kt * 64 <= mymaxA) compute(qA, aqA, oA, mA, sA, kt);
        if (pre) {
            #pragma unroll
            for (int p = 0; p < 2; p++) {
                const int row = srow + 32 * p;
                *(bf16x8*)((char*)&ks[cur ^ 1][0] + ((row * 128 + scol * 2) ^ ((row & 7) << 4))) = kN[p];
                #pragma unroll
                for (int j2 = 0; j2 < 8; j2++) {
                    const int d = scol + j2;
                    *(unsigned short*)((char*)&vt[cur ^ 1][0] + ((d * 128 + row * 2) ^ SWZV(d))) =
                        (unsigned short)vN[p][j2];
                }
            }
        }
        __syncthreads();
        cur ^= 1;
    }

    #pragma unroll
    for (int j = 0; j < 4; j++) {
        const float invA = 1.f / sA[j];
        const float invB = 1.f / sB[j];
        const int rowA = qA * 64 + w * 16 + lg * 4 + j;
        const int rowB = qB * 64 + w * 16 + lg * 4 + j;
        unsigned short* opA = O + obase + (size_t)rowA * DM;
        unsigned short* opB = O + obase + (size_t)rowB * DM;
        #pragma unroll
        for (int dt = 0; dt < 4; dt++) {
            opA[dt * 16 + lq] = f2b(oA[dt][j] * invA);
            opB[dt * 16 + lq] = f2b(oB[dt][j] * invB);
        }
    }
}
#undef SWZV

// ---------------- knowledge scores: 16-key wave-private LDS tiles ----------------
#define CE(a, b) { float hi_ = fmaxf(a, b), lo_ = fminf(a, b); a = hi_; b = lo_; }
__global__ void __launch_bounds__(512, 4) know_score_kernel(const unsigned short* __restrict__ Qmb,
                                                            const unsigned short* __restrict__ kKb,
                                                            float* __restrict__ cand) {
    const int t = threadIdx.x;
    const int w = t >> 6, l = t & 63, lq = l & 15, lg = l >> 4;
    const int tok0 = blockIdx.x * 16;
    __shared__ unsigned short ks[8][16 * 128];

    bf16x8 aq[4];
    {
        const unsigned short* qp = Qmb + (size_t)(tok0 + lq) * 128 + lg * 8;
        #pragma unroll
        for (int c = 0; c < 4; c++) aq[c] = *(const bf16x8*)(qp + c * 32);
    }

    float L[4][8];
    #pragma unroll
    for (int j = 0; j < 4; j++)
        #pragma unroll
        for (int s = 0; s < 8; s++) L[j][s] = __uint_as_float(0xF2000000u | (unsigned)s);

    const unsigned short* gsrc = kKb + (((size_t)w * 2048) << 7) + l * 8;
    unsigned short* myks = &ks[w][0];

    bf16x8 vreg[4];
    #pragma unroll
    for (int p = 0; p < 4; p++) vreg[p] = *(const bf16x8*)(gsrc + p * 512);

    for (int t4 = 0; t4 < 32; t4++) {
        float B[4][4];
        #pragma unroll
        for (int sub = 0; sub < 4; sub++) {
            const int kt = t4 * 4 + sub;
            #pragma unroll
            for (int p = 0; p < 4; p++) {
                const int e = p * 512 + l * 8;
                const int row = e >> 7;
                *(bf16x8*)((char*)myks + ((e * 2) ^ ((row & 7) << 4))) = vreg[p];
            }
            if (kt < 127) {
                const unsigned short* src2 = gsrc + (size_t)(kt + 1) * 2048;
                #pragma unroll
                for (int p = 0; p < 4; p++) vreg[p] = *(const bf16x8*)(src2 + p * 512);
            }
            {
                const char* kb = (const char*)myks + lq * 256;
                const int sw = (lq & 7) << 4;
                f32x4 s = {0.f, 0.f, 0.f, 0.f};
                #pragma unroll
                for (int c = 0; c < 4; c++) {
                    bf16x8 bv = *(const bf16x8*)(kb + ((c * 64 + lg * 16) ^ sw));
                    s = __builtin_amdgcn_mfma_f32_16x16x32_bf16(aq[c], bv, s, 0, 0, 0);
                }
                const unsigned keyb = (unsigned)(w * 2048 + kt * 16 + lq);
                #pragma unroll
                for (int j = 0; j < 4; j++) {
                    unsigned u = __float_as_uint(s[j]);
                    B[j][sub] = __uint_as_float((u & 0xFFFFC000u) | keyb);
                }
            }
        }
        #pragma unroll
        for (int j = 0; j < 4; j++) {
            CE(B[j][0], B[j][2]); CE(B[j][1], B[j][3]);
            CE(B[j][0], B[j][1]); CE(B[j][2], B[j][3]);
            CE(B[j][1], B[j][2]);
            L[j][4] = fmaxf(L[j][4], B[j][3]);
            L[j][5] = fmaxf(L[j][5], B[j][2]);
            L[j][6] = fmaxf(L[j][6], B[j][1]);
            L[j][7] = fmaxf(L[j][7], B[j][0]);
            CE(L[j][0], L[j][4]); CE(L[j][1], L[j][5]); CE(L[j][2], L[j][6]); CE(L[j][3], L[j][7]);
            CE(L[j][0], L[j][2]); CE(L[j][1], L[j][3]); CE(L[j][4], L[j][6]); CE(L[j][5], L[j][7]);
            CE(L[j][0], L[j][1]); CE(L[j][2], L[j][3]); CE(L[j][4], L[j][5]); CE(L[j][6], L[j][7]);
        }
    }
    #pragma unroll
    for (int j = 0; j < 4; j++) {
        const int tok = tok0 + lg * 4 + j;
        float* cp = cand + ((size_t)tok << 10) + w * 128 + lq * 8;
        #pragma unroll
        for (int ss = 0; ss < 8; ss++) cp[ss] = L[j][ss];
    }
}
#undef CE

// ---------------- knowledge merge + V gather ----------------
__global__ void __launch_bounds__(256) know_out_kernel(const float* __restrict__ cand,
                                                       const float* __restrict__ kV,
                                                       float* __restrict__ out) {
    const int t = threadIdx.x, w = t >> 6, l = t & 63;
    const int tok = blockIdx.x * 4 + w;
    const float* cp = cand + ((size_t)tok << 10);
    float lv[16];
    #pragma unroll
    for (int i = 0; i < 16; i++) lv[i] = cp[i * 64 + l];

    float topv[8]; int topi[8];
    #pragma unroll
    for (int kk = 0; kk < 8; kk++) {
        float m = lv[0];
        #pragma unroll
        for (int i = 1; i < 16; i++) m = fmaxf(m, lv[i]);
        #pragma unroll
        for (int d = 1; d < 64; d <<= 1) m = fmaxf(m, __shfl_xor(m, d));
        topv[kk] = m;
        topi[kk] = (int)(__float_as_uint(m) & 0x3FFFu);
        #pragma unroll
        for (int i = 0; i < 16; i++) lv[i] = (lv[i] == m) ? -1e31f : lv[i];
    }
    const float mx = topv[0];
    float e[8]; float ssum = 0.f;
    #pragma unroll
    for (int kk = 0; kk < 8; kk++) { e[kk] = __expf(topv[kk] - mx); ssum += e[kk]; }
    const float inv = 1.f / ssum;

    float4 acc[4];
    #pragma unroll
    for (int ch = 0; ch < 4; ch++) acc[ch] = float4{0.f, 0.f, 0.f, 0.f};
    #pragma unroll
    for (int kk = 0; kk < 8; kk++) {
        const float wk = e[kk] * inv;
        const float* vp = kV + ((size_t)topi[kk] << 10);
        #pragma unroll
        for (int ch = 0; ch < 4; ch++) {
            float4 v = *(const float4*)(vp + ch * 256 + l * 4);
            acc[ch].x += wk * v.x; acc[ch].y += wk * v.y;
            acc[ch].z += wk * v.z; acc[ch].w += wk * v.w;
        }
    }
    float* op = out + ((size_t)tok << 10);
    #pragma unroll
    for (int ch = 0; ch < 4; ch++) {
        float4 o = *(const float4*)(op + ch * 256 + l * 4);
        o.x += acc[ch].x; o.y += acc[ch].y; o.z += acc[ch].z; o.w += acc[ch].w;
        *(float4*)(op + ch * 256 + l * 4) = o;
    }
}

extern "C" void kernel_launch(void* const* d_in, const int* in_sizes, int n_in,
                              void* d_out, int out_size, void* d_ws, size_t ws_size,
                              hipStream_t stream) {
    const float* x    = (const float*)d_in[0];
    const float* imp  = (const float*)d_in[1];
    const float* Wc   = (const float*)d_in[2];
    const float* WQr  = (const float*)d_in[3];
    const float* WKr  = (const float*)d_in[4];
    const float* WVr  = (const float*)d_in[5];
    const float* Wm   = (const float*)d_in[6];
    const float* cneu = (const float*)d_in[7];
    const float* epool= (const float*)d_in[8];
    const float* kK   = (const float*)d_in[9];
    const float* kV   = (const float*)d_in[10];
    const float* WO   = (const float*)d_in[11];
    const float* ln1s = (const float*)d_in[12];
    const float* ln1b = (const float*)d_in[13];
    const float* ln2s = (const float*)d_in[14];
    const float* ln2b = (const float*)d_in[15];
    float* out = (float*)d_out;

    float* ws = (float*)d_ws;
    size_t o = 0;
    unsigned short* n1h = (unsigned short*)(ws + o); o += (size_t)BD * SD * DM / 2;
    unsigned short* n1l = (unsigned short*)(ws + o); o += (size_t)BD * SD * DM / 2;
    float* lgt   = ws + o; o += (size_t)BD * SD * 192;
    float* wpref = ws + o; o += (size_t)BD * SD * 160;
    float* dense = ws + o; o += (size_t)BD * 224;
    int*   ridx  = (int*)(ws + o); o += (size_t)BD * 5 * 8;
    float* rw    = ws + o; o += (size_t)BD * 5 * 8;
    unsigned short* WTh = (unsigned short*)(ws + o); o += (size_t)256 * 1024 / 2;
    unsigned short* WTl = (unsigned short*)(ws + o); o += (size_t)256 * 1024 / 2;
    unsigned short* scompT = (unsigned short*)(ws + o); o += (size_t)BD * RK * DM / 2;
    unsigned short* E3t = (unsigned short*)(ws + o); o += (size_t)BD * 3 * DM * RK / 2;
    unsigned short* hb  = (unsigned short*)(ws + o); o += (size_t)BD * SD * RK / 2;
    unsigned short* QKV16 = (unsigned short*)(ws + o); o += (size_t)BD * SD * 3072 / 2;
    unsigned short* attnb = (unsigned short*)(ws + o); o += (size_t)BD * SD * DM / 2;
    unsigned short* WOt = (unsigned short*)(ws + o); o += (size_t)DM * DM / 2;
    unsigned short* kKb = (unsigned short*)(ws + o); o += (size_t)NK * RK / 2;
    unsigned short* Qmb = (unsigned short*)(ws + o); o += (size_t)BD * SD * RK / 2;
    float* cand = ws + o; o += (size_t)BD * SD * 1024;

    const int NTOK = BD * SD;
    const long long sE3 = (long long)3 * DM * RK;

    // independent prep
    concatw_kernel<<<1024, 256, 0, stream>>>(Wc, WQr, WKr, WVr, Wm, WTh, WTl);
    tcvt_kernel<<<dim3(16, 16, 1), 256, 0, stream>>>(WO, WOt, DM, DM);
    cvt_bf16_kernel<<<(NK * RK / 4) / 256, 256, 0, stream>>>(kK, kKb, 0.0883883476483184f, NK * RK / 4);

    // phase 1
    ln_kernel<<<NTOK, 256, 0, stream>>>(x, ln1s, ln1b, n1h, n1l);
    gemm_split<<<dim3(3, NTOK / 128), 256, 0, stream>>>(n1h, n1l, WTh, WTl, lgt, 192, DM);
    softpref_kernel<<<NTOK / 64, 256, 0, stream>>>(lgt, imp, wpref);
    reduce_pref<<<BD * 160, 256, 0, stream>>>(wpref, dense, 160, 0);
    topk_kernel<<<1, 64, 0, stream>>>(dense, ridx, rw, 0, 4);
    combine_t_kernel<<<dim3(2, 16, BD), 256, 0, stream>>>(cneu, ridx, rw, 0, 8, scompT, DM, RK,
        (long long)DM * RK);
    combine_t_kernel<<<dim3(16, 2, BD), 256, 0, stream>>>(epool, ridx, rw, 1, 4,
        E3t + (size_t)0 * DM * RK, RK, DM, sE3);
    combine_t_kernel<<<dim3(16, 2, BD), 256, 0, stream>>>(epool, ridx, rw, 2, 4,
        E3t + (size_t)1 * DM * RK, RK, DM, sE3);
    combine_t_kernel<<<dim3(16, 2, BD), 256, 0, stream>>>(epool, ridx, rw, 3, 4,
        E3t + (size_t)2 * DM * RK, RK, DM, sE3);
    gemm_h<<<dim3(1, SD / 64, BD), 256, 0, stream>>>(n1h, scompT, hb,
        DM, (long long)SD * DM, (long long)RK * DM, (long long)SD * RK);
    // fused QKV: C[b][s][3072]
    gemm_bf16<1, 0><<<dim3(24, 8, BD), 256, 0, stream>>>(hb, E3t, nullptr, QKV16,
        SD, 3072, RK, (long long)SD * RK, sE3, (long long)SD * 3072);
    attn_mfma_kernel<<<dim3(8, NH, BD), 256, 0, stream>>>(QKV16, QKV16 + 1024, QKV16 + 2048,
        attnb, 3072);
    gemm_bf16<0, 1><<<dim3(8, 64, 1), 256, 0, stream>>>(attnb, WOt, x, out,
        NTOK, DM, DM, 0, 0, 0);

    // phase 2
    ln_kernel<<<NTOK, 256, 0, stream>>>(out, ln2s, ln2b, n1h, n1l);
    gemm_split<<<dim3(1, NTOK / 128), 256, 0, stream>>>(n1h, n1l,
        WTh + (size_t)192 * 1024, WTl + (size_t)192 * 1024, lgt, 64, DM);
    softm_kernel<<<NTOK / 256, 256, 0, stream>>>(lgt, imp, wpref);
    reduce_pref<<<BD * 64, 256, 0, stream>>>(wpref, dense, 64, 160);
    topk_kernel<<<1, 64, 0, stream>>>(dense, ridx, rw, 4, 1);
    combine_t_kernel<<<dim3(2, 16, BD), 256, 0, stream>>>(cneu, ridx, rw, 4, 8, scompT, DM, RK,
        (long long)DM * RK);
    gemm_h<<<dim3(1, SD / 64, BD), 256, 0, stream>>>(n1h, scompT, Qmb,
        DM, (long long)SD * DM, (long long)RK * DM, (long long)SD * RK);
    know_score_kernel<<<NTOK / 16, 512, 0, stream>>>(Qmb, kKb, cand);
    know_out_kernel<<<NTOK / 4, 256, 0, stream>>>(cand, kV, out);
}

// Round 13
// 625.355 us; speedup vs baseline: 10.4346x; 1.0810x over previous
//
#include <hip/hip_runtime.h>
#include <hip/hip_bf16.h>

#define BD 8
#define SD 1024
#define DM 1024
#define NH 16
#define DH 64
#define RK 128
#define NK 16384

typedef __attribute__((ext_vector_type(8))) short bf16x8;
typedef __attribute__((ext_vector_type(4))) float f32x4;

__device__ __forceinline__ unsigned short f2b(float f) {
    unsigned u = __float_as_uint(f);
    unsigned r = (u + 0x7FFFu + ((u >> 16) & 1u)) >> 16;
    return (unsigned short)r;
}
__device__ __forceinline__ float b2f(unsigned short h) {
    return __uint_as_float(((unsigned)h) << 16);
}

// ---------------- LayerNorm: bf16 hi/lo outputs ----------------
__global__ void __launch_bounds__(256) ln_kernel(const float* __restrict__ x,
                                                 const float* __restrict__ sc,
                                                 const float* __restrict__ bi,
                                                 unsigned short* __restrict__ outh,
                                                 unsigned short* __restrict__ outl) {
    const int tok = blockIdx.x;
    __shared__ float xs[DM];
    __shared__ float red[256];
    const float* xp = x + (size_t)tok * DM;
    float s = 0.f;
    for (int i = threadIdx.x; i < DM; i += 256) { float v = xp[i]; xs[i] = v; s += v; }
    red[threadIdx.x] = s; __syncthreads();
    for (int st = 128; st; st >>= 1) { if (threadIdx.x < st) red[threadIdx.x] += red[threadIdx.x + st]; __syncthreads(); }
    float mu = red[0] * (1.f / DM);
    __syncthreads();
    float vs = 0.f;
    for (int i = threadIdx.x; i < DM; i += 256) { float d = xs[i] - mu; vs += d * d; }
    red[threadIdx.x] = vs; __syncthreads();
    for (int st = 128; st; st >>= 1) { if (threadIdx.x < st) red[threadIdx.x] += red[threadIdx.x + st]; __syncthreads(); }
    float rs = rsqrtf(red[0] * (1.f / DM) + 1e-5f);
    for (int i = threadIdx.x; i < DM; i += 256) {
        float v = (xs[i] - mu) * rs * sc[i] + bi[i];
        unsigned short h = f2b(v);
        outh[(size_t)tok * DM + i] = h;
        outl[(size_t)tok * DM + i] = f2b(v - b2f(h));
    }
}

// ---------------- router weights -> transposed hi/lo bf16 [256][1024] ----------------
__global__ void __launch_bounds__(256) concatw_kernel(const float* __restrict__ Wc,
                                                      const float* __restrict__ WQr,
                                                      const float* __restrict__ WKr,
                                                      const float* __restrict__ WVr,
                                                      const float* __restrict__ Wm,
                                                      unsigned short* __restrict__ WTh,
                                                      unsigned short* __restrict__ WTl) {
    const int i = blockIdx.x * 256 + threadIdx.x;
    const int c = i >> 10, d = i & 1023;
    float v = 0.f;
    if (c < 64)       v = Wc[d * 64 + c];
    else if (c < 96)  v = WQr[d * 32 + c - 64];
    else if (c < 128) v = WKr[d * 32 + c - 96];
    else if (c < 160) v = WVr[d * 32 + c - 128];
    else if (c >= 192) v = Wm[d * 64 + c - 192];
    unsigned short h = f2b(v);
    WTh[i] = h;
    WTl[i] = f2b(v - b2f(h));
}

// ---------------- split-bf16 logits GEMM ----------------
__global__ void __launch_bounds__(256) gemm_split(const unsigned short* __restrict__ Ah,
                                                  const unsigned short* __restrict__ Al,
                                                  const unsigned short* __restrict__ Bh,
                                                  const unsigned short* __restrict__ Bl,
                                                  float* __restrict__ C,
                                                  int N, int K) {
    const int row0 = blockIdx.y * 128, col0 = blockIdx.x * 64;
    const int t = threadIdx.x;
    const int w = t >> 6, l = t & 63, lq = l & 15, lg = l >> 4;
    __shared__ unsigned short sAh[128 * 64];
    __shared__ unsigned short sAl[128 * 64];
    __shared__ unsigned short sBh[64 * 64];
    __shared__ unsigned short sBl[64 * 64];
    f32x4 acc[2][4];
    #pragma unroll
    for (int mi = 0; mi < 2; mi++)
        #pragma unroll
        for (int ni = 0; ni < 4; ni++) acc[mi][ni] = f32x4{0.f, 0.f, 0.f, 0.f};

    for (int k0 = 0; k0 < K; k0 += 64) {
        __syncthreads();
        #pragma unroll
        for (int p = 0; p < 4; p++) {
            const int e = t * 8 + p * 2048;
            const int row = e >> 6, col = e & 63;
            const int sw = (e * 2) ^ ((row & 7) << 4);
            *(bf16x8*)((char*)sAh + sw) = *(const bf16x8*)(Ah + (size_t)(row0 + row) * K + k0 + col);
            *(bf16x8*)((char*)sAl + sw) = *(const bf16x8*)(Al + (size_t)(row0 + row) * K + k0 + col);
        }
        #pragma unroll
        for (int p = 0; p < 2; p++) {
            const int e = t * 8 + p * 2048;
            const int row = e >> 6, col = e & 63;
            const int sw = (e * 2) ^ ((row & 7) << 4);
            *(bf16x8*)((char*)sBh + sw) = *(const bf16x8*)(Bh + (size_t)(col0 + row) * K + k0 + col);
            *(bf16x8*)((char*)sBl + sw) = *(const bf16x8*)(Bl + (size_t)(col0 + row) * K + k0 + col);
        }
        __syncthreads();
        #pragma unroll
        for (int kk = 0; kk < 2; kk++) {
            bf16x8 ah[2], al[2], bh[4], bl[4];
            #pragma unroll
            for (int mi = 0; mi < 2; mi++) {
                const int r = w * 32 + mi * 16 + lq;
                const int off = (r * 128 + lg * 16 + kk * 64) ^ ((r & 7) << 4);
                ah[mi] = *(const bf16x8*)((const char*)sAh + off);
                al[mi] = *(const bf16x8*)((const char*)sAl + off);
            }
            #pragma unroll
            for (int ni = 0; ni < 4; ni++) {
                const int r = ni * 16 + lq;
                const int off = (r * 128 + lg * 16 + kk * 64) ^ ((r & 7) << 4);
                bh[ni] = *(const bf16x8*)((const char*)sBh + off);
                bl[ni] = *(const bf16x8*)((const char*)sBl + off);
            }
            #pragma unroll
            for (int mi = 0; mi < 2; mi++)
                #pragma unroll
                for (int ni = 0; ni < 4; ni++) {
                    acc[mi][ni] = __builtin_amdgcn_mfma_f32_16x16x32_bf16(ah[mi], bh[ni], acc[mi][ni], 0, 0, 0);
                    acc[mi][ni] = __builtin_amdgcn_mfma_f32_16x16x32_bf16(ah[mi], bl[ni], acc[mi][ni], 0, 0, 0);
                    acc[mi][ni] = __builtin_amdgcn_mfma_f32_16x16x32_bf16(al[mi], bh[ni], acc[mi][ni], 0, 0, 0);
                }
        }
    }
    #pragma unroll
    for (int mi = 0; mi < 2; mi++)
        #pragma unroll
        for (int j = 0; j < 4; j++) {
            const int row = row0 + w * 32 + mi * 16 + lg * 4 + j;
            #pragma unroll
            for (int ni = 0; ni < 4; ni++)
                C[(size_t)row * N + col0 + ni * 16 + lq] = acc[mi][ni][j];
        }
}

// ---------------- fused phase-1 softmax + chunk reduce ----------------
__global__ void __launch_bounds__(256) softpref_red(const float* __restrict__ lgt,
                                                    const float* __restrict__ imp,
                                                    float* __restrict__ partial) {
    const int b = blockIdx.x, chunk = blockIdx.y;
    __shared__ float wp[64][161];
    const int t = threadIdx.x;
    const int tl = t >> 2, sg = t & 3;
    const int tok = b * SD + chunk * 64 + tl;
    const int o = (sg == 0) ? 0 : (64 + 32 * (sg - 1));
    const int n = (sg == 0) ? 64 : 32;
    const float* lp = lgt + (size_t)tok * 192 + o;
    float m = -1e30f;
    for (int i = 0; i < n; i++) m = fmaxf(m, lp[i]);
    float ss = 0.f;
    for (int i = 0; i < n; i++) ss += __expf(lp[i] - m);
    const float scl = imp[tok] / ss;
    for (int i = 0; i < n; i++) wp[tl][o + i] = __expf(lp[i] - m) * scl;
    __syncthreads();
    if (t < 160) {
        float s = 0.f;
        for (int k = 0; k < 64; k++) s += wp[k][t];
        partial[((size_t)(b * 16 + chunk)) * 224 + t] = s;
    }
}

// ---------------- fused phase-2 softmax + chunk reduce ----------------
__global__ void __launch_bounds__(256) softm_red(const float* __restrict__ lgt,
                                                 const float* __restrict__ imp,
                                                 float* __restrict__ partial) {
    const int b = blockIdx.x, chunk = blockIdx.y;
    __shared__ float wp[64][65];
    const int t = threadIdx.x;
    if (t < 64) {
        const int tok = b * SD + chunk * 64 + t;
        const float* lp = lgt + (size_t)tok * 64;
        float m = -1e30f;
        for (int i = 0; i < 64; i++) m = fmaxf(m, lp[i]);
        float ss = 0.f;
        for (int i = 0; i < 64; i++) ss += __expf(lp[i] - m);
        const float scl = imp[tok] / ss;
        for (int i = 0; i < 64; i++) wp[t][i] = __expf(lp[i] - m) * scl;
    }
    __syncthreads();
    if (t < 64) {
        float s = 0.f;
        for (int k = 0; k < 64; k++) s += wp[k][t];
        partial[((size_t)(b * 16 + chunk)) * 224 + 160 + t] = s;
    }
}

// ---------------- top-k sparsify + renormalize (sums 16 chunk partials) ----------------
__global__ void topk_kernel(const float* __restrict__ partial,
                            int* __restrict__ ridx, float* __restrict__ rw,
                            int r0, int nr) {
    __shared__ float dv[40][65];
    const int t = threadIdx.x;
    if (t >= BD * nr) return;
    const int b = t / nr, r = r0 + (t % nr);
    const int offs[5] = {0, 64, 96, 128, 160};
    const int ns[5]   = {64, 32, 32, 32, 64};
    const int ks[5]   = {8, 4, 4, 4, 8};
    const int n = ns[r], k = ks[r], off = offs[r];
    for (int i = 0; i < n; i++) {
        float s = 0.f;
        for (int c = 0; c < 16; c++) s += partial[((size_t)(b * 16 + c)) * 224 + off + i];
        dv[t][i] = s;
    }
    unsigned long long mask = 0;
    float vals[8]; int idxs[8];
    float ssum = 0.f;
    for (int kk = 0; kk < k; kk++) {
        float best = -1e30f; int bi = 0;
        for (int i = 0; i < n; i++)
            if (!((mask >> i) & 1ull) && dv[t][i] > best) { best = dv[t][i]; bi = i; }
        mask |= 1ull << bi;
        vals[kk] = best; idxs[kk] = bi; ssum += best;
    }
    float inv = 1.f / (ssum + 1e-8f);
    for (int kk = 0; kk < 8; kk++) {
        ridx[(b * 5 + r) * 8 + kk] = (kk < k) ? idxs[kk] : 0;
        rw[(b * 5 + r) * 8 + kk]   = (kk < k) ? vals[kk] * inv : 0.f;
    }
}

// ---------------- fused mixture + transpose + bf16 (scompT) ----------------
__global__ void __launch_bounds__(256) combine_t_kernel(const float* __restrict__ pool,
                                                        const int* __restrict__ ridx,
                                                        const float* __restrict__ rw,
                                                        int router, int kc,
                                                        unsigned short* __restrict__ outT,
                                                        int Rp, int Cp, long long sOut) {
    const int b = blockIdx.z;
    const int r0 = blockIdx.y * 64, c0 = blockIdx.x * 64;
    __shared__ float ls[64][65];
    const int* ii = ridx + (b * 5 + router) * 8;
    const float* ww = rw + (b * 5 + router) * 8;
    const int t = threadIdx.x;
    const int rr = t >> 4, cc = (t & 15) * 4;
    #pragma unroll
    for (int p = 0; p < 4; p++) {
        const int r = rr + p * 16;
        float4 acc = {0.f, 0.f, 0.f, 0.f};
        for (int kk = 0; kk < kc; kk++) {
            const float w = ww[kk];
            float4 v = *(const float4*)&pool[((size_t)ii[kk] * Rp + r0 + r) * Cp + c0 + cc];
            acc.x += w * v.x; acc.y += w * v.y; acc.z += w * v.z; acc.w += w * v.w;
        }
        ls[r][cc] = acc.x; ls[r][cc + 1] = acc.y; ls[r][cc + 2] = acc.z; ls[r][cc + 3] = acc.w;
    }
    __syncthreads();
    unsigned short* op = outT + (size_t)b * sOut;
    #pragma unroll
    for (int q = 0; q < 2; q++) {
        const int c = (t >> 3) + q * 32;
        const int r8 = (t & 7) * 8;
        union { unsigned short s[8]; bf16x8 v; } u;
        #pragma unroll
        for (int j = 0; j < 8; j++) u.s[j] = f2b(ls[r8 + j][c]);
        *(bf16x8*)(op + (size_t)(c0 + c) * Rp + r0 + r8) = u.v;
    }
}

// ---------------- fused 3-router E-combine: z -> (b, router-1) ----------------
__global__ void __launch_bounds__(256) combine_e_kernel(const float* __restrict__ pool,
                                                        const int* __restrict__ ridx,
                                                        const float* __restrict__ rw,
                                                        unsigned short* __restrict__ E3t) {
    const int z = blockIdx.z;
    const int b = z & 7, router = 1 + (z >> 3);
    const int r0 = blockIdx.y * 64, c0 = blockIdx.x * 64;
    __shared__ float ls[64][65];
    const int* ii = ridx + (b * 5 + router) * 8;
    const float* ww = rw + (b * 5 + router) * 8;
    const int t = threadIdx.x;
    const int rr = t >> 4, cc = (t & 15) * 4;
    #pragma unroll
    for (int p = 0; p < 4; p++) {
        const int r = rr + p * 16;
        float4 acc = {0.f, 0.f, 0.f, 0.f};
        #pragma unroll
        for (int kk = 0; kk < 4; kk++) {
            const float w = ww[kk];
            float4 v = *(const float4*)&pool[((size_t)ii[kk] * RK + r0 + r) * DM + c0 + cc];
            acc.x += w * v.x; acc.y += w * v.y; acc.z += w * v.z; acc.w += w * v.w;
        }
        ls[r][cc] = acc.x; ls[r][cc + 1] = acc.y; ls[r][cc + 2] = acc.z; ls[r][cc + 3] = acc.w;
    }
    __syncthreads();
    unsigned short* op = E3t + (size_t)b * 3 * DM * RK + (size_t)(router - 1) * DM * RK;
    #pragma unroll
    for (int q = 0; q < 2; q++) {
        const int c = (t >> 3) + q * 32;
        const int r8 = (t & 7) * 8;
        union { unsigned short s[8]; bf16x8 v; } u;
        #pragma unroll
        for (int j = 0; j < 8; j++) u.s[j] = f2b(ls[r8 + j][c]);
        *(bf16x8*)(op + (size_t)(c0 + c) * RK + r0 + r8) = u.v;
    }
}

// ---------------- tile transpose + fp32->bf16 (WO only) ----------------
__global__ void __launch_bounds__(256) tcvt_kernel(const float* __restrict__ src,
                                                   unsigned short* __restrict__ dst,
                                                   int R, int Cc) {
    __shared__ float ls[64][65];
    const int r0 = blockIdx.y * 64, c0 = blockIdx.x * 64;
    const int t = threadIdx.x;
    #pragma unroll
    for (int p = 0; p < 16; p++) {
        const int e = p * 256 + t;
        const int r = e >> 6, c = e & 63;
        ls[r][c] = src[(size_t)(r0 + r) * Cc + c0 + c];
    }
    __syncthreads();
    #pragma unroll
    for (int p = 0; p < 16; p++) {
        const int e = p * 256 + t;
        const int c = e >> 6, r = e & 63;
        dst[(size_t)(c0 + c) * R + r0 + r] = f2b(ls[r][c]);
    }
}

// ---------------- fp32 -> bf16 convert with scale ----------------
__global__ void __launch_bounds__(256) cvt_bf16_kernel(const float* __restrict__ src,
                                                       unsigned short* __restrict__ dst,
                                                       float scale, int n4) {
    const int i = blockIdx.x * 256 + threadIdx.x;
    if (i >= n4) return;
    float4 v = ((const float4*)src)[i];
    unsigned r0 = (unsigned)f2b(v.x * scale) | ((unsigned)f2b(v.y * scale) << 16);
    unsigned r1 = (unsigned)f2b(v.z * scale) | ((unsigned)f2b(v.w * scale) << 16);
    uint2 o; o.x = r0; o.y = r1;
    ((uint2*)dst)[i] = o;
}

// ---------------- bf16 MFMA GEMM: C = A[M][K] @ Bt[N][K]^T (+X), 128x128 tile ----------------
template<int OUTB, int HASX>
__global__ void __launch_bounds__(256) gemm_bf16(const unsigned short* __restrict__ A,
                                                 const unsigned short* __restrict__ Bt,
                                                 const float* __restrict__ X,
                                                 void* __restrict__ Cv,
                                                 int M, int N, int K,
                                                 long long sA, long long sB, long long sC) {
    const int bz = blockIdx.z;
    const unsigned short* Ab = A + (size_t)bz * sA;
    const unsigned short* Btb = Bt + (size_t)bz * sB;
    const int row0 = blockIdx.y * 128, col0 = blockIdx.x * 128;
    const int t = threadIdx.x;
    const int w = t >> 6, l = t & 63, lq = l & 15, lg = l >> 4;
    const int wr = w >> 1, wc = w & 1;
    __shared__ unsigned short As[128 * 64];
    __shared__ unsigned short Bs[128 * 64];
    f32x4 acc[4][4];
    #pragma unroll
    for (int mi = 0; mi < 4; mi++)
        #pragma unroll
        for (int ni = 0; ni < 4; ni++) acc[mi][ni] = f32x4{0.f, 0.f, 0.f, 0.f};

    for (int k0 = 0; k0 < K; k0 += 64) {
        __syncthreads();
        #pragma unroll
        for (int p = 0; p < 4; p++) {
            const int e = t * 8 + p * 2048;
            const int row = e >> 6, col = e & 63;
            bf16x8 va = *(const bf16x8*)(Ab + (size_t)(row0 + row) * K + k0 + col);
            *(bf16x8*)((char*)As + ((row * 128 + col * 2) ^ ((row & 7) << 4))) = va;
            bf16x8 vb = *(const bf16x8*)(Btb + (size_t)(col0 + row) * K + k0 + col);
            *(bf16x8*)((char*)Bs + ((row * 128 + col * 2) ^ ((row & 7) << 4))) = vb;
        }
        __syncthreads();
        #pragma unroll
        for (int kk = 0; kk < 2; kk++) {
            bf16x8 af[4], bg[4];
            #pragma unroll
            for (int mi = 0; mi < 4; mi++) {
                const int r = wr * 64 + mi * 16 + lq;
                af[mi] = *(const bf16x8*)((const char*)As + ((r * 128 + lg * 16 + kk * 64) ^ ((r & 7) << 4)));
            }
            #pragma unroll
            for (int ni = 0; ni < 4; ni++) {
                const int r = wc * 64 + ni * 16 + lq;
                bg[ni] = *(const bf16x8*)((const char*)Bs + ((r * 128 + lg * 16 + kk * 64) ^ ((r & 7) << 4)));
            }
            #pragma unroll
            for (int mi = 0; mi < 4; mi++)
                #pragma unroll
                for (int ni = 0; ni < 4; ni++)
                    acc[mi][ni] = __builtin_amdgcn_mfma_f32_16x16x32_bf16(af[mi], bg[ni], acc[mi][ni], 0, 0, 0);
        }
    }
    #pragma unroll
    for (int mi = 0; mi < 4; mi++) {
        #pragma unroll
        for (int j = 0; j < 4; j++) {
            const int row = row0 + wr * 64 + mi * 16 + lg * 4 + j;
            #pragma unroll
            for (int ni = 0; ni < 4; ni++) {
                const int col = col0 + wc * 64 + ni * 16 + lq;
                float v = acc[mi][ni][j];
                if (HASX) v += X[(size_t)row * N + col];
                if (OUTB) ((unsigned short*)Cv)[(size_t)bz * sC + (size_t)row * N + col] = f2b(v);
                else      ((float*)Cv)[(size_t)bz * sC + (size_t)row * N + col] = v;
            }
        }
    }
}

// ---------------- narrow GEMM for h/Qm: BM=64, N=128 fixed, bf16 out ----------------
__global__ void __launch_bounds__(256) gemm_h(const unsigned short* __restrict__ A,
                                              const unsigned short* __restrict__ Bt,
                                              unsigned short* __restrict__ C,
                                              int K,
                                              long long sA, long long sB, long long sC) {
    const int bz = blockIdx.z;
    const unsigned short* Ab = A + (size_t)bz * sA;
    const unsigned short* Btb = Bt + (size_t)bz * sB;
    const int row0 = blockIdx.y * 64;
    const int t = threadIdx.x;
    const int w = t >> 6, l = t & 63, lq = l & 15, lg = l >> 4;
    __shared__ unsigned short As[64 * 64];
    __shared__ unsigned short Bs[128 * 64];
    f32x4 acc[8];
    #pragma unroll
    for (int ni = 0; ni < 8; ni++) acc[ni] = f32x4{0.f, 0.f, 0.f, 0.f};

    for (int k0 = 0; k0 < K; k0 += 64) {
        __syncthreads();
        #pragma unroll
        for (int p = 0; p < 2; p++) {
            const int e = t * 8 + p * 2048;
            const int row = e >> 6, col = e & 63;
            bf16x8 va = *(const bf16x8*)(Ab + (size_t)(row0 + row) * K + k0 + col);
            *(bf16x8*)((char*)As + ((row * 128 + col * 2) ^ ((row & 7) << 4))) = va;
        }
        #pragma unroll
        for (int p = 0; p < 4; p++) {
            const int e = t * 8 + p * 2048;
            const int row = e >> 6, col = e & 63;
            bf16x8 vb = *(const bf16x8*)(Btb + (size_t)row * K + k0 + col);
            *(bf16x8*)((char*)Bs + ((row * 128 + col * 2) ^ ((row & 7) << 4))) = vb;
        }
        __syncthreads();
        #pragma unroll
        for (int kk = 0; kk < 2; kk++) {
            const int ra = w * 16 + lq;
            bf16x8 af = *(const bf16x8*)((const char*)As + ((ra * 128 + lg * 16 + kk * 64) ^ ((ra & 7) << 4)));
            #pragma unroll
            for (int ni = 0; ni < 8; ni++) {
                const int r = ni * 16 + lq;
                bf16x8 bg = *(const bf16x8*)((const char*)Bs + ((r * 128 + lg * 16 + kk * 64) ^ ((r & 7) << 4)));
                acc[ni] = __builtin_amdgcn_mfma_f32_16x16x32_bf16(af, bg, acc[ni], 0, 0, 0);
            }
        }
    }
    #pragma unroll
    for (int j = 0; j < 4; j++) {
        const int row = row0 + w * 16 + lg * 4 + j;
        #pragma unroll
        for (int ni = 0; ni < 8; ni++)
            C[(size_t)bz * sC + (size_t)row * 128 + ni * 16 + lq] = f2b(acc[ni][j]);
    }
}

// ---------------- flash attention: paired q-tiles, dbuf K/V, strided QKV input ----------------
#define SWZV(d) (((((d) >> 1) ^ ((d) >> 3)) & 7) << 4)
__global__ void __launch_bounds__(256) attn_mfma_kernel(const unsigned short* __restrict__ Q,
                                                        const unsigned short* __restrict__ K,
                                                        const unsigned short* __restrict__ V,
                                                        unsigned short* __restrict__ O,
                                                        int ldq) {
    const int qt = blockIdx.x, hh = blockIdx.y, b = blockIdx.z;
    const int t = threadIdx.x;
    const int w = t >> 6, l = t & 63, lq = l & 15, lg = l >> 4;

    __shared__ unsigned short ks[2][64 * 64];
    __shared__ unsigned short vt[2][64 * 64];
    __shared__ unsigned short pl[4][16 * 64];

    const size_t base = (size_t)b * SD * ldq + (size_t)hh * DH;
    const size_t obase = (size_t)b * SD * DM + (size_t)hh * DH;
    const int qA = qt;
    const int qB = 15 - qt;

    bf16x8 aqA[2], aqB[2];
    {
        const unsigned short* qp = Q + base + (size_t)(qA * 64 + w * 16 + lq) * ldq + lg * 8;
        aqA[0] = *(const bf16x8*)qp; aqA[1] = *(const bf16x8*)(qp + 32);
        const unsigned short* qp2 = Q + base + (size_t)(qB * 64 + w * 16 + lq) * ldq + lg * 8;
        aqB[0] = *(const bf16x8*)qp2; aqB[1] = *(const bf16x8*)(qp2 + 32);
    }

    f32x4 oA[4], oB[4];
    #pragma unroll
    for (int dt = 0; dt < 4; dt++) { oA[dt] = f32x4{0.f,0.f,0.f,0.f}; oB[dt] = f32x4{0.f,0.f,0.f,0.f}; }
    float mA[4] = {-1e30f,-1e30f,-1e30f,-1e30f}, sA[4] = {0.f,0.f,0.f,0.f};
    float mB[4] = {-1e30f,-1e30f,-1e30f,-1e30f}, sB[4] = {0.f,0.f,0.f,0.f};

    const int ntile = 16 - qt;
    const int srow = t >> 3;
    const int scol = (t & 7) * 8;

    int cur = 0;

    #pragma unroll
    for (int p = 0; p < 2; p++) {
        const int row = srow + 32 * p;
        bf16x8 kv = *(const bf16x8*)(K + base + (size_t)row * ldq + scol);
        *(bf16x8*)((char*)&ks[0][0] + ((row * 128 + scol * 2) ^ ((row & 7) << 4))) = kv;
        bf16x8 vv = *(const bf16x8*)(V + base + (size_t)row * ldq + scol);
        #pragma unroll
        for (int j2 = 0; j2 < 8; j2++) {
            const int d = scol + j2;
            *(unsigned short*)((char*)&vt[0][0] + ((d * 128 + row * 2) ^ SWZV(d))) = (unsigned short)vv[j2];
        }
    }
    __syncthreads();

    auto compute = [&](int q0, const bf16x8* aq, f32x4* o_, float* m_, float* s_, int kt) {
        const f32x4 zero4 = {0.f, 0.f, 0.f, 0.f};
        f32x4 sacc[4];
        __builtin_amdgcn_s_setprio(1);
        #pragma unroll
        for (int ct = 0; ct < 4; ct++) {
            const int krow = ct * 16 + lq;
            bf16x8 b0 = *(const bf16x8*)((const char*)&ks[cur][0] + ((krow * 128 + lg * 16) ^ ((lq & 7) << 4)));
            bf16x8 b1 = *(const bf16x8*)((const char*)&ks[cur][0] + ((krow * 128 + lg * 16 + 64) ^ ((lq & 7) << 4)));
            f32x4 s = __builtin_amdgcn_mfma_f32_16x16x32_bf16(aq[0], b0, zero4, 0, 0, 0);
            s = __builtin_amdgcn_mfma_f32_16x16x32_bf16(aq[1], b1, s, 0, 0, 0);
            sacc[ct] = s;
        }
        __builtin_amdgcn_s_setprio(0);
        float tm[4];
        #pragma unroll
        for (int j = 0; j < 4; j++) {
            const int qg = q0 * 64 + w * 16 + lg * 4 + j;
            float mx = -1e30f;
            #pragma unroll
            for (int ct = 0; ct < 4; ct++) {
                const int kg = kt * 64 + ct * 16 + lq;
                float v = sacc[ct][j] * 0.125f;
                v = (kg <= qg) ? v : -1e30f;
                sacc[ct][j] = v;
                mx = fmaxf(mx, v);
            }
            #pragma unroll
            for (int d = 1; d < 16; d <<= 1) mx = fmaxf(mx, __shfl_xor(mx, d));
            tm[j] = mx;
        }
        #pragma unroll
        for (int j = 0; j < 4; j++) {
            const float nm = fmaxf(m_[j], tm[j]);
            const float so = __expf(m_[j] - nm);
            m_[j] = nm;
            float rs = 0.f;
            const int prow = lg * 4 + j;
            #pragma unroll
            for (int ct = 0; ct < 4; ct++) {
                const float p = __expf(sacc[ct][j] - nm);
                rs += p;
                const int byteoff = ((prow * 128) + (ct * 16 + lq) * 2) ^ ((prow & 7) << 4);
                *(unsigned short*)((char*)&pl[w][0] + byteoff) = f2b(p);
            }
            #pragma unroll
            for (int d = 1; d < 16; d <<= 1) rs += __shfl_xor(rs, d);
            s_[j] = s_[j] * so + rs;
            #pragma unroll
            for (int dt = 0; dt < 4; dt++) o_[dt][j] *= so;
        }
        asm volatile("s_waitcnt lgkmcnt(0)" ::: "memory");
        __builtin_amdgcn_sched_barrier(0);
        __builtin_amdgcn_s_setprio(1);
        #pragma unroll
        for (int c = 0; c < 2; c++) {
            bf16x8 pa = *(const bf16x8*)((const char*)&pl[w][0] +
                          ((lq * 128 + lg * 16 + 64 * c) ^ ((lq & 7) << 4)));
            #pragma unroll
            for (int dt = 0; dt < 4; dt++) {
                const int dd = dt * 16 + lq;
                bf16x8 bv = *(const bf16x8*)((const char*)&vt[cur][0] +
                              ((dd * 128 + lg * 16 + 64 * c) ^ SWZV(dd)));
                o_[dt] = __builtin_amdgcn_mfma_f32_16x16x32_bf16(pa, bv, o_[dt], 0, 0, 0);
            }
        }
        __builtin_amdgcn_s_setprio(0);
    };

    const int mymaxA = qA * 64 + w * 16 + 15;
    for (int kt = 0; kt < ntile; kt++) {
        bf16x8 kN[2], vN[2];
        const bool pre = (kt + 1 < ntile);
        if (pre) {
            #pragma unroll
            for (int p = 0; p < 2; p++) {
                const int row = srow + 32 * p;
                kN[p] = *(const bf16x8*)(K + base + (size_t)((kt + 1) * 64 + row) * ldq + scol);
                vN[p] = *(const bf16x8*)(V + base + (size_t)((kt + 1) * 64 + row) * ldq + scol);
            }
        }
        compute(qB, aqB, oB, mB, sB, kt);
        if (kt * 64 <= mymaxA) compute(qA, aqA, oA, mA, sA, kt);
        if (pre) {
            #pragma unroll
            for (int p = 0; p < 2; p++) {
                const int row = srow + 32 * p;
                *(bf16x8*)((char*)&ks[cur ^ 1][0] + ((row * 128 + scol * 2) ^ ((row & 7) << 4))) = kN[p];
                #pragma unroll
                for (int j2 = 0; j2 < 8; j2++) {
                    const int d = scol + j2;
                    *(unsigned short*)((char*)&vt[cur ^ 1][0] + ((d * 128 + row * 2) ^ SWZV(d))) =
                        (unsigned short)vN[p][j2];
                }
            }
        }
        __syncthreads();
        cur ^= 1;
    }

    #pragma unroll
    for (int j = 0; j < 4; j++) {
        const float invA = 1.f / sA[j];
        const float invB = 1.f / sB[j];
        const int rowA = qA * 64 + w * 16 + lg * 4 + j;
        const int rowB = qB * 64 + w * 16 + lg * 4 + j;
        unsigned short* opA = O + obase + (size_t)rowA * DM;
        unsigned short* opB = O + obase + (size_t)rowB * DM;
        #pragma unroll
        for (int dt = 0; dt < 4; dt++) {
            opA[dt * 16 + lq] = f2b(oA[dt][j] * invA);
            opB[dt * 16 + lq] = f2b(oB[dt][j] * invB);
        }
    }
}
#undef SWZV

// ---------------- knowledge scores: 16-key wave-private LDS tiles + wave top-8 merge ----------------
#define CE(a, b) { float hi_ = fmaxf(a, b), lo_ = fminf(a, b); a = hi_; b = lo_; }
__global__ void __launch_bounds__(512, 4) know_score_kernel(const unsigned short* __restrict__ Qmb,
                                                            const unsigned short* __restrict__ kKb,
                                                            float* __restrict__ cand) {
    const int t = threadIdx.x;
    const int w = t >> 6, l = t & 63, lq = l & 15, lg = l >> 4;
    const int tok0 = blockIdx.x * 16;
    __shared__ unsigned short ks[8][16 * 128];

    bf16x8 aq[4];
    {
        const unsigned short* qp = Qmb + (size_t)(tok0 + lq) * 128 + lg * 8;
        #pragma unroll
        for (int c = 0; c < 4; c++) aq[c] = *(const bf16x8*)(qp + c * 32);
    }

    float L[4][8];
    #pragma unroll
    for (int j = 0; j < 4; j++)
        #pragma unroll
        for (int s = 0; s < 8; s++) L[j][s] = __uint_as_float(0xF2000000u | (unsigned)s);

    const unsigned short* gsrc = kKb + (((size_t)w * 2048) << 7) + l * 8;
    unsigned short* myks = &ks[w][0];

    bf16x8 vreg[4];
    #pragma unroll
    for (int p = 0; p < 4; p++) vreg[p] = *(const bf16x8*)(gsrc + p * 512);

    for (int t4 = 0; t4 < 32; t4++) {
        float B[4][4];
        #pragma unroll
        for (int sub = 0; sub < 4; sub++) {
            const int kt = t4 * 4 + sub;
            #pragma unroll
            for (int p = 0; p < 4; p++) {
                const int e = p * 512 + l * 8;
                const int row = e >> 7;
                *(bf16x8*)((char*)myks + ((e * 2) ^ ((row & 7) << 4))) = vreg[p];
            }
            if (kt < 127) {
                const unsigned short* src2 = gsrc + (size_t)(kt + 1) * 2048;
                #pragma unroll
                for (int p = 0; p < 4; p++) vreg[p] = *(const bf16x8*)(src2 + p * 512);
            }
            {
                const char* kb = (const char*)myks + lq * 256;
                const int sw = (lq & 7) << 4;
                f32x4 s = {0.f, 0.f, 0.f, 0.f};
                #pragma unroll
                for (int c = 0; c < 4; c++) {
                    bf16x8 bv = *(const bf16x8*)(kb + ((c * 64 + lg * 16) ^ sw));
                    s = __builtin_amdgcn_mfma_f32_16x16x32_bf16(aq[c], bv, s, 0, 0, 0);
                }
                const unsigned keyb = (unsigned)(w * 2048 + kt * 16 + lq);
                #pragma unroll
                for (int j = 0; j < 4; j++) {
                    unsigned u = __float_as_uint(s[j]);
                    B[j][sub] = __uint_as_float((u & 0xFFFFC000u) | keyb);
                }
            }
        }
        #pragma unroll
        for (int j = 0; j < 4; j++) {
            CE(B[j][0], B[j][2]); CE(B[j][1], B[j][3]);
            CE(B[j][0], B[j][1]); CE(B[j][2], B[j][3]);
            CE(B[j][1], B[j][2]);
            L[j][4] = fmaxf(L[j][4], B[j][3]);
            L[j][5] = fmaxf(L[j][5], B[j][2]);
            L[j][6] = fmaxf(L[j][6], B[j][1]);
            L[j][7] = fmaxf(L[j][7], B[j][0]);
            CE(L[j][0], L[j][4]); CE(L[j][1], L[j][5]); CE(L[j][2], L[j][6]); CE(L[j][3], L[j][7]);
            CE(L[j][0], L[j][2]); CE(L[j][1], L[j][3]); CE(L[j][4], L[j][6]); CE(L[j][5], L[j][7]);
            CE(L[j][0], L[j][1]); CE(L[j][2], L[j][3]); CE(L[j][4], L[j][5]); CE(L[j][6], L[j][7]);
        }
    }
    // cross-lq butterfly merge: all 16 lq lanes -> wave top-8 per j
    #pragma unroll
    for (int j = 0; j < 4; j++) {
        #pragma unroll
        for (int d = 1; d < 16; d <<= 1) {
            float P[8];
            #pragma unroll
            for (int s = 0; s < 8; s++) P[s] = __shfl_xor(L[j][s], d);
            L[j][0] = fmaxf(L[j][0], P[7]);
            L[j][1] = fmaxf(L[j][1], P[6]);
            L[j][2] = fmaxf(L[j][2], P[5]);
            L[j][3] = fmaxf(L[j][3], P[4]);
            L[j][4] = fmaxf(L[j][4], P[3]);
            L[j][5] = fmaxf(L[j][5], P[2]);
            L[j][6] = fmaxf(L[j][6], P[1]);
            L[j][7] = fmaxf(L[j][7], P[0]);
            CE(L[j][0], L[j][4]); CE(L[j][1], L[j][5]); CE(L[j][2], L[j][6]); CE(L[j][3], L[j][7]);
            CE(L[j][0], L[j][2]); CE(L[j][1], L[j][3]); CE(L[j][4], L[j][6]); CE(L[j][5], L[j][7]);
            CE(L[j][0], L[j][1]); CE(L[j][2], L[j][3]); CE(L[j][4], L[j][5]); CE(L[j][6], L[j][7]);
        }
    }
    if (lq == 0) {
        #pragma unroll
        for (int j = 0; j < 4; j++) {
            const int tok = tok0 + lg * 4 + j;
            float* cp = cand + (size_t)tok * 64 + w * 8;
            #pragma unroll
            for (int ss = 0; ss < 8; ss++) cp[ss] = L[j][ss];
        }
    }
}
#undef CE

// ---------------- knowledge merge + V gather: one wave per token, 64 candidates ----------------
__global__ void __launch_bounds__(256) know_out_kernel(const float* __restrict__ cand,
                                                       const float* __restrict__ kV,
                                                       float* __restrict__ out) {
    const int t = threadIdx.x, w = t >> 6, l = t & 63;
    const int tok = blockIdx.x * 4 + w;
    float lv = cand[(size_t)tok * 64 + l];

    float topv[8]; int topi[8];
    #pragma unroll
    for (int kk = 0; kk < 8; kk++) {
        float m = lv;
        #pragma unroll
        for (int d = 1; d < 64; d <<= 1) m = fmaxf(m, __shfl_xor(m, d));
        topv[kk] = m;
        topi[kk] = (int)(__float_as_uint(m) & 0x3FFFu);
        lv = (lv == m) ? -1e31f : lv;
    }
    const float mx = topv[0];
    float e[8]; float ssum = 0.f;
    #pragma unroll
    for (int kk = 0; kk < 8; kk++) { e[kk] = __expf(topv[kk] - mx); ssum += e[kk]; }
    const float inv = 1.f / ssum;

    float4 acc[4];
    #pragma unroll
    for (int ch = 0; ch < 4; ch++) acc[ch] = float4{0.f, 0.f, 0.f, 0.f};
    #pragma unroll
    for (int kk = 0; kk < 8; kk++) {
        const float wk = e[kk] * inv;
        const float* vp = kV + ((size_t)topi[kk] << 10);
        #pragma unroll
        for (int ch = 0; ch < 4; ch++) {
            float4 v = *(const float4*)(vp + ch * 256 + l * 4);
            acc[ch].x += wk * v.x; acc[ch].y += wk * v.y;
            acc[ch].z += wk * v.z; acc[ch].w += wk * v.w;
        }
    }
    float* op = out + ((size_t)tok << 10);
    #pragma unroll
    for (int ch = 0; ch < 4; ch++) {
        float4 o = *(const float4*)(op + ch * 256 + l * 4);
        o.x += acc[ch].x; o.y += acc[ch].y; o.z += acc[ch].z; o.w += acc[ch].w;
        *(float4*)(op + ch * 256 + l * 4) = o;
    }
}

extern "C" void kernel_launch(void* const* d_in, const int* in_sizes, int n_in,
                              void* d_out, int out_size, void* d_ws, size_t ws_size,
                              hipStream_t stream) {
    const float* x    = (const float*)d_in[0];
    const float* imp  = (const float*)d_in[1];
    const float* Wc   = (const float*)d_in[2];
    const float* WQr  = (const float*)d_in[3];
    const float* WKr  = (const float*)d_in[4];
    const float* WVr  = (const float*)d_in[5];
    const float* Wm   = (const float*)d_in[6];
    const float* cneu = (const float*)d_in[7];
    const float* epool= (const float*)d_in[8];
    const float* kK   = (const float*)d_in[9];
    const float* kV   = (const float*)d_in[10];
    const float* WO   = (const float*)d_in[11];
    const float* ln1s = (const float*)d_in[12];
    const float* ln1b = (const float*)d_in[13];
    const float* ln2s = (const float*)d_in[14];
    const float* ln2b = (const float*)d_in[15];
    float* out = (float*)d_out;

    float* ws = (float*)d_ws;
    size_t o = 0;
    unsigned short* n1h = (unsigned short*)(ws + o); o += (size_t)BD * SD * DM / 2;
    unsigned short* n1l = (unsigned short*)(ws + o); o += (size_t)BD * SD * DM / 2;
    float* lgt   = ws + o; o += (size_t)BD * SD * 192;
    float* partial = ws + o; o += (size_t)BD * 16 * 224;
    int*   ridx  = (int*)(ws + o); o += (size_t)BD * 5 * 8;
    float* rw    = ws + o; o += (size_t)BD * 5 * 8;
    unsigned short* WTh = (unsigned short*)(ws + o); o += (size_t)256 * 1024 / 2;
    unsigned short* WTl = (unsigned short*)(ws + o); o += (size_t)256 * 1024 / 2;
    unsigned short* scompT = (unsigned short*)(ws + o); o += (size_t)BD * RK * DM / 2;
    unsigned short* E3t = (unsigned short*)(ws + o); o += (size_t)BD * 3 * DM * RK / 2;
    unsigned short* hb  = (unsigned short*)(ws + o); o += (size_t)BD * SD * RK / 2;
    unsigned short* QKV16 = (unsigned short*)(ws + o); o += (size_t)BD * SD * 3072 / 2;
    unsigned short* attnb = (unsigned short*)(ws + o); o += (size_t)BD * SD * DM / 2;
    unsigned short* WOt = (unsigned short*)(ws + o); o += (size_t)DM * DM / 2;
    unsigned short* kKb = (unsigned short*)(ws + o); o += (size_t)NK * RK / 2;
    unsigned short* Qmb = (unsigned short*)(ws + o); o += (size_t)BD * SD * RK / 2;
    float* cand = ws + o; o += (size_t)BD * SD * 64;

    const int NTOK = BD * SD;
    const long long sE3 = (long long)3 * DM * RK;

    // independent prep
    concatw_kernel<<<1024, 256, 0, stream>>>(Wc, WQr, WKr, WVr, Wm, WTh, WTl);
    tcvt_kernel<<<dim3(16, 16, 1), 256, 0, stream>>>(WO, WOt, DM, DM);
    cvt_bf16_kernel<<<(NK * RK / 4) / 256, 256, 0, stream>>>(kK, kKb, 0.0883883476483184f, NK * RK / 4);

    // phase 1
    ln_kernel<<<NTOK, 256, 0, stream>>>(x, ln1s, ln1b, n1h, n1l);
    gemm_split<<<dim3(3, NTOK / 128), 256, 0, stream>>>(n1h, n1l, WTh, WTl, lgt, 192, DM);
    softpref_red<<<dim3(BD, 16), 256, 0, stream>>>(lgt, imp, partial);
    topk_kernel<<<1, 64, 0, stream>>>(partial, ridx, rw, 0, 4);
    combine_t_kernel<<<dim3(2, 16, BD), 256, 0, stream>>>(cneu, ridx, rw, 0, 8, scompT, DM, RK,
        (long long)DM * RK);
    combine_e_kernel<<<dim3(16, 2, 24), 256, 0, stream>>>(epool, ridx, rw, E3t);
    gemm_h<<<dim3(1, SD / 64, BD), 256, 0, stream>>>(n1h, scompT, hb,
        DM, (long long)SD * DM, (long long)RK * DM, (long long)SD * RK);
    gemm_bf16<1, 0><<<dim3(24, 8, BD), 256, 0, stream>>>(hb, E3t, nullptr, QKV16,
        SD, 3072, RK, (long long)SD * RK, sE3, (long long)SD * 3072);
    attn_mfma_kernel<<<dim3(8, NH, BD), 256, 0, stream>>>(QKV16, QKV16 + 1024, QKV16 + 2048,
        attnb, 3072);
    gemm_bf16<0, 1><<<dim3(8, 64, 1), 256, 0, stream>>>(attnb, WOt, x, out,
        NTOK, DM, DM, 0, 0, 0);

    // phase 2
    ln_kernel<<<NTOK, 256, 0, stream>>>(out, ln2s, ln2b, n1h, n1l);
    gemm_split<<<dim3(1, NTOK / 128), 256, 0, stream>>>(n1h, n1l,
        WTh + (size_t)192 * 1024, WTl + (size_t)192 * 1024, lgt, 64, DM);
    softm_red<<<dim3(BD, 16), 256, 0, stream>>>(lgt, imp, partial);
    topk_kernel<<<1, 64, 0, stream>>>(partial, ridx, rw, 4, 1);
    combine_t_kernel<<<dim3(2, 16, BD), 256, 0, stream>>>(cneu, ridx, rw, 4, 8, scompT, DM, RK,
        (long long)DM * RK);
    gemm_h<<<dim3(1, SD / 64, BD), 256, 0, stream>>>(n1h, scompT, Qmb,
        DM, (long long)SD * DM, (long long)RK * DM, (long long)SD * RK);
    know_score_kernel<<<NTOK / 16, 512, 0, stream>>>(Qmb, kKb, cand);
    know_out_kernel<<<NTOK / 4, 256, 0, stream>>>(cand, kV, out);
}